// Round 1
// baseline (13255.142 us; speedup 1.0000x reference)
//
#include <hip/hip_runtime.h>
#include <hip/hip_bf16.h>
#include <math.h>

// Problem constants
constexpr int cB = 8, cSE = 2048, cSD = 1024, cIN = 1280, cD = 512,
              cDEPTH = 4, cH = 8, cDH = 64, cM = 266, cFF = 2048, cNB = 128;

#define DEV __device__ __forceinline__

DEV float gelu_f(float x) { return 0.5f * x * (1.0f + erff(x * 0.70710678118654752440f)); }

DEV float wave_sum(float v) {
#pragma unroll
  for (int o = 32; o; o >>= 1) v += __shfl_xor(v, o);
  return v;
}
DEV float wave_max(float v) {
#pragma unroll
  for (int o = 32; o; o >>= 1) v = fmaxf(v, __shfl_xor(v, o));
  return v;
}

// ---------------------------------------------------------------------------
// Main fp32 GEMM: C[M,N] = epi(A[M,K] @ B[K,N]).  Requires M%64==0, N%64==0,
// K%16==0 (true for every non-FAVOR GEMM in this model). 64x64 tile, BK=16,
// 256 threads, 4x4 micro-tile.
// ---------------------------------------------------------------------------
template <int ACT, bool BIAS, bool RES>
__global__ __launch_bounds__(256) void gemm_f32(
    const float* __restrict__ A, int lda,
    const float* __restrict__ B, int ldb,
    float* __restrict__ C, int ldc,
    const float* __restrict__ bias,
    int M, int N, int K) {
  __shared__ __align__(16) float As[16][68];
  __shared__ __align__(16) float Bs[16][68];
  const int m0 = blockIdx.y * 64, n0 = blockIdx.x * 64;
  const int t = threadIdx.x;
  const int ar = t >> 2, ac = (t & 3) << 2;      // A tile load coords
  const int bk = t >> 4, bn = (t & 15) << 2;     // B tile load coords
  const int row0 = (t >> 4) << 2, col0 = (t & 15) << 2;
  const float* Ap = A + (size_t)(m0 + ar) * lda + ac;
  const float* Bp = B + (size_t)bk * ldb + n0 + bn;
  float acc[4][4] = {};
  for (int k0 = 0; k0 < K; k0 += 16) {
    float4 av = *(const float4*)Ap; Ap += 16;
    float4 bv = *(const float4*)Bp; Bp += (size_t)16 * ldb;
    As[ac + 0][ar] = av.x; As[ac + 1][ar] = av.y;
    As[ac + 2][ar] = av.z; As[ac + 3][ar] = av.w;
    *(float4*)&Bs[bk][bn] = bv;
    __syncthreads();
#pragma unroll
    for (int kk = 0; kk < 16; kk++) {
      float4 a4 = *(const float4*)&As[kk][row0];
      float4 b4 = *(const float4*)&Bs[kk][col0];
      float aa[4] = {a4.x, a4.y, a4.z, a4.w};
      float bb[4] = {b4.x, b4.y, b4.z, b4.w};
#pragma unroll
      for (int i = 0; i < 4; i++)
#pragma unroll
        for (int j = 0; j < 4; j++) acc[i][j] = fmaf(aa[i], bb[j], acc[i][j]);
    }
    __syncthreads();
  }
#pragma unroll
  for (int i = 0; i < 4; i++) {
    const int m = m0 + row0 + i;
#pragma unroll
    for (int j = 0; j < 4; j++) {
      const int n = n0 + col0 + j;
      float v = acc[i][j];
      if (BIAS) v += bias[n];
      if (ACT == 1) v = gelu_f(v);
      float* cp = C + (size_t)m * ldc + n;
      if (RES) v += *cp;
      *cp = v;
    }
  }
}

// ---------------------------------------------------------------------------
// Batched (per b,h) guarded GEMM for FAVOR einsums.
// TA==0: A is [M,K] row-major; TA==1: A is [K,M] row-major (A^T @ ...).
// TB==0: B is [K,N] row-major; TB==1: B is [N,K] row-major (... @ B^T).
// z = b*8+h selects per-batch base pointers via (sXb, sXh) strides.
// RS: multiply output row m by rs[z*sRz + m].
// ---------------------------------------------------------------------------
template <int TA, int TB, bool RS>
__global__ __launch_bounds__(256) void gemm_bat(
    const float* __restrict__ Ab, long long sAb, long long sAh, int lda,
    const float* __restrict__ Bb, long long sBb, long long sBh, int ldb,
    float* __restrict__ Cb, long long sCb, long long sCh, int ldc,
    const float* __restrict__ rsb, long long sRz,
    int M, int N, int K, float alpha) {
  const int z = blockIdx.z, b = z >> 3, h = z & 7;
  const float* A = Ab + (size_t)b * sAb + (size_t)h * sAh;
  const float* B = Bb + (size_t)b * sBb + (size_t)h * sBh;
  float* C = Cb + (size_t)b * sCb + (size_t)h * sCh;
  __shared__ __align__(16) float As[16][68];
  __shared__ __align__(16) float Bs[16][68];
  const int m0 = blockIdx.y * 64, n0 = blockIdx.x * 64;
  const int t = threadIdx.x;
  float acc[4][4] = {};
  for (int k0 = 0; k0 < K; k0 += 16) {
    if (TA == 0) {
      const int r = t >> 2, c = (t & 3) << 2;
      const int gm = m0 + r;
#pragma unroll
      for (int i = 0; i < 4; i++) {
        const int gk = k0 + c + i;
        As[c + i][r] = (gm < M && gk < K) ? A[(size_t)gm * lda + gk] : 0.f;
      }
    } else {
      const int kk = t >> 4, mm = (t & 15) << 2;
      const int gk = k0 + kk;
#pragma unroll
      for (int i = 0; i < 4; i++) {
        const int gm = m0 + mm + i;
        As[kk][mm + i] = (gk < K && gm < M) ? A[(size_t)gk * lda + gm] : 0.f;
      }
    }
    if (TB == 0) {
      const int kk = t >> 4, nn = (t & 15) << 2;
      const int gk = k0 + kk;
#pragma unroll
      for (int i = 0; i < 4; i++) {
        const int gn = n0 + nn + i;
        Bs[kk][nn + i] = (gk < K && gn < N) ? B[(size_t)gk * ldb + gn] : 0.f;
      }
    } else {
      const int r = t >> 2, c = (t & 3) << 2;
      const int gn = n0 + r;
#pragma unroll
      for (int i = 0; i < 4; i++) {
        const int gk = k0 + c + i;
        Bs[c + i][r] = (gn < N && gk < K) ? B[(size_t)gn * ldb + gk] : 0.f;
      }
    }
    __syncthreads();
    const int row0 = (t >> 4) << 2, col0 = (t & 15) << 2;
#pragma unroll
    for (int kk = 0; kk < 16; kk++) {
      float4 a4 = *(const float4*)&As[kk][row0];
      float4 b4 = *(const float4*)&Bs[kk][col0];
      float aa[4] = {a4.x, a4.y, a4.z, a4.w};
      float bb[4] = {b4.x, b4.y, b4.z, b4.w};
#pragma unroll
      for (int i = 0; i < 4; i++)
#pragma unroll
        for (int j = 0; j < 4; j++) acc[i][j] = fmaf(aa[i], bb[j], acc[i][j]);
    }
    __syncthreads();
  }
  const int row0 = (t >> 4) << 2, col0 = (t & 15) << 2;
  const float* rsp = RS ? (rsb + (size_t)z * sRz) : nullptr;
#pragma unroll
  for (int i = 0; i < 4; i++) {
    const int m = m0 + row0 + i;
#pragma unroll
    for (int j = 0; j < 4; j++) {
      const int n = n0 + col0 + j;
      if (m < M && n < N) {
        float v = acc[i][j] * alpha;
        if (RS) v *= rsp[m];
        C[(size_t)m * ldc + n] = v;
      }
    }
  }
}

// ---------------------------------------------------------------------------
// LayerNorm over rows of width 512; one wave per row, 4 rows per block.
// out = LN(in (+ add)) * g + b
// ---------------------------------------------------------------------------
template <bool ADD>
__global__ __launch_bounds__(256) void ln_rows(
    const float* __restrict__ in, const float* __restrict__ add,
    const float* __restrict__ g, const float* __restrict__ be,
    float* __restrict__ out) {
  const int wid = blockIdx.x * 4 + (threadIdx.x >> 6);
  const int lane = threadIdx.x & 63;
  const float* ip = in + (size_t)wid * cD + lane * 8;
  float x[8];
  {
    float4 a = *(const float4*)ip;
    float4 b4 = *(const float4*)(ip + 4);
    x[0] = a.x; x[1] = a.y; x[2] = a.z; x[3] = a.w;
    x[4] = b4.x; x[5] = b4.y; x[6] = b4.z; x[7] = b4.w;
  }
  if (ADD) {
    const float* ap = add + (size_t)wid * cD + lane * 8;
    float4 a = *(const float4*)ap;
    float4 b4 = *(const float4*)(ap + 4);
    x[0] += a.x; x[1] += a.y; x[2] += a.z; x[3] += a.w;
    x[4] += b4.x; x[5] += b4.y; x[6] += b4.z; x[7] += b4.w;
  }
  float s = 0;
#pragma unroll
  for (int i = 0; i < 8; i++) s += x[i];
  s = wave_sum(s);
  const float mu = s * (1.0f / cD);
  float vs = 0;
#pragma unroll
  for (int i = 0; i < 8; i++) { const float d = x[i] - mu; vs += d * d; }
  vs = wave_sum(vs);
  const float rstd = 1.0f / sqrtf(vs * (1.0f / cD) + 1e-5f);
  float* op = out + (size_t)wid * cD + lane * 8;
#pragma unroll
  for (int i = 0; i < 8; i++) {
    const int d = lane * 8 + i;
    op[i] = (x[i] - mu) * rstd * g[d] + be[d];
  }
}

// LN of (enc + sinusoidal(expr)) with embedding computed on the fly.
__global__ __launch_bounds__(256) void embed_ln(
    float* __restrict__ X, const int* __restrict__ ids,
    const float* __restrict__ g, const float* __restrict__ be) {
  const int wid = blockIdx.x * 4 + (threadIdx.x >> 6);
  const int lane = threadIdx.x & 63;
  const float idv = (float)ids[wid];
  float* xp = X + (size_t)wid * cD + lane * 8;
  float x[8];
  {
    float4 a = *(const float4*)xp;
    float4 b4 = *(const float4*)(xp + 4);
    x[0] = a.x; x[1] = a.y; x[2] = a.z; x[3] = a.w;
    x[4] = b4.x; x[5] = b4.y; x[6] = b4.z; x[7] = b4.w;
  }
  // freqs[j] = exp(-ln(10000)*j/256); first 256 dims sin, last 256 cos
  const float kf = -0.03597789207803197f;
#pragma unroll
  for (int i = 0; i < 8; i++) {
    const int d = lane * 8 + i;
    float e;
    if (d < 256) e = sinf(idv * expf(kf * (float)d));
    else         e = cosf(idv * expf(kf * (float)(d - 256)));
    x[i] += e;
  }
  float s = 0;
#pragma unroll
  for (int i = 0; i < 8; i++) s += x[i];
  s = wave_sum(s);
  const float mu = s * (1.0f / cD);
  float vs = 0;
#pragma unroll
  for (int i = 0; i < 8; i++) { const float d = x[i] - mu; vs += d * d; }
  vs = wave_sum(vs);
  const float rstd = 1.0f / sqrtf(vs * (1.0f / cD) + 1e-5f);
#pragma unroll
  for (int i = 0; i < 8; i++) {
    const int d = lane * 8 + i;
    xp[i] = (x[i] - mu) * rstd * g[d] + be[d];
  }
}

// ---------------------------------------------------------------------------
// FAVOR feature map: P row (266 wide) -> ratio*(exp(v - diag - mx) + eps).
// GMAX: mx is the global max scalar (k path); else per-row max (q path).
// diag = 0.5 * ||row of QK head slice||^2 * dn^2. One wave per row.
// ---------------------------------------------------------------------------
template <bool GMAX>
__global__ __launch_bounds__(256) void phi_kernel(
    float* __restrict__ P, const float* __restrict__ QK,
    const float* __restrict__ gmaxp) {
  const int wid = (blockIdx.x << 2) + (threadIdx.x >> 6);  // row = z*2048+s
  const int lane = threadIdx.x & 63;
  const int z = wid >> 11, s = wid & 2047;
  const int b = z >> 3, h = z & 7;
  const float dn2 = 0.125f;                                  // (64^-0.25)^2
  const float ratio = (float)(1.0 / 16.30950643030009);      // 266^-0.5
  const float q = QK[((size_t)b * cSE + s) * cD + h * cDH + lane];
  const float ss = wave_sum(q * q);
  const float diag = 0.5f * ss * dn2;
  float* prow = P + (size_t)wid * cM;
  float v[5];
#pragma unroll
  for (int j = 0; j < 5; j++) {
    const int m = (j << 6) + lane;
    v[j] = (m < cM) ? prow[m] : -1e30f;
  }
  float mx;
  if (GMAX) {
    mx = *gmaxp;
  } else {
    float lm = v[0];
#pragma unroll
    for (int j = 1; j < 5; j++) lm = fmaxf(lm, v[j]);
    mx = wave_max(lm);
  }
#pragma unroll
  for (int j = 0; j < 5; j++) {
    const int m = (j << 6) + lane;
    if (m < cM) prow[m] = ratio * (expf(v[j] - diag - mx) + 1e-4f);
  }
}

// Global max over kd (two pass, deterministic)
__global__ __launch_bounds__(256) void redmax_part(
    const float* __restrict__ P, size_t n, float* __restrict__ part) {
  float m = -1e30f;
  for (size_t i = (size_t)blockIdx.x * 256 + threadIdx.x; i < n; i += (size_t)256 * 1024)
    m = fmaxf(m, P[i]);
  m = wave_max(m);
  __shared__ float sm[4];
  if ((threadIdx.x & 63) == 0) sm[threadIdx.x >> 6] = m;
  __syncthreads();
  if (threadIdx.x == 0)
    part[blockIdx.x] = fmaxf(fmaxf(sm[0], sm[1]), fmaxf(sm[2], sm[3]));
}
__global__ __launch_bounds__(256) void redmax_final(
    const float* __restrict__ part, float* __restrict__ gm) {
  float m = -1e30f;
  for (int i = threadIdx.x; i < 1024; i += 256) m = fmaxf(m, part[i]);
  m = wave_max(m);
  __shared__ float sm[4];
  if ((threadIdx.x & 63) == 0) sm[threadIdx.x >> 6] = m;
  __syncthreads();
  if (threadIdx.x == 0) gm[0] = fmaxf(fmaxf(sm[0], sm[1]), fmaxf(sm[2], sm[3]));
}

// ksum[z,m] = sum_s kp[z,s,m]  (two-pass over s, deterministic)
__global__ __launch_bounds__(320) void ksum_part(
    const float* __restrict__ P, float* __restrict__ part) {
  const int z = blockIdx.x, c = blockIdx.y, t = threadIdx.x;
  if (t >= cM) return;
  const float* p = P + ((size_t)z * cSE + c * 256) * cM + t;
  float s = 0;
  for (int i = 0; i < 256; i++) s += p[(size_t)i * cM];
  part[((size_t)z * 8 + c) * cM + t] = s;
}
__global__ __launch_bounds__(320) void ksum_final(
    const float* __restrict__ part, float* __restrict__ ksum) {
  const int z = blockIdx.x, t = threadIdx.x;
  if (t >= cM) return;
  float s = 0;
#pragma unroll
  for (int c = 0; c < 8; c++) s += part[((size_t)z * 8 + c) * cM + t];
  ksum[(size_t)z * cM + t] = s;
}

// dinv[z,s] = 1 / dot(qp[z,s,:], ksum[z,:]); one wave per row
__global__ __launch_bounds__(256) void dinv_kernel(
    const float* __restrict__ P, const float* __restrict__ ksum,
    float* __restrict__ dinv) {
  const int wid = (blockIdx.x << 2) + (threadIdx.x >> 6);
  const int lane = threadIdx.x & 63;
  const int z = wid >> 11;
  const float* prow = P + (size_t)wid * cM;
  const float* ks = ksum + (size_t)z * cM;
  float s = 0;
#pragma unroll
  for (int j = 0; j < 5; j++) {
    const int m = (j << 6) + lane;
    if (m < cM) s += prow[m] * ks[m];
  }
  s = wave_sum(s);
  if (lane == 0) dinv[wid] = 1.0f / s;
}

// ---------------------------------------------------------------------------
// Cross-attention (softmax, non-causal): thread-per-query-row online softmax.
// Q merged [b, SD, 512], K/V merged [b, SE, 512], O merged [b, SD, 512].
// grid (SD/256, H, B), 256 threads.
// ---------------------------------------------------------------------------
__global__ __launch_bounds__(256, 1) void flash_cross(
    const float* __restrict__ Q, const float* __restrict__ Kc,
    const float* __restrict__ Vc, float* __restrict__ O) {
  __shared__ __align__(16) float ks[32][64];
  __shared__ __align__(16) float vs[32][64];
  const int b = blockIdx.z, h = blockIdx.y;
  const int qr = blockIdx.x * 256 + threadIdx.x;
  const float* qp = Q + ((size_t)b * cSD + qr) * cD + h * cDH;
  float q[64];
#pragma unroll
  for (int i = 0; i < 16; i++) {
    float4 t4 = *(const float4*)(qp + i * 4);
    q[4 * i] = t4.x; q[4 * i + 1] = t4.y; q[4 * i + 2] = t4.z; q[4 * i + 3] = t4.w;
  }
  float o[64];
#pragma unroll
  for (int i = 0; i < 64; i++) o[i] = 0.f;
  float mr = -3e38f, l = 0.f;
  const size_t kbase = (size_t)b * cSE * cD + h * cDH;
#pragma unroll 1
  for (int kt = 0; kt < cSE; kt += 32) {
#pragma unroll
    for (int u = 0; u < 2; u++) {
      const int idx = threadIdx.x + u * 256;  // float4 units, 0..511
      const int r = idx >> 4, c4 = (idx & 15) << 2;
      *(float4*)&ks[r][c4] = *(const float4*)(Kc + kbase + (size_t)(kt + r) * cD + c4);
      *(float4*)&vs[r][c4] = *(const float4*)(Vc + kbase + (size_t)(kt + r) * cD + c4);
    }
    __syncthreads();
#pragma unroll 1
    for (int j = 0; j < 32; j++) {
      float sc = 0.f;
#pragma unroll
      for (int i = 0; i < 16; i++) {
        float4 k4 = *(const float4*)&ks[j][i * 4];
        sc = fmaf(q[4 * i], k4.x, sc);
        sc = fmaf(q[4 * i + 1], k4.y, sc);
        sc = fmaf(q[4 * i + 2], k4.z, sc);
        sc = fmaf(q[4 * i + 3], k4.w, sc);
      }
      sc *= 0.125f;  // DH^-0.5
      const float mn = fmaxf(mr, sc);
      const float corr = __expf(mr - mn);
      const float w = __expf(sc - mn);
      l = l * corr + w;
#pragma unroll
      for (int i = 0; i < 16; i++) {
        float4 v4 = *(const float4*)&vs[j][i * 4];
        o[4 * i] = fmaf(w, v4.x, o[4 * i] * corr);
        o[4 * i + 1] = fmaf(w, v4.y, o[4 * i + 1] * corr);
        o[4 * i + 2] = fmaf(w, v4.z, o[4 * i + 2] * corr);
        o[4 * i + 3] = fmaf(w, v4.w, o[4 * i + 3] * corr);
      }
      mr = mn;
    }
    __syncthreads();
  }
  const float inv = 1.0f / l;
  float* op = O + ((size_t)b * cSD + qr) * cD + h * cDH;
#pragma unroll
  for (int i = 0; i < 16; i++) {
    float4 r4;
    r4.x = o[4 * i] * inv; r4.y = o[4 * i + 1] * inv;
    r4.z = o[4 * i + 2] * inv; r4.w = o[4 * i + 3] * inv;
    *(float4*)(op + i * 4) = r4;
  }
}

// ---------------------------------------------------------------------------
extern "C" void kernel_launch(void* const* d_in, const int* in_sizes, int n_in,
                              void* d_out, int out_size, void* d_ws, size_t ws_size,
                              hipStream_t stream) {
  const float* in_enc = (const float*)d_in[0];
  const float* in_dec = (const float*)d_in[1];
  const int* expr = (const int*)d_in[2];
  const float* var_W = (const float*)d_in[3];
  const float* var_b = (const float*)d_in[4];
  const float* enc_g = (const float*)d_in[5];
  const float* enc_b = (const float*)d_in[6];
  const float* dec_g = (const float*)d_in[7];
  const float* dec_b = (const float*)d_in[8];
  const float* ln1_g = (const float*)d_in[9];
  const float* ln1_b = (const float*)d_in[10];
  const float* Wq = (const float*)d_in[11];
  const float* Wk = (const float*)d_in[12];
  const float* Wv = (const float*)d_in[13];
  const float* Wo = (const float*)d_in[14];
  const float* bo = (const float*)d_in[15];
  const float* ln2_g = (const float*)d_in[16];
  const float* ln2_b = (const float*)d_in[17];
  const float* w1 = (const float*)d_in[18];
  const float* b1 = (const float*)d_in[19];
  const float* w2 = (const float*)d_in[20];
  const float* b2 = (const float*)d_in[21];
  const float* proj = (const float*)d_in[22];
  const float* caWq = (const float*)d_in[23];
  const float* caWk = (const float*)d_in[24];
  const float* caWv = (const float*)d_in[25];
  const float* caWo = (const float*)d_in[26];
  const float* cabo = (const float*)d_in[27];
  const float* crg = (const float*)d_in[28];
  const float* crb = (const float*)d_in[29];
  const float* fw1 = (const float*)d_in[30];
  const float* fb1 = (const float*)d_in[31];
  const float* fw2 = (const float*)d_in[32];
  const float* fb2 = (const float*)d_in[33];
  const float* og = (const float*)d_in[34];
  const float* ob = (const float*)d_in[35];
  const float* hW = (const float*)d_in[36];
  const float* hb = (const float*)d_in[37];

  // workspace layout (floats)
  float* X = (float*)d_ws;              // [16384, 512]
  float* Y = X + 8388608;               // [16384, 512]
  float* Qb = Y + 8388608;              // [16384, 512]
  float* Kb = Qb + 8388608;             // [16384, 512]
  float* Vb = Kb + 8388608;             // [16384, 512]
  float* DC = Vb + 8388608;             // [8192, 512]
  float* P = DC + 4194304;              // [64, 2048, 266] (also FF mid)
  float* KV = P + 34865152;             // [64, 266, 64]
  float* KS = KV + 1089536;             // [64, 266]
  float* KSP = KS + 17024;              // [64, 8, 266]
  float* DI = KSP + 136192;             // [64, 2048]
  float* RD = DI + 131072;              // [1025]
  const size_t need_bytes = (size_t)(82377345) * 4;
  if (ws_size < need_bytes) return;  // insufficient workspace; fail visibly

  const dim3 blk(256);
  const float dn = 0.35355339059327373f;  // 64^-0.25

  // embeddings
  gemm_f32<0, true, false><<<dim3(cD / 64, (cB * cSE) / 64), blk, 0, stream>>>(
      in_enc, cIN, var_W, cD, X, cD, var_b, cB * cSE, cD, cIN);
  gemm_f32<0, true, false><<<dim3(cD / 64, (cB * cSD) / 64), blk, 0, stream>>>(
      in_dec, cIN, var_W, cD, DC, cD, var_b, cB * cSD, cD, cIN);
  embed_ln<<<dim3((cB * cSE) / 4), blk, 0, stream>>>(X, expr, enc_g, enc_b);
  ln_rows<false><<<dim3((cB * cSD) / 4), blk, 0, stream>>>(DC, nullptr, dec_g, dec_b, DC);

  for (int i = 0; i < cDEPTH; i++) {
    const float* wq = Wq + (size_t)i * cD * cD;
    const float* wk = Wk + (size_t)i * cD * cD;
    const float* wv = Wv + (size_t)i * cD * cD;
    const float* wo = Wo + (size_t)i * cD * cD;
    const float* pj = proj + (size_t)i * cM * cDH;
    ln_rows<false><<<dim3(4096), blk, 0, stream>>>(X, nullptr, ln1_g + i * cD, ln1_b + i * cD, Y);
    gemm_f32<0, false, false><<<dim3(8, 256), blk, 0, stream>>>(Y, cD, wq, cD, Qb, cD, nullptr, 16384, cD, cD);
    gemm_f32<0, false, false><<<dim3(8, 256), blk, 0, stream>>>(Y, cD, wk, cD, Kb, cD, nullptr, 16384, cD, cD);
    gemm_f32<0, false, false><<<dim3(8, 256), blk, 0, stream>>>(Y, cD, wv, cD, Vb, cD, nullptr, 16384, cD, cD);
    // kd = dn * k @ proj^T  -> P[z, s, m]
    gemm_bat<0, 1, false><<<dim3(5, 32, 64), blk, 0, stream>>>(
        Kb, (long long)cSE * cD, 64, cD,
        pj, 0, 0, cDH,
        P, (long long)cH * cSE * cM, (long long)cSE * cM, cM,
        nullptr, 0, cSE, cM, cDH, dn);
    redmax_part<<<dim3(1024), blk, 0, stream>>>(P, (size_t)64 * cSE * cM, RD);
    redmax_final<<<dim3(1), blk, 0, stream>>>(RD, RD + 1024);
    phi_kernel<true><<<dim3(32768), blk, 0, stream>>>(P, Kb, RD + 1024);
    ksum_part<<<dim3(64, 8), dim3(320), 0, stream>>>(P, KSP);
    ksum_final<<<dim3(64), dim3(320), 0, stream>>>(KSP, KS);
    // kv[z, m, d] = sum_s kp[z,s,m] * v[z,s,d]
    gemm_bat<1, 0, false><<<dim3(1, 5, 64), blk, 0, stream>>>(
        P, (long long)cH * cSE * cM, (long long)cSE * cM, cM,
        Vb, (long long)cSE * cD, 64, cD,
        KV, (long long)cH * cM * cDH, (long long)cM * cDH, cDH,
        nullptr, 0, cM, cDH, cSE, 1.0f);
    // qd = dn * q @ proj^T -> P (overwrite)
    gemm_bat<0, 1, false><<<dim3(5, 32, 64), blk, 0, stream>>>(
        Qb, (long long)cSE * cD, 64, cD,
        pj, 0, 0, cDH,
        P, (long long)cH * cSE * cM, (long long)cSE * cM, cM,
        nullptr, 0, cSE, cM, cDH, dn);
    phi_kernel<false><<<dim3(32768), blk, 0, stream>>>(P, Qb, nullptr);
    dinv_kernel<<<dim3(32768), blk, 0, stream>>>(P, KS, DI);
    // out[z,s,d] = (qp @ kv) * dinv -> merged into Y
    gemm_bat<0, 0, true><<<dim3(1, 32, 64), blk, 0, stream>>>(
        P, (long long)cH * cSE * cM, (long long)cSE * cM, cM,
        KV, (long long)cH * cM * cDH, (long long)cM * cDH, cDH,
        Y, (long long)cSE * cD, 64, cD,
        DI, cSE,
        cSE, cDH, cM, 1.0f);
    gemm_f32<0, true, true><<<dim3(8, 256), blk, 0, stream>>>(Y, cD, wo, cD, X, cD, bo + i * cD, 16384, cD, cD);
    ln_rows<false><<<dim3(4096), blk, 0, stream>>>(X, nullptr, ln2_g + i * cD, ln2_b + i * cD, Y);
    gemm_f32<1, true, false><<<dim3(32, 256), blk, 0, stream>>>(Y, cD, w1 + (size_t)i * cD * cFF, cFF, P, cFF, b1 + i * cFF, 16384, cFF, cD);
    gemm_f32<0, true, true><<<dim3(8, 256), blk, 0, stream>>>(P, cFF, w2 + (size_t)i * cFF * cD, cD, X, cD, b2 + i * cD, 16384, cD, cFF);
  }

  // decoder / cross attention
  gemm_f32<0, false, false><<<dim3(8, 128), blk, 0, stream>>>(DC, cD, caWq, cD, Qb, cD, nullptr, 8192, cD, cD);
  gemm_f32<0, false, false><<<dim3(8, 256), blk, 0, stream>>>(X, cD, caWk, cD, Kb, cD, nullptr, 16384, cD, cD);
  gemm_f32<0, false, false><<<dim3(8, 256), blk, 0, stream>>>(X, cD, caWv, cD, Vb, cD, nullptr, 16384, cD, cD);
  flash_cross<<<dim3(4, 8, 8), blk, 0, stream>>>(Qb, Kb, Vb, Y);
  gemm_f32<0, true, false><<<dim3(8, 128), blk, 0, stream>>>(Y, cD, caWo, cD, Qb, cD, cabo, 8192, cD, cD);
  ln_rows<true><<<dim3(2048), blk, 0, stream>>>(Qb, DC, crg, crb, Y);
  gemm_f32<1, true, false><<<dim3(32, 128), blk, 0, stream>>>(Y, cD, fw1, cFF, P, cFF, fb1, 8192, cFF, cD);
  gemm_f32<0, true, false><<<dim3(8, 128), blk, 0, stream>>>(P, cFF, fw2, cD, Y, cD, fb2, 8192, cD, cFF);
  ln_rows<false><<<dim3(2048), blk, 0, stream>>>(Y, nullptr, og, ob, Y);
  gemm_f32<0, true, false><<<dim3(2, 128), blk, 0, stream>>>(Y, cD, hW, cNB, (float*)d_out, cNB, hb, 8192, cNB, cD);
}

// Round 2
// 5482.925 us; speedup vs baseline: 2.4175x; 2.4175x over previous
//
#include <hip/hip_runtime.h>
#include <hip/hip_bf16.h>
#include <math.h>

// Problem constants
constexpr int cB = 8, cSE = 2048, cSD = 1024, cIN = 1280, cD = 512,
              cDEPTH = 4, cH = 8, cDH = 64, cM = 266, cFF = 2048, cNB = 128;

#define DEV __device__ __forceinline__

typedef __bf16 bf16;
typedef __attribute__((ext_vector_type(8))) __bf16 bf16x8;
typedef __attribute__((ext_vector_type(4))) __bf16 bf16x4;
typedef __attribute__((ext_vector_type(4))) float f32x4;

DEV float gelu_f(float x) { return 0.5f * x * (1.0f + erff(x * 0.70710678118654752440f)); }

DEV float wave_sum(float v) {
#pragma unroll
  for (int o = 32; o; o >>= 1) v += __shfl_xor(v, o);
  return v;
}
DEV float wave_max(float v) {
#pragma unroll
  for (int o = 32; o; o >>= 1) v = fmaxf(v, __shfl_xor(v, o));
  return v;
}

#define GL2LDS(gp, lp) __builtin_amdgcn_global_load_lds(                    \
    (const __attribute__((address_space(1))) void*)(gp),                    \
    (__attribute__((address_space(3))) void*)(lp), 16, 0, 0)

// ---------------------------------------------------------------------------
// bf16 MFMA GEMM (m97 structure): C[M,N] = epi(A[M,K] @ Bt[N,K]^T).
// M%128==0, N%128==0, K%32==0. 128x128 tile, BK=32, 256 thr (4 waves, 2x2),
// each wave 4x4 frags of mfma_f32_16x16x32_bf16. global_load_lds width 16.
// OUT: 0 = f32 C, 1 = bf16 C. ACT: 1 = exact GELU. RES: C += (f32 only).
// ---------------------------------------------------------------------------
template <int OUT, int ACT, bool BIAS, bool RES>
__global__ __launch_bounds__(256) void gemm_mfma(
    const bf16* __restrict__ A, const bf16* __restrict__ Bt,
    void* __restrict__ Cv, const float* __restrict__ bias,
    int M, int N, int K) {
  __shared__ bf16 As[128 * 32];
  __shared__ bf16 Bs[128 * 32];
  const int t = threadIdx.x, l = t & 63, w = t >> 6;
  const int g = l >> 4, c = l & 15;
  const int m0 = blockIdx.y * 128, n0 = blockIdx.x * 128;
  const int wr = (w >> 1) * 64, wc = (w & 1) * 64;
  // staging: wave w covers rows [w*32, w*32+32) of each tile, 2 loads of 16 rows
  const int srow = w * 32 + (l >> 2);
  const int scol = (l & 3) * 8;
  const bf16* gA = A + (size_t)(m0 + srow) * K + scol;
  const bf16* gB = Bt + (size_t)(n0 + srow) * K + scol;
  bf16* lA = As + w * 1024;  // wave-uniform LDS base
  bf16* lB = Bs + w * 1024;

  const f32x4 zero4 = {0.f, 0.f, 0.f, 0.f};
  f32x4 acc[4][4];
#pragma unroll
  for (int i = 0; i < 4; i++)
#pragma unroll
    for (int j = 0; j < 4; j++) acc[i][j] = zero4;

  for (int k0 = 0; k0 < K; k0 += 32) {
    GL2LDS(gA + k0, lA);
    GL2LDS(gA + (size_t)16 * K + k0, lA + 512);
    GL2LDS(gB + k0, lB);
    GL2LDS(gB + (size_t)16 * K + k0, lB + 512);
    __syncthreads();
    bf16x8 af[4], bfr[4];
#pragma unroll
    for (int i = 0; i < 4; i++)
      af[i] = *(const bf16x8*)(As + (wr + i * 16 + c) * 32 + g * 8);
#pragma unroll
    for (int j = 0; j < 4; j++)
      bfr[j] = *(const bf16x8*)(Bs + (wc + j * 16 + c) * 32 + g * 8);
#pragma unroll
    for (int i = 0; i < 4; i++)
#pragma unroll
      for (int j = 0; j < 4; j++)
        acc[i][j] = __builtin_amdgcn_mfma_f32_16x16x32_bf16(af[i], bfr[j], acc[i][j], 0, 0, 0);
    __syncthreads();
  }
  // epilogue: D layout col = lane&15, row = (lane>>4)*4 + r  (m89-verified)
  float* Cf = (float*)Cv;
  bf16* Cb = (bf16*)Cv;
#pragma unroll
  for (int i = 0; i < 4; i++) {
    const int mb = m0 + wr + i * 16 + g * 4;
#pragma unroll
    for (int j = 0; j < 4; j++) {
      const int n = n0 + wc + j * 16 + c;
      const float bv = BIAS ? bias[n] : 0.f;
#pragma unroll
      for (int r = 0; r < 4; r++) {
        float v = acc[i][j][r] + bv;
        if (ACT == 1) v = gelu_f(v);
        if (OUT == 0) {
          float* cp = Cf + (size_t)(mb + r) * N + n;
          if (RES) v += *cp;
          *cp = v;
        } else {
          Cb[(size_t)(mb + r) * N + n] = (bf16)v;
        }
      }
    }
  }
}

// ---------------------------------------------------------------------------
// transpose + cast: W[K,N] f32 -> Wt[N,K] bf16. 32x32 tiles, 256 threads.
// ---------------------------------------------------------------------------
__global__ __launch_bounds__(256) void transpose_cast(
    const float* __restrict__ W, bf16* __restrict__ Wt, int K, int N) {
  __shared__ float tile[32][33];
  const int tx = threadIdx.x & 31, ty = threadIdx.x >> 5;
  const int k0 = blockIdx.y * 32, n0 = blockIdx.x * 32;
#pragma unroll
  for (int i = ty; i < 32; i += 8) tile[i][tx] = W[(size_t)(k0 + i) * N + n0 + tx];
  __syncthreads();
#pragma unroll
  for (int i = ty; i < 32; i += 8)
    Wt[(size_t)(n0 + i) * K + k0 + tx] = (bf16)tile[tx][i];
}

// flat f32 -> bf16 cast, n % 4 == 0
__global__ __launch_bounds__(256) void castf2b(
    const float* __restrict__ x, bf16* __restrict__ y, int n) {
  int i = (blockIdx.x * 256 + threadIdx.x) * 4;
  const int stride = gridDim.x * 1024;
  for (; i < n; i += stride) {
    float4 v = *(const float4*)(x + i);
    bf16x4 o;
    o[0] = (bf16)v.x; o[1] = (bf16)v.y; o[2] = (bf16)v.z; o[3] = (bf16)v.w;
    *(bf16x4*)(y + i) = o;
  }
}

// ---------------------------------------------------------------------------
// Batched (per b,h) guarded fp32 GEMM for FAVOR einsums (unchanged math).
// OUT: 0 = f32 C, 1 = bf16 C.
// ---------------------------------------------------------------------------
template <int TA, int TB, bool RS, int OUT>
__global__ __launch_bounds__(256) void gemm_bat(
    const float* __restrict__ Ab, long long sAb, long long sAh, int lda,
    const float* __restrict__ Bb, long long sBb, long long sBh, int ldb,
    void* __restrict__ Cv, long long sCb, long long sCh, int ldc,
    const float* __restrict__ rsb, long long sRz,
    int M, int N, int K, float alpha) {
  const int z = blockIdx.z, b = z >> 3, h = z & 7;
  const float* A = Ab + (size_t)b * sAb + (size_t)h * sAh;
  const float* B = Bb + (size_t)b * sBb + (size_t)h * sBh;
  __shared__ __align__(16) float As[16][68];
  __shared__ __align__(16) float Bs[16][68];
  const int m0 = blockIdx.y * 64, n0 = blockIdx.x * 64;
  const int t = threadIdx.x;
  float acc[4][4] = {};
  for (int k0 = 0; k0 < K; k0 += 16) {
    if (TA == 0) {
      const int r = t >> 2, cc = (t & 3) << 2;
      const int gm = m0 + r;
#pragma unroll
      for (int i = 0; i < 4; i++) {
        const int gk = k0 + cc + i;
        As[cc + i][r] = (gm < M && gk < K) ? A[(size_t)gm * lda + gk] : 0.f;
      }
    } else {
      const int kk = t >> 4, mm = (t & 15) << 2;
      const int gk = k0 + kk;
#pragma unroll
      for (int i = 0; i < 4; i++) {
        const int gm = m0 + mm + i;
        As[kk][mm + i] = (gk < K && gm < M) ? A[(size_t)gk * lda + gm] : 0.f;
      }
    }
    if (TB == 0) {
      const int kk = t >> 4, nn = (t & 15) << 2;
      const int gk = k0 + kk;
#pragma unroll
      for (int i = 0; i < 4; i++) {
        const int gn = n0 + nn + i;
        Bs[kk][nn + i] = (gk < K && gn < N) ? B[(size_t)gk * ldb + gn] : 0.f;
      }
    } else {
      const int r = t >> 2, cc = (t & 3) << 2;
      const int gn = n0 + r;
#pragma unroll
      for (int i = 0; i < 4; i++) {
        const int gk = k0 + cc + i;
        Bs[cc + i][r] = (gn < N && gk < K) ? B[(size_t)gn * ldb + gk] : 0.f;
      }
    }
    __syncthreads();
    const int row0 = (t >> 4) << 2, col0 = (t & 15) << 2;
#pragma unroll
    for (int kk = 0; kk < 16; kk++) {
      float4 a4 = *(const float4*)&As[kk][row0];
      float4 b4 = *(const float4*)&Bs[kk][col0];
      float aa[4] = {a4.x, a4.y, a4.z, a4.w};
      float bb[4] = {b4.x, b4.y, b4.z, b4.w};
#pragma unroll
      for (int i = 0; i < 4; i++)
#pragma unroll
        for (int j = 0; j < 4; j++) acc[i][j] = fmaf(aa[i], bb[j], acc[i][j]);
    }
    __syncthreads();
  }
  const int row0 = (t >> 4) << 2, col0 = (t & 15) << 2;
  const float* rsp = RS ? (rsb + (size_t)z * sRz) : nullptr;
  float* Cf = (float*)Cv;
  bf16* Cb = (bf16*)Cv;
#pragma unroll
  for (int i = 0; i < 4; i++) {
    const int m = m0 + row0 + i;
#pragma unroll
    for (int j = 0; j < 4; j++) {
      const int n = n0 + col0 + j;
      if (m < M && n < N) {
        float v = acc[i][j] * alpha;
        if (RS) v *= rsp[m];
        if (OUT == 0)
          Cf[(size_t)b * sCb + (size_t)h * sCh + (size_t)m * ldc + n] = v;
        else
          Cb[(size_t)b * sCb + (size_t)h * sCh + (size_t)m * ldc + n] = (bf16)v;
      }
    }
  }
}

// ---------------------------------------------------------------------------
// LayerNorm rows of 512; wave per row, 4 rows/block. WF: write f32 out,
// WB: write bf16 out2.  out = LN(in (+ add)) * g + b
// ---------------------------------------------------------------------------
template <bool ADD, bool WF, bool WB>
__global__ __launch_bounds__(256) void ln_rows(
    const float* __restrict__ in, const float* __restrict__ add,
    const float* __restrict__ g, const float* __restrict__ be,
    float* __restrict__ out, bf16* __restrict__ out2) {
  const int wid = blockIdx.x * 4 + (threadIdx.x >> 6);
  const int lane = threadIdx.x & 63;
  const float* ip = in + (size_t)wid * cD + lane * 8;
  float x[8];
  {
    float4 a = *(const float4*)ip;
    float4 b4 = *(const float4*)(ip + 4);
    x[0] = a.x; x[1] = a.y; x[2] = a.z; x[3] = a.w;
    x[4] = b4.x; x[5] = b4.y; x[6] = b4.z; x[7] = b4.w;
  }
  if (ADD) {
    const float* ap = add + (size_t)wid * cD + lane * 8;
    float4 a = *(const float4*)ap;
    float4 b4 = *(const float4*)(ap + 4);
    x[0] += a.x; x[1] += a.y; x[2] += a.z; x[3] += a.w;
    x[4] += b4.x; x[5] += b4.y; x[6] += b4.z; x[7] += b4.w;
  }
  float s = 0;
#pragma unroll
  for (int i = 0; i < 8; i++) s += x[i];
  s = wave_sum(s);
  const float mu = s * (1.0f / cD);
  float vs = 0;
#pragma unroll
  for (int i = 0; i < 8; i++) { const float d = x[i] - mu; vs += d * d; }
  vs = wave_sum(vs);
  const float rstd = 1.0f / sqrtf(vs * (1.0f / cD) + 1e-5f);
  float r[8];
#pragma unroll
  for (int i = 0; i < 8; i++) {
    const int d = lane * 8 + i;
    r[i] = (x[i] - mu) * rstd * g[d] + be[d];
  }
  if (WF) {
    float* op = out + (size_t)wid * cD + lane * 8;
    float4 a, b4;
    a.x = r[0]; a.y = r[1]; a.z = r[2]; a.w = r[3];
    b4.x = r[4]; b4.y = r[5]; b4.z = r[6]; b4.w = r[7];
    *(float4*)op = a; *(float4*)(op + 4) = b4;
  }
  if (WB) {
    bf16x8 ov;
#pragma unroll
    for (int i = 0; i < 8; i++) ov[i] = (bf16)r[i];
    *(bf16x8*)(out2 + (size_t)wid * cD + lane * 8) = ov;
  }
}

// LN of (enc + sinusoidal(expr)), in-place on f32 X.
__global__ __launch_bounds__(256) void embed_ln(
    float* __restrict__ X, const int* __restrict__ ids,
    const float* __restrict__ g, const float* __restrict__ be) {
  const int wid = blockIdx.x * 4 + (threadIdx.x >> 6);
  const int lane = threadIdx.x & 63;
  const float idv = (float)ids[wid];
  float* xp = X + (size_t)wid * cD + lane * 8;
  float x[8];
  {
    float4 a = *(const float4*)xp;
    float4 b4 = *(const float4*)(xp + 4);
    x[0] = a.x; x[1] = a.y; x[2] = a.z; x[3] = a.w;
    x[4] = b4.x; x[5] = b4.y; x[6] = b4.z; x[7] = b4.w;
  }
  const float kf = -0.03597789207803197f;  // -ln(10000)/256
#pragma unroll
  for (int i = 0; i < 8; i++) {
    const int d = lane * 8 + i;
    float e;
    if (d < 256) e = sinf(idv * expf(kf * (float)d));
    else         e = cosf(idv * expf(kf * (float)(d - 256)));
    x[i] += e;
  }
  float s = 0;
#pragma unroll
  for (int i = 0; i < 8; i++) s += x[i];
  s = wave_sum(s);
  const float mu = s * (1.0f / cD);
  float vs = 0;
#pragma unroll
  for (int i = 0; i < 8; i++) { const float d = x[i] - mu; vs += d * d; }
  vs = wave_sum(vs);
  const float rstd = 1.0f / sqrtf(vs * (1.0f / cD) + 1e-5f);
#pragma unroll
  for (int i = 0; i < 8; i++) {
    const int d = lane * 8 + i;
    xp[i] = (x[i] - mu) * rstd * g[d] + be[d];
  }
}

// ---------------------------------------------------------------------------
// FAVOR feature map (unchanged from round 1)
// ---------------------------------------------------------------------------
template <bool GMAX>
__global__ __launch_bounds__(256) void phi_kernel(
    float* __restrict__ P, const float* __restrict__ QK,
    const float* __restrict__ gmaxp) {
  const int wid = (blockIdx.x << 2) + (threadIdx.x >> 6);
  const int lane = threadIdx.x & 63;
  const int z = wid >> 11, s = wid & 2047;
  const int b = z >> 3, h = z & 7;
  const float dn2 = 0.125f;
  const float ratio = (float)(1.0 / 16.30950643030009);
  const float q = QK[((size_t)b * cSE + s) * cD + h * cDH + lane];
  const float ss = wave_sum(q * q);
  const float diag = 0.5f * ss * dn2;
  float* prow = P + (size_t)wid * cM;
  float v[5];
#pragma unroll
  for (int j = 0; j < 5; j++) {
    const int m = (j << 6) + lane;
    v[j] = (m < cM) ? prow[m] : -1e30f;
  }
  float mx;
  if (GMAX) {
    mx = *gmaxp;
  } else {
    float lm = v[0];
#pragma unroll
    for (int j = 1; j < 5; j++) lm = fmaxf(lm, v[j]);
    mx = wave_max(lm);
  }
#pragma unroll
  for (int j = 0; j < 5; j++) {
    const int m = (j << 6) + lane;
    if (m < cM) prow[m] = ratio * (expf(v[j] - diag - mx) + 1e-4f);
  }
}

__global__ __launch_bounds__(256) void redmax_part(
    const float* __restrict__ P, size_t n, float* __restrict__ part) {
  float m = -1e30f;
  for (size_t i = (size_t)blockIdx.x * 256 + threadIdx.x; i < n; i += (size_t)256 * 1024)
    m = fmaxf(m, P[i]);
  m = wave_max(m);
  __shared__ float sm[4];
  if ((threadIdx.x & 63) == 0) sm[threadIdx.x >> 6] = m;
  __syncthreads();
  if (threadIdx.x == 0)
    part[blockIdx.x] = fmaxf(fmaxf(sm[0], sm[1]), fmaxf(sm[2], sm[3]));
}
__global__ __launch_bounds__(256) void redmax_final(
    const float* __restrict__ part, float* __restrict__ gm) {
  float m = -1e30f;
  for (int i = threadIdx.x; i < 1024; i += 256) m = fmaxf(m, part[i]);
  m = wave_max(m);
  __shared__ float sm[4];
  if ((threadIdx.x & 63) == 0) sm[threadIdx.x >> 6] = m;
  __syncthreads();
  if (threadIdx.x == 0) gm[0] = fmaxf(fmaxf(sm[0], sm[1]), fmaxf(sm[2], sm[3]));
}

__global__ __launch_bounds__(320) void ksum_part(
    const float* __restrict__ P, float* __restrict__ part) {
  const int z = blockIdx.x, c = blockIdx.y, t = threadIdx.x;
  if (t >= cM) return;
  const float* p = P + ((size_t)z * cSE + c * 256) * cM + t;
  float s = 0;
  for (int i = 0; i < 256; i++) s += p[(size_t)i * cM];
  part[((size_t)z * 8 + c) * cM + t] = s;
}
__global__ __launch_bounds__(320) void ksum_final(
    const float* __restrict__ part, float* __restrict__ ksum) {
  const int z = blockIdx.x, t = threadIdx.x;
  if (t >= cM) return;
  float s = 0;
#pragma unroll
  for (int c = 0; c < 8; c++) s += part[((size_t)z * 8 + c) * cM + t];
  ksum[(size_t)z * cM + t] = s;
}

__global__ __launch_bounds__(256) void dinv_kernel(
    const float* __restrict__ P, const float* __restrict__ ksum,
    float* __restrict__ dinv) {
  const int wid = (blockIdx.x << 2) + (threadIdx.x >> 6);
  const int lane = threadIdx.x & 63;
  const int z = wid >> 11;
  const float* prow = P + (size_t)wid * cM;
  const float* ks = ksum + (size_t)z * cM;
  float s = 0;
#pragma unroll
  for (int j = 0; j < 5; j++) {
    const int m = (j << 6) + lane;
    if (m < cM) s += prow[m] * ks[m];
  }
  s = wave_sum(s);
  if (lane == 0) dinv[wid] = 1.0f / s;
}

// ---------------------------------------------------------------------------
// bf16 MFMA flash cross-attention. Q [B*SD,512], K/V [B*SE,512] bf16 merged.
// grid (SD/64, H, B), 256 thr = 4 waves; wave handles 16 q-rows.
// KV tiles of 32: K in XOR-swizzled LDS, V transposed [64][40] in LDS,
// P re-layout via per-wave padded LDS [16][40].
// ---------------------------------------------------------------------------
__global__ __launch_bounds__(256) void flash_mfma(
    const bf16* __restrict__ Q, const bf16* __restrict__ Kc,
    const bf16* __restrict__ Vc, bf16* __restrict__ O) {
  __shared__ bf16 Ks[32 * 64];
  __shared__ bf16 Vt[64 * 40];
  __shared__ bf16 Pl[4 * 16 * 40];
  const int b = blockIdx.z, h = blockIdx.y;
  const int t = threadIdx.x, l = t & 63, w = t >> 6;
  const int g = l >> 4, c = l & 15;
  const int q0 = blockIdx.x * 64 + w * 16;
  // Q fragments: A layout row = lane&15, k = (lane>>4)*8 + e
  bf16x8 aq[2];
  {
    const bf16* qp = Q + ((size_t)b * cSD + q0 + c) * cD + h * cDH + g * 8;
    aq[0] = *(const bf16x8*)qp;
    aq[1] = *(const bf16x8*)(qp + 32);
  }
  const f32x4 zero4 = {0.f, 0.f, 0.f, 0.f};
  f32x4 o4[4];
#pragma unroll
  for (int j = 0; j < 4; j++) o4[j] = zero4;
  float mrow[4], lrow[4];
#pragma unroll
  for (int r = 0; r < 4; r++) { mrow[r] = -3e38f; lrow[r] = 0.f; }

  const int krow = t >> 3, dseg = (t & 7) * 8;   // K staging
  const int vrow = t & 31, vds = (t >> 5) * 8;   // V staging
  const size_t kvbase = (size_t)b * cSE * cD + h * cDH;
  bf16* Pw = Pl + w * 640;

  for (int kt = 0; kt < cSE; kt += 32) {
    bf16x8 kv8 = *(const bf16x8*)(Kc + kvbase + (size_t)(kt + krow) * cD + dseg);
    bf16x8 vv8 = *(const bf16x8*)(Vc + kvbase + (size_t)(kt + vrow) * cD + vds);
    *(bf16x8*)((char*)Ks + krow * 128 + ((dseg * 2) ^ ((krow & 7) << 4))) = kv8;
#pragma unroll
    for (int e = 0; e < 8; e++) Vt[(vds + e) * 40 + vrow] = vv8[e];
    __syncthreads();
    // QK^T: S[q, kk], two 16-col tiles
    f32x4 s[2];
#pragma unroll
    for (int t2 = 0; t2 < 2; t2++) {
      const int kr = t2 * 16 + c;
      bf16x8 bk0 = *(const bf16x8*)((char*)Ks + kr * 128 + ((g * 16) ^ ((kr & 7) << 4)));
      bf16x8 bk1 = *(const bf16x8*)((char*)Ks + kr * 128 + ((64 + g * 16) ^ ((kr & 7) << 4)));
      f32x4 z = zero4;
      z = __builtin_amdgcn_mfma_f32_16x16x32_bf16(aq[0], bk0, z, 0, 0, 0);
      z = __builtin_amdgcn_mfma_f32_16x16x32_bf16(aq[1], bk1, z, 0, 0, 0);
      s[t2] = z;
    }
    // online softmax; lane holds (q = g*4+r, kk = t2*16 + c)
#pragma unroll
    for (int r = 0; r < 4; r++) {
      const float s0 = s[0][r] * 0.125f, s1 = s[1][r] * 0.125f;
      float tm = fmaxf(s0, s1);
      tm = fmaxf(tm, __shfl_xor(tm, 1));
      tm = fmaxf(tm, __shfl_xor(tm, 2));
      tm = fmaxf(tm, __shfl_xor(tm, 4));
      tm = fmaxf(tm, __shfl_xor(tm, 8));
      const float mn = fmaxf(mrow[r], tm);
      const float corr = __expf(mrow[r] - mn);
      mrow[r] = mn;
      const float p0 = __expf(s0 - mn), p1 = __expf(s1 - mn);
      float ps = p0 + p1;
      ps += __shfl_xor(ps, 1);
      ps += __shfl_xor(ps, 2);
      ps += __shfl_xor(ps, 4);
      ps += __shfl_xor(ps, 8);
      lrow[r] = lrow[r] * corr + ps;
#pragma unroll
      for (int j = 0; j < 4; j++) o4[j][r] *= corr;
      const int qr = g * 4 + r;
      Pw[qr * 40 + c] = (bf16)p0;
      Pw[qr * 40 + 16 + c] = (bf16)p1;
    }
    // PV: A = P[16q x 32kk] from LDS, B = V^T
    bf16x8 pa = *(const bf16x8*)(Pw + c * 40 + g * 8);
#pragma unroll
    for (int j = 0; j < 4; j++) {
      bf16x8 bv = *(const bf16x8*)(Vt + (j * 16 + c) * 40 + g * 8);
      o4[j] = __builtin_amdgcn_mfma_f32_16x16x32_bf16(pa, bv, o4[j], 0, 0, 0);
    }
    __syncthreads();
  }
#pragma unroll
  for (int r = 0; r < 4; r++) {
    const float inv = 1.0f / lrow[r];
    const size_t row = (size_t)b * cSD + q0 + g * 4 + r;
#pragma unroll
    for (int j = 0; j < 4; j++)
      O[row * cD + h * cDH + j * 16 + c] = (bf16)(o4[j][r] * inv);
  }
}

// ---------------------------------------------------------------------------
extern "C" void kernel_launch(void* const* d_in, const int* in_sizes, int n_in,
                              void* d_out, int out_size, void* d_ws, size_t ws_size,
                              hipStream_t stream) {
  const float* in_enc = (const float*)d_in[0];
  const float* in_dec = (const float*)d_in[1];
  const int* expr = (const int*)d_in[2];
  const float* var_W = (const float*)d_in[3];
  const float* var_b = (const float*)d_in[4];
  const float* enc_g = (const float*)d_in[5];
  const float* enc_b = (const float*)d_in[6];
  const float* dec_g = (const float*)d_in[7];
  const float* dec_b = (const float*)d_in[8];
  const float* ln1_g = (const float*)d_in[9];
  const float* ln1_b = (const float*)d_in[10];
  const float* Wq = (const float*)d_in[11];
  const float* Wk = (const float*)d_in[12];
  const float* Wv = (const float*)d_in[13];
  const float* Wo = (const float*)d_in[14];
  const float* bo = (const float*)d_in[15];
  const float* ln2_g = (const float*)d_in[16];
  const float* ln2_b = (const float*)d_in[17];
  const float* w1 = (const float*)d_in[18];
  const float* b1 = (const float*)d_in[19];
  const float* w2 = (const float*)d_in[20];
  const float* b2 = (const float*)d_in[21];
  const float* proj = (const float*)d_in[22];
  const float* caWq = (const float*)d_in[23];
  const float* caWk = (const float*)d_in[24];
  const float* caWv = (const float*)d_in[25];
  const float* caWo = (const float*)d_in[26];
  const float* cabo = (const float*)d_in[27];
  const float* crg = (const float*)d_in[28];
  const float* crb = (const float*)d_in[29];
  const float* fw1 = (const float*)d_in[30];
  const float* fb1 = (const float*)d_in[31];
  const float* fw2 = (const float*)d_in[32];
  const float* fb2 = (const float*)d_in[33];
  const float* og = (const float*)d_in[34];
  const float* ob = (const float*)d_in[35];
  const float* hW = (const float*)d_in[36];
  const float* hb = (const float*)d_in[37];

  // ---- workspace layout (f32 units) -------------------------------------
  float* X   = (float*)d_ws;        // [16384,512]
  float* Qb  = X + 8388608;         // [16384,512]
  float* Kb  = Qb + 8388608;
  float* Vb  = Kb + 8388608;
  float* DC  = Vb + 8388608;        // [8192,512]
  float* P   = DC + 4194304;        // [64,2048,266] f32 / bf16 overlays
  float* KV  = P + 34865152;        // [64,266,64]
  float* KSP = KV + 1089536;        // [64,8,266]
  float* KS  = KSP + 136192;        // [64,266]
  float* DI  = KS + 17024;          // [64,2048]
  float* RD  = DI + 131072;         // [1040]
  bf16* Yb   = (bf16*)(RD + 1040);  // [16384,512] bf16
  bf16* DCb  = Yb + 8388608;        // [8192,512] bf16
  bf16* Wt   = DCb + 4194304;       // max 2048*512 bf16
  const size_t need_bytes = (size_t)80804496 * 4;
  if (ws_size < need_bytes) return;

  // P-region bf16 overlays
  bf16* Pb   = (bf16*)P;
  bf16* encB = Pb;                   // [16384,1280] (phase 0)
  bf16* decB = Pb + 20971520;        // [8192,1280]  (phase 0)
  bf16* Pmid = Pb;                   // [16384,2048] (FF mid, layer loop)
  bf16* Xb   = Pb;                   // [16384,512]  (decoder)
  bf16* Qc   = Pb + 8388608;         // [8192,512]
  bf16* Kc   = Pb + 12582912;        // [16384,512]
  bf16* Vc   = Pb + 20971520;        // [16384,512]
  bf16* Fb   = Pb + 29360128;        // [8192,512]
  bf16* Pm2  = Pb + 33554432;        // [8192,2048]

  const dim3 blk(256);
  const float dn = 0.35355339059327373f;  // 64^-0.25

  // ---- phase 0: embeddings ----------------------------------------------
  castf2b<<<2048, blk, 0, stream>>>(in_enc, encB, 16384 * 1280);
  castf2b<<<2048, blk, 0, stream>>>(in_dec, decB, 8192 * 1280);
  transpose_cast<<<dim3(16, 40), blk, 0, stream>>>(var_W, Wt, 1280, 512);
  gemm_mfma<0, 0, true, false><<<dim3(4, 128), blk, 0, stream>>>(encB, Wt, X, var_b, 16384, 512, 1280);
  gemm_mfma<0, 0, true, false><<<dim3(4, 64), blk, 0, stream>>>(decB, Wt, DC, var_b, 8192, 512, 1280);
  embed_ln<<<4096, blk, 0, stream>>>(X, expr, enc_g, enc_b);
  ln_rows<false, true, true><<<2048, blk, 0, stream>>>(DC, nullptr, dec_g, dec_b, DC, DCb);

  // ---- encoder layers ----------------------------------------------------
  for (int i = 0; i < cDEPTH; i++) {
    const float* pj = proj + (size_t)i * cM * cDH;
    ln_rows<false, false, true><<<4096, blk, 0, stream>>>(X, nullptr, ln1_g + i * cD, ln1_b + i * cD, nullptr, Yb);
    transpose_cast<<<dim3(16, 16), blk, 0, stream>>>(Wq + (size_t)i * cD * cD, Wt, 512, 512);
    gemm_mfma<0, 0, false, false><<<dim3(4, 128), blk, 0, stream>>>(Yb, Wt, Qb, nullptr, 16384, 512, 512);
    transpose_cast<<<dim3(16, 16), blk, 0, stream>>>(Wk + (size_t)i * cD * cD, Wt, 512, 512);
    gemm_mfma<0, 0, false, false><<<dim3(4, 128), blk, 0, stream>>>(Yb, Wt, Kb, nullptr, 16384, 512, 512);
    transpose_cast<<<dim3(16, 16), blk, 0, stream>>>(Wv + (size_t)i * cD * cD, Wt, 512, 512);
    gemm_mfma<0, 0, false, false><<<dim3(4, 128), blk, 0, stream>>>(Yb, Wt, Vb, nullptr, 16384, 512, 512);
    // FAVOR+ (fp32, unchanged)
    gemm_bat<0, 1, false, 0><<<dim3(5, 32, 64), blk, 0, stream>>>(
        Kb, (long long)cSE * cD, 64, cD, pj, 0, 0, cDH,
        P, (long long)cH * cSE * cM, (long long)cSE * cM, cM,
        nullptr, 0, cSE, cM, cDH, dn);
    redmax_part<<<1024, blk, 0, stream>>>(P, (size_t)64 * cSE * cM, RD);
    redmax_final<<<1, blk, 0, stream>>>(RD, RD + 1024);
    phi_kernel<true><<<32768, blk, 0, stream>>>(P, Kb, RD + 1024);
    ksum_part<<<dim3(64, 8), dim3(320), 0, stream>>>(P, KSP);
    ksum_final<<<64, dim3(320), 0, stream>>>(KSP, KS);
    gemm_bat<1, 0, false, 0><<<dim3(1, 5, 64), blk, 0, stream>>>(
        P, (long long)cH * cSE * cM, (long long)cSE * cM, cM,
        Vb, (long long)cSE * cD, 64, cD,
        KV, (long long)cH * cM * cDH, (long long)cM * cDH, cDH,
        nullptr, 0, cM, cDH, cSE, 1.0f);
    gemm_bat<0, 1, false, 0><<<dim3(5, 32, 64), blk, 0, stream>>>(
        Qb, (long long)cSE * cD, 64, cD, pj, 0, 0, cDH,
        P, (long long)cH * cSE * cM, (long long)cSE * cM, cM,
        nullptr, 0, cSE, cM, cDH, dn);
    phi_kernel<false><<<32768, blk, 0, stream>>>(P, Qb, nullptr);
    dinv_kernel<<<32768, blk, 0, stream>>>(P, KS, DI);
    gemm_bat<0, 0, true, 1><<<dim3(1, 32, 64), blk, 0, stream>>>(
        P, (long long)cH * cSE * cM, (long long)cSE * cM, cM,
        KV, (long long)cH * cM * cDH, (long long)cM * cDH, cDH,
        Yb, (long long)cSE * cD, 64, cD, DI, cSE,
        cSE, cDH, cM, 1.0f);
    transpose_cast<<<dim3(16, 16), blk, 0, stream>>>(Wo + (size_t)i * cD * cD, Wt, 512, 512);
    gemm_mfma<0, 0, true, true><<<dim3(4, 128), blk, 0, stream>>>(Yb, Wt, X, bo + i * cD, 16384, 512, 512);
    ln_rows<false, false, true><<<4096, blk, 0, stream>>>(X, nullptr, ln2_g + i * cD, ln2_b + i * cD, nullptr, Yb);
    transpose_cast<<<dim3(64, 16), blk, 0, stream>>>(w1 + (size_t)i * cD * cFF, Wt, 512, 2048);
    gemm_mfma<1, 1, true, false><<<dim3(16, 128), blk, 0, stream>>>(Yb, Wt, Pmid, b1 + i * cFF, 16384, 2048, 512);
    transpose_cast<<<dim3(16, 64), blk, 0, stream>>>(w2 + (size_t)i * cFF * cD, Wt, 2048, 512);
    gemm_mfma<0, 0, true, true><<<dim3(4, 128), blk, 0, stream>>>(Pmid, Wt, X, b2 + i * cD, 16384, 512, 2048);
  }

  // ---- decoder / cross-attention ----------------------------------------
  castf2b<<<2048, blk, 0, stream>>>(X, Xb, 16384 * 512);
  transpose_cast<<<dim3(16, 16), blk, 0, stream>>>(caWq, Wt, 512, 512);
  gemm_mfma<1, 0, false, false><<<dim3(4, 64), blk, 0, stream>>>(DCb, Wt, Qc, nullptr, 8192, 512, 512);
  transpose_cast<<<dim3(16, 16), blk, 0, stream>>>(caWk, Wt, 512, 512);
  gemm_mfma<1, 0, false, false><<<dim3(4, 128), blk, 0, stream>>>(Xb, Wt, Kc, nullptr, 16384, 512, 512);
  transpose_cast<<<dim3(16, 16), blk, 0, stream>>>(caWv, Wt, 512, 512);
  gemm_mfma<1, 0, false, false><<<dim3(4, 128), blk, 0, stream>>>(Xb, Wt, Vc, nullptr, 16384, 512, 512);
  flash_mfma<<<dim3(16, 8, 8), blk, 0, stream>>>(Qc, Kc, Vc, Fb);
  transpose_cast<<<dim3(16, 16), blk, 0, stream>>>(caWo, Wt, 512, 512);
  gemm_mfma<0, 0, true, false><<<dim3(4, 64), blk, 0, stream>>>(Fb, Wt, Qb, cabo, 8192, 512, 512);
  ln_rows<true, false, true><<<2048, blk, 0, stream>>>(Qb, DC, crg, crb, nullptr, Yb);
  transpose_cast<<<dim3(64, 16), blk, 0, stream>>>(fw1, Wt, 512, 2048);
  gemm_mfma<1, 1, true, false><<<dim3(16, 64), blk, 0, stream>>>(Yb, Wt, Pm2, fb1, 8192, 2048, 512);
  transpose_cast<<<dim3(16, 64), blk, 0, stream>>>(fw2, Wt, 2048, 512);
  gemm_mfma<0, 0, true, false><<<dim3(4, 64), blk, 0, stream>>>(Pm2, Wt, Qb, fb2, 8192, 512, 2048);
  ln_rows<false, false, true><<<2048, blk, 0, stream>>>(Qb, nullptr, og, ob, nullptr, Yb);
  transpose_cast<<<dim3(4, 16), blk, 0, stream>>>(hW, Wt, 512, 128);
  gemm_mfma<0, 0, true, false><<<dim3(1, 64), blk, 0, stream>>>(Yb, Wt, (float*)d_out, hb, 8192, 128, 512);
}

// Round 3
// 2674.120 us; speedup vs baseline: 4.9568x; 2.0504x over previous
//
#include <hip/hip_runtime.h>
#include <hip/hip_bf16.h>
#include <math.h>

// Problem constants
constexpr int cB = 8, cSE = 2048, cSD = 1024, cIN = 1280, cD = 512,
              cDEPTH = 4, cH = 8, cDH = 64, cM = 266, cFF = 2048, cNB = 128;
constexpr int cMP = 288;  // cM padded to multiple of 16 (features pad -> 0)

#define DEV __device__ __forceinline__

typedef __bf16 bf16;
typedef __attribute__((ext_vector_type(8))) __bf16 bf16x8;
typedef __attribute__((ext_vector_type(4))) __bf16 bf16x4;
typedef __attribute__((ext_vector_type(4))) float f32x4;

DEV float gelu_f(float x) { return 0.5f * x * (1.0f + erff(x * 0.70710678118654752440f)); }

DEV float wave_sum(float v) {
#pragma unroll
  for (int o = 32; o; o >>= 1) v += __shfl_xor(v, o);
  return v;
}
DEV float wave_max(float v) {
#pragma unroll
  for (int o = 32; o; o >>= 1) v = fmaxf(v, __shfl_xor(v, o));
  return v;
}

#define GL2LDS(gp, lp) __builtin_amdgcn_global_load_lds(                    \
    (const __attribute__((address_space(1))) void*)(gp),                    \
    (__attribute__((address_space(3))) void*)(lp), 16, 0, 0)

// ---------------------------------------------------------------------------
// bf16 MFMA GEMM (m97 structure): C[M,N] = epi(A[M,K] @ Bt[N,K]^T).
// M%128==0, N%128==0, K%32==0. OUT: 0=f32 C, 1=bf16 C. ACT 1 = exact GELU.
// ---------------------------------------------------------------------------
template <int OUT, int ACT, bool BIAS, bool RES>
__global__ __launch_bounds__(256) void gemm_mfma(
    const bf16* __restrict__ A, const bf16* __restrict__ Bt,
    void* __restrict__ Cv, const float* __restrict__ bias,
    int M, int N, int K) {
  __shared__ bf16 As[128 * 32];
  __shared__ bf16 Bs[128 * 32];
  const int t = threadIdx.x, l = t & 63, w = t >> 6;
  const int g = l >> 4, c = l & 15;
  const int m0 = blockIdx.y * 128, n0 = blockIdx.x * 128;
  const int wr = (w >> 1) * 64, wc = (w & 1) * 64;
  const int srow = w * 32 + (l >> 2);
  const int scol = (l & 3) * 8;
  const bf16* gA = A + (size_t)(m0 + srow) * K + scol;
  const bf16* gB = Bt + (size_t)(n0 + srow) * K + scol;
  bf16* lA = As + w * 1024;
  bf16* lB = Bs + w * 1024;

  const f32x4 zero4 = {0.f, 0.f, 0.f, 0.f};
  f32x4 acc[4][4];
#pragma unroll
  for (int i = 0; i < 4; i++)
#pragma unroll
    for (int j = 0; j < 4; j++) acc[i][j] = zero4;

  for (int k0 = 0; k0 < K; k0 += 32) {
    GL2LDS(gA + k0, lA);
    GL2LDS(gA + (size_t)16 * K + k0, lA + 512);
    GL2LDS(gB + k0, lB);
    GL2LDS(gB + (size_t)16 * K + k0, lB + 512);
    __syncthreads();
    bf16x8 af[4], bfr[4];
#pragma unroll
    for (int i = 0; i < 4; i++)
      af[i] = *(const bf16x8*)(As + (wr + i * 16 + c) * 32 + g * 8);
#pragma unroll
    for (int j = 0; j < 4; j++)
      bfr[j] = *(const bf16x8*)(Bs + (wc + j * 16 + c) * 32 + g * 8);
#pragma unroll
    for (int i = 0; i < 4; i++)
#pragma unroll
      for (int j = 0; j < 4; j++)
        acc[i][j] = __builtin_amdgcn_mfma_f32_16x16x32_bf16(af[i], bfr[j], acc[i][j], 0, 0, 0);
    __syncthreads();
  }
  float* Cf = (float*)Cv;
  bf16* Cb = (bf16*)Cv;
#pragma unroll
  for (int i = 0; i < 4; i++) {
    const int mb = m0 + wr + i * 16 + g * 4;
#pragma unroll
    for (int j = 0; j < 4; j++) {
      const int n = n0 + wc + j * 16 + c;
      const float bv = BIAS ? bias[n] : 0.f;
#pragma unroll
      for (int r = 0; r < 4; r++) {
        float v = acc[i][j][r] + bv;
        if (ACT == 1) v = gelu_f(v);
        if (OUT == 0) {
          float* cp = Cf + (size_t)(mb + r) * N + n;
          if (RES) v += *cp;
          *cp = v;
        } else {
          Cb[(size_t)(mb + r) * N + n] = (bf16)v;
        }
      }
    }
  }
}

// ---------------------------------------------------------------------------
// transpose + cast: W[K,N] f32 -> Wt[N,K] bf16. 32x32 tiles.
// ---------------------------------------------------------------------------
__global__ __launch_bounds__(256) void transpose_cast(
    const float* __restrict__ W, bf16* __restrict__ Wt, int K, int N) {
  __shared__ float tile[32][33];
  const int tx = threadIdx.x & 31, ty = threadIdx.x >> 5;
  const int k0 = blockIdx.y * 32, n0 = blockIdx.x * 32;
#pragma unroll
  for (int i = ty; i < 32; i += 8) tile[i][tx] = W[(size_t)(k0 + i) * N + n0 + tx];
  __syncthreads();
#pragma unroll
  for (int i = ty; i < 32; i += 8)
    Wt[(size_t)(n0 + i) * K + k0 + tx] = (bf16)tile[tx][i];
}

// flat f32 -> bf16 cast, n % 4 == 0
__global__ __launch_bounds__(256) void castf2b(
    const float* __restrict__ x, bf16* __restrict__ y, int n) {
  int i = (blockIdx.x * 256 + threadIdx.x) * 4;
  const int stride = gridDim.x * 1024;
  for (; i < n; i += stride) {
    float4 v = *(const float4*)(x + i);
    bf16x4 o;
    o[0] = (bf16)v.x; o[1] = (bf16)v.y; o[2] = (bf16)v.z; o[3] = (bf16)v.w;
    *(bf16x4*)(y + i) = o;
  }
}

// proj [266,64] f32 -> projB [288,64] bf16 with dn prescale, pad rows = 0
__global__ __launch_bounds__(256) void proj_cast(
    const float* __restrict__ proj, bf16* __restrict__ projB) {
  const int idx = blockIdx.x * 256 + threadIdx.x;
  if (idx >= cMP * cDH) return;
  const int m = idx >> 6;
  projB[idx] = (bf16)(m < cM ? proj[idx] * 0.35355339059327373f : 0.f);
}

// diag[z,s] = 0.5*||qk head slice||^2 * dn^2 for Q and K
__global__ __launch_bounds__(256) void diag_kernel(
    const bf16* __restrict__ Qh, const bf16* __restrict__ Kh,
    float* __restrict__ dQ, float* __restrict__ dK) {
  const int tid = blockIdx.x * 256 + threadIdx.x;  // (bs, h)
  const int h = tid & 7, bs = tid >> 3;
  const int b = bs >> 11, s = bs & 2047;
  const size_t base = (size_t)bs * cD + h * cDH;
  float sq = 0.f, sk = 0.f;
#pragma unroll
  for (int i = 0; i < 8; i++) {
    bf16x8 q8 = *(const bf16x8*)(Qh + base + i * 8);
    bf16x8 k8 = *(const bf16x8*)(Kh + base + i * 8);
#pragma unroll
    for (int e = 0; e < 8; e++) {
      const float qv = (float)q8[e], kv = (float)k8[e];
      sq += qv * qv; sk += kv * kv;
    }
  }
  const int z = b * 8 + h;
  dQ[(size_t)z * cSE + s] = sq * 0.0625f;  // 0.5 * dn^2
  dK[(size_t)z * cSE + s] = sk * 0.0625f;
}

// V head-transpose: Vh merged [16384,512] -> Vt [64 z][64 d][2048 s]
__global__ __launch_bounds__(256) void vtrans(
    const bf16* __restrict__ Vh, bf16* __restrict__ Vt) {
  __shared__ bf16 tile[64][65];
  const int z = blockIdx.y, b = z >> 3, h = z & 7;
  const int s0 = blockIdx.x * 64;
  const int t = threadIdx.x;
#pragma unroll
  for (int r = t >> 3; r < 64; r += 32) {
    bf16x8 v = *(const bf16x8*)(Vh + ((size_t)b * cSE + s0 + r) * cD + h * cDH + (t & 7) * 8);
#pragma unroll
    for (int e = 0; e < 8; e++) tile[(t & 7) * 8 + e][r] = v[e];
  }
  __syncthreads();
#pragma unroll
  for (int d = t >> 3; d < 64; d += 32) {
    bf16x8 o;
#pragma unroll
    for (int e = 0; e < 8; e++) o[e] = tile[d][(t & 7) * 8 + e];
    *(bf16x8*)(Vt + ((size_t)z * 64 + d) * cSE + s0 + (t & 7) * 8) = o;
  }
}

// ---------------------------------------------------------------------------
// FAVOR feature kernel. Computes 128x288 tile of qd/kd = (qk*dn) @ proj^T via
// MFMA (register-resident, direct global operand loads), then:
// MODE 0: per-row max, qp = ratio*(exp(qd-diag-rmax)+eps) -> Pq [z,2048,288]
// MODE 1: masked block max of kd -> bmax[1024] (no stores)
// MODE 2: kp = ratio*(exp(kd-diag-gmax)+eps) -> Pk TRANSPOSED [z,288,2048]
// grid (16, 64), 256 threads (4 waves; 2x2 wave grid: 64 rows x 144 cols).
// ---------------------------------------------------------------------------
template <int MODE>
__global__ __launch_bounds__(256, 1) void favor_phi(
    const bf16* __restrict__ QK, const bf16* __restrict__ projB,
    const float* __restrict__ diag, const float* __restrict__ gmax,
    bf16* __restrict__ Pout, float* __restrict__ bmax) {
  __shared__ float rmaxs[4][64];
  __shared__ float sm[4];
  const int z = blockIdx.y, b = z >> 3, h = z & 7;
  const int s0 = blockIdx.x * 128;
  const int t = threadIdx.x, l = t & 63, w = t >> 6, g = l >> 4, c = l & 15;
  const int wr = (w >> 1) * 64, wcol = (w & 1) * 144;
  const f32x4 zero4 = {0.f, 0.f, 0.f, 0.f};
  f32x4 acc[4][9];
#pragma unroll
  for (int i = 0; i < 4; i++)
#pragma unroll
    for (int j = 0; j < 9; j++) acc[i][j] = zero4;
  const size_t abase = ((size_t)b * cSE + s0) * cD + h * cDH;
#pragma unroll
  for (int k0 = 0; k0 < 64; k0 += 32) {
    bf16x8 af[4];
#pragma unroll
    for (int i = 0; i < 4; i++)
      af[i] = *(const bf16x8*)(QK + abase + (size_t)(wr + i * 16 + c) * cD + k0 + g * 8);
#pragma unroll
    for (int j = 0; j < 9; j++) {
      bf16x8 bfr = *(const bf16x8*)(projB + (wcol + j * 16 + c) * 64 + k0 + g * 8);
#pragma unroll
      for (int i = 0; i < 4; i++)
        acc[i][j] = __builtin_amdgcn_mfma_f32_16x16x32_bf16(af[i], bfr, acc[i][j], 0, 0, 0);
    }
  }
  const float ratio = 0.061313927f;  // 266^-0.5

  if (MODE == 1) {
    float m = -3e38f;
#pragma unroll
    for (int i = 0; i < 4; i++)
#pragma unroll
      for (int j = 0; j < 9; j++) {
        const int mc = wcol + j * 16 + c;
        if (mc < cM) {
#pragma unroll
          for (int r = 0; r < 4; r++) m = fmaxf(m, acc[i][j][r]);
        }
      }
    m = wave_max(m);
    if (l == 0) sm[w] = m;
    __syncthreads();
    if (t == 0)
      bmax[blockIdx.y * 16 + blockIdx.x] =
          fmaxf(fmaxf(sm[0], sm[1]), fmaxf(sm[2], sm[3]));
    return;
  }

  float rowsub[4][4];  // diag + max per (i, r)
  if (MODE == 0) {
#pragma unroll
    for (int i = 0; i < 4; i++)
#pragma unroll
      for (int r = 0; r < 4; r++) {
        float m = -3e38f;
#pragma unroll
        for (int j = 0; j < 9; j++) {
          const int mc = wcol + j * 16 + c;
          m = (mc < cM) ? fmaxf(m, acc[i][j][r]) : m;
        }
        m = fmaxf(m, __shfl_xor(m, 1));
        m = fmaxf(m, __shfl_xor(m, 2));
        m = fmaxf(m, __shfl_xor(m, 4));
        m = fmaxf(m, __shfl_xor(m, 8));
        rowsub[i][r] = m;
      }
    if (c == 0) {
#pragma unroll
      for (int i = 0; i < 4; i++)
#pragma unroll
        for (int r = 0; r < 4; r++) rmaxs[w][i * 16 + g * 4 + r] = rowsub[i][r];
    }
    __syncthreads();
#pragma unroll
    for (int i = 0; i < 4; i++)
#pragma unroll
      for (int r = 0; r < 4; r++) {
        const int row = i * 16 + g * 4 + r;
        rowsub[i][r] = fmaxf(rowsub[i][r], rmaxs[w ^ 1][row]) +
                       diag[(size_t)z * cSE + s0 + wr + row];
      }
  } else {
    const float gm = *gmax;
#pragma unroll
    for (int i = 0; i < 4; i++)
#pragma unroll
      for (int r = 0; r < 4; r++)
        rowsub[i][r] = gm + diag[(size_t)z * cSE + s0 + wr + i * 16 + g * 4 + r];
  }

  if (MODE == 0) {
#pragma unroll
    for (int i = 0; i < 4; i++)
#pragma unroll
      for (int j = 0; j < 9; j++) {
        const int mc = wcol + j * 16 + c;
#pragma unroll
        for (int r = 0; r < 4; r++) {
          const float v = (mc < cM)
              ? ratio * (__expf(acc[i][j][r] - rowsub[i][r]) + 1e-4f) : 0.f;
          Pout[((size_t)z * cSE + s0 + wr + i * 16 + g * 4 + r) * cMP + mc] = (bf16)v;
        }
      }
  } else {
#pragma unroll
    for (int i = 0; i < 4; i++)
#pragma unroll
      for (int j = 0; j < 9; j++) {
        const int mc = wcol + j * 16 + c;
        bf16x4 o;
#pragma unroll
        for (int r = 0; r < 4; r++) {
          const float v = (mc < cM)
              ? ratio * (__expf(acc[i][j][r] - rowsub[i][r]) + 1e-4f) : 0.f;
          o[r] = (bf16)v;
        }
        *(bf16x4*)(Pout + ((size_t)z * cMP + mc) * cSE + s0 + wr + i * 16 + g * 4) = o;
      }
  }
}

// global max over bmax[1024] -> gm[0]
__global__ __launch_bounds__(256) void redmax_final(
    const float* __restrict__ part, float* __restrict__ gm) {
  float m = -1e30f;
  for (int i = threadIdx.x; i < 1024; i += 256) m = fmaxf(m, part[i]);
  m = wave_max(m);
  __shared__ float sm[4];
  if ((threadIdx.x & 63) == 0) sm[threadIdx.x >> 6] = m;
  __syncthreads();
  if (threadIdx.x == 0) gm[0] = fmaxf(fmaxf(sm[0], sm[1]), fmaxf(sm[2], sm[3]));
}

// ksum[z*288+m] = sum_s Pk[z,m,s]; wave per row
__global__ __launch_bounds__(256) void ksum_rows(
    const bf16* __restrict__ Pk, float* __restrict__ ksum) {
  const int row = blockIdx.x * 4 + (threadIdx.x >> 6);
  const int l = threadIdx.x & 63;
  const bf16* p = Pk + (size_t)row * cSE + l * 8;
  float s = 0.f;
#pragma unroll
  for (int i = 0; i < 4; i++) {
    bf16x8 v = *(const bf16x8*)(p + i * 512);
#pragma unroll
    for (int e = 0; e < 8; e++) s += (float)v[e];
  }
  s = wave_sum(s);
  if (l == 0) ksum[row] = s;
}

// dinv[z*2048+s] = 1/dot(Pq[z,s,:], ksum[z,:]); wave per row
__global__ __launch_bounds__(256) void dinv2(
    const bf16* __restrict__ Pq, const float* __restrict__ ksum,
    float* __restrict__ dinv) {
  const int row = blockIdx.x * 4 + (threadIdx.x >> 6);
  const int l = threadIdx.x & 63;
  const int z = row >> 11;
  const bf16* p = Pq + (size_t)row * cMP;
  const float* ks = ksum + (size_t)z * cMP;
  float s = 0.f;
  bf16x4 v = *(const bf16x4*)(p + l * 4);
#pragma unroll
  for (int e = 0; e < 4; e++) s += (float)v[e] * ks[l * 4 + e];
  if (l < 8) {
    bf16x4 v2 = *(const bf16x4*)(p + 256 + l * 4);
#pragma unroll
    for (int e = 0; e < 4; e++) s += (float)v2[e] * ks[256 + l * 4 + e];
  }
  s = wave_sum(s);
  if (l == 0) dinv[row] = 1.0f / s;
}

// ---------------------------------------------------------------------------
// kv partials: part[z,ch,m,d] = sum_{s in chunk} Pk[z,m,s] * Vt[z,d,s].
// grid (4, 64); 4 waves 2x2: wave = 144 m x 32 d. Direct global operands.
// ---------------------------------------------------------------------------
__global__ __launch_bounds__(256) void favor_kv(
    const bf16* __restrict__ Pk, const bf16* __restrict__ Vt,
    float* __restrict__ part) {
  const int z = blockIdx.y, ch = blockIdx.x;
  const int t = threadIdx.x, l = t & 63, w = t >> 6, g = l >> 4, c = l & 15;
  const int wm = (w & 1) * 144, wd = (w >> 1) * 32;
  const size_t pkz = (size_t)z * cMP * cSE, vtz = (size_t)z * 64 * cSE;
  const f32x4 zero4 = {0.f, 0.f, 0.f, 0.f};
  f32x4 acc[9][2];
#pragma unroll
  for (int j = 0; j < 9; j++)
#pragma unroll
    for (int i = 0; i < 2; i++) acc[j][i] = zero4;
  for (int k0 = ch * 512; k0 < ch * 512 + 512; k0 += 32) {
    bf16x8 bv[2];
#pragma unroll
    for (int i = 0; i < 2; i++)
      bv[i] = *(const bf16x8*)(Vt + vtz + (size_t)(wd + i * 16 + c) * cSE + k0 + g * 8);
#pragma unroll
    for (int j = 0; j < 9; j++) {
      bf16x8 am = *(const bf16x8*)(Pk + pkz + (size_t)(wm + j * 16 + c) * cSE + k0 + g * 8);
#pragma unroll
      for (int i = 0; i < 2; i++)
        acc[j][i] = __builtin_amdgcn_mfma_f32_16x16x32_bf16(am, bv[i], acc[j][i], 0, 0, 0);
    }
  }
  float* po = part + ((size_t)z * 4 + ch) * (cMP * 64);
#pragma unroll
  for (int j = 0; j < 9; j++)
#pragma unroll
    for (int i = 0; i < 2; i++)
#pragma unroll
      for (int r = 0; r < 4; r++)
        po[(size_t)(wm + j * 16 + g * 4 + r) * 64 + wd + i * 16 + c] = acc[j][i][r];
}

// reduce 4 chunks + transpose: kvT[z,d,m] bf16
__global__ __launch_bounds__(256) void kv_reduce(
    const float* __restrict__ part, bf16* __restrict__ kvT) {
  const int z = blockIdx.x;
  const float* p = part + (size_t)z * 4 * (cMP * 64);
  bf16* o = kvT + (size_t)z * 64 * cMP;
  for (int idx = threadIdx.x; idx < cMP * 64; idx += 256) {
    const int m = idx >> 6, d = idx & 63;
    const float s = p[idx] + p[idx + cMP * 64] + p[idx + 2 * cMP * 64] + p[idx + 3 * cMP * 64];
    o[(size_t)d * cMP + m] = (bf16)s;
  }
}

// ---------------------------------------------------------------------------
// out[z,s,d] = dinv[z,s] * sum_m Pq[z,s,m] * kvT[z,d,m] -> Y merged [16384,512]
// grid (16, 64); 4 waves 2x2: wave = 64 s x 32 d.
// ---------------------------------------------------------------------------
__global__ __launch_bounds__(256) void favor_out(
    const bf16* __restrict__ Pq, const bf16* __restrict__ kvT,
    const float* __restrict__ dinv, bf16* __restrict__ Y) {
  const int z = blockIdx.y, b = z >> 3, h = z & 7;
  const int s0 = blockIdx.x * 128;
  const int t = threadIdx.x, l = t & 63, w = t >> 6, g = l >> 4, c = l & 15;
  const int wr = (w >> 1) * 64, wd = (w & 1) * 32;
  const f32x4 zero4 = {0.f, 0.f, 0.f, 0.f};
  f32x4 acc[4][2];
#pragma unroll
  for (int i = 0; i < 4; i++)
#pragma unroll
    for (int j = 0; j < 2; j++) acc[i][j] = zero4;
  const size_t pqz = ((size_t)z * cSE + s0) * cMP;
  const size_t kz = (size_t)z * 64 * cMP;
#pragma unroll 3
  for (int k0 = 0; k0 < cMP; k0 += 32) {
    bf16x8 bv[2];
#pragma unroll
    for (int j = 0; j < 2; j++)
      bv[j] = *(const bf16x8*)(kvT + kz + (size_t)(wd + j * 16 + c) * cMP + k0 + g * 8);
#pragma unroll
    for (int i = 0; i < 4; i++) {
      bf16x8 av = *(const bf16x8*)(Pq + pqz + (size_t)(wr + i * 16 + c) * cMP + k0 + g * 8);
#pragma unroll
      for (int j = 0; j < 2; j++)
        acc[i][j] = __builtin_amdgcn_mfma_f32_16x16x32_bf16(av, bv[j], acc[i][j], 0, 0, 0);
    }
  }
#pragma unroll
  for (int i = 0; i < 4; i++)
#pragma unroll
    for (int r = 0; r < 4; r++) {
      const int row = wr + i * 16 + g * 4 + r;
      const float di = dinv[(size_t)z * cSE + s0 + row];
#pragma unroll
      for (int j = 0; j < 2; j++)
        Y[((size_t)b * cSE + s0 + row) * cD + h * cDH + wd + j * 16 + c] =
            (bf16)(acc[i][j][r] * di);
    }
}

// ---------------------------------------------------------------------------
// LayerNorm rows of 512; wave per row. WF: f32 out, WB: bf16 out2.
// ---------------------------------------------------------------------------
template <bool ADD, bool WF, bool WB>
__global__ __launch_bounds__(256) void ln_rows(
    const float* __restrict__ in, const float* __restrict__ add,
    const float* __restrict__ g, const float* __restrict__ be,
    float* __restrict__ out, bf16* __restrict__ out2) {
  const int wid = blockIdx.x * 4 + (threadIdx.x >> 6);
  const int lane = threadIdx.x & 63;
  const float* ip = in + (size_t)wid * cD + lane * 8;
  float x[8];
  {
    float4 a = *(const float4*)ip;
    float4 b4 = *(const float4*)(ip + 4);
    x[0] = a.x; x[1] = a.y; x[2] = a.z; x[3] = a.w;
    x[4] = b4.x; x[5] = b4.y; x[6] = b4.z; x[7] = b4.w;
  }
  if (ADD) {
    const float* ap = add + (size_t)wid * cD + lane * 8;
    float4 a = *(const float4*)ap;
    float4 b4 = *(const float4*)(ap + 4);
    x[0] += a.x; x[1] += a.y; x[2] += a.z; x[3] += a.w;
    x[4] += b4.x; x[5] += b4.y; x[6] += b4.z; x[7] += b4.w;
  }
  float s = 0;
#pragma unroll
  for (int i = 0; i < 8; i++) s += x[i];
  s = wave_sum(s);
  const float mu = s * (1.0f / cD);
  float vs = 0;
#pragma unroll
  for (int i = 0; i < 8; i++) { const float d = x[i] - mu; vs += d * d; }
  vs = wave_sum(vs);
  const float rstd = 1.0f / sqrtf(vs * (1.0f / cD) + 1e-5f);
  float r[8];
#pragma unroll
  for (int i = 0; i < 8; i++) {
    const int d = lane * 8 + i;
    r[i] = (x[i] - mu) * rstd * g[d] + be[d];
  }
  if (WF) {
    float* op = out + (size_t)wid * cD + lane * 8;
    float4 a, b4;
    a.x = r[0]; a.y = r[1]; a.z = r[2]; a.w = r[3];
    b4.x = r[4]; b4.y = r[5]; b4.z = r[6]; b4.w = r[7];
    *(float4*)op = a; *(float4*)(op + 4) = b4;
  }
  if (WB) {
    bf16x8 ov;
#pragma unroll
    for (int i = 0; i < 8; i++) ov[i] = (bf16)r[i];
    *(bf16x8*)(out2 + (size_t)wid * cD + lane * 8) = ov;
  }
}

// LN of (enc + sinusoidal(expr)), in-place on f32 X.
__global__ __launch_bounds__(256) void embed_ln(
    float* __restrict__ X, const int* __restrict__ ids,
    const float* __restrict__ g, const float* __restrict__ be) {
  const int wid = blockIdx.x * 4 + (threadIdx.x >> 6);
  const int lane = threadIdx.x & 63;
  const float idv = (float)ids[wid];
  float* xp = X + (size_t)wid * cD + lane * 8;
  float x[8];
  {
    float4 a = *(const float4*)xp;
    float4 b4 = *(const float4*)(xp + 4);
    x[0] = a.x; x[1] = a.y; x[2] = a.z; x[3] = a.w;
    x[4] = b4.x; x[5] = b4.y; x[6] = b4.z; x[7] = b4.w;
  }
  const float kf = -0.03597789207803197f;  // -ln(10000)/256
#pragma unroll
  for (int i = 0; i < 8; i++) {
    const int d = lane * 8 + i;
    float e;
    if (d < 256) e = sinf(idv * expf(kf * (float)d));
    else         e = cosf(idv * expf(kf * (float)(d - 256)));
    x[i] += e;
  }
  float s = 0;
#pragma unroll
  for (int i = 0; i < 8; i++) s += x[i];
  s = wave_sum(s);
  const float mu = s * (1.0f / cD);
  float vs = 0;
#pragma unroll
  for (int i = 0; i < 8; i++) { const float d = x[i] - mu; vs += d * d; }
  vs = wave_sum(vs);
  const float rstd = 1.0f / sqrtf(vs * (1.0f / cD) + 1e-5f);
#pragma unroll
  for (int i = 0; i < 8; i++) {
    const int d = lane * 8 + i;
    xp[i] = (x[i] - mu) * rstd * g[d] + be[d];
  }
}

// ---------------------------------------------------------------------------
// bf16 MFMA flash cross-attention (unchanged from round 2).
// ---------------------------------------------------------------------------
__global__ __launch_bounds__(256) void flash_mfma(
    const bf16* __restrict__ Q, const bf16* __restrict__ Kc,
    const bf16* __restrict__ Vc, bf16* __restrict__ O) {
  __shared__ bf16 Ks[32 * 64];
  __shared__ bf16 Vt[64 * 40];
  __shared__ bf16 Pl[4 * 16 * 40];
  const int b = blockIdx.z, h = blockIdx.y;
  const int t = threadIdx.x, l = t & 63, w = t >> 6;
  const int g = l >> 4, c = l & 15;
  const int q0 = blockIdx.x * 64 + w * 16;
  bf16x8 aq[2];
  {
    const bf16* qp = Q + ((size_t)b * cSD + q0 + c) * cD + h * cDH + g * 8;
    aq[0] = *(const bf16x8*)qp;
    aq[1] = *(const bf16x8*)(qp + 32);
  }
  const f32x4 zero4 = {0.f, 0.f, 0.f, 0.f};
  f32x4 o4[4];
#pragma unroll
  for (int j = 0; j < 4; j++) o4[j] = zero4;
  float mrow[4], lrow[4];
#pragma unroll
  for (int r = 0; r < 4; r++) { mrow[r] = -3e38f; lrow[r] = 0.f; }

  const int krow = t >> 3, dseg = (t & 7) * 8;
  const int vrow = t & 31, vds = (t >> 5) * 8;
  const size_t kvbase = (size_t)b * cSE * cD + h * cDH;
  bf16* Pw = Pl + w * 640;

  for (int kt = 0; kt < cSE; kt += 32) {
    bf16x8 kv8 = *(const bf16x8*)(Kc + kvbase + (size_t)(kt + krow) * cD + dseg);
    bf16x8 vv8 = *(const bf16x8*)(Vc + kvbase + (size_t)(kt + vrow) * cD + vds);
    *(bf16x8*)((char*)Ks + krow * 128 + ((dseg * 2) ^ ((krow & 7) << 4))) = kv8;
#pragma unroll
    for (int e = 0; e < 8; e++) Vt[(vds + e) * 40 + vrow] = vv8[e];
    __syncthreads();
    f32x4 s[2];
#pragma unroll
    for (int t2 = 0; t2 < 2; t2++) {
      const int kr = t2 * 16 + c;
      bf16x8 bk0 = *(const bf16x8*)((char*)Ks + kr * 128 + ((g * 16) ^ ((kr & 7) << 4)));
      bf16x8 bk1 = *(const bf16x8*)((char*)Ks + kr * 128 + ((64 + g * 16) ^ ((kr & 7) << 4)));
      f32x4 z = zero4;
      z = __builtin_amdgcn_mfma_f32_16x16x32_bf16(aq[0], bk0, z, 0, 0, 0);
      z = __builtin_amdgcn_mfma_f32_16x16x32_bf16(aq[1], bk1, z, 0, 0, 0);
      s[t2] = z;
    }
#pragma unroll
    for (int r = 0; r < 4; r++) {
      const float s0 = s[0][r] * 0.125f, s1 = s[1][r] * 0.125f;
      float tm = fmaxf(s0, s1);
      tm = fmaxf(tm, __shfl_xor(tm, 1));
      tm = fmaxf(tm, __shfl_xor(tm, 2));
      tm = fmaxf(tm, __shfl_xor(tm, 4));
      tm = fmaxf(tm, __shfl_xor(tm, 8));
      const float mn = fmaxf(mrow[r], tm);
      const float corr = __expf(mrow[r] - mn);
      const float w0 = __expf(s0 - mn), w1 = __expf(s1 - mn);
      float ps = w0 + w1;
      ps += __shfl_xor(ps, 1);
      ps += __shfl_xor(ps, 2);
      ps += __shfl_xor(ps, 4);
      ps += __shfl_xor(ps, 8);
      lrow[r] = lrow[r] * corr + ps;
#pragma unroll
      for (int j = 0; j < 4; j++) o4[j][r] *= corr;
      mrow[r] = mn;
      const int qr = g * 4 + r;
      Pw[qr * 40 + c] = (bf16)w0;
      Pw[qr * 40 + 16 + c] = (bf16)w1;
    }
    bf16x8 pa = *(const bf16x8*)(Pw + c * 40 + g * 8);
#pragma unroll
    for (int j = 0; j < 4; j++) {
      bf16x8 bv = *(const bf16x8*)(Vt + (j * 16 + c) * 40 + g * 8);
      o4[j] = __builtin_amdgcn_mfma_f32_16x16x32_bf16(pa, bv, o4[j], 0, 0, 0);
    }
    __syncthreads();
  }
#pragma unroll
  for (int r = 0; r < 4; r++) {
    const float inv = 1.0f / lrow[r];
    const size_t row = (size_t)b * cSD + q0 + g * 4 + r;
#pragma unroll
    for (int j = 0; j < 4; j++)
      O[row * cD + h * cDH + j * 16 + c] = (bf16)(o4[j][r] * inv);
  }
}

// ---------------------------------------------------------------------------
extern "C" void kernel_launch(void* const* d_in, const int* in_sizes, int n_in,
                              void* d_out, int out_size, void* d_ws, size_t ws_size,
                              hipStream_t stream) {
  const float* in_enc = (const float*)d_in[0];
  const float* in_dec = (const float*)d_in[1];
  const int* expr = (const int*)d_in[2];
  const float* var_W = (const float*)d_in[3];
  const float* var_b = (const float*)d_in[4];
  const float* enc_g = (const float*)d_in[5];
  const float* enc_b = (const float*)d_in[6];
  const float* dec_g = (const float*)d_in[7];
  const float* dec_b = (const float*)d_in[8];
  const float* ln1_g = (const float*)d_in[9];
  const float* ln1_b = (const float*)d_in[10];
  const float* Wq = (const float*)d_in[11];
  const float* Wk = (const float*)d_in[12];
  const float* Wv = (const float*)d_in[13];
  const float* Wo = (const float*)d_in[14];
  const float* bo = (const float*)d_in[15];
  const float* ln2_g = (const float*)d_in[16];
  const float* ln2_b = (const float*)d_in[17];
  const float* w1 = (const float*)d_in[18];
  const float* b1 = (const float*)d_in[19];
  const float* w2 = (const float*)d_in[20];
  const float* b2 = (const float*)d_in[21];
  const float* proj = (const float*)d_in[22];
  const float* caWq = (const float*)d_in[23];
  const float* caWk = (const float*)d_in[24];
  const float* caWv = (const float*)d_in[25];
  const float* caWo = (const float*)d_in[26];
  const float* cabo = (const float*)d_in[27];
  const float* crg = (const float*)d_in[28];
  const float* crb = (const float*)d_in[29];
  const float* fw1 = (const float*)d_in[30];
  const float* fb1 = (const float*)d_in[31];
  const float* fw2 = (const float*)d_in[32];
  const float* fb2 = (const float*)d_in[33];
  const float* og = (const float*)d_in[34];
  const float* ob = (const float*)d_in[35];
  const float* hW = (const float*)d_in[36];
  const float* hb = (const float*)d_in[37];

  // ---- workspace layout (f32 units, all offsets %16==0) ------------------
  float* X     = (float*)d_ws;          // [16384,512] f32
  float* DC    = X + 8388608;           // [8192,512] f32
  bf16*  Qh    = (bf16*)(DC + 4194304); // [16384,512] bf16
  bf16*  Kh    = Qh + 8388608;
  bf16*  Vh    = Kh + 8388608;
  bf16*  Vt    = Vh + 8388608;          // [64,64,2048] bf16
  bf16*  Pq    = Vt + 8388608;          // [64,2048,288] bf16
  bf16*  Pk    = Pq + 37748736;         // [64,288,2048] bf16
  float* part  = (float*)(Pk + 37748736);  // [64,4,288,64] f32
  bf16*  kvT   = (bf16*)(part + 4718592);  // [64,64,288] bf16
  float* ksumB = (float*)(kvT + 1179648);  // [64,288] f32
  float* diagQ = ksumB + 18432;            // [64,2048]
  float* diagK = diagQ + 131072;
  float* dinvB = diagK + 131072;
  float* bmax  = dinvB + 131072;           // [1024+1]
  bf16*  Yb    = (bf16*)(bmax + 1056);     // [16384,512] bf16
  bf16*  DCb   = Yb + 8388608;             // [8192,512] bf16
  bf16*  Wt    = DCb + 4194304;            // [2048,512] bf16 max
  bf16*  projB = Wt + 1048576;             // [288,64] bf16
  const size_t need_bytes = (size_t)79654992 * 4;
  if (ws_size < need_bytes) return;

  // P-region overlays (phase 0 + decoder)
  bf16* Pb   = Pq;
  bf16* encB = Pb;                   // [16384,1280] (phase 0)
  bf16* decB = Pk;                   // [8192,1280]  (phase 0)
  bf16* Pmid = Pb;                   // [16384,2048] (FF mid, layer loop)
  bf16* Xb   = Pb;                   // [16384,512]  (decoder)
  bf16* Qc   = Pb + 8388608;         // [8192,512]
  bf16* Kc   = Pb + 12582912;        // [16384,512]
  bf16* Vc   = Pb + 20971520;        // [16384,512]
  bf16* Fb   = Pb + 29360128;        // [8192,512]
  bf16* Pm2  = Pb + 33554432;        // [8192,2048]

  const dim3 blk(256);

  // ---- phase 0: embeddings ----------------------------------------------
  castf2b<<<2048, blk, 0, stream>>>(in_enc, encB, 16384 * 1280);
  castf2b<<<2048, blk, 0, stream>>>(in_dec, decB, 8192 * 1280);
  transpose_cast<<<dim3(16, 40), blk, 0, stream>>>(var_W, Wt, 1280, 512);
  gemm_mfma<0, 0, true, false><<<dim3(4, 128), blk, 0, stream>>>(encB, Wt, X, var_b, 16384, 512, 1280);
  gemm_mfma<0, 0, true, false><<<dim3(4, 64), blk, 0, stream>>>(decB, Wt, DC, var_b, 8192, 512, 1280);
  embed_ln<<<4096, blk, 0, stream>>>(X, expr, enc_g, enc_b);
  ln_rows<false, true, true><<<2048, blk, 0, stream>>>(DC, nullptr, dec_g, dec_b, DC, DCb);

  // ---- encoder layers ----------------------------------------------------
  for (int i = 0; i < cDEPTH; i++) {
    ln_rows<false, false, true><<<4096, blk, 0, stream>>>(X, nullptr, ln1_g + i * cD, ln1_b + i * cD, nullptr, Yb);
    transpose_cast<<<dim3(16, 16), blk, 0, stream>>>(Wq + (size_t)i * cD * cD, Wt, 512, 512);
    gemm_mfma<1, 0, false, false><<<dim3(4, 128), blk, 0, stream>>>(Yb, Wt, Qh, nullptr, 16384, 512, 512);
    transpose_cast<<<dim3(16, 16), blk, 0, stream>>>(Wk + (size_t)i * cD * cD, Wt, 512, 512);
    gemm_mfma<1, 0, false, false><<<dim3(4, 128), blk, 0, stream>>>(Yb, Wt, Kh, nullptr, 16384, 512, 512);
    transpose_cast<<<dim3(16, 16), blk, 0, stream>>>(Wv + (size_t)i * cD * cD, Wt, 512, 512);
    gemm_mfma<1, 0, false, false><<<dim3(4, 128), blk, 0, stream>>>(Yb, Wt, Vh, nullptr, 16384, 512, 512);
    // FAVOR+ (bf16 MFMA)
    proj_cast<<<72, blk, 0, stream>>>(proj + (size_t)i * cM * cDH, projB);
    diag_kernel<<<512, blk, 0, stream>>>(Qh, Kh, diagQ, diagK);
    vtrans<<<dim3(32, 64), blk, 0, stream>>>(Vh, Vt);
    favor_phi<1><<<dim3(16, 64), blk, 0, stream>>>(Kh, projB, nullptr, nullptr, nullptr, bmax);
    redmax_final<<<1, blk, 0, stream>>>(bmax, bmax + 1024);
    favor_phi<2><<<dim3(16, 64), blk, 0, stream>>>(Kh, projB, diagK, bmax + 1024, Pk, nullptr);
    favor_phi<0><<<dim3(16, 64), blk, 0, stream>>>(Qh, projB, diagQ, nullptr, Pq, nullptr);
    ksum_rows<<<4608, blk, 0, stream>>>(Pk, ksumB);
    dinv2<<<32768, blk, 0, stream>>>(Pq, ksumB, dinvB);
    favor_kv<<<dim3(4, 64), blk, 0, stream>>>(Pk, Vt, part);
    kv_reduce<<<64, blk, 0, stream>>>(part, kvT);
    favor_out<<<dim3(16, 64), blk, 0, stream>>>(Pq, kvT, dinvB, Yb);
    // Wo + residual
    transpose_cast<<<dim3(16, 16), blk, 0, stream>>>(Wo + (size_t)i * cD * cD, Wt, 512, 512);
    gemm_mfma<0, 0, true, true><<<dim3(4, 128), blk, 0, stream>>>(Yb, Wt, X, bo + i * cD, 16384, 512, 512);
    // FF
    ln_rows<false, false, true><<<4096, blk, 0, stream>>>(X, nullptr, ln2_g + i * cD, ln2_b + i * cD, nullptr, Yb);
    transpose_cast<<<dim3(64, 16), blk, 0, stream>>>(w1 + (size_t)i * cD * cFF, Wt, 512, 2048);
    gemm_mfma<1, 1, true, false><<<dim3(16, 128), blk, 0, stream>>>(Yb, Wt, Pmid, b1 + i * cFF, 16384, 2048, 512);
    transpose_cast<<<dim3(16, 64), blk, 0, stream>>>(w2 + (size_t)i * cFF * cD, Wt, 2048, 512);
    gemm_mfma<0, 0, true, true><<<dim3(4, 128), blk, 0, stream>>>(Pmid, Wt, X, b2 + i * cD, 16384, 512, 2048);
  }

  // ---- decoder / cross-attention ----------------------------------------
  castf2b<<<2048, blk, 0, stream>>>(X, Xb, 16384 * 512);
  transpose_cast<<<dim3(16, 16), blk, 0, stream>>>(caWq, Wt, 512, 512);
  gemm_mfma<1, 0, false, false><<<dim3(4, 64), blk, 0, stream>>>(DCb, Wt, Qc, nullptr, 8192, 512, 512);
  transpose_cast<<<dim3(16, 16), blk, 0, stream>>>(caWk, Wt, 512, 512);
  gemm_mfma<1, 0, false, false><<<dim3(4, 128), blk, 0, stream>>>(Xb, Wt, Kc, nullptr, 16384, 512, 512);
  transpose_cast<<<dim3(16, 16), blk, 0, stream>>>(caWv, Wt, 512, 512);
  gemm_mfma<1, 0, false, false><<<dim3(4, 128), blk, 0, stream>>>(Xb, Wt, Vc, nullptr, 16384, 512, 512);
  flash_mfma<<<dim3(16, 8, 8), blk, 0, stream>>>(Qc, Kc, Vc, Fb);
  transpose_cast<<<dim3(16, 16), blk, 0, stream>>>(caWo, Wt, 512, 512);
  gemm_mfma<0, 0, true, false><<<dim3(4, 64), blk, 0, stream>>>(Fb, Wt, X, cabo, 8192, 512, 512);
  ln_rows<true, false, true><<<2048, blk, 0, stream>>>(X, DC, crg, crb, nullptr, Yb);
  transpose_cast<<<dim3(64, 16), blk, 0, stream>>>(fw1, Wt, 512, 2048);
  gemm_mfma<1, 1, true, false><<<dim3(16, 64), blk, 0, stream>>>(Yb, Wt, Pm2, fb1, 8192, 2048, 512);
  transpose_cast<<<dim3(16, 64), blk, 0, stream>>>(fw2, Wt, 2048, 512);
  gemm_mfma<0, 0, true, false><<<dim3(4, 64), blk, 0, stream>>>(Pm2, Wt, X + 4194304, fb2, 8192, 512, 2048);
  ln_rows<false, false, true><<<2048, blk, 0, stream>>>(X + 4194304, nullptr, og, ob, nullptr, Yb);
  transpose_cast<<<dim3(4, 16), blk, 0, stream>>>(hW, Wt, 512, 128);
  gemm_mfma<0, 0, true, false><<<dim3(1, 64), blk, 0, stream>>>(Yb, Wt, (float*)d_out, hb, 8192, 128, 512);
}

// Round 4
// 2579.946 us; speedup vs baseline: 5.1378x; 1.0365x over previous
//
#include <hip/hip_runtime.h>
#include <hip/hip_bf16.h>
#include <math.h>

// Problem constants
constexpr int cB = 8, cSE = 2048, cSD = 1024, cIN = 1280, cD = 512,
              cDEPTH = 4, cH = 8, cDH = 64, cM = 266, cFF = 2048, cNB = 128;
constexpr int cMP = 288;  // cM padded to multiple of 16 (features pad -> 0)

#define DEV __device__ __forceinline__

typedef __bf16 bf16;
typedef __attribute__((ext_vector_type(8))) __bf16 bf16x8;
typedef __attribute__((ext_vector_type(4))) __bf16 bf16x4;
typedef __attribute__((ext_vector_type(2))) __bf16 bf16x2;
typedef __attribute__((ext_vector_type(4))) float f32x4;

DEV float gelu_f(float x) { return 0.5f * x * (1.0f + erff(x * 0.70710678118654752440f)); }

DEV float wave_sum(float v) {
#pragma unroll
  for (int o = 32; o; o >>= 1) v += __shfl_xor(v, o);
  return v;
}
DEV float wave_max(float v) {
#pragma unroll
  for (int o = 32; o; o >>= 1) v = fmaxf(v, __shfl_xor(v, o));
  return v;
}

#define GL2LDS(gp, lp) __builtin_amdgcn_global_load_lds(                    \
    (const __attribute__((address_space(1))) void*)(gp),                    \
    (__attribute__((address_space(3))) void*)(lp), 16, 0, 0)

// ---------------------------------------------------------------------------
// bf16 MFMA GEMM (m97 structure): C[M,N] = epi(A[M,K] @ Bt[N,K]^T).
// M%128==0, N%128==0, K%32==0. OUT: 0=f32 C, 1=bf16 C. ACT 1 = exact GELU.
// ---------------------------------------------------------------------------
template <int OUT, int ACT, bool BIAS, bool RES>
__global__ __launch_bounds__(256) void gemm_mfma(
    const bf16* __restrict__ A, const bf16* __restrict__ Bt,
    void* __restrict__ Cv, const float* __restrict__ bias,
    int M, int N, int K) {
  __shared__ bf16 As[128 * 32];
  __shared__ bf16 Bs[128 * 32];
  const int t = threadIdx.x, l = t & 63, w = t >> 6;
  const int g = l >> 4, c = l & 15;
  const int m0 = blockIdx.y * 128, n0 = blockIdx.x * 128;
  const int wr = (w >> 1) * 64, wc = (w & 1) * 64;
  const int srow = w * 32 + (l >> 2);
  const int scol = (l & 3) * 8;
  const bf16* gA = A + (size_t)(m0 + srow) * K + scol;
  const bf16* gB = Bt + (size_t)(n0 + srow) * K + scol;
  bf16* lA = As + w * 1024;
  bf16* lB = Bs + w * 1024;

  const f32x4 zero4 = {0.f, 0.f, 0.f, 0.f};
  f32x4 acc[4][4];
#pragma unroll
  for (int i = 0; i < 4; i++)
#pragma unroll
    for (int j = 0; j < 4; j++) acc[i][j] = zero4;

  for (int k0 = 0; k0 < K; k0 += 32) {
    GL2LDS(gA + k0, lA);
    GL2LDS(gA + (size_t)16 * K + k0, lA + 512);
    GL2LDS(gB + k0, lB);
    GL2LDS(gB + (size_t)16 * K + k0, lB + 512);
    __syncthreads();
    bf16x8 af[4], bfr[4];
#pragma unroll
    for (int i = 0; i < 4; i++)
      af[i] = *(const bf16x8*)(As + (wr + i * 16 + c) * 32 + g * 8);
#pragma unroll
    for (int j = 0; j < 4; j++)
      bfr[j] = *(const bf16x8*)(Bs + (wc + j * 16 + c) * 32 + g * 8);
#pragma unroll
    for (int i = 0; i < 4; i++)
#pragma unroll
      for (int j = 0; j < 4; j++)
        acc[i][j] = __builtin_amdgcn_mfma_f32_16x16x32_bf16(af[i], bfr[j], acc[i][j], 0, 0, 0);
    __syncthreads();
  }
  float* Cf = (float*)Cv;
  bf16* Cb = (bf16*)Cv;
#pragma unroll
  for (int i = 0; i < 4; i++) {
    const int mb = m0 + wr + i * 16 + g * 4;
#pragma unroll
    for (int j = 0; j < 4; j++) {
      const int n = n0 + wc + j * 16 + c;
      const float bv = BIAS ? bias[n] : 0.f;
#pragma unroll
      for (int r = 0; r < 4; r++) {
        float v = acc[i][j][r] + bv;
        if (ACT == 1) v = gelu_f(v);
        if (OUT == 0) {
          float* cp = Cf + (size_t)(mb + r) * N + n;
          if (RES) v += *cp;
          *cp = v;
        } else {
          Cb[(size_t)(mb + r) * N + n] = (bf16)v;
        }
      }
    }
  }
}

// ---------------------------------------------------------------------------
// transpose + cast: W[K,N] f32 -> Wt[N,K] bf16. 32x32 tiles.
// ---------------------------------------------------------------------------
__global__ __launch_bounds__(256) void transpose_cast(
    const float* __restrict__ W, bf16* __restrict__ Wt, int K, int N) {
  __shared__ float tile[32][33];
  const int tx = threadIdx.x & 31, ty = threadIdx.x >> 5;
  const int k0 = blockIdx.y * 32, n0 = blockIdx.x * 32;
#pragma unroll
  for (int i = ty; i < 32; i += 8) tile[i][tx] = W[(size_t)(k0 + i) * N + n0 + tx];
  __syncthreads();
#pragma unroll
  for (int i = ty; i < 32; i += 8)
    Wt[(size_t)(n0 + i) * K + k0 + tx] = (bf16)tile[tx][i];
}

// 4x 512x512 transposes in one launch; dst slice z*262144
__global__ __launch_bounds__(256) void transpose_cast4(
    const float* __restrict__ W0, const float* __restrict__ W1,
    const float* __restrict__ W2, const float* __restrict__ W3,
    bf16* __restrict__ Wt) {
  __shared__ float tile[32][33];
  const int zz = blockIdx.z;
  const float* W = zz == 0 ? W0 : zz == 1 ? W1 : zz == 2 ? W2 : W3;
  bf16* dst = Wt + (size_t)zz * 262144;
  const int tx = threadIdx.x & 31, ty = threadIdx.x >> 5;
  const int k0 = blockIdx.y * 32, n0 = blockIdx.x * 32;
#pragma unroll
  for (int i = ty; i < 32; i += 8) tile[i][tx] = W[(size_t)(k0 + i) * 512 + n0 + tx];
  __syncthreads();
#pragma unroll
  for (int i = ty; i < 32; i += 8)
    dst[(size_t)(n0 + i) * 512 + k0 + tx] = (bf16)tile[tx][i];
}

// flat f32 -> bf16 cast, n % 4 == 0
__global__ __launch_bounds__(256) void castf2b(
    const float* __restrict__ x, bf16* __restrict__ y, int n) {
  int i = (blockIdx.x * 256 + threadIdx.x) * 4;
  const int stride = gridDim.x * 1024;
  for (; i < n; i += stride) {
    float4 v = *(const float4*)(x + i);
    bf16x4 o;
    o[0] = (bf16)v.x; o[1] = (bf16)v.y; o[2] = (bf16)v.z; o[3] = (bf16)v.w;
    *(bf16x4*)(y + i) = o;
  }
}

// proj [266,64] f32 -> projB [288,64] bf16 with dn prescale, pad rows = 0
__global__ __launch_bounds__(256) void proj_cast(
    const float* __restrict__ proj, bf16* __restrict__ projB) {
  const int idx = blockIdx.x * 256 + threadIdx.x;
  if (idx >= cMP * cDH) return;
  const int m = idx >> 6;
  projB[idx] = (bf16)(m < cM ? proj[idx] * 0.35355339059327373f : 0.f);
}

// diag[z,s] = 0.5*||qk head slice||^2 * dn^2 for Q and K
__global__ __launch_bounds__(256) void diag_kernel(
    const bf16* __restrict__ Qh, const bf16* __restrict__ Kh,
    float* __restrict__ dQ, float* __restrict__ dK) {
  const int tid = blockIdx.x * 256 + threadIdx.x;  // (bs, h)
  const int h = tid & 7, bs = tid >> 3;
  const int b = bs >> 11, s = bs & 2047;
  const size_t base = (size_t)bs * cD + h * cDH;
  float sq = 0.f, sk = 0.f;
#pragma unroll
  for (int i = 0; i < 8; i++) {
    bf16x8 q8 = *(const bf16x8*)(Qh + base + i * 8);
    bf16x8 k8 = *(const bf16x8*)(Kh + base + i * 8);
#pragma unroll
    for (int e = 0; e < 8; e++) {
      const float qv = (float)q8[e], kv = (float)k8[e];
      sq += qv * qv; sk += kv * kv;
    }
  }
  const int z = b * 8 + h;
  dQ[(size_t)z * cSE + s] = sq * 0.0625f;  // 0.5 * dn^2
  dK[(size_t)z * cSE + s] = sk * 0.0625f;
}

// V head-transpose: Vh merged [16384,512] -> Vt [64 z][80 d][2048 s]
// rows 64 = ones (ksum fusion), 65..79 = zeros.
__global__ __launch_bounds__(256) void vtrans(
    const bf16* __restrict__ Vh, bf16* __restrict__ Vt) {
  __shared__ bf16 tile[64][65];
  const int z = blockIdx.y, b = z >> 3, h = z & 7;
  const int s0 = blockIdx.x * 64;
  const int t = threadIdx.x;
#pragma unroll
  for (int r = t >> 3; r < 64; r += 32) {
    bf16x8 v = *(const bf16x8*)(Vh + ((size_t)b * cSE + s0 + r) * cD + h * cDH + (t & 7) * 8);
#pragma unroll
    for (int e = 0; e < 8; e++) tile[(t & 7) * 8 + e][r] = v[e];
  }
  __syncthreads();
  bf16* vz = Vt + (size_t)z * 80 * cSE;
#pragma unroll
  for (int d = t >> 3; d < 64; d += 32) {
    bf16x8 o;
#pragma unroll
    for (int e = 0; e < 8; e++) o[e] = tile[d][(t & 7) * 8 + e];
    *(bf16x8*)(vz + (size_t)d * cSE + s0 + (t & 7) * 8) = o;
  }
  // ones / zeros rows 64..79
  const int rr = t >> 4, seg = (t & 15) * 4;
  bf16x4 ov;
  const float val = (rr == 0) ? 1.f : 0.f;
  ov[0] = (bf16)val; ov[1] = (bf16)val; ov[2] = (bf16)val; ov[3] = (bf16)val;
  *(bf16x4*)(vz + (size_t)(64 + rr) * cSE + s0 + seg) = ov;
}

// ---------------------------------------------------------------------------
// FAVOR feature kernel (MODE 0: Pq + row max; 1: block max; 2: Pk^T + gmax)
// ---------------------------------------------------------------------------
template <int MODE>
__global__ __launch_bounds__(256, 1) void favor_phi(
    const bf16* __restrict__ QK, const bf16* __restrict__ projB,
    const float* __restrict__ diag, const float* __restrict__ gmax,
    bf16* __restrict__ Pout, float* __restrict__ bmax) {
  __shared__ float rmaxs[4][64];
  __shared__ float sm[4];
  const int z = blockIdx.y, b = z >> 3, h = z & 7;
  const int s0 = blockIdx.x * 128;
  const int t = threadIdx.x, l = t & 63, w = t >> 6, g = l >> 4, c = l & 15;
  const int wr = (w >> 1) * 64, wcol = (w & 1) * 144;
  const f32x4 zero4 = {0.f, 0.f, 0.f, 0.f};
  f32x4 acc[4][9];
#pragma unroll
  for (int i = 0; i < 4; i++)
#pragma unroll
    for (int j = 0; j < 9; j++) acc[i][j] = zero4;
  const size_t abase = ((size_t)b * cSE + s0) * cD + h * cDH;
#pragma unroll
  for (int k0 = 0; k0 < 64; k0 += 32) {
    bf16x8 af[4];
#pragma unroll
    for (int i = 0; i < 4; i++)
      af[i] = *(const bf16x8*)(QK + abase + (size_t)(wr + i * 16 + c) * cD + k0 + g * 8);
#pragma unroll
    for (int j = 0; j < 9; j++) {
      bf16x8 bfr = *(const bf16x8*)(projB + (wcol + j * 16 + c) * 64 + k0 + g * 8);
#pragma unroll
      for (int i = 0; i < 4; i++)
        acc[i][j] = __builtin_amdgcn_mfma_f32_16x16x32_bf16(af[i], bfr, acc[i][j], 0, 0, 0);
    }
  }
  const float ratio = 0.061313927f;  // 266^-0.5

  if (MODE == 1) {
    float m = -3e38f;
#pragma unroll
    for (int i = 0; i < 4; i++)
#pragma unroll
      for (int j = 0; j < 9; j++) {
        const int mc = wcol + j * 16 + c;
        if (mc < cM) {
#pragma unroll
          for (int r = 0; r < 4; r++) m = fmaxf(m, acc[i][j][r]);
        }
      }
    m = wave_max(m);
    if (l == 0) sm[w] = m;
    __syncthreads();
    if (t == 0)
      bmax[blockIdx.y * 16 + blockIdx.x] =
          fmaxf(fmaxf(sm[0], sm[1]), fmaxf(sm[2], sm[3]));
    return;
  }

  float rowsub[4][4];  // diag + max per (i, r)
  if (MODE == 0) {
#pragma unroll
    for (int i = 0; i < 4; i++)
#pragma unroll
      for (int r = 0; r < 4; r++) {
        float m = -3e38f;
#pragma unroll
        for (int j = 0; j < 9; j++) {
          const int mc = wcol + j * 16 + c;
          m = (mc < cM) ? fmaxf(m, acc[i][j][r]) : m;
        }
        m = fmaxf(m, __shfl_xor(m, 1));
        m = fmaxf(m, __shfl_xor(m, 2));
        m = fmaxf(m, __shfl_xor(m, 4));
        m = fmaxf(m, __shfl_xor(m, 8));
        rowsub[i][r] = m;
      }
    if (c == 0) {
#pragma unroll
      for (int i = 0; i < 4; i++)
#pragma unroll
        for (int r = 0; r < 4; r++) rmaxs[w][i * 16 + g * 4 + r] = rowsub[i][r];
    }
    __syncthreads();
#pragma unroll
    for (int i = 0; i < 4; i++)
#pragma unroll
      for (int r = 0; r < 4; r++) {
        const int row = i * 16 + g * 4 + r;
        rowsub[i][r] = fmaxf(rowsub[i][r], rmaxs[w ^ 1][row]) +
                       diag[(size_t)z * cSE + s0 + wr + row];
      }
  } else {
    const float gm = *gmax;
#pragma unroll
    for (int i = 0; i < 4; i++)
#pragma unroll
      for (int r = 0; r < 4; r++)
        rowsub[i][r] = gm + diag[(size_t)z * cSE + s0 + wr + i * 16 + g * 4 + r];
  }

  if (MODE == 0) {
#pragma unroll
    for (int i = 0; i < 4; i++)
#pragma unroll
      for (int j = 0; j < 9; j++) {
        const int mc = wcol + j * 16 + c;
#pragma unroll
        for (int r = 0; r < 4; r++) {
          const float v = (mc < cM)
              ? ratio * (__expf(acc[i][j][r] - rowsub[i][r]) + 1e-4f) : 0.f;
          Pout[((size_t)z * cSE + s0 + wr + i * 16 + g * 4 + r) * cMP + mc] = (bf16)v;
        }
      }
  } else {
#pragma unroll
    for (int i = 0; i < 4; i++)
#pragma unroll
      for (int j = 0; j < 9; j++) {
        const int mc = wcol + j * 16 + c;
        bf16x4 o;
#pragma unroll
        for (int r = 0; r < 4; r++) {
          const float v = (mc < cM)
              ? ratio * (__expf(acc[i][j][r] - rowsub[i][r]) + 1e-4f) : 0.f;
          o[r] = (bf16)v;
        }
        *(bf16x4*)(Pout + ((size_t)z * cMP + mc) * cSE + s0 + wr + i * 16 + g * 4) = o;
      }
  }
}

// global max over bmax[1024] -> gm[0]
__global__ __launch_bounds__(256) void redmax_final(
    const float* __restrict__ part, float* __restrict__ gm) {
  float m = -1e30f;
  for (int i = threadIdx.x; i < 1024; i += 256) m = fmaxf(m, part[i]);
  m = wave_max(m);
  __shared__ float sm[4];
  if ((threadIdx.x & 63) == 0) sm[threadIdx.x >> 6] = m;
  __syncthreads();
  if (threadIdx.x == 0) gm[0] = fmaxf(fmaxf(sm[0], sm[1]), fmaxf(sm[2], sm[3]));
}

// ---------------------------------------------------------------------------
// kv partials: part[z,ch,m,d(80)] = sum_{s chunk} Pk[z,m,s] * Vt[z,d,s].
// d=64 column = ksum chunk (ones row of Vt). grid (4, 64).
// ---------------------------------------------------------------------------
__global__ __launch_bounds__(256) void favor_kv(
    const bf16* __restrict__ Pk, const bf16* __restrict__ Vt,
    float* __restrict__ part) {
  const int z = blockIdx.y, ch = blockIdx.x;
  const int t = threadIdx.x, l = t & 63, w = t >> 6, g = l >> 4, c = l & 15;
  const int wm = (w & 1) * 144, wd = (w >> 1) * 32;
  const bool dden = (wd == 32);
  const size_t pkz = (size_t)z * cMP * cSE, vtz = (size_t)z * 80 * cSE;
  const f32x4 zero4 = {0.f, 0.f, 0.f, 0.f};
  f32x4 acc[9][2], accx[9];
#pragma unroll
  for (int j = 0; j < 9; j++) {
    acc[j][0] = zero4; acc[j][1] = zero4; accx[j] = zero4;
  }
  for (int k0 = ch * 512; k0 < ch * 512 + 512; k0 += 32) {
    bf16x8 bv[2], bvx;
#pragma unroll
    for (int i = 0; i < 2; i++)
      bv[i] = *(const bf16x8*)(Vt + vtz + (size_t)(wd + i * 16 + c) * cSE + k0 + g * 8);
    if (dden)
      bvx = *(const bf16x8*)(Vt + vtz + (size_t)(64 + c) * cSE + k0 + g * 8);
#pragma unroll
    for (int j = 0; j < 9; j++) {
      bf16x8 am = *(const bf16x8*)(Pk + pkz + (size_t)(wm + j * 16 + c) * cSE + k0 + g * 8);
      acc[j][0] = __builtin_amdgcn_mfma_f32_16x16x32_bf16(am, bv[0], acc[j][0], 0, 0, 0);
      acc[j][1] = __builtin_amdgcn_mfma_f32_16x16x32_bf16(am, bv[1], acc[j][1], 0, 0, 0);
      if (dden)
        accx[j] = __builtin_amdgcn_mfma_f32_16x16x32_bf16(am, bvx, accx[j], 0, 0, 0);
    }
  }
  float* po = part + ((size_t)z * 4 + ch) * (cMP * 80);
#pragma unroll
  for (int j = 0; j < 9; j++)
#pragma unroll
    for (int i = 0; i < 2; i++)
#pragma unroll
      for (int r = 0; r < 4; r++)
        po[(size_t)(wm + j * 16 + g * 4 + r) * 80 + wd + i * 16 + c] = acc[j][i][r];
  if (dden) {
#pragma unroll
    for (int j = 0; j < 9; j++)
#pragma unroll
      for (int r = 0; r < 4; r++)
        po[(size_t)(wm + j * 16 + g * 4 + r) * 80 + 64 + c] = accx[j][r];
  }
}

// reduce 4 chunks + transpose: kvT[z,d(80),m]; row 64 = ksum
__global__ __launch_bounds__(256) void kv_reduce(
    const float* __restrict__ part, bf16* __restrict__ kvT) {
  const int z = blockIdx.x;
  const float* p = part + (size_t)z * 4 * (cMP * 80);
  bf16* o = kvT + (size_t)z * 80 * cMP;
  for (int idx = threadIdx.x; idx < cMP * 80; idx += 256) {
    const int m = idx / 80, d = idx - m * 80;
    const float s = p[idx] + p[idx + cMP * 80] + p[idx + 2 * cMP * 80] + p[idx + 3 * cMP * 80];
    o[(size_t)d * cMP + m] = (bf16)s;
  }
}

// ---------------------------------------------------------------------------
// out[z,s,d] = (1/den) * sum_m Pq[z,s,m] * kvT[z,d,m]; den from kvT ksum row.
// grid (16, 64); 4 waves 2x2: wave = 64 s x 32 d (+den tile on wd==32).
// ---------------------------------------------------------------------------
__global__ __launch_bounds__(256) void favor_out(
    const bf16* __restrict__ Pq, const bf16* __restrict__ kvT,
    bf16* __restrict__ Y) {
  __shared__ float denl[128];
  const int z = blockIdx.y, b = z >> 3, h = z & 7;
  const int s0 = blockIdx.x * 128;
  const int t = threadIdx.x, l = t & 63, w = t >> 6, g = l >> 4, c = l & 15;
  const int wr = (w >> 1) * 64, wd = (w & 1) * 32;
  const bool dden = (wd == 32);
  const f32x4 zero4 = {0.f, 0.f, 0.f, 0.f};
  f32x4 acc[4][2], accx[4];
#pragma unroll
  for (int i = 0; i < 4; i++) {
    acc[i][0] = zero4; acc[i][1] = zero4; accx[i] = zero4;
  }
  const size_t pqz = ((size_t)z * cSE + s0) * cMP;
  const size_t kz = (size_t)z * 80 * cMP;
#pragma unroll 3
  for (int k0 = 0; k0 < cMP; k0 += 32) {
    bf16x8 bv[2], bvx;
#pragma unroll
    for (int j = 0; j < 2; j++)
      bv[j] = *(const bf16x8*)(kvT + kz + (size_t)(wd + j * 16 + c) * cMP + k0 + g * 8);
    if (dden)
      bvx = *(const bf16x8*)(kvT + kz + (size_t)(64 + c) * cMP + k0 + g * 8);
#pragma unroll
    for (int i = 0; i < 4; i++) {
      bf16x8 av = *(const bf16x8*)(Pq + pqz + (size_t)(wr + i * 16 + c) * cMP + k0 + g * 8);
      acc[i][0] = __builtin_amdgcn_mfma_f32_16x16x32_bf16(av, bv[0], acc[i][0], 0, 0, 0);
      acc[i][1] = __builtin_amdgcn_mfma_f32_16x16x32_bf16(av, bv[1], acc[i][1], 0, 0, 0);
      if (dden)
        accx[i] = __builtin_amdgcn_mfma_f32_16x16x32_bf16(av, bvx, accx[i], 0, 0, 0);
    }
  }
  if (dden && c == 0) {
#pragma unroll
    for (int i = 0; i < 4; i++)
#pragma unroll
      for (int r = 0; r < 4; r++)
        denl[wr + i * 16 + g * 4 + r] = accx[i][r];
  }
  __syncthreads();
#pragma unroll
  for (int i = 0; i < 4; i++)
#pragma unroll
    for (int r = 0; r < 4; r++) {
      const int row = wr + i * 16 + g * 4 + r;
      const float inv = 1.0f / denl[row];
#pragma unroll
      for (int j = 0; j < 2; j++)
        Y[((size_t)b * cSE + s0 + row) * cD + h * cDH + wd + j * 16 + c] =
            (bf16)(acc[i][j][r] * inv);
    }
}

// ---------------------------------------------------------------------------
// LayerNorm rows of 512; wave per row. WF: f32 out, WB: bf16 out2.
// ---------------------------------------------------------------------------
template <bool ADD, bool WF, bool WB>
__global__ __launch_bounds__(256) void ln_rows(
    const float* __restrict__ in, const float* __restrict__ add,
    const float* __restrict__ g, const float* __restrict__ be,
    float* __restrict__ out, bf16* __restrict__ out2) {
  const int wid = blockIdx.x * 4 + (threadIdx.x >> 6);
  const int lane = threadIdx.x & 63;
  const float* ip = in + (size_t)wid * cD + lane * 8;
  float x[8];
  {
    float4 a = *(const float4*)ip;
    float4 b4 = *(const float4*)(ip + 4);
    x[0] = a.x; x[1] = a.y; x[2] = a.z; x[3] = a.w;
    x[4] = b4.x; x[5] = b4.y; x[6] = b4.z; x[7] = b4.w;
  }
  if (ADD) {
    const float* ap = add + (size_t)wid * cD + lane * 8;
    float4 a = *(const float4*)ap;
    float4 b4 = *(const float4*)(ap + 4);
    x[0] += a.x; x[1] += a.y; x[2] += a.z; x[3] += a.w;
    x[4] += b4.x; x[5] += b4.y; x[6] += b4.z; x[7] += b4.w;
  }
  float s = 0;
#pragma unroll
  for (int i = 0; i < 8; i++) s += x[i];
  s = wave_sum(s);
  const float mu = s * (1.0f / cD);
  float vs = 0;
#pragma unroll
  for (int i = 0; i < 8; i++) { const float d = x[i] - mu; vs += d * d; }
  vs = wave_sum(vs);
  const float rstd = 1.0f / sqrtf(vs * (1.0f / cD) + 1e-5f);
  float r[8];
#pragma unroll
  for (int i = 0; i < 8; i++) {
    const int d = lane * 8 + i;
    r[i] = (x[i] - mu) * rstd * g[d] + be[d];
  }
  if (WF) {
    float* op = out + (size_t)wid * cD + lane * 8;
    float4 a, b4;
    a.x = r[0]; a.y = r[1]; a.z = r[2]; a.w = r[3];
    b4.x = r[4]; b4.y = r[5]; b4.z = r[6]; b4.w = r[7];
    *(float4*)op = a; *(float4*)(op + 4) = b4;
  }
  if (WB) {
    bf16x8 ov;
#pragma unroll
    for (int i = 0; i < 8; i++) ov[i] = (bf16)r[i];
    *(bf16x8*)(out2 + (size_t)wid * cD + lane * 8) = ov;
  }
}

// LN of (enc + sinusoidal(expr)), in-place on f32 X.
__global__ __launch_bounds__(256) void embed_ln(
    float* __restrict__ X, const int* __restrict__ ids,
    const float* __restrict__ g, const float* __restrict__ be) {
  const int wid = blockIdx.x * 4 + (threadIdx.x >> 6);
  const int lane = threadIdx.x & 63;
  const float idv = (float)ids[wid];
  float* xp = X + (size_t)wid * cD + lane * 8;
  float x[8];
  {
    float4 a = *(const float4*)xp;
    float4 b4 = *(const float4*)(xp + 4);
    x[0] = a.x; x[1] = a.y; x[2] = a.z; x[3] = a.w;
    x[4] = b4.x; x[5] = b4.y; x[6] = b4.z; x[7] = b4.w;
  }
  const float kf = -0.03597789207803197f;  // -ln(10000)/256
#pragma unroll
  for (int i = 0; i < 8; i++) {
    const int d = lane * 8 + i;
    float e;
    if (d < 256) e = sinf(idv * expf(kf * (float)d));
    else         e = cosf(idv * expf(kf * (float)(d - 256)));
    x[i] += e;
  }
  float s = 0;
#pragma unroll
  for (int i = 0; i < 8; i++) s += x[i];
  s = wave_sum(s);
  const float mu = s * (1.0f / cD);
  float vs = 0;
#pragma unroll
  for (int i = 0; i < 8; i++) { const float d = x[i] - mu; vs += d * d; }
  vs = wave_sum(vs);
  const float rstd = 1.0f / sqrtf(vs * (1.0f / cD) + 1e-5f);
#pragma unroll
  for (int i = 0; i < 8; i++) {
    const int d = lane * 8 + i;
    xp[i] = (x[i] - mu) * rstd * g[d] + be[d];
  }
}

// ---------------------------------------------------------------------------
// bf16 MFMA flash cross-attention, KVBLK=64, denominator-via-ones-row,
// defer-max (THR=8), XCD-aware 1-D grid (1024 blocks).
// ---------------------------------------------------------------------------
__global__ __launch_bounds__(256) void flash_mfma(
    const bf16* __restrict__ Q, const bf16* __restrict__ Kc,
    const bf16* __restrict__ Vc, bf16* __restrict__ O) {
  __shared__ bf16 Ks[64 * 64];     // swizzled rows of 128B
  __shared__ bf16 Vs[80 * 72];     // [d][s] padded; row 64 = ones
  __shared__ bf16 Pl[4 * 16 * 72];
  const int id = blockIdx.x;
  const int b = (id & 63) >> 3, h = id & 7, qb = id >> 6;
  const int t = threadIdx.x, l = t & 63, w = t >> 6, g = l >> 4, c = l & 15;
  const int q0 = qb * 64 + w * 16;
  bf16x8 aq[2];
  {
    const bf16* qp = Q + ((size_t)b * cSD + q0 + c) * cD + h * cDH + g * 8;
    aq[0] = *(const bf16x8*)qp;
    aq[1] = *(const bf16x8*)(qp + 32);
  }
  // init ones/zero rows of Vs (rows 64..79)
  for (int idx = t; idx < 16 * 72; idx += 256) {
    const int rr = idx / 72, cc = idx - rr * 72;
    Vs[(64 + rr) * 72 + cc] = (bf16)(rr == 0 ? 1.f : 0.f);
  }
  const f32x4 zero4 = {0.f, 0.f, 0.f, 0.f};
  f32x4 o5[5];
#pragma unroll
  for (int j = 0; j < 5; j++) o5[j] = zero4;
  float mrow[4];
#pragma unroll
  for (int r = 0; r < 4; r++) mrow[r] = -1e30f;

  const int kr = t >> 2, kseg = t & 3;    // K staging: row, 32B segment
  const int s2 = t & 31, dseg = t >> 5;   // V staging: row pair, d segment
  const size_t kvbase = (size_t)b * cSE * cD + h * cDH;
  char* KsC = (char*)Ks;
  bf16* Pw = Pl + w * 16 * 72;

  for (int kt = 0; kt < cSE; kt += 64) {
    // stage K (XOR swizzled rows of 128B)
    {
      const bf16* kp = Kc + kvbase + (size_t)(kt + kr) * cD + kseg * 16;
      bf16x8 k0v = *(const bf16x8*)kp;
      bf16x8 k1v = *(const bf16x8*)(kp + 8);
      const int sw = (kr & 7) << 4;
      *(bf16x8*)(KsC + kr * 128 + ((kseg * 32) ^ sw)) = k0v;
      *(bf16x8*)(KsC + kr * 128 + ((kseg * 32 + 16) ^ sw)) = k1v;
    }
    // stage V transposed: pair rows -> bf16x2 writes
    {
      const bf16* vp = Vc + kvbase + (size_t)(kt + 2 * s2) * cD + dseg * 8;
      bf16x8 v0 = *(const bf16x8*)vp;
      bf16x8 v1 = *(const bf16x8*)(vp + cD);
#pragma unroll
      for (int e = 0; e < 8; e++) {
        bf16x2 pr; pr[0] = v0[e]; pr[1] = v1[e];
        *(bf16x2*)(Vs + (dseg * 8 + e) * 72 + 2 * s2) = pr;
      }
    }
    __syncthreads();
    // QK^T: 4 key tiles of 16
    f32x4 s4[4];
#pragma unroll
    for (int t2 = 0; t2 < 4; t2++) {
      const int kr2 = t2 * 16 + c;
      const int sw2 = (kr2 & 7) << 4;
      bf16x8 bk0 = *(const bf16x8*)(KsC + kr2 * 128 + ((g * 16) ^ sw2));
      bf16x8 bk1 = *(const bf16x8*)(KsC + kr2 * 128 + ((64 + g * 16) ^ sw2));
      f32x4 z = zero4;
      z = __builtin_amdgcn_mfma_f32_16x16x32_bf16(aq[0], bk0, z, 0, 0, 0);
      z = __builtin_amdgcn_mfma_f32_16x16x32_bf16(aq[1], bk1, z, 0, 0, 0);
      s4[t2] = z;
    }
    // softmax: defer-max; denominator comes from ones-row via PV MFMA
#pragma unroll
    for (int r = 0; r < 4; r++) {
      const float x0 = s4[0][r] * 0.125f, x1 = s4[1][r] * 0.125f;
      const float x2 = s4[2][r] * 0.125f, x3 = s4[3][r] * 0.125f;
      float tm = fmaxf(fmaxf(x0, x1), fmaxf(x2, x3));
      tm = fmaxf(tm, __shfl_xor(tm, 1));
      tm = fmaxf(tm, __shfl_xor(tm, 2));
      tm = fmaxf(tm, __shfl_xor(tm, 4));
      tm = fmaxf(tm, __shfl_xor(tm, 8));
      if (tm > mrow[r] + 8.f) {
        const float corr = __expf(mrow[r] - tm);
        mrow[r] = tm;
#pragma unroll
        for (int j = 0; j < 5; j++) o5[j][r] *= corr;
      }
      const float m = mrow[r];
      const int qr = g * 4 + r;
      Pw[qr * 72 + c]      = (bf16)__expf(x0 - m);
      Pw[qr * 72 + 16 + c] = (bf16)__expf(x1 - m);
      Pw[qr * 72 + 32 + c] = (bf16)__expf(x2 - m);
      Pw[qr * 72 + 48 + c] = (bf16)__expf(x3 - m);
    }
    // PV: A = P[16x64], B = Vs (5 d-tiles incl. denominator tile)
    bf16x8 pa0 = *(const bf16x8*)(Pw + c * 72 + g * 8);
    bf16x8 pa1 = *(const bf16x8*)(Pw + c * 72 + 32 + g * 8);
#pragma unroll
    for (int j = 0; j < 5; j++) {
      bf16x8 bv0 = *(const bf16x8*)(Vs + (j * 16 + c) * 72 + g * 8);
      bf16x8 bv1 = *(const bf16x8*)(Vs + (j * 16 + c) * 72 + 32 + g * 8);
      o5[j] = __builtin_amdgcn_mfma_f32_16x16x32_bf16(pa0, bv0, o5[j], 0, 0, 0);
      o5[j] = __builtin_amdgcn_mfma_f32_16x16x32_bf16(pa1, bv1, o5[j], 0, 0, 0);
    }
    __syncthreads();
  }
#pragma unroll
  for (int r = 0; r < 4; r++) {
    const float den = __shfl(o5[4][r], l & 48);
    const float inv = 1.0f / den;
    const size_t row = (size_t)b * cSD + q0 + g * 4 + r;
#pragma unroll
    for (int j = 0; j < 4; j++)
      O[row * cD + h * cDH + j * 16 + c] = (bf16)(o5[j][r] * inv);
  }
}

// ---------------------------------------------------------------------------
extern "C" void kernel_launch(void* const* d_in, const int* in_sizes, int n_in,
                              void* d_out, int out_size, void* d_ws, size_t ws_size,
                              hipStream_t stream) {
  const float* in_enc = (const float*)d_in[0];
  const float* in_dec = (const float*)d_in[1];
  const int* expr = (const int*)d_in[2];
  const float* var_W = (const float*)d_in[3];
  const float* var_b = (const float*)d_in[4];
  const float* enc_g = (const float*)d_in[5];
  const float* enc_b = (const float*)d_in[6];
  const float* dec_g = (const float*)d_in[7];
  const float* dec_b = (const float*)d_in[8];
  const float* ln1_g = (const float*)d_in[9];
  const float* ln1_b = (const float*)d_in[10];
  const float* Wq = (const float*)d_in[11];
  const float* Wk = (const float*)d_in[12];
  const float* Wv = (const float*)d_in[13];
  const float* Wo = (const float*)d_in[14];
  const float* bo = (const float*)d_in[15];
  const float* ln2_g = (const float*)d_in[16];
  const float* ln2_b = (const float*)d_in[17];
  const float* w1 = (const float*)d_in[18];
  const float* b1 = (const float*)d_in[19];
  const float* w2 = (const float*)d_in[20];
  const float* b2 = (const float*)d_in[21];
  const float* proj = (const float*)d_in[22];
  const float* caWq = (const float*)d_in[23];
  const float* caWk = (const float*)d_in[24];
  const float* caWv = (const float*)d_in[25];
  const float* caWo = (const float*)d_in[26];
  const float* cabo = (const float*)d_in[27];
  const float* crg = (const float*)d_in[28];
  const float* crb = (const float*)d_in[29];
  const float* fw1 = (const float*)d_in[30];
  const float* fb1 = (const float*)d_in[31];
  const float* fw2 = (const float*)d_in[32];
  const float* fb2 = (const float*)d_in[33];
  const float* og = (const float*)d_in[34];
  const float* ob = (const float*)d_in[35];
  const float* hW = (const float*)d_in[36];
  const float* hb = (const float*)d_in[37];

  // ---- workspace layout (f32 units, all offsets %4==0 -> 16B aligned) ----
  float* X     = (float*)d_ws;             // [16384,512] f32
  float* DC    = X + 8388608;              // [8192,512] f32
  bf16*  Qh    = (bf16*)(DC + 4194304);    // [16384,512] bf16
  bf16*  Kh    = Qh + 8388608;
  bf16*  Vh    = Kh + 8388608;
  bf16*  Vt    = Vh + 8388608;             // [64,80,2048] bf16
  bf16*  Pq    = Vt + 10485760;            // [64,2048,288] bf16
  bf16*  Pk    = Pq + 37748736;            // [64,288,2048] bf16
  float* part  = (float*)(Pk + 37748736);  // [64,4,288,80] f32
  bf16*  kvT   = (bf16*)(part + 5898240);  // [64,80,288] bf16
  float* diagQ = (float*)(kvT + 1474560);  // [64,2048]
  float* diagK = diagQ + 131072;
  float* bmax  = diagK + 131072;           // [1024+1]
  bf16*  Yb    = (bf16*)(bmax + 1056);     // [16384,512] bf16
  bf16*  DCb   = Yb + 8388608;             // [8192,512] bf16
  bf16*  Wt    = DCb + 4194304;            // [1048576] bf16 arena
  bf16*  projB = Wt + 1048576;             // [288,64] bf16
  const size_t need_bytes = (size_t)81881120 * 4;
  if (ws_size < need_bytes) return;

  // P-region overlays (phase 0 + decoder); Pq..Pk contiguous 75.5M bf16
  bf16* Pb   = Pq;
  bf16* encB = Pb;                   // [16384,1280] (phase 0)
  bf16* decB = Pk;                   // [8192,1280]  (phase 0)
  bf16* Pmid = Pb;                   // [16384,2048] (FF mid, layer loop)
  bf16* Xb   = Pb;                   // [16384,512]  (decoder)
  bf16* Qc   = Pb + 8388608;         // [8192,512]
  bf16* Kc   = Pb + 12582912;        // [16384,512]
  bf16* Vc   = Pb + 20971520;        // [16384,512]
  bf16* Fb   = Pb + 29360128;        // [8192,512]
  bf16* Pm2  = Pb + 33554432;        // [8192,2048]

  const dim3 blk(256);

  // ---- phase 0: embeddings ----------------------------------------------
  castf2b<<<2048, blk, 0, stream>>>(in_enc, encB, 16384 * 1280);
  castf2b<<<2048, blk, 0, stream>>>(in_dec, decB, 8192 * 1280);
  transpose_cast<<<dim3(16, 40), blk, 0, stream>>>(var_W, Wt, 1280, 512);
  gemm_mfma<0, 0, true, false><<<dim3(4, 128), blk, 0, stream>>>(encB, Wt, X, var_b, 16384, 512, 1280);
  gemm_mfma<0, 0, true, false><<<dim3(4, 64), blk, 0, stream>>>(decB, Wt, DC, var_b, 8192, 512, 1280);
  embed_ln<<<4096, blk, 0, stream>>>(X, expr, enc_g, enc_b);
  ln_rows<false, true, true><<<2048, blk, 0, stream>>>(DC, nullptr, dec_g, dec_b, DC, DCb);

  // ---- encoder layers ----------------------------------------------------
  for (int i = 0; i < cDEPTH; i++) {
    ln_rows<false, false, true><<<4096, blk, 0, stream>>>(X, nullptr, ln1_g + i * cD, ln1_b + i * cD, nullptr, Yb);
    transpose_cast4<<<dim3(16, 16, 4), blk, 0, stream>>>(
        Wq + (size_t)i * cD * cD, Wk + (size_t)i * cD * cD,
        Wv + (size_t)i * cD * cD, Wo + (size_t)i * cD * cD, Wt);
    gemm_mfma<1, 0, false, false><<<dim3(4, 128), blk, 0, stream>>>(Yb, Wt, Qh, nullptr, 16384, 512, 512);
    gemm_mfma<1, 0, false, false><<<dim3(4, 128), blk, 0, stream>>>(Yb, Wt + 262144, Kh, nullptr, 16384, 512, 512);
    gemm_mfma<1, 0, false, false><<<dim3(4, 128), blk, 0, stream>>>(Yb, Wt + 524288, Vh, nullptr, 16384, 512, 512);
    // FAVOR+ (bf16 MFMA, ksum/denominator fused via ones-row)
    proj_cast<<<72, blk, 0, stream>>>(proj + (size_t)i * cM * cDH, projB);
    diag_kernel<<<512, blk, 0, stream>>>(Qh, Kh, diagQ, diagK);
    vtrans<<<dim3(32, 64), blk, 0, stream>>>(Vh, Vt);
    favor_phi<1><<<dim3(16, 64), blk, 0, stream>>>(Kh, projB, nullptr, nullptr, nullptr, bmax);
    redmax_final<<<1, blk, 0, stream>>>(bmax, bmax + 1024);
    favor_phi<2><<<dim3(16, 64), blk, 0, stream>>>(Kh, projB, diagK, bmax + 1024, Pk, nullptr);
    favor_phi<0><<<dim3(16, 64), blk, 0, stream>>>(Qh, projB, diagQ, nullptr, Pq, nullptr);
    favor_kv<<<dim3(4, 64), blk, 0, stream>>>(Pk, Vt, part);
    kv_reduce<<<64, blk, 0, stream>>>(part, kvT);
    favor_out<<<dim3(16, 64), blk, 0, stream>>>(Pq, kvT, Yb);
    // Wo + residual
    gemm_mfma<0, 0, true, true><<<dim3(4, 128), blk, 0, stream>>>(Yb, Wt + 786432, X, bo + i * cD, 16384, 512, 512);
    // FF
    ln_rows<false, false, true><<<4096, blk, 0, stream>>>(X, nullptr, ln2_g + i * cD, ln2_b + i * cD, nullptr, Yb);
    transpose_cast<<<dim3(64, 16), blk, 0, stream>>>(w1 + (size_t)i * cD * cFF, Wt, 512, 2048);
    gemm_mfma<1, 1, true, false><<<dim3(16, 128), blk, 0, stream>>>(Yb, Wt, Pmid, b1 + i * cFF, 16384, 2048, 512);
    transpose_cast<<<dim3(16, 64), blk, 0, stream>>>(w2 + (size_t)i * cFF * cD, Wt, 2048, 512);
    gemm_mfma<0, 0, true, true><<<dim3(4, 128), blk, 0, stream>>>(Pmid, Wt, X, b2 + i * cD, 16384, 512, 2048);
  }

  // ---- decoder / cross-attention ----------------------------------------
  castf2b<<<2048, blk, 0, stream>>>(X, Xb, 16384 * 512);
  transpose_cast4<<<dim3(16, 16, 4), blk, 0, stream>>>(caWq, caWk, caWv, caWo, Wt);
  gemm_mfma<1, 0, false, false><<<dim3(4, 64), blk, 0, stream>>>(DCb, Wt, Qc, nullptr, 8192, 512, 512);
  gemm_mfma<1, 0, false, false><<<dim3(4, 128), blk, 0, stream>>>(Xb, Wt + 262144, Kc, nullptr, 16384, 512, 512);
  gemm_mfma<1, 0, false, false><<<dim3(4, 128), blk, 0, stream>>>(Xb, Wt + 524288, Vc, nullptr, 16384, 512, 512);
  flash_mfma<<<dim3(1024), blk, 0, stream>>>(Qc, Kc, Vc, Fb);
  gemm_mfma<0, 0, true, false><<<dim3(4, 64), blk, 0, stream>>>(Fb, Wt + 786432, X, cabo, 8192, 512, 512);
  ln_rows<true, false, true><<<2048, blk, 0, stream>>>(X, DC, crg, crb, nullptr, Yb);
  transpose_cast<<<dim3(64, 16), blk, 0, stream>>>(fw1, Wt, 512, 2048);
  gemm_mfma<1, 1, true, false><<<dim3(16, 64), blk, 0, stream>>>(Yb, Wt, Pm2, fb1, 8192, 2048, 512);
  transpose_cast<<<dim3(16, 64), blk, 0, stream>>>(fw2, Wt, 2048, 512);
  gemm_mfma<0, 0, true, false><<<dim3(4, 64), blk, 0, stream>>>(Pm2, Wt, X + 4194304, fb2, 8192, 512, 2048);
  ln_rows<false, false, true><<<2048, blk, 0, stream>>>(X + 4194304, nullptr, og, ob, nullptr, Yb);
  transpose_cast<<<dim3(4, 16), blk, 0, stream>>>(hW, Wt, 512, 128);
  gemm_mfma<0, 0, true, false><<<dim3(1, 64), blk, 0, stream>>>(Yb, Wt, (float*)d_out, hb, 8192, 128, 512);
}

// Round 5
// 2403.591 us; speedup vs baseline: 5.5147x; 1.0734x over previous
//
#include <hip/hip_runtime.h>
#include <hip/hip_bf16.h>
#include <math.h>

// Problem constants
constexpr int cB = 8, cSE = 2048, cSD = 1024, cIN = 1280, cD = 512,
              cDEPTH = 4, cH = 8, cDH = 64, cM = 266, cFF = 2048, cNB = 128;
constexpr int cMP = 288;  // cM padded to multiple of 16 (features pad -> 0)

#define DEV __device__ __forceinline__

typedef __bf16 bf16;
typedef __attribute__((ext_vector_type(8))) __bf16 bf16x8;
typedef __attribute__((ext_vector_type(4))) __bf16 bf16x4;
typedef __attribute__((ext_vector_type(2))) __bf16 bf16x2;
typedef __attribute__((ext_vector_type(4))) float f32x4;

DEV float gelu_f(float x) { return 0.5f * x * (1.0f + erff(x * 0.70710678118654752440f)); }

DEV float wave_sum(float v) {
#pragma unroll
  for (int o = 32; o; o >>= 1) v += __shfl_xor(v, o);
  return v;
}
DEV float wave_max(float v) {
#pragma unroll
  for (int o = 32; o; o >>= 1) v = fmaxf(v, __shfl_xor(v, o));
  return v;
}

#define GL2LDS(gp, lp) __builtin_amdgcn_global_load_lds(                    \
    (const __attribute__((address_space(1))) void*)(gp),                    \
    (__attribute__((address_space(3))) void*)(lp), 16, 0, 0)

// ---------------------------------------------------------------------------
// bf16 MFMA GEMM (m97 structure): C[M,N] = epi(A[M,K] @ Bt[N,K]^T).
// M%128==0, N%128==0, K%32==0. OUT: 0=f32 C, 1=bf16 C. ACT 1 = exact GELU.
// ---------------------------------------------------------------------------
template <int OUT, int ACT, bool BIAS, bool RES>
__global__ __launch_bounds__(256) void gemm_mfma(
    const bf16* __restrict__ A, const bf16* __restrict__ Bt,
    void* __restrict__ Cv, const float* __restrict__ bias,
    int M, int N, int K) {
  __shared__ bf16 As[128 * 32];
  __shared__ bf16 Bs[128 * 32];
  const int t = threadIdx.x, l = t & 63, w = t >> 6;
  const int g = l >> 4, c = l & 15;
  const int m0 = blockIdx.y * 128, n0 = blockIdx.x * 128;
  const int wr = (w >> 1) * 64, wc = (w & 1) * 64;
  const int srow = w * 32 + (l >> 2);
  const int scol = (l & 3) * 8;
  const bf16* gA = A + (size_t)(m0 + srow) * K + scol;
  const bf16* gB = Bt + (size_t)(n0 + srow) * K + scol;
  bf16* lA = As + w * 1024;
  bf16* lB = Bs + w * 1024;

  const f32x4 zero4 = {0.f, 0.f, 0.f, 0.f};
  f32x4 acc[4][4];
#pragma unroll
  for (int i = 0; i < 4; i++)
#pragma unroll
    for (int j = 0; j < 4; j++) acc[i][j] = zero4;

  for (int k0 = 0; k0 < K; k0 += 32) {
    GL2LDS(gA + k0, lA);
    GL2LDS(gA + (size_t)16 * K + k0, lA + 512);
    GL2LDS(gB + k0, lB);
    GL2LDS(gB + (size_t)16 * K + k0, lB + 512);
    __syncthreads();
    bf16x8 af[4], bfr[4];
#pragma unroll
    for (int i = 0; i < 4; i++)
      af[i] = *(const bf16x8*)(As + (wr + i * 16 + c) * 32 + g * 8);
#pragma unroll
    for (int j = 0; j < 4; j++)
      bfr[j] = *(const bf16x8*)(Bs + (wc + j * 16 + c) * 32 + g * 8);
#pragma unroll
    for (int i = 0; i < 4; i++)
#pragma unroll
      for (int j = 0; j < 4; j++)
        acc[i][j] = __builtin_amdgcn_mfma_f32_16x16x32_bf16(af[i], bfr[j], acc[i][j], 0, 0, 0);
    __syncthreads();
  }
  float* Cf = (float*)Cv;
  bf16* Cb = (bf16*)Cv;
#pragma unroll
  for (int i = 0; i < 4; i++) {
    const int mb = m0 + wr + i * 16 + g * 4;
#pragma unroll
    for (int j = 0; j < 4; j++) {
      const int n = n0 + wc + j * 16 + c;
      const float bv = BIAS ? bias[n] : 0.f;
#pragma unroll
      for (int r = 0; r < 4; r++) {
        float v = acc[i][j][r] + bv;
        if (ACT == 1) v = gelu_f(v);
        if (OUT == 0) {
          float* cp = Cf + (size_t)(mb + r) * N + n;
          if (RES) v += *cp;
          *cp = v;
        } else {
          Cb[(size_t)(mb + r) * N + n] = (bf16)v;
        }
      }
    }
  }
}

// ---------------------------------------------------------------------------
// transpose + cast: W[K,N] f32 -> Wt[N,K] bf16. 32x32 tiles.
// ---------------------------------------------------------------------------
__global__ __launch_bounds__(256) void transpose_cast(
    const float* __restrict__ W, bf16* __restrict__ Wt, int K, int N) {
  __shared__ float tile[32][33];
  const int tx = threadIdx.x & 31, ty = threadIdx.x >> 5;
  const int k0 = blockIdx.y * 32, n0 = blockIdx.x * 32;
#pragma unroll
  for (int i = ty; i < 32; i += 8) tile[i][tx] = W[(size_t)(k0 + i) * N + n0 + tx];
  __syncthreads();
#pragma unroll
  for (int i = ty; i < 32; i += 8)
    Wt[(size_t)(n0 + i) * K + k0 + tx] = (bf16)tile[tx][i];
}

// 4x 512x512 transposes in one launch; dst slice z*262144
__global__ __launch_bounds__(256) void transpose_cast4(
    const float* __restrict__ W0, const float* __restrict__ W1,
    const float* __restrict__ W2, const float* __restrict__ W3,
    bf16* __restrict__ Wt) {
  __shared__ float tile[32][33];
  const int zz = blockIdx.z;
  const float* W = zz == 0 ? W0 : zz == 1 ? W1 : zz == 2 ? W2 : W3;
  bf16* dst = Wt + (size_t)zz * 262144;
  const int tx = threadIdx.x & 31, ty = threadIdx.x >> 5;
  const int k0 = blockIdx.y * 32, n0 = blockIdx.x * 32;
#pragma unroll
  for (int i = ty; i < 32; i += 8) tile[i][tx] = W[(size_t)(k0 + i) * 512 + n0 + tx];
  __syncthreads();
#pragma unroll
  for (int i = ty; i < 32; i += 8)
    dst[(size_t)(n0 + i) * 512 + k0 + tx] = (bf16)tile[tx][i];
}

// flat f32 -> bf16 cast, n % 4 == 0
__global__ __launch_bounds__(256) void castf2b(
    const float* __restrict__ x, bf16* __restrict__ y, int n) {
  int i = (blockIdx.x * 256 + threadIdx.x) * 4;
  const int stride = gridDim.x * 1024;
  for (; i < n; i += stride) {
    float4 v = *(const float4*)(x + i);
    bf16x4 o;
    o[0] = (bf16)v.x; o[1] = (bf16)v.y; o[2] = (bf16)v.z; o[3] = (bf16)v.w;
    *(bf16x4*)(y + i) = o;
  }
}

// proj [266,64] f32 -> projB [288,64] bf16 with dn prescale, pad rows = 0
__global__ __launch_bounds__(256) void proj_cast(
    const float* __restrict__ proj, bf16* __restrict__ projB) {
  const int idx = blockIdx.x * 256 + threadIdx.x;
  if (idx >= cMP * cDH) return;
  const int m = idx >> 6;
  projB[idx] = (bf16)(m < cM ? proj[idx] * 0.35355339059327373f : 0.f);
}

// V head-transpose: Vh merged [16384,512] -> Vt [64 z][80 d][2048 s]
// rows 64 = ones (ksum fusion), 65..79 = zeros.
__global__ __launch_bounds__(256) void vtrans(
    const bf16* __restrict__ Vh, bf16* __restrict__ Vt) {
  __shared__ bf16 tile[64][65];
  const int z = blockIdx.y, b = z >> 3, h = z & 7;
  const int s0 = blockIdx.x * 64;
  const int t = threadIdx.x;
#pragma unroll
  for (int r = t >> 3; r < 64; r += 32) {
    bf16x8 v = *(const bf16x8*)(Vh + ((size_t)b * cSE + s0 + r) * cD + h * cDH + (t & 7) * 8);
#pragma unroll
    for (int e = 0; e < 8; e++) tile[(t & 7) * 8 + e][r] = v[e];
  }
  __syncthreads();
  bf16* vz = Vt + (size_t)z * 80 * cSE;
#pragma unroll
  for (int d = t >> 3; d < 64; d += 32) {
    bf16x8 o;
#pragma unroll
    for (int e = 0; e < 8; e++) o[e] = tile[d][(t & 7) * 8 + e];
    *(bf16x8*)(vz + (size_t)d * cSE + s0 + (t & 7) * 8) = o;
  }
  // ones / zeros rows 64..79
  const int rr = t >> 4, seg = (t & 15) * 4;
  bf16x4 ov;
  const float val = (rr == 0) ? 1.f : 0.f;
  ov[0] = (bf16)val; ov[1] = (bf16)val; ov[2] = (bf16)val; ov[3] = (bf16)val;
  *(bf16x4*)(vz + (size_t)(64 + rr) * cSE + s0 + seg) = ov;
}

// ---------------------------------------------------------------------------
// FAVOR k-feature kernel. MODE 1: block max of kd -> bmax (no diag).
// MODE 2: kp = ratio*(exp(kd - diag - gmax)+eps) -> Pk TRANSPOSED [z,288,2048].
// diag computed inline from the K fragments (no separate pass).
// ---------------------------------------------------------------------------
template <int MODE>
__global__ __launch_bounds__(256, 1) void favor_phik(
    const bf16* __restrict__ Kh, const bf16* __restrict__ projB,
    const float* __restrict__ gmax, bf16* __restrict__ Pout,
    float* __restrict__ bmax) {
  __shared__ float sm[4];
  const int z = blockIdx.y, b = z >> 3, h = z & 7;
  const int s0 = blockIdx.x * 128;
  const int t = threadIdx.x, l = t & 63, w = t >> 6, g = l >> 4, c = l & 15;
  const int wr = (w >> 1) * 64, wcol = (w & 1) * 144;
  const f32x4 zero4 = {0.f, 0.f, 0.f, 0.f};
  f32x4 acc[4][9];
#pragma unroll
  for (int i = 0; i < 4; i++)
#pragma unroll
    for (int j = 0; j < 9; j++) acc[i][j] = zero4;
  float sq[4] = {0.f, 0.f, 0.f, 0.f};
  const size_t abase = ((size_t)b * cSE + s0) * cD + h * cDH;
#pragma unroll
  for (int k0 = 0; k0 < 64; k0 += 32) {
    bf16x8 af[4];
#pragma unroll
    for (int i = 0; i < 4; i++) {
      af[i] = *(const bf16x8*)(Kh + abase + (size_t)(wr + i * 16 + c) * cD + k0 + g * 8);
      if (MODE == 2) {
#pragma unroll
        for (int e = 0; e < 8; e++) {
          const float v = (float)af[i][e];
          sq[i] += v * v;
        }
      }
    }
#pragma unroll
    for (int j = 0; j < 9; j++) {
      bf16x8 bfr = *(const bf16x8*)(projB + (wcol + j * 16 + c) * 64 + k0 + g * 8);
#pragma unroll
      for (int i = 0; i < 4; i++)
        acc[i][j] = __builtin_amdgcn_mfma_f32_16x16x32_bf16(af[i], bfr, acc[i][j], 0, 0, 0);
    }
  }
  const float ratio = 0.061313927f;  // 266^-0.5

  if (MODE == 1) {
    float m = -3e38f;
#pragma unroll
    for (int i = 0; i < 4; i++)
#pragma unroll
      for (int j = 0; j < 9; j++) {
        const int mc = wcol + j * 16 + c;
        if (mc < cM) {
#pragma unroll
          for (int r = 0; r < 4; r++) m = fmaxf(m, acc[i][j][r]);
        }
      }
    m = wave_max(m);
    if (l == 0) sm[w] = m;
    __syncthreads();
    if (t == 0)
      bmax[blockIdx.y * 16 + blockIdx.x] =
          fmaxf(fmaxf(sm[0], sm[1]), fmaxf(sm[2], sm[3]));
    return;
  }

  // MODE 2: diag via in-register norms (lanes sharing c hold same after reduce)
#pragma unroll
  for (int i = 0; i < 4; i++) {
    sq[i] += __shfl_xor(sq[i], 16);
    sq[i] += __shfl_xor(sq[i], 32);
  }
  const float gm = *gmax;
  float rowsub[4][4];
#pragma unroll
  for (int i = 0; i < 4; i++)
#pragma unroll
    for (int r = 0; r < 4; r++)
      rowsub[i][r] = gm + 0.0625f * __shfl(sq[i], g * 4 + r);

#pragma unroll
  for (int i = 0; i < 4; i++)
#pragma unroll
    for (int j = 0; j < 9; j++) {
      const int mc = wcol + j * 16 + c;
      bf16x4 o;
#pragma unroll
      for (int r = 0; r < 4; r++) {
        const float v = (mc < cM)
            ? ratio * (__expf(acc[i][j][r] - rowsub[i][r]) + 1e-4f) : 0.f;
        o[r] = (bf16)v;
      }
      *(bf16x4*)(Pout + ((size_t)z * cMP + mc) * cSE + s0 + wr + i * 16 + g * 4) = o;
    }
}

// global max over bmax[1024] -> gm[0]
__global__ __launch_bounds__(256) void redmax_final(
    const float* __restrict__ part, float* __restrict__ gm) {
  float m = -1e30f;
  for (int i = threadIdx.x; i < 1024; i += 256) m = fmaxf(m, part[i]);
  m = wave_max(m);
  __shared__ float sm[4];
  if ((threadIdx.x & 63) == 0) sm[threadIdx.x >> 6] = m;
  __syncthreads();
  if (threadIdx.x == 0) gm[0] = fmaxf(fmaxf(sm[0], sm[1]), fmaxf(sm[2], sm[3]));
}

// ---------------------------------------------------------------------------
// kv partials: part[z,ch,m,d(80)] = sum_{s chunk} Pk[z,m,s] * Vt[z,d,s].
// d=64 column = ksum chunk (ones row of Vt). grid (4, 64).
// ---------------------------------------------------------------------------
__global__ __launch_bounds__(256) void favor_kv(
    const bf16* __restrict__ Pk, const bf16* __restrict__ Vt,
    float* __restrict__ part) {
  const int z = blockIdx.y, ch = blockIdx.x;
  const int t = threadIdx.x, l = t & 63, w = t >> 6, g = l >> 4, c = l & 15;
  const int wm = (w & 1) * 144, wd = (w >> 1) * 32;
  const bool dden = (wd == 32);
  const size_t pkz = (size_t)z * cMP * cSE, vtz = (size_t)z * 80 * cSE;
  const f32x4 zero4 = {0.f, 0.f, 0.f, 0.f};
  f32x4 acc[9][2], accx[9];
#pragma unroll
  for (int j = 0; j < 9; j++) {
    acc[j][0] = zero4; acc[j][1] = zero4; accx[j] = zero4;
  }
  for (int k0 = ch * 512; k0 < ch * 512 + 512; k0 += 32) {
    bf16x8 bv[2], bvx;
#pragma unroll
    for (int i = 0; i < 2; i++)
      bv[i] = *(const bf16x8*)(Vt + vtz + (size_t)(wd + i * 16 + c) * cSE + k0 + g * 8);
    if (dden)
      bvx = *(const bf16x8*)(Vt + vtz + (size_t)(64 + c) * cSE + k0 + g * 8);
#pragma unroll
    for (int j = 0; j < 9; j++) {
      bf16x8 am = *(const bf16x8*)(Pk + pkz + (size_t)(wm + j * 16 + c) * cSE + k0 + g * 8);
      acc[j][0] = __builtin_amdgcn_mfma_f32_16x16x32_bf16(am, bv[0], acc[j][0], 0, 0, 0);
      acc[j][1] = __builtin_amdgcn_mfma_f32_16x16x32_bf16(am, bv[1], acc[j][1], 0, 0, 0);
      if (dden)
        accx[j] = __builtin_amdgcn_mfma_f32_16x16x32_bf16(am, bvx, accx[j], 0, 0, 0);
    }
  }
  float* po = part + ((size_t)z * 4 + ch) * (cMP * 80);
#pragma unroll
  for (int j = 0; j < 9; j++)
#pragma unroll
    for (int i = 0; i < 2; i++)
#pragma unroll
      for (int r = 0; r < 4; r++)
        po[(size_t)(wm + j * 16 + g * 4 + r) * 80 + wd + i * 16 + c] = acc[j][i][r];
  if (dden) {
#pragma unroll
    for (int j = 0; j < 9; j++)
#pragma unroll
      for (int r = 0; r < 4; r++)
        po[(size_t)(wm + j * 16 + g * 4 + r) * 80 + 64 + c] = accx[j][r];
  }
}

// reduce 4 chunks + transpose: kvT[z,d(80),m]; row 64 = ksum
__global__ __launch_bounds__(256) void kv_reduce(
    const float* __restrict__ part, bf16* __restrict__ kvT) {
  const int z = blockIdx.x;
  const float* p = part + (size_t)z * 4 * (cMP * 80);
  bf16* o = kvT + (size_t)z * 80 * cMP;
  for (int idx = threadIdx.x; idx < cMP * 80; idx += 256) {
    const int m = idx / 80, d = idx - m * 80;
    const float s = p[idx] + p[idx + cMP * 80] + p[idx + 2 * cMP * 80] + p[idx + 3 * cMP * 80];
    o[(size_t)d * cMP + m] = (bf16)s;
  }
}

// ---------------------------------------------------------------------------
// Fused phi(q) + output: per 128-row tile of one (b,h):
//   qd = (Q*dn) @ projB^T (in regs) -> row max (cross-wave) + inline diag ->
//   qp bf16 staged in LDS [128][296] -> out = qp @ kvT^T (+den col) -> Y.
// grid (16, 64), 256 thr (4 waves, 2x2).
// ---------------------------------------------------------------------------
__global__ __launch_bounds__(256, 1) void favor_qout(
    const bf16* __restrict__ Qh, const bf16* __restrict__ projB,
    const bf16* __restrict__ kvT, bf16* __restrict__ Y) {
  __shared__ bf16 Plds[128 * 296];
  __shared__ float rmaxs[4][64];
  __shared__ float denl[128];
  const int z = blockIdx.y, b = z >> 3, h = z & 7;
  const int s0 = blockIdx.x * 128;
  const int t = threadIdx.x, l = t & 63, w = t >> 6, g = l >> 4, c = l & 15;
  const int wr = (w >> 1) * 64, wcol = (w & 1) * 144;
  const f32x4 zero4 = {0.f, 0.f, 0.f, 0.f};
  f32x4 acc[4][9];
#pragma unroll
  for (int i = 0; i < 4; i++)
#pragma unroll
    for (int j = 0; j < 9; j++) acc[i][j] = zero4;
  float sq[4] = {0.f, 0.f, 0.f, 0.f};
  const size_t abase = ((size_t)b * cSE + s0) * cD + h * cDH;
#pragma unroll
  for (int k0 = 0; k0 < 64; k0 += 32) {
    bf16x8 af[4];
#pragma unroll
    for (int i = 0; i < 4; i++) {
      af[i] = *(const bf16x8*)(Qh + abase + (size_t)(wr + i * 16 + c) * cD + k0 + g * 8);
#pragma unroll
      for (int e = 0; e < 8; e++) {
        const float v = (float)af[i][e];
        sq[i] += v * v;
      }
    }
#pragma unroll
    for (int j = 0; j < 9; j++) {
      bf16x8 bfr = *(const bf16x8*)(projB + (wcol + j * 16 + c) * 64 + k0 + g * 8);
#pragma unroll
      for (int i = 0; i < 4; i++)
        acc[i][j] = __builtin_amdgcn_mfma_f32_16x16x32_bf16(af[i], bfr, acc[i][j], 0, 0, 0);
    }
  }
#pragma unroll
  for (int i = 0; i < 4; i++) {
    sq[i] += __shfl_xor(sq[i], 16);
    sq[i] += __shfl_xor(sq[i], 32);
  }
  const float ratio = 0.061313927f;  // 266^-0.5
  // per-row max over m<cM (within wave, then cross-wave via rmaxs)
  float rowsub[4][4];
#pragma unroll
  for (int i = 0; i < 4; i++)
#pragma unroll
    for (int r = 0; r < 4; r++) {
      float m = -3e38f;
#pragma unroll
      for (int j = 0; j < 9; j++) {
        const int mc = wcol + j * 16 + c;
        m = (mc < cM) ? fmaxf(m, acc[i][j][r]) : m;
      }
      m = fmaxf(m, __shfl_xor(m, 1));
      m = fmaxf(m, __shfl_xor(m, 2));
      m = fmaxf(m, __shfl_xor(m, 4));
      m = fmaxf(m, __shfl_xor(m, 8));
      rowsub[i][r] = m;
    }
  if (c == 0) {
#pragma unroll
    for (int i = 0; i < 4; i++)
#pragma unroll
      for (int r = 0; r < 4; r++) rmaxs[w][i * 16 + g * 4 + r] = rowsub[i][r];
  }
  __syncthreads();
#pragma unroll
  for (int i = 0; i < 4; i++)
#pragma unroll
    for (int r = 0; r < 4; r++) {
      const int row = i * 16 + g * 4 + r;
      rowsub[i][r] = fmaxf(rowsub[i][r], rmaxs[w ^ 1][row]) +
                     0.0625f * __shfl(sq[i], g * 4 + r);
    }
  // write qp features to LDS (row stride 296 -> conflict-light)
#pragma unroll
  for (int i = 0; i < 4; i++)
#pragma unroll
    for (int j = 0; j < 9; j++) {
      const int mc = wcol + j * 16 + c;
#pragma unroll
      for (int r = 0; r < 4; r++) {
        const float v = (mc < cM)
            ? ratio * (__expf(acc[i][j][r] - rowsub[i][r]) + 1e-4f) : 0.f;
        Plds[(wr + i * 16 + g * 4 + r) * 296 + mc] = (bf16)v;
      }
    }
  __syncthreads();

  // ---- output phase: out = qp @ kvT^T, den from kvT ksum row ----
  const int wd = (w & 1) * 32;
  const bool dden = (wd == 32);
  f32x4 acc2[4][2], accx[4];
#pragma unroll
  for (int i = 0; i < 4; i++) {
    acc2[i][0] = zero4; acc2[i][1] = zero4; accx[i] = zero4;
  }
  const size_t kz = (size_t)z * 80 * cMP;
#pragma unroll 3
  for (int k0 = 0; k0 < cMP; k0 += 32) {
    bf16x8 bv[2], bvx;
#pragma unroll
    for (int j = 0; j < 2; j++)
      bv[j] = *(const bf16x8*)(kvT + kz + (size_t)(wd + j * 16 + c) * cMP + k0 + g * 8);
    if (dden)
      bvx = *(const bf16x8*)(kvT + kz + (size_t)(64 + c) * cMP + k0 + g * 8);
#pragma unroll
    for (int i = 0; i < 4; i++) {
      bf16x8 av = *(const bf16x8*)(Plds + (wr + i * 16 + c) * 296 + k0 + g * 8);
      acc2[i][0] = __builtin_amdgcn_mfma_f32_16x16x32_bf16(av, bv[0], acc2[i][0], 0, 0, 0);
      acc2[i][1] = __builtin_amdgcn_mfma_f32_16x16x32_bf16(av, bv[1], acc2[i][1], 0, 0, 0);
      if (dden)
        accx[i] = __builtin_amdgcn_mfma_f32_16x16x32_bf16(av, bvx, accx[i], 0, 0, 0);
    }
  }
  if (dden && c == 0) {
#pragma unroll
    for (int i = 0; i < 4; i++)
#pragma unroll
      for (int r = 0; r < 4; r++)
        denl[wr + i * 16 + g * 4 + r] = accx[i][r];
  }
  __syncthreads();
#pragma unroll
  for (int i = 0; i < 4; i++)
#pragma unroll
    for (int r = 0; r < 4; r++) {
      const int row = wr + i * 16 + g * 4 + r;
      const float inv = 1.0f / denl[row];
#pragma unroll
      for (int j = 0; j < 2; j++)
        Y[((size_t)b * cSE + s0 + row) * cD + h * cDH + wd + j * 16 + c] =
            (bf16)(acc2[i][j][r] * inv);
    }
}

// ---------------------------------------------------------------------------
// LayerNorm rows of 512; wave per row. WF: f32 out, WB: bf16 out2.
// ---------------------------------------------------------------------------
template <bool ADD, bool WF, bool WB>
__global__ __launch_bounds__(256) void ln_rows(
    const float* __restrict__ in, const float* __restrict__ add,
    const float* __restrict__ g, const float* __restrict__ be,
    float* __restrict__ out, bf16* __restrict__ out2) {
  const int wid = blockIdx.x * 4 + (threadIdx.x >> 6);
  const int lane = threadIdx.x & 63;
  const float* ip = in + (size_t)wid * cD + lane * 8;
  float x[8];
  {
    float4 a = *(const float4*)ip;
    float4 b4 = *(const float4*)(ip + 4);
    x[0] = a.x; x[1] = a.y; x[2] = a.z; x[3] = a.w;
    x[4] = b4.x; x[5] = b4.y; x[6] = b4.z; x[7] = b4.w;
  }
  if (ADD) {
    const float* ap = add + (size_t)wid * cD + lane * 8;
    float4 a = *(const float4*)ap;
    float4 b4 = *(const float4*)(ap + 4);
    x[0] += a.x; x[1] += a.y; x[2] += a.z; x[3] += a.w;
    x[4] += b4.x; x[5] += b4.y; x[6] += b4.z; x[7] += b4.w;
  }
  float s = 0;
#pragma unroll
  for (int i = 0; i < 8; i++) s += x[i];
  s = wave_sum(s);
  const float mu = s * (1.0f / cD);
  float vs = 0;
#pragma unroll
  for (int i = 0; i < 8; i++) { const float d = x[i] - mu; vs += d * d; }
  vs = wave_sum(vs);
  const float rstd = 1.0f / sqrtf(vs * (1.0f / cD) + 1e-5f);
  float r[8];
#pragma unroll
  for (int i = 0; i < 8; i++) {
    const int d = lane * 8 + i;
    r[i] = (x[i] - mu) * rstd * g[d] + be[d];
  }
  if (WF) {
    float* op = out + (size_t)wid * cD + lane * 8;
    float4 a, b4;
    a.x = r[0]; a.y = r[1]; a.z = r[2]; a.w = r[3];
    b4.x = r[4]; b4.y = r[5]; b4.z = r[6]; b4.w = r[7];
    *(float4*)op = a; *(float4*)(op + 4) = b4;
  }
  if (WB) {
    bf16x8 ov;
#pragma unroll
    for (int i = 0; i < 8; i++) ov[i] = (bf16)r[i];
    *(bf16x8*)(out2 + (size_t)wid * cD + lane * 8) = ov;
  }
}

// LN of (enc + sinusoidal(expr)), in-place on f32 X.
__global__ __launch_bounds__(256) void embed_ln(
    float* __restrict__ X, const int* __restrict__ ids,
    const float* __restrict__ g, const float* __restrict__ be) {
  const int wid = blockIdx.x * 4 + (threadIdx.x >> 6);
  const int lane = threadIdx.x & 63;
  const float idv = (float)ids[wid];
  float* xp = X + (size_t)wid * cD + lane * 8;
  float x[8];
  {
    float4 a = *(const float4*)xp;
    float4 b4 = *(const float4*)(xp + 4);
    x[0] = a.x; x[1] = a.y; x[2] = a.z; x[3] = a.w;
    x[4] = b4.x; x[5] = b4.y; x[6] = b4.z; x[7] = b4.w;
  }
  const float kf = -0.03597789207803197f;  // -ln(10000)/256
#pragma unroll
  for (int i = 0; i < 8; i++) {
    const int d = lane * 8 + i;
    float e;
    if (d < 256) e = sinf(idv * expf(kf * (float)d));
    else         e = cosf(idv * expf(kf * (float)(d - 256)));
    x[i] += e;
  }
  float s = 0;
#pragma unroll
  for (int i = 0; i < 8; i++) s += x[i];
  s = wave_sum(s);
  const float mu = s * (1.0f / cD);
  float vs = 0;
#pragma unroll
  for (int i = 0; i < 8; i++) { const float d = x[i] - mu; vs += d * d; }
  vs = wave_sum(vs);
  const float rstd = 1.0f / sqrtf(vs * (1.0f / cD) + 1e-5f);
#pragma unroll
  for (int i = 0; i < 8; i++) {
    const int d = lane * 8 + i;
    xp[i] = (x[i] - mu) * rstd * g[d] + be[d];
  }
}

// ---------------------------------------------------------------------------
// bf16 MFMA flash cross-attention, KVBLK=64, denominator-via-ones-row,
// defer-max (base-2, THR=8 nats), async reg-prefetch staging (T14),
// XCD-aware 1-D grid (1024 blocks).
// ---------------------------------------------------------------------------
__global__ __launch_bounds__(256) void flash_mfma(
    const bf16* __restrict__ Q, const bf16* __restrict__ Kc,
    const bf16* __restrict__ Vc, bf16* __restrict__ O) {
  __shared__ bf16 Ks[64 * 64];     // swizzled rows of 128B
  __shared__ bf16 Vs[80 * 72];     // [d][s] padded; row 64 = ones
  __shared__ bf16 Pl[4 * 16 * 72];
  const int id = blockIdx.x;
  const int b = (id & 63) >> 3, h = id & 7, qb = id >> 6;
  const int t = threadIdx.x, l = t & 63, w = t >> 6, g = l >> 4, c = l & 15;
  const int q0 = qb * 64 + w * 16;
  bf16x8 aq[2];
  {
    const bf16* qp = Q + ((size_t)b * cSD + q0 + c) * cD + h * cDH + g * 8;
    aq[0] = *(const bf16x8*)qp;
    aq[1] = *(const bf16x8*)(qp + 32);
  }
  // init ones/zero rows of Vs (rows 64..79)
  for (int idx = t; idx < 16 * 72; idx += 256) {
    const int rr = idx / 72, cc = idx - rr * 72;
    Vs[(64 + rr) * 72 + cc] = (bf16)(rr == 0 ? 1.f : 0.f);
  }
  const f32x4 zero4 = {0.f, 0.f, 0.f, 0.f};
  f32x4 o5[5];
#pragma unroll
  for (int j = 0; j < 5; j++) o5[j] = zero4;
  float mrow[4];
#pragma unroll
  for (int r = 0; r < 4; r++) mrow[r] = -1e30f;

  const int kr = t >> 2, kseg = t & 3;    // K staging: row, 32B segment
  const int s2 = t & 31, dseg = t >> 5;   // V staging: row pair, d segment
  const size_t kvbase = (size_t)b * cSE * cD + h * cDH;
  char* KsC = (char*)Ks;
  bf16* Pw = Pl + w * 16 * 72;
  const float S2 = 0.18033688011112042f;  // 0.125 * log2(e)
  const float T2 = 11.541560327111708f;   // 8 * log2(e)

  bf16x8 pk0, pk1, pv0, pv1;  // prefetch registers
  auto LOADR = [&](int kt) {
    const bf16* kp = Kc + kvbase + (size_t)(kt + kr) * cD + kseg * 16;
    pk0 = *(const bf16x8*)kp;
    pk1 = *(const bf16x8*)(kp + 8);
    const bf16* vp = Vc + kvbase + (size_t)(kt + 2 * s2) * cD + dseg * 8;
    pv0 = *(const bf16x8*)vp;
    pv1 = *(const bf16x8*)(vp + cD);
  };
  auto WRITEL = [&]() {
    const int sw = (kr & 7) << 4;
    *(bf16x8*)(KsC + kr * 128 + ((kseg * 32) ^ sw)) = pk0;
    *(bf16x8*)(KsC + kr * 128 + ((kseg * 32 + 16) ^ sw)) = pk1;
#pragma unroll
    for (int e = 0; e < 8; e++) {
      bf16x2 pr; pr[0] = pv0[e]; pr[1] = pv1[e];
      *(bf16x2*)(Vs + (dseg * 8 + e) * 72 + 2 * s2) = pr;
    }
  };
  LOADR(0);
  WRITEL();

  for (int kt = 0; kt < cSE; kt += 64) {
    const bool more = (kt + 64 < cSE);
    if (more) LOADR(kt + 64);     // issue next-tile loads early (T14)
    __syncthreads();              // current tile LDS visible
    // QK^T: 4 key tiles of 16
    f32x4 s4[4];
#pragma unroll
    for (int t2 = 0; t2 < 4; t2++) {
      const int kr2 = t2 * 16 + c;
      const int sw2 = (kr2 & 7) << 4;
      bf16x8 bk0 = *(const bf16x8*)(KsC + kr2 * 128 + ((g * 16) ^ sw2));
      bf16x8 bk1 = *(const bf16x8*)(KsC + kr2 * 128 + ((64 + g * 16) ^ sw2));
      f32x4 z = zero4;
      z = __builtin_amdgcn_mfma_f32_16x16x32_bf16(aq[0], bk0, z, 0, 0, 0);
      z = __builtin_amdgcn_mfma_f32_16x16x32_bf16(aq[1], bk1, z, 0, 0, 0);
      s4[t2] = z;
    }
    // softmax in base-2; defer-max; den via ones-row of Vs
#pragma unroll
    for (int r = 0; r < 4; r++) {
      const float x0 = s4[0][r] * S2, x1 = s4[1][r] * S2;
      const float x2 = s4[2][r] * S2, x3 = s4[3][r] * S2;
      float tm = fmaxf(fmaxf(x0, x1), fmaxf(x2, x3));
      tm = fmaxf(tm, __shfl_xor(tm, 1));
      tm = fmaxf(tm, __shfl_xor(tm, 2));
      tm = fmaxf(tm, __shfl_xor(tm, 4));
      tm = fmaxf(tm, __shfl_xor(tm, 8));
      if (tm > mrow[r] + T2) {
        const float corr = exp2f(mrow[r] - tm);
        mrow[r] = tm;
#pragma unroll
        for (int j = 0; j < 5; j++) o5[j][r] *= corr;
      }
      const float m = mrow[r];
      const int qr = g * 4 + r;
      Pw[qr * 72 + c]      = (bf16)exp2f(x0 - m);
      Pw[qr * 72 + 16 + c] = (bf16)exp2f(x1 - m);
      Pw[qr * 72 + 32 + c] = (bf16)exp2f(x2 - m);
      Pw[qr * 72 + 48 + c] = (bf16)exp2f(x3 - m);
    }
    // PV: A = P[16x64], B = Vs (5 d-tiles incl. denominator tile)
    bf16x8 pa0 = *(const bf16x8*)(Pw + c * 72 + g * 8);
    bf16x8 pa1 = *(const bf16x8*)(Pw + c * 72 + 32 + g * 8);
#pragma unroll
    for (int j = 0; j < 5; j++) {
      bf16x8 bv0 = *(const bf16x8*)(Vs + (j * 16 + c) * 72 + g * 8);
      bf16x8 bv1 = *(const bf16x8*)(Vs + (j * 16 + c) * 72 + 32 + g * 8);
      o5[j] = __builtin_amdgcn_mfma_f32_16x16x32_bf16(pa0, bv0, o5[j], 0, 0, 0);
      o5[j] = __builtin_amdgcn_mfma_f32_16x16x32_bf16(pa1, bv1, o5[j], 0, 0, 0);
    }
    __syncthreads();              // all waves done reading this tile
    if (more) WRITEL();           // overwrite LDS with next tile
  }
#pragma unroll
  for (int r = 0; r < 4; r++) {
    const float den = __shfl(o5[4][r], l & 48);
    const float inv = 1.0f / den;
    const size_t row = (size_t)b * cSD + q0 + g * 4 + r;
#pragma unroll
    for (int j = 0; j < 4; j++)
      O[row * cD + h * cDH + j * 16 + c] = (bf16)(o5[j][r] * inv);
  }
}

// ---------------------------------------------------------------------------
extern "C" void kernel_launch(void* const* d_in, const int* in_sizes, int n_in,
                              void* d_out, int out_size, void* d_ws, size_t ws_size,
                              hipStream_t stream) {
  const float* in_enc = (const float*)d_in[0];
  const float* in_dec = (const float*)d_in[1];
  const int* expr = (const int*)d_in[2];
  const float* var_W = (const float*)d_in[3];
  const float* var_b = (const float*)d_in[4];
  const float* enc_g = (const float*)d_in[5];
  const float* enc_b = (const float*)d_in[6];
  const float* dec_g = (const float*)d_in[7];
  const float* dec_b = (const float*)d_in[8];
  const float* ln1_g = (const float*)d_in[9];
  const float* ln1_b = (const float*)d_in[10];
  const float* Wq = (const float*)d_in[11];
  const float* Wk = (const float*)d_in[12];
  const float* Wv = (const float*)d_in[13];
  const float* Wo = (const float*)d_in[14];
  const float* bo = (const float*)d_in[15];
  const float* ln2_g = (const float*)d_in[16];
  const float* ln2_b = (const float*)d_in[17];
  const float* w1 = (const float*)d_in[18];
  const float* b1 = (const float*)d_in[19];
  const float* w2 = (const float*)d_in[20];
  const float* b2 = (const float*)d_in[21];
  const float* proj = (const float*)d_in[22];
  const float* caWq = (const float*)d_in[23];
  const float* caWk = (const float*)d_in[24];
  const float* caWv = (const float*)d_in[25];
  const float* caWo = (const float*)d_in[26];
  const float* cabo = (const float*)d_in[27];
  const float* crg = (const float*)d_in[28];
  const float* crb = (const float*)d_in[29];
  const float* fw1 = (const float*)d_in[30];
  const float* fb1 = (const float*)d_in[31];
  const float* fw2 = (const float*)d_in[32];
  const float* fb2 = (const float*)d_in[33];
  const float* og = (const float*)d_in[34];
  const float* ob = (const float*)d_in[35];
  const float* hW = (const float*)d_in[36];
  const float* hb = (const float*)d_in[37];

  // ---- workspace layout (f32 units, all offsets %4==0 -> 16B aligned) ----
  float* X     = (float*)d_ws;             // [16384,512] f32
  float* DC    = X + 8388608;              // [8192,512] f32
  bf16*  Qh    = (bf16*)(DC + 4194304);    // [16384,512] bf16
  bf16*  Kh    = Qh + 8388608;
  bf16*  Vh    = Kh + 8388608;
  bf16*  Vt    = Vh + 8388608;             // [64,80,2048] bf16
  bf16*  Pq    = Vt + 10485760;            // arena (FF mid / decoder overlays)
  bf16*  Pk    = Pq + 37748736;            // [64,288,2048] bf16
  float* part  = (float*)(Pk + 37748736);  // [64,4,288,80] f32
  bf16*  kvT   = (bf16*)(part + 5898240);  // [64,80,288] bf16
  float* diagQ = (float*)(kvT + 1474560);  // (unused, layout kept)
  float* diagK = diagQ + 131072;
  float* bmax  = diagK + 131072;           // [1024+1]
  bf16*  Yb    = (bf16*)(bmax + 1056);     // [16384,512] bf16
  bf16*  DCb   = Yb + 8388608;             // [8192,512] bf16
  bf16*  Wt    = DCb + 4194304;            // [1048576] bf16 arena
  bf16*  projB = Wt + 1048576;             // [288,64] bf16
  const size_t need_bytes = (size_t)81881120 * 4;
  if (ws_size < need_bytes) return;
  (void)diagQ; (void)diagK;

  // P-region overlays (phase 0 + decoder); Pq..Pk contiguous 75.5M bf16
  bf16* Pb   = Pq;
  bf16* encB = Pb;                   // [16384,1280] (phase 0)
  bf16* decB = Pk;                   // [8192,1280]  (phase 0)
  bf16* Pmid = Pb;                   // [16384,2048] (FF mid, layer loop)
  bf16* Xb   = Pb;                   // [16384,512]  (decoder)
  bf16* Qc   = Pb + 8388608;         // [8192,512]
  bf16* Kc   = Pb + 12582912;        // [16384,512]
  bf16* Vc   = Pb + 20971520;        // [16384,512]
  bf16* Fb   = Pb + 29360128;        // [8192,512]
  bf16* Pm2  = Pb + 33554432;        // [8192,2048]

  const dim3 blk(256);

  // ---- phase 0: embeddings ----------------------------------------------
  castf2b<<<2048, blk, 0, stream>>>(in_enc, encB, 16384 * 1280);
  castf2b<<<2048, blk, 0, stream>>>(in_dec, decB, 8192 * 1280);
  transpose_cast<<<dim3(16, 40), blk, 0, stream>>>(var_W, Wt, 1280, 512);
  gemm_mfma<0, 0, true, false><<<dim3(4, 128), blk, 0, stream>>>(encB, Wt, X, var_b, 16384, 512, 1280);
  gemm_mfma<0, 0, true, false><<<dim3(4, 64), blk, 0, stream>>>(decB, Wt, DC, var_b, 8192, 512, 1280);
  embed_ln<<<4096, blk, 0, stream>>>(X, expr, enc_g, enc_b);
  ln_rows<false, true, true><<<2048, blk, 0, stream>>>(DC, nullptr, dec_g, dec_b, DC, DCb);

  // ---- encoder layers ----------------------------------------------------
  for (int i = 0; i < cDEPTH; i++) {
    ln_rows<false, false, true><<<4096, blk, 0, stream>>>(X, nullptr, ln1_g + i * cD, ln1_b + i * cD, nullptr, Yb);
    transpose_cast4<<<dim3(16, 16, 4), blk, 0, stream>>>(
        Wq + (size_t)i * cD * cD, Wk + (size_t)i * cD * cD,
        Wv + (size_t)i * cD * cD, Wo + (size_t)i * cD * cD, Wt);
    gemm_mfma<1, 0, false, false><<<dim3(4, 128), blk, 0, stream>>>(Yb, Wt, Qh, nullptr, 16384, 512, 512);
    gemm_mfma<1, 0, false, false><<<dim3(4, 128), blk, 0, stream>>>(Yb, Wt + 262144, Kh, nullptr, 16384, 512, 512);
    gemm_mfma<1, 0, false, false><<<dim3(4, 128), blk, 0, stream>>>(Yb, Wt + 524288, Vh, nullptr, 16384, 512, 512);
    // FAVOR+ (bf16 MFMA, diag inline, Pq fused away)
    proj_cast<<<72, blk, 0, stream>>>(proj + (size_t)i * cM * cDH, projB);
    vtrans<<<dim3(32, 64), blk, 0, stream>>>(Vh, Vt);
    favor_phik<1><<<dim3(16, 64), blk, 0, stream>>>(Kh, projB, nullptr, nullptr, bmax);
    redmax_final<<<1, blk, 0, stream>>>(bmax, bmax + 1024);
    favor_phik<2><<<dim3(16, 64), blk, 0, stream>>>(Kh, projB, bmax + 1024, Pk, nullptr);
    favor_kv<<<dim3(4, 64), blk, 0, stream>>>(Pk, Vt, part);
    kv_reduce<<<64, blk, 0, stream>>>(part, kvT);
    favor_qout<<<dim3(16, 64), blk, 0, stream>>>(Qh, projB, kvT, Yb);
    // Wo + residual
    gemm_mfma<0, 0, true, true><<<dim3(4, 128), blk, 0, stream>>>(Yb, Wt + 786432, X, bo + i * cD, 16384, 512, 512);
    // FF
    ln_rows<false, false, true><<<4096, blk, 0, stream>>>(X, nullptr, ln2_g + i * cD, ln2_b + i * cD, nullptr, Yb);
    transpose_cast<<<dim3(64, 16), blk, 0, stream>>>(w1 + (size_t)i * cD * cFF, Wt, 512, 2048);
    gemm_mfma<1, 1, true, false><<<dim3(16, 128), blk, 0, stream>>>(Yb, Wt, Pmid, b1 + i * cFF, 16384, 2048, 512);
    transpose_cast<<<dim3(16, 64), blk, 0, stream>>>(w2 + (size_t)i * cFF * cD, Wt, 2048, 512);
    gemm_mfma<0, 0, true, true><<<dim3(4, 128), blk, 0, stream>>>(Pmid, Wt, X, b2 + i * cD, 16384, 512, 2048);
  }

  // ---- decoder / cross-attention ----------------------------------------
  castf2b<<<2048, blk, 0, stream>>>(X, Xb, 16384 * 512);
  transpose_cast4<<<dim3(16, 16, 4), blk, 0, stream>>>(caWq, caWk, caWv, caWo, Wt);
  gemm_mfma<1, 0, false, false><<<dim3(4, 64), blk, 0, stream>>>(DCb, Wt, Qc, nullptr, 8192, 512, 512);
  gemm_mfma<1, 0, false, false><<<dim3(4, 128), blk, 0, stream>>>(Xb, Wt + 262144, Kc, nullptr, 16384, 512, 512);
  gemm_mfma<1, 0, false, false><<<dim3(4, 128), blk, 0, stream>>>(Xb, Wt + 524288, Vc, nullptr, 16384, 512, 512);
  flash_mfma<<<dim3(1024), blk, 0, stream>>>(Qc, Kc, Vc, Fb);
  gemm_mfma<0, 0, true, false><<<dim3(4, 64), blk, 0, stream>>>(Fb, Wt + 786432, X, cabo, 8192, 512, 512);
  ln_rows<true, false, true><<<2048, blk, 0, stream>>>(X, DC, crg, crb, nullptr, Yb);
  transpose_cast<<<dim3(64, 16), blk, 0, stream>>>(fw1, Wt, 512, 2048);
  gemm_mfma<1, 1, true, false><<<dim3(16, 64), blk, 0, stream>>>(Yb, Wt, Pm2, fb1, 8192, 2048, 512);
  transpose_cast<<<dim3(16, 64), blk, 0, stream>>>(fw2, Wt, 2048, 512);
  gemm_mfma<0, 0, true, false><<<dim3(4, 64), blk, 0, stream>>>(Pm2, Wt, X + 4194304, fb2, 8192, 512, 2048);
  ln_rows<false, false, true><<<2048, blk, 0, stream>>>(X + 4194304, nullptr, og, ob, nullptr, Yb);
  transpose_cast<<<dim3(4, 16), blk, 0, stream>>>(hW, Wt, 512, 128);
  gemm_mfma<0, 0, true, false><<<dim3(1, 64), blk, 0, stream>>>(Yb, Wt, (float*)d_out, hb, 8192, 128, 512);
}

// Round 6
// 2303.578 us; speedup vs baseline: 5.7542x; 1.0434x over previous
//
#include <hip/hip_runtime.h>
#include <hip/hip_bf16.h>
#include <math.h>

// Problem constants
constexpr int cB = 8, cSE = 2048, cSD = 1024, cIN = 1280, cD = 512,
              cDEPTH = 4, cH = 8, cDH = 64, cM = 266, cFF = 2048, cNB = 128;
constexpr int cMP = 288;  // cM padded to multiple of 16 (features pad -> 0)

#define DEV __device__ __forceinline__

typedef __bf16 bf16;
typedef __attribute__((ext_vector_type(8))) __bf16 bf16x8;
typedef __attribute__((ext_vector_type(4))) __bf16 bf16x4;
typedef __attribute__((ext_vector_type(2))) __bf16 bf16x2;
typedef __attribute__((ext_vector_type(4))) float f32x4;

DEV float gelu_f(float x) { return 0.5f * x * (1.0f + erff(x * 0.70710678118654752440f)); }

DEV float wave_sum(float v) {
#pragma unroll
  for (int o = 32; o; o >>= 1) v += __shfl_xor(v, o);
  return v;
}
DEV float wave_max(float v) {
#pragma unroll
  for (int o = 32; o; o >>= 1) v = fmaxf(v, __shfl_xor(v, o));
  return v;
}

#define GL2LDS(gp, lp) __builtin_amdgcn_global_load_lds(                    \
    (const __attribute__((address_space(1))) void*)(gp),                    \
    (__attribute__((address_space(3))) void*)(lp), 16, 0, 0)

// ---------------------------------------------------------------------------
// bf16 MFMA GEMM (m97 structure) with XCD-aware bijective block swizzle.
// C[M,N] = epi(A[M,K] @ Bt[N,K]^T). M%128==0, N%128==0, K%32==0.
// OUT: 0=f32 C, 1=bf16 C. ACT 1 = exact GELU.
// ---------------------------------------------------------------------------
template <int OUT, int ACT, bool BIAS, bool RES>
__global__ __launch_bounds__(256) void gemm_mfma(
    const bf16* __restrict__ A, const bf16* __restrict__ Bt,
    void* __restrict__ Cv, const float* __restrict__ bias,
    int M, int N, int K) {
  __shared__ bf16 As[128 * 32];
  __shared__ bf16 Bs[128 * 32];
  const int t = threadIdx.x, l = t & 63, w = t >> 6;
  const int g = l >> 4, c = l & 15;
  // XCD swizzle: blocks on one XCD (id%8) take a contiguous panel chunk
  const int nwg = gridDim.x * gridDim.y;
  int id = blockIdx.y * gridDim.x + blockIdx.x;
  if ((nwg & 7) == 0) id = (id & 7) * (nwg >> 3) + (id >> 3);
  const int m0 = (id / gridDim.x) * 128, n0 = (id % gridDim.x) * 128;
  const int wr = (w >> 1) * 64, wc = (w & 1) * 64;
  const int srow = w * 32 + (l >> 2);
  const int scol = (l & 3) * 8;
  const bf16* gA = A + (size_t)(m0 + srow) * K + scol;
  const bf16* gB = Bt + (size_t)(n0 + srow) * K + scol;
  bf16* lA = As + w * 1024;
  bf16* lB = Bs + w * 1024;

  const f32x4 zero4 = {0.f, 0.f, 0.f, 0.f};
  f32x4 acc[4][4];
#pragma unroll
  for (int i = 0; i < 4; i++)
#pragma unroll
    for (int j = 0; j < 4; j++) acc[i][j] = zero4;

  for (int k0 = 0; k0 < K; k0 += 32) {
    GL2LDS(gA + k0, lA);
    GL2LDS(gA + (size_t)16 * K + k0, lA + 512);
    GL2LDS(gB + k0, lB);
    GL2LDS(gB + (size_t)16 * K + k0, lB + 512);
    __syncthreads();
    bf16x8 af[4], bfr[4];
#pragma unroll
    for (int i = 0; i < 4; i++)
      af[i] = *(const bf16x8*)(As + (wr + i * 16 + c) * 32 + g * 8);
#pragma unroll
    for (int j = 0; j < 4; j++)
      bfr[j] = *(const bf16x8*)(Bs + (wc + j * 16 + c) * 32 + g * 8);
#pragma unroll
    for (int i = 0; i < 4; i++)
#pragma unroll
      for (int j = 0; j < 4; j++)
        acc[i][j] = __builtin_amdgcn_mfma_f32_16x16x32_bf16(af[i], bfr[j], acc[i][j], 0, 0, 0);
    __syncthreads();
  }
  float* Cf = (float*)Cv;
  bf16* Cb = (bf16*)Cv;
#pragma unroll
  for (int i = 0; i < 4; i++) {
    const int mb = m0 + wr + i * 16 + g * 4;
#pragma unroll
    for (int j = 0; j < 4; j++) {
      const int n = n0 + wc + j * 16 + c;
      const float bv = BIAS ? bias[n] : 0.f;
#pragma unroll
      for (int r = 0; r < 4; r++) {
        float v = acc[i][j][r] + bv;
        if (ACT == 1) v = gelu_f(v);
        if (OUT == 0) {
          float* cp = Cf + (size_t)(mb + r) * N + n;
          if (RES) v += *cp;
          *cp = v;
        } else {
          Cb[(size_t)(mb + r) * N + n] = (bf16)v;
        }
      }
    }
  }
}

// ---------------------------------------------------------------------------
// transpose + cast: W[K,N] f32 -> Wt[N,K] bf16. 32x32 tiles.
// ---------------------------------------------------------------------------
__global__ __launch_bounds__(256) void transpose_cast(
    const float* __restrict__ W, bf16* __restrict__ Wt, int K, int N) {
  __shared__ float tile[32][33];
  const int tx = threadIdx.x & 31, ty = threadIdx.x >> 5;
  const int k0 = blockIdx.y * 32, n0 = blockIdx.x * 32;
#pragma unroll
  for (int i = ty; i < 32; i += 8) tile[i][tx] = W[(size_t)(k0 + i) * N + n0 + tx];
  __syncthreads();
#pragma unroll
  for (int i = ty; i < 32; i += 8)
    Wt[(size_t)(n0 + i) * K + k0 + tx] = (bf16)tile[tx][i];
}

// 4x 512x512 transposes in one launch; dst slice z*262144
__global__ __launch_bounds__(256) void transpose_cast4(
    const float* __restrict__ W0, const float* __restrict__ W1,
    const float* __restrict__ W2, const float* __restrict__ W3,
    bf16* __restrict__ Wt) {
  __shared__ float tile[32][33];
  const int zz = blockIdx.z;
  const float* W = zz == 0 ? W0 : zz == 1 ? W1 : zz == 2 ? W2 : W3;
  bf16* dst = Wt + (size_t)zz * 262144;
  const int tx = threadIdx.x & 31, ty = threadIdx.x >> 5;
  const int k0 = blockIdx.y * 32, n0 = blockIdx.x * 32;
#pragma unroll
  for (int i = ty; i < 32; i += 8) tile[i][tx] = W[(size_t)(k0 + i) * 512 + n0 + tx];
  __syncthreads();
#pragma unroll
  for (int i = ty; i < 32; i += 8)
    dst[(size_t)(n0 + i) * 512 + k0 + tx] = (bf16)tile[tx][i];
}

// flat f32 -> bf16 cast, n % 4 == 0
__global__ __launch_bounds__(256) void castf2b(
    const float* __restrict__ x, bf16* __restrict__ y, int n) {
  int i = (blockIdx.x * 256 + threadIdx.x) * 4;
  const int stride = gridDim.x * 1024;
  for (; i < n; i += stride) {
    float4 v = *(const float4*)(x + i);
    bf16x4 o;
    o[0] = (bf16)v.x; o[1] = (bf16)v.y; o[2] = (bf16)v.z; o[3] = (bf16)v.w;
    *(bf16x4*)(y + i) = o;
  }
}

// proj [266,64] f32 -> projB [288,64] bf16 with dn prescale, pad rows = 0
__global__ __launch_bounds__(256) void proj_cast(
    const float* __restrict__ proj, bf16* __restrict__ projB) {
  const int idx = blockIdx.x * 256 + threadIdx.x;
  if (idx >= cMP * cDH) return;
  const int m = idx >> 6;
  projB[idx] = (bf16)(m < cM ? proj[idx] * 0.35355339059327373f : 0.f);
}

// V head-transpose: Vh (stride ld) -> Vt [64 z][80 d][2048 s]
// rows 64 = ones (ksum fusion), 65..79 = zeros.
__global__ __launch_bounds__(256) void vtrans(
    const bf16* __restrict__ Vh, int ld, bf16* __restrict__ Vt) {
  __shared__ bf16 tile[64][65];
  const int z = blockIdx.y, b = z >> 3, h = z & 7;
  const int s0 = blockIdx.x * 64;
  const int t = threadIdx.x;
#pragma unroll
  for (int r = t >> 3; r < 64; r += 32) {
    bf16x8 v = *(const bf16x8*)(Vh + ((size_t)b * cSE + s0 + r) * ld + h * cDH + (t & 7) * 8);
#pragma unroll
    for (int e = 0; e < 8; e++) tile[(t & 7) * 8 + e][r] = v[e];
  }
  __syncthreads();
  bf16* vz = Vt + (size_t)z * 80 * cSE;
#pragma unroll
  for (int d = t >> 3; d < 64; d += 32) {
    bf16x8 o;
#pragma unroll
    for (int e = 0; e < 8; e++) o[e] = tile[d][(t & 7) * 8 + e];
    *(bf16x8*)(vz + (size_t)d * cSE + s0 + (t & 7) * 8) = o;
  }
  // ones / zeros rows 64..79
  const int rr = t >> 4, seg = (t & 15) * 4;
  bf16x4 ov;
  const float val = (rr == 0) ? 1.f : 0.f;
  ov[0] = (bf16)val; ov[1] = (bf16)val; ov[2] = (bf16)val; ov[3] = (bf16)val;
  *(bf16x4*)(vz + (size_t)(64 + rr) * cSE + s0 + seg) = ov;
}

// ---------------------------------------------------------------------------
// FAVOR k-feature kernel. MODE 1: block max of kd -> bmax (no diag).
// MODE 2: reduces bmax[1024] inline, kp = ratio*(exp(kd-diag-gmax)+eps)
//         -> Pk TRANSPOSED [z,288,2048]. diag inline from K fragments.
// QK has row stride ld (fused-QKV layout).
// ---------------------------------------------------------------------------
template <int MODE>
__global__ __launch_bounds__(256, 1) void favor_phik(
    const bf16* __restrict__ Kh, int ld, const bf16* __restrict__ projB,
    float* __restrict__ bmax, bf16* __restrict__ Pout) {
  __shared__ float sm[4];
  const int z = blockIdx.y, b = z >> 3, h = z & 7;
  const int s0 = blockIdx.x * 128;
  const int t = threadIdx.x, l = t & 63, w = t >> 6, g = l >> 4, c = l & 15;
  const int wr = (w >> 1) * 64, wcol = (w & 1) * 144;

  float gm = 0.f;
  if (MODE == 2) {  // inline global-max reduction of bmax[1024]
    float m = -1e30f;
    for (int i = t; i < 1024; i += 256) m = fmaxf(m, bmax[i]);
    m = wave_max(m);
    if (l == 0) sm[w] = m;
    __syncthreads();
    gm = fmaxf(fmaxf(sm[0], sm[1]), fmaxf(sm[2], sm[3]));
  }

  const f32x4 zero4 = {0.f, 0.f, 0.f, 0.f};
  f32x4 acc[4][9];
#pragma unroll
  for (int i = 0; i < 4; i++)
#pragma unroll
    for (int j = 0; j < 9; j++) acc[i][j] = zero4;
  float sq[4] = {0.f, 0.f, 0.f, 0.f};
  const size_t abase = ((size_t)b * cSE + s0) * ld + h * cDH;
#pragma unroll
  for (int k0 = 0; k0 < 64; k0 += 32) {
    bf16x8 af[4];
#pragma unroll
    for (int i = 0; i < 4; i++) {
      af[i] = *(const bf16x8*)(Kh + abase + (size_t)(wr + i * 16 + c) * ld + k0 + g * 8);
      if (MODE == 2) {
#pragma unroll
        for (int e = 0; e < 8; e++) {
          const float v = (float)af[i][e];
          sq[i] += v * v;
        }
      }
    }
#pragma unroll
    for (int j = 0; j < 9; j++) {
      bf16x8 bfr = *(const bf16x8*)(projB + (wcol + j * 16 + c) * 64 + k0 + g * 8);
#pragma unroll
      for (int i = 0; i < 4; i++)
        acc[i][j] = __builtin_amdgcn_mfma_f32_16x16x32_bf16(af[i], bfr, acc[i][j], 0, 0, 0);
    }
  }
  const float ratio = 0.061313927f;  // 266^-0.5

  if (MODE == 1) {
    float m = -3e38f;
#pragma unroll
    for (int i = 0; i < 4; i++)
#pragma unroll
      for (int j = 0; j < 9; j++) {
        const int mc = wcol + j * 16 + c;
        if (mc < cM) {
#pragma unroll
          for (int r = 0; r < 4; r++) m = fmaxf(m, acc[i][j][r]);
        }
      }
    m = wave_max(m);
    if (l == 0) sm[w] = m;
    __syncthreads();
    if (t == 0)
      bmax[blockIdx.y * 16 + blockIdx.x] =
          fmaxf(fmaxf(sm[0], sm[1]), fmaxf(sm[2], sm[3]));
    return;
  }

  // MODE 2: diag via in-register norms
#pragma unroll
  for (int i = 0; i < 4; i++) {
    sq[i] += __shfl_xor(sq[i], 16);
    sq[i] += __shfl_xor(sq[i], 32);
  }
  float rowsub[4][4];
#pragma unroll
  for (int i = 0; i < 4; i++)
#pragma unroll
    for (int r = 0; r < 4; r++)
      rowsub[i][r] = gm + 0.0625f * __shfl(sq[i], g * 4 + r);

#pragma unroll
  for (int i = 0; i < 4; i++)
#pragma unroll
    for (int j = 0; j < 9; j++) {
      const int mc = wcol + j * 16 + c;
      bf16x4 o;
#pragma unroll
      for (int r = 0; r < 4; r++) {
        const float v = (mc < cM)
            ? ratio * (__expf(acc[i][j][r] - rowsub[i][r]) + 1e-4f) : 0.f;
        o[r] = (bf16)v;
      }
      *(bf16x4*)(Pout + ((size_t)z * cMP + mc) * cSE + s0 + wr + i * 16 + g * 4) = o;
    }
}

// ---------------------------------------------------------------------------
// kv partials: part[z,ch,m,d(80)] = sum_{s chunk} Pk[z,m,s] * Vt[z,d,s].
// d=64 column = ksum chunk (ones row of Vt). grid (4, 64).
// ---------------------------------------------------------------------------
__global__ __launch_bounds__(256) void favor_kv(
    const bf16* __restrict__ Pk, const bf16* __restrict__ Vt,
    float* __restrict__ part) {
  const int z = blockIdx.y, ch = blockIdx.x;
  const int t = threadIdx.x, l = t & 63, w = t >> 6, g = l >> 4, c = l & 15;
  const int wm = (w & 1) * 144, wd = (w >> 1) * 32;
  const bool dden = (wd == 32);
  const size_t pkz = (size_t)z * cMP * cSE, vtz = (size_t)z * 80 * cSE;
  const f32x4 zero4 = {0.f, 0.f, 0.f, 0.f};
  f32x4 acc[9][2], accx[9];
#pragma unroll
  for (int j = 0; j < 9; j++) {
    acc[j][0] = zero4; acc[j][1] = zero4; accx[j] = zero4;
  }
  for (int k0 = ch * 512; k0 < ch * 512 + 512; k0 += 32) {
    bf16x8 bv[2], bvx;
#pragma unroll
    for (int i = 0; i < 2; i++)
      bv[i] = *(const bf16x8*)(Vt + vtz + (size_t)(wd + i * 16 + c) * cSE + k0 + g * 8);
    if (dden)
      bvx = *(const bf16x8*)(Vt + vtz + (size_t)(64 + c) * cSE + k0 + g * 8);
#pragma unroll
    for (int j = 0; j < 9; j++) {
      bf16x8 am = *(const bf16x8*)(Pk + pkz + (size_t)(wm + j * 16 + c) * cSE + k0 + g * 8);
      acc[j][0] = __builtin_amdgcn_mfma_f32_16x16x32_bf16(am, bv[0], acc[j][0], 0, 0, 0);
      acc[j][1] = __builtin_amdgcn_mfma_f32_16x16x32_bf16(am, bv[1], acc[j][1], 0, 0, 0);
      if (dden)
        accx[j] = __builtin_amdgcn_mfma_f32_16x16x32_bf16(am, bvx, accx[j], 0, 0, 0);
    }
  }
  float* po = part + ((size_t)z * 4 + ch) * (cMP * 80);
#pragma unroll
  for (int j = 0; j < 9; j++)
#pragma unroll
    for (int i = 0; i < 2; i++)
#pragma unroll
      for (int r = 0; r < 4; r++)
        po[(size_t)(wm + j * 16 + g * 4 + r) * 80 + wd + i * 16 + c] = acc[j][i][r];
  if (dden) {
#pragma unroll
    for (int j = 0; j < 9; j++)
#pragma unroll
      for (int r = 0; r < 4; r++)
        po[(size_t)(wm + j * 16 + g * 4 + r) * 80 + 64 + c] = accx[j][r];
  }
}

// reduce 4 chunks + transpose: kvT[z,d(80),m]; row 64 = ksum
__global__ __launch_bounds__(256) void kv_reduce(
    const float* __restrict__ part, bf16* __restrict__ kvT) {
  const int z = blockIdx.x;
  const float* p = part + (size_t)z * 4 * (cMP * 80);
  bf16* o = kvT + (size_t)z * 80 * cMP;
  for (int idx = threadIdx.x; idx < cMP * 80; idx += 256) {
    const int m = idx / 80, d = idx - m * 80;
    const float s = p[idx] + p[idx + cMP * 80] + p[idx + 2 * cMP * 80] + p[idx + 3 * cMP * 80];
    o[(size_t)d * cMP + m] = (bf16)s;
  }
}

// ---------------------------------------------------------------------------
// Fused phi(q) + output (Qh stride ld): qd in regs -> row max + inline diag ->
// qp staged in LDS [128][296] -> out = qp @ kvT^T (+den col) -> Y.
// ---------------------------------------------------------------------------
__global__ __launch_bounds__(256, 1) void favor_qout(
    const bf16* __restrict__ Qh, int ld, const bf16* __restrict__ projB,
    const bf16* __restrict__ kvT, bf16* __restrict__ Y) {
  __shared__ bf16 Plds[128 * 296];
  __shared__ float rmaxs[4][64];
  __shared__ float denl[128];
  const int z = blockIdx.y, b = z >> 3, h = z & 7;
  const int s0 = blockIdx.x * 128;
  const int t = threadIdx.x, l = t & 63, w = t >> 6, g = l >> 4, c = l & 15;
  const int wr = (w >> 1) * 64, wcol = (w & 1) * 144;
  const f32x4 zero4 = {0.f, 0.f, 0.f, 0.f};
  f32x4 acc[4][9];
#pragma unroll
  for (int i = 0; i < 4; i++)
#pragma unroll
    for (int j = 0; j < 9; j++) acc[i][j] = zero4;
  float sq[4] = {0.f, 0.f, 0.f, 0.f};
  const size_t abase = ((size_t)b * cSE + s0) * ld + h * cDH;
#pragma unroll
  for (int k0 = 0; k0 < 64; k0 += 32) {
    bf16x8 af[4];
#pragma unroll
    for (int i = 0; i < 4; i++) {
      af[i] = *(const bf16x8*)(Qh + abase + (size_t)(wr + i * 16 + c) * ld + k0 + g * 8);
#pragma unroll
      for (int e = 0; e < 8; e++) {
        const float v = (float)af[i][e];
        sq[i] += v * v;
      }
    }
#pragma unroll
    for (int j = 0; j < 9; j++) {
      bf16x8 bfr = *(const bf16x8*)(projB + (wcol + j * 16 + c) * 64 + k0 + g * 8);
#pragma unroll
      for (int i = 0; i < 4; i++)
        acc[i][j] = __builtin_amdgcn_mfma_f32_16x16x32_bf16(af[i], bfr, acc[i][j], 0, 0, 0);
    }
  }
#pragma unroll
  for (int i = 0; i < 4; i++) {
    sq[i] += __shfl_xor(sq[i], 16);
    sq[i] += __shfl_xor(sq[i], 32);
  }
  const float ratio = 0.061313927f;  // 266^-0.5
  float rowsub[4][4];
#pragma unroll
  for (int i = 0; i < 4; i++)
#pragma unroll
    for (int r = 0; r < 4; r++) {
      float m = -3e38f;
#pragma unroll
      for (int j = 0; j < 9; j++) {
        const int mc = wcol + j * 16 + c;
        m = (mc < cM) ? fmaxf(m, acc[i][j][r]) : m;
      }
      m = fmaxf(m, __shfl_xor(m, 1));
      m = fmaxf(m, __shfl_xor(m, 2));
      m = fmaxf(m, __shfl_xor(m, 4));
      m = fmaxf(m, __shfl_xor(m, 8));
      rowsub[i][r] = m;
    }
  if (c == 0) {
#pragma unroll
    for (int i = 0; i < 4; i++)
#pragma unroll
      for (int r = 0; r < 4; r++) rmaxs[w][i * 16 + g * 4 + r] = rowsub[i][r];
  }
  __syncthreads();
#pragma unroll
  for (int i = 0; i < 4; i++)
#pragma unroll
    for (int r = 0; r < 4; r++) {
      const int row = i * 16 + g * 4 + r;
      rowsub[i][r] = fmaxf(rowsub[i][r], rmaxs[w ^ 1][row]) +
                     0.0625f * __shfl(sq[i], g * 4 + r);
    }
#pragma unroll
  for (int i = 0; i < 4; i++)
#pragma unroll
    for (int j = 0; j < 9; j++) {
      const int mc = wcol + j * 16 + c;
#pragma unroll
      for (int r = 0; r < 4; r++) {
        const float v = (mc < cM)
            ? ratio * (__expf(acc[i][j][r] - rowsub[i][r]) + 1e-4f) : 0.f;
        Plds[(wr + i * 16 + g * 4 + r) * 296 + mc] = (bf16)v;
      }
    }
  __syncthreads();

  // ---- output phase: out = qp @ kvT^T, den from kvT ksum row ----
  const int wd = (w & 1) * 32;
  const bool dden = (wd == 32);
  f32x4 acc2[4][2], accx[4];
#pragma unroll
  for (int i = 0; i < 4; i++) {
    acc2[i][0] = zero4; acc2[i][1] = zero4; accx[i] = zero4;
  }
  const size_t kz = (size_t)z * 80 * cMP;
#pragma unroll 3
  for (int k0 = 0; k0 < cMP; k0 += 32) {
    bf16x8 bv[2], bvx;
#pragma unroll
    for (int j = 0; j < 2; j++)
      bv[j] = *(const bf16x8*)(kvT + kz + (size_t)(wd + j * 16 + c) * cMP + k0 + g * 8);
    if (dden)
      bvx = *(const bf16x8*)(kvT + kz + (size_t)(64 + c) * cMP + k0 + g * 8);
#pragma unroll
    for (int i = 0; i < 4; i++) {
      bf16x8 av = *(const bf16x8*)(Plds + (wr + i * 16 + c) * 296 + k0 + g * 8);
      acc2[i][0] = __builtin_amdgcn_mfma_f32_16x16x32_bf16(av, bv[0], acc2[i][0], 0, 0, 0);
      acc2[i][1] = __builtin_amdgcn_mfma_f32_16x16x32_bf16(av, bv[1], acc2[i][1], 0, 0, 0);
      if (dden)
        accx[i] = __builtin_amdgcn_mfma_f32_16x16x32_bf16(av, bvx, accx[i], 0, 0, 0);
    }
  }
  if (dden && c == 0) {
#pragma unroll
    for (int i = 0; i < 4; i++)
#pragma unroll
      for (int r = 0; r < 4; r++)
        denl[wr + i * 16 + g * 4 + r] = accx[i][r];
  }
  __syncthreads();
#pragma unroll
  for (int i = 0; i < 4; i++)
#pragma unroll
    for (int r = 0; r < 4; r++) {
      const int row = wr + i * 16 + g * 4 + r;
      const float inv = 1.0f / denl[row];
#pragma unroll
      for (int j = 0; j < 2; j++)
        Y[((size_t)b * cSE + s0 + row) * cD + h * cDH + wd + j * 16 + c] =
            (bf16)(acc2[i][j][r] * inv);
    }
}

// ---------------------------------------------------------------------------
// LayerNorm rows of 512; wave per row. WF: f32 out, WB: bf16 out2.
// ---------------------------------------------------------------------------
template <bool ADD, bool WF, bool WB>
__global__ __launch_bounds__(256) void ln_rows(
    const float* __restrict__ in, const float* __restrict__ add,
    const float* __restrict__ g, const float* __restrict__ be,
    float* __restrict__ out, bf16* __restrict__ out2) {
  const int wid = blockIdx.x * 4 + (threadIdx.x >> 6);
  const int lane = threadIdx.x & 63;
  const float* ip = in + (size_t)wid * cD + lane * 8;
  float x[8];
  {
    float4 a = *(const float4*)ip;
    float4 b4 = *(const float4*)(ip + 4);
    x[0] = a.x; x[1] = a.y; x[2] = a.z; x[3] = a.w;
    x[4] = b4.x; x[5] = b4.y; x[6] = b4.z; x[7] = b4.w;
  }
  if (ADD) {
    const float* ap = add + (size_t)wid * cD + lane * 8;
    float4 a = *(const float4*)ap;
    float4 b4 = *(const float4*)(ap + 4);
    x[0] += a.x; x[1] += a.y; x[2] += a.z; x[3] += a.w;
    x[4] += b4.x; x[5] += b4.y; x[6] += b4.z; x[7] += b4.w;
  }
  float s = 0;
#pragma unroll
  for (int i = 0; i < 8; i++) s += x[i];
  s = wave_sum(s);
  const float mu = s * (1.0f / cD);
  float vs = 0;
#pragma unroll
  for (int i = 0; i < 8; i++) { const float d = x[i] - mu; vs += d * d; }
  vs = wave_sum(vs);
  const float rstd = 1.0f / sqrtf(vs * (1.0f / cD) + 1e-5f);
  float r[8];
#pragma unroll
  for (int i = 0; i < 8; i++) {
    const int d = lane * 8 + i;
    r[i] = (x[i] - mu) * rstd * g[d] + be[d];
  }
  if (WF) {
    float* op = out + (size_t)wid * cD + lane * 8;
    float4 a, b4;
    a.x = r[0]; a.y = r[1]; a.z = r[2]; a.w = r[3];
    b4.x = r[4]; b4.y = r[5]; b4.z = r[6]; b4.w = r[7];
    *(float4*)op = a; *(float4*)(op + 4) = b4;
  }
  if (WB) {
    bf16x8 ov;
#pragma unroll
    for (int i = 0; i < 8; i++) ov[i] = (bf16)r[i];
    *(bf16x8*)(out2 + (size_t)wid * cD + lane * 8) = ov;
  }
}

// LN of (enc + sinusoidal(expr)), in-place on f32 X.
__global__ __launch_bounds__(256) void embed_ln(
    float* __restrict__ X, const int* __restrict__ ids,
    const float* __restrict__ g, const float* __restrict__ be) {
  const int wid = blockIdx.x * 4 + (threadIdx.x >> 6);
  const int lane = threadIdx.x & 63;
  const float idv = (float)ids[wid];
  float* xp = X + (size_t)wid * cD + lane * 8;
  float x[8];
  {
    float4 a = *(const float4*)xp;
    float4 b4 = *(const float4*)(xp + 4);
    x[0] = a.x; x[1] = a.y; x[2] = a.z; x[3] = a.w;
    x[4] = b4.x; x[5] = b4.y; x[6] = b4.z; x[7] = b4.w;
  }
  const float kf = -0.03597789207803197f;  // -ln(10000)/256
#pragma unroll
  for (int i = 0; i < 8; i++) {
    const int d = lane * 8 + i;
    float e;
    if (d < 256) e = sinf(idv * expf(kf * (float)d));
    else         e = cosf(idv * expf(kf * (float)(d - 256)));
    x[i] += e;
  }
  float s = 0;
#pragma unroll
  for (int i = 0; i < 8; i++) s += x[i];
  s = wave_sum(s);
  const float mu = s * (1.0f / cD);
  float vs = 0;
#pragma unroll
  for (int i = 0; i < 8; i++) { const float d = x[i] - mu; vs += d * d; }
  vs = wave_sum(vs);
  const float rstd = 1.0f / sqrtf(vs * (1.0f / cD) + 1e-5f);
#pragma unroll
  for (int i = 0; i < 8; i++) {
    const int d = lane * 8 + i;
    xp[i] = (x[i] - mu) * rstd * g[d] + be[d];
  }
}

// ---------------------------------------------------------------------------
// bf16 MFMA flash cross-attention, KVBLK=128, denominator-via-ones-row,
// defer-max (base-2, THR=8 nats), reg-prefetch staging, XCD-aware 1-D grid.
// K/V merged buffer with row stride ldkv (K at col 0, V at col 512).
// ---------------------------------------------------------------------------
__global__ __launch_bounds__(256) void flash_mfma(
    const bf16* __restrict__ Q, const bf16* __restrict__ Kc,
    const bf16* __restrict__ Vc, bf16* __restrict__ O, int ldkv) {
  __shared__ bf16 Ks[128 * 64];    // 16KB, swizzled rows of 128B
  __shared__ bf16 Vs[80 * 136];    // [d][s] padded; row 64 = ones
  __shared__ bf16 Pl[4 * 16 * 136];
  const int id = blockIdx.x;
  const int b = (id & 63) >> 3, h = id & 7, qb = id >> 6;
  const int t = threadIdx.x, l = t & 63, w = t >> 6, g = l >> 4, c = l & 15;
  const int q0 = qb * 64 + w * 16;
  bf16x8 aq[2];
  {
    const bf16* qp = Q + ((size_t)b * cSD + q0 + c) * cD + h * cDH + g * 8;
    aq[0] = *(const bf16x8*)qp;
    aq[1] = *(const bf16x8*)(qp + 32);
  }
  // init ones/zero rows of Vs (rows 64..79)
  for (int idx = t; idx < 16 * 136; idx += 256) {
    const int rr = idx / 136, cc = idx - rr * 136;
    Vs[(64 + rr) * 136 + cc] = (bf16)(rr == 0 ? 1.f : 0.f);
  }
  const f32x4 zero4 = {0.f, 0.f, 0.f, 0.f};
  f32x4 o5[5];
#pragma unroll
  for (int j = 0; j < 5; j++) o5[j] = zero4;
  float mrow[4];
#pragma unroll
  for (int r = 0; r < 4; r++) mrow[r] = -1e30f;

  const int kr = t >> 1, kof = (t & 1) * 32;  // K stage: row, elem offset
  const int sidx = t & 31, dseg = t >> 5;     // V stage: s quad, d segment
  const size_t kvbase = (size_t)b * cSE * ldkv + h * cDH;
  char* KsC = (char*)Ks;
  bf16* Pw = Pl + w * 16 * 136;
  const float S2 = 0.18033688011112042f;  // 0.125 * log2(e)
  const float T2 = 11.541560327111708f;   // 8 * log2(e)

  bf16x8 pk[4], pv[4];  // prefetch registers
  auto LOADR = [&](int kt) {
    const bf16* kp = Kc + kvbase + (size_t)(kt + kr) * ldkv + kof;
#pragma unroll
    for (int i = 0; i < 4; i++) pk[i] = *(const bf16x8*)(kp + i * 8);
    const bf16* vp = Vc + kvbase + (size_t)(kt + 4 * sidx) * ldkv + dseg * 8;
#pragma unroll
    for (int i = 0; i < 4; i++) pv[i] = *(const bf16x8*)(vp + (size_t)i * ldkv);
  };
  auto WRITEL = [&]() {
    const int sw = (kr & 7) << 4;
#pragma unroll
    for (int i = 0; i < 4; i++)
      *(bf16x8*)(KsC + kr * 128 + (((kof + i * 8) * 2) ^ sw)) = pk[i];
#pragma unroll
    for (int e = 0; e < 8; e++) {
      bf16x4 q4;
      q4[0] = pv[0][e]; q4[1] = pv[1][e]; q4[2] = pv[2][e]; q4[3] = pv[3][e];
      *(bf16x4*)(Vs + (dseg * 8 + e) * 136 + 4 * sidx) = q4;
    }
  };
  LOADR(0);
  WRITEL();

  for (int kt = 0; kt < cSE; kt += 128) {
    const bool more = (kt + 128 < cSE);
    if (more) LOADR(kt + 128);    // issue next-tile loads early
    __syncthreads();              // current tile LDS visible
    // QK^T: 8 key tiles of 16
    f32x4 s4[8];
#pragma unroll
    for (int t2 = 0; t2 < 8; t2++) {
      const int kr2 = t2 * 16 + c;
      const int sw2 = (kr2 & 7) << 4;
      bf16x8 bk0 = *(const bf16x8*)(KsC + kr2 * 128 + ((g * 16) ^ sw2));
      bf16x8 bk1 = *(const bf16x8*)(KsC + kr2 * 128 + ((64 + g * 16) ^ sw2));
      f32x4 z = zero4;
      z = __builtin_amdgcn_mfma_f32_16x16x32_bf16(aq[0], bk0, z, 0, 0, 0);
      z = __builtin_amdgcn_mfma_f32_16x16x32_bf16(aq[1], bk1, z, 0, 0, 0);
      s4[t2] = z;
    }
    // softmax in base-2; defer-max; den via ones-row of Vs
#pragma unroll
    for (int r = 0; r < 4; r++) {
      float xv[8];
#pragma unroll
      for (int t2 = 0; t2 < 8; t2++) xv[t2] = s4[t2][r] * S2;
      float tm = xv[0];
#pragma unroll
      for (int t2 = 1; t2 < 8; t2++) tm = fmaxf(tm, xv[t2]);
      tm = fmaxf(tm, __shfl_xor(tm, 1));
      tm = fmaxf(tm, __shfl_xor(tm, 2));
      tm = fmaxf(tm, __shfl_xor(tm, 4));
      tm = fmaxf(tm, __shfl_xor(tm, 8));
      if (tm > mrow[r] + T2) {
        const float corr = exp2f(mrow[r] - tm);
        mrow[r] = tm;
#pragma unroll
        for (int j = 0; j < 5; j++) o5[j][r] *= corr;
      }
      const float m = mrow[r];
      const int qr = g * 4 + r;
#pragma unroll
      for (int t2 = 0; t2 < 8; t2++)
        Pw[qr * 136 + t2 * 16 + c] = (bf16)exp2f(xv[t2] - m);
    }
    // PV: A = P[16x128] (4 k-slots), B = Vs (5 d-tiles incl. den tile)
    bf16x8 pa[4];
#pragma unroll
    for (int ks = 0; ks < 4; ks++)
      pa[ks] = *(const bf16x8*)(Pw + c * 136 + ks * 32 + g * 8);
#pragma unroll
    for (int j = 0; j < 5; j++) {
#pragma unroll
      for (int ks = 0; ks < 4; ks++) {
        bf16x8 bv = *(const bf16x8*)(Vs + (j * 16 + c) * 136 + ks * 32 + g * 8);
        o5[j] = __builtin_amdgcn_mfma_f32_16x16x32_bf16(pa[ks], bv, o5[j], 0, 0, 0);
      }
    }
    __syncthreads();              // all waves done reading this tile
    if (more) WRITEL();           // overwrite LDS with next tile
  }
#pragma unroll
  for (int r = 0; r < 4; r++) {
    const float den = __shfl(o5[4][r], l & 48);
    const float inv = 1.0f / den;
    const size_t row = (size_t)b * cSD + q0 + g * 4 + r;
#pragma unroll
    for (int j = 0; j < 4; j++)
      O[row * cD + h * cDH + j * 16 + c] = (bf16)(o5[j][r] * inv);
  }
}

// ---------------------------------------------------------------------------
extern "C" void kernel_launch(void* const* d_in, const int* in_sizes, int n_in,
                              void* d_out, int out_size, void* d_ws, size_t ws_size,
                              hipStream_t stream) {
  const float* in_enc = (const float*)d_in[0];
  const float* in_dec = (const float*)d_in[1];
  const int* expr = (const int*)d_in[2];
  const float* var_W = (const float*)d_in[3];
  const float* var_b = (const float*)d_in[4];
  const float* enc_g = (const float*)d_in[5];
  const float* enc_b = (const float*)d_in[6];
  const float* dec_g = (const float*)d_in[7];
  const float* dec_b = (const float*)d_in[8];
  const float* ln1_g = (const float*)d_in[9];
  const float* ln1_b = (const float*)d_in[10];
  const float* Wq = (const float*)d_in[11];
  const float* Wk = (const float*)d_in[12];
  const float* Wv = (const float*)d_in[13];
  const float* Wo = (const float*)d_in[14];
  const float* bo = (const float*)d_in[15];
  const float* ln2_g = (const float*)d_in[16];
  const float* ln2_b = (const float*)d_in[17];
  const float* w1 = (const float*)d_in[18];
  const float* b1 = (const float*)d_in[19];
  const float* w2 = (const float*)d_in[20];
  const float* b2 = (const float*)d_in[21];
  const float* proj = (const float*)d_in[22];
  const float* caWq = (const float*)d_in[23];
  const float* caWk = (const float*)d_in[24];
  const float* caWv = (const float*)d_in[25];
  const float* caWo = (const float*)d_in[26];
  const float* cabo = (const float*)d_in[27];
  const float* crg = (const float*)d_in[28];
  const float* crb = (const float*)d_in[29];
  const float* fw1 = (const float*)d_in[30];
  const float* fb1 = (const float*)d_in[31];
  const float* fw2 = (const float*)d_in[32];
  const float* fb2 = (const float*)d_in[33];
  const float* og = (const float*)d_in[34];
  const float* ob = (const float*)d_in[35];
  const float* hW = (const float*)d_in[36];
  const float* hb = (const float*)d_in[37];

  // ---- workspace layout (f32 units) --------------------------------------
  float* X     = (float*)d_ws;             // [16384,512] f32
  float* DC    = X + 8388608;              // [8192,512] f32
  bf16*  QKV   = (bf16*)(DC + 4194304);    // [16384,1536] bf16 fused
  bf16*  Vt    = QKV + 25165824;           // [64,80,2048] bf16
  bf16*  Pq    = Vt + 10485760;            // arena (FF mid / decoder overlays)
  bf16*  Pk    = Pq + 37748736;            // [64,288,2048] bf16
  float* part  = (float*)(Pk + 37748736);  // [64,4,288,80] f32
  bf16*  kvT   = (bf16*)(part + 5898240);  // [64,80,288] bf16
  float* bmax  = (float*)(kvT + 1474560);  // [1024+16]
  bf16*  Yb    = (bf16*)(bmax + 1040);     // [16384,512] bf16
  bf16*  DCb   = Yb + 8388608;             // [8192,512] bf16
  bf16*  Wt    = DCb + 4194304;            // [2048,512] bf16 arena
  bf16*  projB = Wt + 1048576;             // [288,64] bf16
  const size_t need_bytes = (size_t)81618960 * 4;
  if (ws_size < need_bytes) return;

  // P-region overlays (phase 0 + decoder); Pq..Pk contiguous 75.5M bf16
  bf16* Pb   = Pq;
  bf16* encB = Pb;                   // [16384,1280] (phase 0)
  bf16* decB = Pk;                   // [8192,1280]  (phase 0)
  bf16* Pmid = Pb;                   // [16384,2048] (FF mid, layer loop)
  bf16* Xb   = Pb;                   // [16384,512]  (decoder)
  bf16* Qc   = Pb + 8388608;         // [8192,512]
  bf16* KVc  = Pb + 12582912;        // [16384,1024] (K cols 0..511, V 512..1023)
  bf16* Fb   = Pb + 29360128;        // [8192,512]
  bf16* Pm2  = Pb + 33554432;        // [8192,2048]

  const dim3 blk(256);

  // ---- phase 0: embeddings ----------------------------------------------
  castf2b<<<2048, blk, 0, stream>>>(in_enc, encB, 16384 * 1280);
  castf2b<<<2048, blk, 0, stream>>>(in_dec, decB, 8192 * 1280);
  transpose_cast<<<dim3(16, 40), blk, 0, stream>>>(var_W, Wt, 1280, 512);
  gemm_mfma<0, 0, true, false><<<dim3(4, 128), blk, 0, stream>>>(encB, Wt, X, var_b, 16384, 512, 1280);
  gemm_mfma<0, 0, true, false><<<dim3(4, 64), blk, 0, stream>>>(decB, Wt, DC, var_b, 8192, 512, 1280);
  embed_ln<<<4096, blk, 0, stream>>>(X, expr, enc_g, enc_b);
  ln_rows<false, true, true><<<2048, blk, 0, stream>>>(DC, nullptr, dec_g, dec_b, DC, DCb);

  // ---- encoder layers ----------------------------------------------------
  for (int i = 0; i < cDEPTH; i++) {
    ln_rows<false, false, true><<<4096, blk, 0, stream>>>(X, nullptr, ln1_g + i * cD, ln1_b + i * cD, nullptr, Yb);
    transpose_cast4<<<dim3(16, 16, 4), blk, 0, stream>>>(
        Wq + (size_t)i * cD * cD, Wk + (size_t)i * cD * cD,
        Wv + (size_t)i * cD * cD, Wo + (size_t)i * cD * cD, Wt);
    // fused QKV GEMM: N=1536, B = [WqT;WkT;WvT]
    gemm_mfma<1, 0, false, false><<<dim3(12, 128), blk, 0, stream>>>(Yb, Wt, QKV, nullptr, 16384, 1536, 512);
    // FAVOR+ (bf16 MFMA; Q at +0, K at +512, V at +1024, stride 1536)
    proj_cast<<<72, blk, 0, stream>>>(proj + (size_t)i * cM * cDH, projB);
    vtrans<<<dim3(32, 64), blk, 0, stream>>>(QKV + 1024, 1536, Vt);
    favor_phik<1><<<dim3(16, 64), blk, 0, stream>>>(QKV + 512, 1536, projB, bmax, nullptr);
    favor_phik<2><<<dim3(16, 64), blk, 0, stream>>>(QKV + 512, 1536, projB, bmax, Pk);
    favor_kv<<<dim3(4, 64), blk, 0, stream>>>(Pk, Vt, part);
    kv_reduce<<<64, blk, 0, stream>>>(part, kvT);
    favor_qout<<<dim3(16, 64), blk, 0, stream>>>(QKV, 1536, projB, kvT, Yb);
    // Wo + residual
    gemm_mfma<0, 0, true, true><<<dim3(4, 128), blk, 0, stream>>>(Yb, Wt + 786432, X, bo + i * cD, 16384, 512, 512);
    // FF
    ln_rows<false, false, true><<<4096, blk, 0, stream>>>(X, nullptr, ln2_g + i * cD, ln2_b + i * cD, nullptr, Yb);
    transpose_cast<<<dim3(64, 16), blk, 0, stream>>>(w1 + (size_t)i * cD * cFF, Wt, 512, 2048);
    gemm_mfma<1, 1, true, false><<<dim3(16, 128), blk, 0, stream>>>(Yb, Wt, Pmid, b1 + i * cFF, 16384, 2048, 512);
    transpose_cast<<<dim3(16, 64), blk, 0, stream>>>(w2 + (size_t)i * cFF * cD, Wt, 2048, 512);
    gemm_mfma<0, 0, true, true><<<dim3(4, 128), blk, 0, stream>>>(Pmid, Wt, X, b2 + i * cD, 16384, 512, 2048);
  }

  // ---- decoder / cross-attention ----------------------------------------
  castf2b<<<2048, blk, 0, stream>>>(X, Xb, 16384 * 512);
  transpose_cast4<<<dim3(16, 16, 4), blk, 0, stream>>>(caWq, caWk, caWv, caWo, Wt);
  gemm_mfma<1, 0, false, false><<<dim3(4, 64), blk, 0, stream>>>(DCb, Wt, Qc, nullptr, 8192, 512, 512);
  // fused K+V GEMM: N=1024, B = [WkT;WvT]
  gemm_mfma<1, 0, false, false><<<dim3(8, 128), blk, 0, stream>>>(Xb, Wt + 262144, KVc, nullptr, 16384, 1024, 512);
  flash_mfma<<<dim3(1024), blk, 0, stream>>>(Qc, KVc, KVc + 512, Fb, 1024);
  gemm_mfma<0, 0, true, false><<<dim3(4, 64), blk, 0, stream>>>(Fb, Wt + 786432, X, cabo, 8192, 512, 512);
  ln_rows<true, false, true><<<2048, blk, 0, stream>>>(X, DC, crg, crb, nullptr, Yb);
  transpose_cast<<<dim3(64, 16), blk, 0, stream>>>(fw1, Wt, 512, 2048);
  gemm_mfma<1, 1, true, false><<<dim3(16, 64), blk, 0, stream>>>(Yb, Wt, Pm2, fb1, 8192, 2048, 512);
  transpose_cast<<<dim3(16, 64), blk, 0, stream>>>(fw2, Wt, 2048, 512);
  gemm_mfma<0, 0, true, false><<<dim3(4, 64), blk, 0, stream>>>(Pm2, Wt, X + 4194304, fb2, 8192, 512, 2048);
  ln_rows<false, false, true><<<2048, blk, 0, stream>>>(X + 4194304, nullptr, og, ob, nullptr, Yb);
  transpose_cast<<<dim3(4, 16), blk, 0, stream>>>(hW, Wt, 512, 128);
  gemm_mfma<0, 0, true, false><<<dim3(1, 64), blk, 0, stream>>>(Yb, Wt, (float*)d_out, hb, 8192, 128, 512);
}

// Round 7
// 2276.346 us; speedup vs baseline: 5.8230x; 1.0120x over previous
//
#include <hip/hip_runtime.h>
#include <hip/hip_bf16.h>
#include <math.h>

// Problem constants
constexpr int cB = 8, cSE = 2048, cSD = 1024, cIN = 1280, cD = 512,
              cDEPTH = 4, cH = 8, cDH = 64, cM = 266, cFF = 2048, cNB = 128;
constexpr int cMP = 288;  // cM padded to multiple of 16 (features pad -> 0)

#define DEV __device__ __forceinline__

typedef __bf16 bf16;
typedef __attribute__((ext_vector_type(8))) __bf16 bf16x8;
typedef __attribute__((ext_vector_type(4))) __bf16 bf16x4;
typedef __attribute__((ext_vector_type(2))) __bf16 bf16x2;
typedef __attribute__((ext_vector_type(4))) float f32x4;

DEV float gelu_f(float x) { return 0.5f * x * (1.0f + erff(x * 0.70710678118654752440f)); }

DEV float wave_sum(float v) {
#pragma unroll
  for (int o = 32; o; o >>= 1) v += __shfl_xor(v, o);
  return v;
}
DEV float wave_max(float v) {
#pragma unroll
  for (int o = 32; o; o >>= 1) v = fmaxf(v, __shfl_xor(v, o));
  return v;
}

#define GL2LDS(gp, lp) __builtin_amdgcn_global_load_lds(                    \
    (const __attribute__((address_space(1))) void*)(gp),                    \
    (__attribute__((address_space(3))) void*)(lp), 16, 0, 0)

// ---------------------------------------------------------------------------
// bf16 MFMA GEMM (m97 structure) with XCD-aware bijective block swizzle.
// C[M,N] = epi(A[M,K] @ Bt[N,K]^T). M%128==0, N%128==0, K%32==0.
// OUT: 0=f32 C, 1=bf16 C, 2=f32 C (+RES) AND bf16 mirror to Cv2.
// ---------------------------------------------------------------------------
template <int OUT, int ACT, bool BIAS, bool RES>
__global__ __launch_bounds__(256) void gemm_mfma(
    const bf16* __restrict__ A, const bf16* __restrict__ Bt,
    void* __restrict__ Cv, bf16* __restrict__ Cv2,
    const float* __restrict__ bias, int M, int N, int K) {
  __shared__ bf16 As[128 * 32];
  __shared__ bf16 Bs[128 * 32];
  const int t = threadIdx.x, l = t & 63, w = t >> 6;
  const int g = l >> 4, c = l & 15;
  // XCD swizzle: blocks on one XCD (id%8) take a contiguous panel chunk
  const int nwg = gridDim.x * gridDim.y;
  int id = blockIdx.y * gridDim.x + blockIdx.x;
  if ((nwg & 7) == 0) id = (id & 7) * (nwg >> 3) + (id >> 3);
  const int m0 = (id / gridDim.x) * 128, n0 = (id % gridDim.x) * 128;
  const int wr = (w >> 1) * 64, wc = (w & 1) * 64;
  const int srow = w * 32 + (l >> 2);
  const int scol = (l & 3) * 8;
  const bf16* gA = A + (size_t)(m0 + srow) * K + scol;
  const bf16* gB = Bt + (size_t)(n0 + srow) * K + scol;
  bf16* lA = As + w * 1024;
  bf16* lB = Bs + w * 1024;

  const f32x4 zero4 = {0.f, 0.f, 0.f, 0.f};
  f32x4 acc[4][4];
#pragma unroll
  for (int i = 0; i < 4; i++)
#pragma unroll
    for (int j = 0; j < 4; j++) acc[i][j] = zero4;

  for (int k0 = 0; k0 < K; k0 += 32) {
    GL2LDS(gA + k0, lA);
    GL2LDS(gA + (size_t)16 * K + k0, lA + 512);
    GL2LDS(gB + k0, lB);
    GL2LDS(gB + (size_t)16 * K + k0, lB + 512);
    __syncthreads();
    bf16x8 af[4], bfr[4];
#pragma unroll
    for (int i = 0; i < 4; i++)
      af[i] = *(const bf16x8*)(As + (wr + i * 16 + c) * 32 + g * 8);
#pragma unroll
    for (int j = 0; j < 4; j++)
      bfr[j] = *(const bf16x8*)(Bs + (wc + j * 16 + c) * 32 + g * 8);
#pragma unroll
    for (int i = 0; i < 4; i++)
#pragma unroll
      for (int j = 0; j < 4; j++)
        acc[i][j] = __builtin_amdgcn_mfma_f32_16x16x32_bf16(af[i], bfr[j], acc[i][j], 0, 0, 0);
    __syncthreads();
  }
  float* Cf = (float*)Cv;
  bf16* Cb = (bf16*)Cv;
#pragma unroll
  for (int i = 0; i < 4; i++) {
    const int mb = m0 + wr + i * 16 + g * 4;
#pragma unroll
    for (int j = 0; j < 4; j++) {
      const int n = n0 + wc + j * 16 + c;
      const float bv = BIAS ? bias[n] : 0.f;
#pragma unroll
      for (int r = 0; r < 4; r++) {
        float v = acc[i][j][r] + bv;
        if (ACT == 1) v = gelu_f(v);
        const size_t idx = (size_t)(mb + r) * N + n;
        if (OUT == 0 || OUT == 2) {
          float* cp = Cf + idx;
          if (RES) v += *cp;
          *cp = v;
          if (OUT == 2) Cv2[idx] = (bf16)v;
        } else {
          Cb[idx] = (bf16)v;
        }
      }
    }
  }
}

// ---------------------------------------------------------------------------
// transpose + cast: W[K,N] f32 -> Wt[N,K] bf16. 32x32 tiles.
// ---------------------------------------------------------------------------
__global__ __launch_bounds__(256) void transpose_cast(
    const float* __restrict__ W, bf16* __restrict__ Wt, int K, int N) {
  __shared__ float tile[32][33];
  const int tx = threadIdx.x & 31, ty = threadIdx.x >> 5;
  const int k0 = blockIdx.y * 32, n0 = blockIdx.x * 32;
#pragma unroll
  for (int i = ty; i < 32; i += 8) tile[i][tx] = W[(size_t)(k0 + i) * N + n0 + tx];
  __syncthreads();
#pragma unroll
  for (int i = ty; i < 32; i += 8)
    Wt[(size_t)(n0 + i) * K + k0 + tx] = (bf16)tile[tx][i];
}

// 4x 512x512 transposes in one launch; dst slice z*262144
__global__ __launch_bounds__(256) void transpose_cast4(
    const float* __restrict__ W0, const float* __restrict__ W1,
    const float* __restrict__ W2, const float* __restrict__ W3,
    bf16* __restrict__ Wt) {
  __shared__ float tile[32][33];
  const int zz = blockIdx.z;
  const float* W = zz == 0 ? W0 : zz == 1 ? W1 : zz == 2 ? W2 : W3;
  bf16* dst = Wt + (size_t)zz * 262144;
  const int tx = threadIdx.x & 31, ty = threadIdx.x >> 5;
  const int k0 = blockIdx.y * 32, n0 = blockIdx.x * 32;
#pragma unroll
  for (int i = ty; i < 32; i += 8) tile[i][tx] = W[(size_t)(k0 + i) * 512 + n0 + tx];
  __syncthreads();
#pragma unroll
  for (int i = ty; i < 32; i += 8)
    dst[(size_t)(n0 + i) * 512 + k0 + tx] = (bf16)tile[tx][i];
}

// FF pair: z=0 transposes w1 [512,2048]->d1 [2048,512]; z=1: w2 [2048,512]->d2.
__global__ __launch_bounds__(256) void transpose_castFF(
    const float* __restrict__ w1s, const float* __restrict__ w2s,
    bf16* __restrict__ d1, bf16* __restrict__ d2) {
  __shared__ float tile[32][33];
  const int z = blockIdx.y;
  const int K = z ? 2048 : 512, N = z ? 512 : 2048;
  const float* W = z ? w2s : w1s;
  bf16* dst = z ? d2 : d1;
  const int nt = N >> 5;
  const int bid = blockIdx.x;
  const int n0 = (bid % nt) * 32, k0 = (bid / nt) * 32;
  const int tx = threadIdx.x & 31, ty = threadIdx.x >> 5;
#pragma unroll
  for (int i = ty; i < 32; i += 8) tile[i][tx] = W[(size_t)(k0 + i) * N + n0 + tx];
  __syncthreads();
#pragma unroll
  for (int i = ty; i < 32; i += 8)
    dst[(size_t)(n0 + i) * K + k0 + tx] = (bf16)tile[tx][i];
}

// flat f32 -> bf16 cast, n % 4 == 0
__global__ __launch_bounds__(256) void castf2b(
    const float* __restrict__ x, bf16* __restrict__ y, int n) {
  int i = (blockIdx.x * 256 + threadIdx.x) * 4;
  const int stride = gridDim.x * 1024;
  for (; i < n; i += stride) {
    float4 v = *(const float4*)(x + i);
    bf16x4 o;
    o[0] = (bf16)v.x; o[1] = (bf16)v.y; o[2] = (bf16)v.z; o[3] = (bf16)v.w;
    *(bf16x4*)(y + i) = o;
  }
}

// proj [266,64] f32 -> projB [288,64] bf16 with dn prescale, pad rows = 0
__global__ __launch_bounds__(256) void proj_cast(
    const float* __restrict__ proj, bf16* __restrict__ projB) {
  const int idx = blockIdx.x * 256 + threadIdx.x;
  if (idx >= cMP * cDH) return;
  const int m = idx >> 6;
  projB[idx] = (bf16)(m < cM ? proj[idx] * 0.35355339059327373f : 0.f);
}

// V head-transpose: Vh (stride ld) -> Vt [64 z][80 d][2048 s]
// rows 64 = ones (ksum fusion), 65..79 = zeros.
__global__ __launch_bounds__(256) void vtrans(
    const bf16* __restrict__ Vh, int ld, bf16* __restrict__ Vt) {
  __shared__ bf16 tile[64][65];
  const int z = blockIdx.y, b = z >> 3, h = z & 7;
  const int s0 = blockIdx.x * 64;
  const int t = threadIdx.x;
#pragma unroll
  for (int r = t >> 3; r < 64; r += 32) {
    bf16x8 v = *(const bf16x8*)(Vh + ((size_t)b * cSE + s0 + r) * ld + h * cDH + (t & 7) * 8);
#pragma unroll
    for (int e = 0; e < 8; e++) tile[(t & 7) * 8 + e][r] = v[e];
  }
  __syncthreads();
  bf16* vz = Vt + (size_t)z * 80 * cSE;
#pragma unroll
  for (int d = t >> 3; d < 64; d += 32) {
    bf16x8 o;
#pragma unroll
    for (int e = 0; e < 8; e++) o[e] = tile[d][(t & 7) * 8 + e];
    *(bf16x8*)(vz + (size_t)d * cSE + s0 + (t & 7) * 8) = o;
  }
  // ones / zeros rows 64..79
  const int rr = t >> 4, seg = (t & 15) * 4;
  bf16x4 ov;
  const float val = (rr == 0) ? 1.f : 0.f;
  ov[0] = (bf16)val; ov[1] = (bf16)val; ov[2] = (bf16)val; ov[3] = (bf16)val;
  *(bf16x4*)(vz + (size_t)(64 + rr) * cSE + s0 + seg) = ov;
}

// ---------------------------------------------------------------------------
// FAVOR k-feature kernel. MODE 1: block max of kd -> bmax (no diag).
// MODE 2: reduces bmax[1024] inline, kp = ratio*(exp(kd-diag-gmax)+eps)
//         -> Pk TRANSPOSED [z,288,2048]. diag inline from K fragments.
// ---------------------------------------------------------------------------
template <int MODE>
__global__ __launch_bounds__(256, 1) void favor_phik(
    const bf16* __restrict__ Kh, int ld, const bf16* __restrict__ projB,
    float* __restrict__ bmax, bf16* __restrict__ Pout) {
  __shared__ float sm[4];
  const int z = blockIdx.y, b = z >> 3, h = z & 7;
  const int s0 = blockIdx.x * 128;
  const int t = threadIdx.x, l = t & 63, w = t >> 6, g = l >> 4, c = l & 15;
  const int wr = (w >> 1) * 64, wcol = (w & 1) * 144;

  float gm = 0.f;
  if (MODE == 2) {  // inline global-max reduction of bmax[1024]
    float m = -1e30f;
    for (int i = t; i < 1024; i += 256) m = fmaxf(m, bmax[i]);
    m = wave_max(m);
    if (l == 0) sm[w] = m;
    __syncthreads();
    gm = fmaxf(fmaxf(sm[0], sm[1]), fmaxf(sm[2], sm[3]));
  }

  const f32x4 zero4 = {0.f, 0.f, 0.f, 0.f};
  f32x4 acc[4][9];
#pragma unroll
  for (int i = 0; i < 4; i++)
#pragma unroll
    for (int j = 0; j < 9; j++) acc[i][j] = zero4;
  float sq[4] = {0.f, 0.f, 0.f, 0.f};
  const size_t abase = ((size_t)b * cSE + s0) * ld + h * cDH;
#pragma unroll
  for (int k0 = 0; k0 < 64; k0 += 32) {
    bf16x8 af[4];
#pragma unroll
    for (int i = 0; i < 4; i++) {
      af[i] = *(const bf16x8*)(Kh + abase + (size_t)(wr + i * 16 + c) * ld + k0 + g * 8);
      if (MODE == 2) {
#pragma unroll
        for (int e = 0; e < 8; e++) {
          const float v = (float)af[i][e];
          sq[i] += v * v;
        }
      }
    }
#pragma unroll
    for (int j = 0; j < 9; j++) {
      bf16x8 bfr = *(const bf16x8*)(projB + (wcol + j * 16 + c) * 64 + k0 + g * 8);
#pragma unroll
      for (int i = 0; i < 4; i++)
        acc[i][j] = __builtin_amdgcn_mfma_f32_16x16x32_bf16(af[i], bfr, acc[i][j], 0, 0, 0);
    }
  }
  const float ratio = 0.061313927f;  // 266^-0.5

  if (MODE == 1) {
    float m = -3e38f;
#pragma unroll
    for (int i = 0; i < 4; i++)
#pragma unroll
      for (int j = 0; j < 9; j++) {
        const int mc = wcol + j * 16 + c;
        if (mc < cM) {
#pragma unroll
          for (int r = 0; r < 4; r++) m = fmaxf(m, acc[i][j][r]);
        }
      }
    m = wave_max(m);
    if (l == 0) sm[w] = m;
    __syncthreads();
    if (t == 0)
      bmax[blockIdx.y * 16 + blockIdx.x] =
          fmaxf(fmaxf(sm[0], sm[1]), fmaxf(sm[2], sm[3]));
    return;
  }

  // MODE 2: diag via in-register norms
#pragma unroll
  for (int i = 0; i < 4; i++) {
    sq[i] += __shfl_xor(sq[i], 16);
    sq[i] += __shfl_xor(sq[i], 32);
  }
  float rowsub[4][4];
#pragma unroll
  for (int i = 0; i < 4; i++)
#pragma unroll
    for (int r = 0; r < 4; r++)
      rowsub[i][r] = gm + 0.0625f * __shfl(sq[i], g * 4 + r);

#pragma unroll
  for (int i = 0; i < 4; i++)
#pragma unroll
    for (int j = 0; j < 9; j++) {
      const int mc = wcol + j * 16 + c;
      bf16x4 o;
#pragma unroll
      for (int r = 0; r < 4; r++) {
        const float v = (mc < cM)
            ? ratio * (__expf(acc[i][j][r] - rowsub[i][r]) + 1e-4f) : 0.f;
        o[r] = (bf16)v;
      }
      *(bf16x4*)(Pout + ((size_t)z * cMP + mc) * cSE + s0 + wr + i * 16 + g * 4) = o;
    }
}

// ---------------------------------------------------------------------------
// kv partials: part[z,ch,m,d(80)] = sum_{s chunk} Pk[z,m,s] * Vt[z,d,s].
// d=64 column = ksum chunk (ones row of Vt). grid (4, 64).
// ---------------------------------------------------------------------------
__global__ __launch_bounds__(256) void favor_kv(
    const bf16* __restrict__ Pk, const bf16* __restrict__ Vt,
    float* __restrict__ part) {
  const int z = blockIdx.y, ch = blockIdx.x;
  const int t = threadIdx.x, l = t & 63, w = t >> 6, g = l >> 4, c = l & 15;
  const int wm = (w & 1) * 144, wd = (w >> 1) * 32;
  const bool dden = (wd == 32);
  const size_t pkz = (size_t)z * cMP * cSE, vtz = (size_t)z * 80 * cSE;
  const f32x4 zero4 = {0.f, 0.f, 0.f, 0.f};
  f32x4 acc[9][2], accx[9];
#pragma unroll
  for (int j = 0; j < 9; j++) {
    acc[j][0] = zero4; acc[j][1] = zero4; accx[j] = zero4;
  }
  for (int k0 = ch * 512; k0 < ch * 512 + 512; k0 += 32) {
    bf16x8 bv[2], bvx;
#pragma unroll
    for (int i = 0; i < 2; i++)
      bv[i] = *(const bf16x8*)(Vt + vtz + (size_t)(wd + i * 16 + c) * cSE + k0 + g * 8);
    if (dden)
      bvx = *(const bf16x8*)(Vt + vtz + (size_t)(64 + c) * cSE + k0 + g * 8);
#pragma unroll
    for (int j = 0; j < 9; j++) {
      bf16x8 am = *(const bf16x8*)(Pk + pkz + (size_t)(wm + j * 16 + c) * cSE + k0 + g * 8);
      acc[j][0] = __builtin_amdgcn_mfma_f32_16x16x32_bf16(am, bv[0], acc[j][0], 0, 0, 0);
      acc[j][1] = __builtin_amdgcn_mfma_f32_16x16x32_bf16(am, bv[1], acc[j][1], 0, 0, 0);
      if (dden)
        accx[j] = __builtin_amdgcn_mfma_f32_16x16x32_bf16(am, bvx, accx[j], 0, 0, 0);
    }
  }
  float* po = part + ((size_t)z * 4 + ch) * (cMP * 80);
#pragma unroll
  for (int j = 0; j < 9; j++)
#pragma unroll
    for (int i = 0; i < 2; i++)
#pragma unroll
      for (int r = 0; r < 4; r++)
        po[(size_t)(wm + j * 16 + g * 4 + r) * 80 + wd + i * 16 + c] = acc[j][i][r];
  if (dden) {
#pragma unroll
    for (int j = 0; j < 9; j++)
#pragma unroll
      for (int r = 0; r < 4; r++)
        po[(size_t)(wm + j * 16 + g * 4 + r) * 80 + 64 + c] = accx[j][r];
  }
}

// reduce 4 chunks + transpose: kvT[z,d(80),m]; row 64 = ksum
__global__ __launch_bounds__(256) void kv_reduce(
    const float* __restrict__ part, bf16* __restrict__ kvT) {
  const int z = blockIdx.x;
  const float* p = part + (size_t)z * 4 * (cMP * 80);
  bf16* o = kvT + (size_t)z * 80 * cMP;
  for (int idx = threadIdx.x; idx < cMP * 80; idx += 256) {
    const int m = idx / 80, d = idx - m * 80;
    const float s = p[idx] + p[idx + cMP * 80] + p[idx + 2 * cMP * 80] + p[idx + 3 * cMP * 80];
    o[(size_t)d * cMP + m] = (bf16)s;
  }
}

// ---------------------------------------------------------------------------
// Fused phi(q) + output (Qh stride ld): qd in regs -> row max + inline diag ->
// qp staged in LDS [128][296] -> out = qp @ kvT^T (+den col) -> Y.
// ---------------------------------------------------------------------------
__global__ __launch_bounds__(256, 1) void favor_qout(
    const bf16* __restrict__ Qh, int ld, const bf16* __restrict__ projB,
    const bf16* __restrict__ kvT, bf16* __restrict__ Y) {
  __shared__ bf16 Plds[128 * 296];
  __shared__ float rmaxs[4][64];
  __shared__ float denl[128];
  const int z = blockIdx.y, b = z >> 3, h = z & 7;
  const int s0 = blockIdx.x * 128;
  const int t = threadIdx.x, l = t & 63, w = t >> 6, g = l >> 4, c = l & 15;
  const int wr = (w >> 1) * 64, wcol = (w & 1) * 144;
  const f32x4 zero4 = {0.f, 0.f, 0.f, 0.f};
  f32x4 acc[4][9];
#pragma unroll
  for (int i = 0; i < 4; i++)
#pragma unroll
    for (int j = 0; j < 9; j++) acc[i][j] = zero4;
  float sq[4] = {0.f, 0.f, 0.f, 0.f};
  const size_t abase = ((size_t)b * cSE + s0) * ld + h * cDH;
#pragma unroll
  for (int k0 = 0; k0 < 64; k0 += 32) {
    bf16x8 af[4];
#pragma unroll
    for (int i = 0; i < 4; i++) {
      af[i] = *(const bf16x8*)(Qh + abase + (size_t)(wr + i * 16 + c) * ld + k0 + g * 8);
#pragma unroll
      for (int e = 0; e < 8; e++) {
        const float v = (float)af[i][e];
        sq[i] += v * v;
      }
    }
#pragma unroll
    for (int j = 0; j < 9; j++) {
      bf16x8 bfr = *(const bf16x8*)(projB + (wcol + j * 16 + c) * 64 + k0 + g * 8);
#pragma unroll
      for (int i = 0; i < 4; i++)
        acc[i][j] = __builtin_amdgcn_mfma_f32_16x16x32_bf16(af[i], bfr, acc[i][j], 0, 0, 0);
    }
  }
#pragma unroll
  for (int i = 0; i < 4; i++) {
    sq[i] += __shfl_xor(sq[i], 16);
    sq[i] += __shfl_xor(sq[i], 32);
  }
  const float ratio = 0.061313927f;  // 266^-0.5
  float rowsub[4][4];
#pragma unroll
  for (int i = 0; i < 4; i++)
#pragma unroll
    for (int r = 0; r < 4; r++) {
      float m = -3e38f;
#pragma unroll
      for (int j = 0; j < 9; j++) {
        const int mc = wcol + j * 16 + c;
        m = (mc < cM) ? fmaxf(m, acc[i][j][r]) : m;
      }
      m = fmaxf(m, __shfl_xor(m, 1));
      m = fmaxf(m, __shfl_xor(m, 2));
      m = fmaxf(m, __shfl_xor(m, 4));
      m = fmaxf(m, __shfl_xor(m, 8));
      rowsub[i][r] = m;
    }
  if (c == 0) {
#pragma unroll
    for (int i = 0; i < 4; i++)
#pragma unroll
      for (int r = 0; r < 4; r++) rmaxs[w][i * 16 + g * 4 + r] = rowsub[i][r];
  }
  __syncthreads();
#pragma unroll
  for (int i = 0; i < 4; i++)
#pragma unroll
    for (int r = 0; r < 4; r++) {
      const int row = i * 16 + g * 4 + r;
      rowsub[i][r] = fmaxf(rowsub[i][r], rmaxs[w ^ 1][row]) +
                     0.0625f * __shfl(sq[i], g * 4 + r);
    }
#pragma unroll
  for (int i = 0; i < 4; i++)
#pragma unroll
    for (int j = 0; j < 9; j++) {
      const int mc = wcol + j * 16 + c;
#pragma unroll
      for (int r = 0; r < 4; r++) {
        const float v = (mc < cM)
            ? ratio * (__expf(acc[i][j][r] - rowsub[i][r]) + 1e-4f) : 0.f;
        Plds[(wr + i * 16 + g * 4 + r) * 296 + mc] = (bf16)v;
      }
    }
  __syncthreads();

  // ---- output phase: out = qp @ kvT^T, den from kvT ksum row ----
  const int wd = (w & 1) * 32;
  const bool dden = (wd == 32);
  f32x4 acc2[4][2], accx[4];
#pragma unroll
  for (int i = 0; i < 4; i++) {
    acc2[i][0] = zero4; acc2[i][1] = zero4; accx[i] = zero4;
  }
  const size_t kz = (size_t)z * 80 * cMP;
#pragma unroll 3
  for (int k0 = 0; k0 < cMP; k0 += 32) {
    bf16x8 bv[2], bvx;
#pragma unroll
    for (int j = 0; j < 2; j++)
      bv[j] = *(const bf16x8*)(kvT + kz + (size_t)(wd + j * 16 + c) * cMP + k0 + g * 8);
    if (dden)
      bvx = *(const bf16x8*)(kvT + kz + (size_t)(64 + c) * cMP + k0 + g * 8);
#pragma unroll
    for (int i = 0; i < 4; i++) {
      bf16x8 av = *(const bf16x8*)(Plds + (wr + i * 16 + c) * 296 + k0 + g * 8);
      acc2[i][0] = __builtin_amdgcn_mfma_f32_16x16x32_bf16(av, bv[0], acc2[i][0], 0, 0, 0);
      acc2[i][1] = __builtin_amdgcn_mfma_f32_16x16x32_bf16(av, bv[1], acc2[i][1], 0, 0, 0);
      if (dden)
        accx[i] = __builtin_amdgcn_mfma_f32_16x16x32_bf16(av, bvx, accx[i], 0, 0, 0);
    }
  }
  if (dden && c == 0) {
#pragma unroll
    for (int i = 0; i < 4; i++)
#pragma unroll
      for (int r = 0; r < 4; r++)
        denl[wr + i * 16 + g * 4 + r] = accx[i][r];
  }
  __syncthreads();
#pragma unroll
  for (int i = 0; i < 4; i++)
#pragma unroll
    for (int r = 0; r < 4; r++) {
      const int row = wr + i * 16 + g * 4 + r;
      const float inv = 1.0f / denl[row];
#pragma unroll
      for (int j = 0; j < 2; j++)
        Y[((size_t)b * cSE + s0 + row) * cD + h * cDH + wd + j * 16 + c] =
            (bf16)(acc2[i][j][r] * inv);
    }
}

// ---------------------------------------------------------------------------
// LayerNorm rows of 512; wave per row. WF: f32 out, WB: bf16 out2.
// ---------------------------------------------------------------------------
template <bool ADD, bool WF, bool WB>
__global__ __launch_bounds__(256) void ln_rows(
    const float* __restrict__ in, const float* __restrict__ add,
    const float* __restrict__ g, const float* __restrict__ be,
    float* __restrict__ out, bf16* __restrict__ out2) {
  const int wid = blockIdx.x * 4 + (threadIdx.x >> 6);
  const int lane = threadIdx.x & 63;
  const float* ip = in + (size_t)wid * cD + lane * 8;
  float x[8];
  {
    float4 a = *(const float4*)ip;
    float4 b4 = *(const float4*)(ip + 4);
    x[0] = a.x; x[1] = a.y; x[2] = a.z; x[3] = a.w;
    x[4] = b4.x; x[5] = b4.y; x[6] = b4.z; x[7] = b4.w;
  }
  if (ADD) {
    const float* ap = add + (size_t)wid * cD + lane * 8;
    float4 a = *(const float4*)ap;
    float4 b4 = *(const float4*)(ap + 4);
    x[0] += a.x; x[1] += a.y; x[2] += a.z; x[3] += a.w;
    x[4] += b4.x; x[5] += b4.y; x[6] += b4.z; x[7] += b4.w;
  }
  float s = 0;
#pragma unroll
  for (int i = 0; i < 8; i++) s += x[i];
  s = wave_sum(s);
  const float mu = s * (1.0f / cD);
  float vs = 0;
#pragma unroll
  for (int i = 0; i < 8; i++) { const float d = x[i] - mu; vs += d * d; }
  vs = wave_sum(vs);
  const float rstd = 1.0f / sqrtf(vs * (1.0f / cD) + 1e-5f);
  float r[8];
#pragma unroll
  for (int i = 0; i < 8; i++) {
    const int d = lane * 8 + i;
    r[i] = (x[i] - mu) * rstd * g[d] + be[d];
  }
  if (WF) {
    float* op = out + (size_t)wid * cD + lane * 8;
    float4 a, b4;
    a.x = r[0]; a.y = r[1]; a.z = r[2]; a.w = r[3];
    b4.x = r[4]; b4.y = r[5]; b4.z = r[6]; b4.w = r[7];
    *(float4*)op = a; *(float4*)(op + 4) = b4;
  }
  if (WB) {
    bf16x8 ov;
#pragma unroll
    for (int i = 0; i < 8; i++) ov[i] = (bf16)r[i];
    *(bf16x8*)(out2 + (size_t)wid * cD + lane * 8) = ov;
  }
}

// LN of (enc + sinusoidal(expr)), in-place on f32 X.
__global__ __launch_bounds__(256) void embed_ln(
    float* __restrict__ X, const int* __restrict__ ids,
    const float* __restrict__ g, const float* __restrict__ be) {
  const int wid = blockIdx.x * 4 + (threadIdx.x >> 6);
  const int lane = threadIdx.x & 63;
  const float idv = (float)ids[wid];
  float* xp = X + (size_t)wid * cD + lane * 8;
  float x[8];
  {
    float4 a = *(const float4*)xp;
    float4 b4 = *(const float4*)(xp + 4);
    x[0] = a.x; x[1] = a.y; x[2] = a.z; x[3] = a.w;
    x[4] = b4.x; x[5] = b4.y; x[6] = b4.z; x[7] = b4.w;
  }
  const float kf = -0.03597789207803197f;  // -ln(10000)/256
#pragma unroll
  for (int i = 0; i < 8; i++) {
    const int d = lane * 8 + i;
    float e;
    if (d < 256) e = sinf(idv * expf(kf * (float)d));
    else         e = cosf(idv * expf(kf * (float)(d - 256)));
    x[i] += e;
  }
  float s = 0;
#pragma unroll
  for (int i = 0; i < 8; i++) s += x[i];
  s = wave_sum(s);
  const float mu = s * (1.0f / cD);
  float vs = 0;
#pragma unroll
  for (int i = 0; i < 8; i++) { const float d = x[i] - mu; vs += d * d; }
  vs = wave_sum(vs);
  const float rstd = 1.0f / sqrtf(vs * (1.0f / cD) + 1e-5f);
#pragma unroll
  for (int i = 0; i < 8; i++) {
    const int d = lane * 8 + i;
    xp[i] = (x[i] - mu) * rstd * g[d] + be[d];
  }
}

// ---------------------------------------------------------------------------
// bf16 MFMA flash cross-attention, KVBLK=128, denominator-via-ones-row,
// defer-max (base-2, THR=8 nats), reg-prefetch staging, XCD-aware 1-D grid.
// LDS: K tile and P staging share one buffer (never live simultaneously);
// 3 barriers/tile, 39 KB LDS -> 4 blocks/CU.
// ---------------------------------------------------------------------------
__global__ __launch_bounds__(256) void flash_mfma(
    const bf16* __restrict__ Q, const bf16* __restrict__ Kc,
    const bf16* __restrict__ Vc, bf16* __restrict__ O, int ldkv) {
  __shared__ __align__(16) bf16 KP[4 * 16 * 136];  // K (16KB) ∪ P (17.4KB)
  __shared__ __align__(16) bf16 Vs[80 * 136];      // [d][s] padded; row 64 = ones
  const int id = blockIdx.x;
  const int b = (id & 63) >> 3, h = id & 7, qb = id >> 6;
  const int t = threadIdx.x, l = t & 63, w = t >> 6, g = l >> 4, c = l & 15;
  const int q0 = qb * 64 + w * 16;
  bf16x8 aq[2];
  {
    const bf16* qp = Q + ((size_t)b * cSD + q0 + c) * cD + h * cDH + g * 8;
    aq[0] = *(const bf16x8*)qp;
    aq[1] = *(const bf16x8*)(qp + 32);
  }
  // init ones/zero rows of Vs (rows 64..79); persists across tiles
  for (int idx = t; idx < 16 * 136; idx += 256) {
    const int rr = idx / 136, cc = idx - rr * 136;
    Vs[(64 + rr) * 136 + cc] = (bf16)(rr == 0 ? 1.f : 0.f);
  }
  const f32x4 zero4 = {0.f, 0.f, 0.f, 0.f};
  f32x4 o5[5];
#pragma unroll
  for (int j = 0; j < 5; j++) o5[j] = zero4;
  float mrow[4];
#pragma unroll
  for (int r = 0; r < 4; r++) mrow[r] = -1e30f;

  const int kr = t >> 1, kof = (t & 1) * 32;  // K stage: row, elem offset
  const int sidx = t & 31, dseg = t >> 5;     // V stage: s quad, d segment
  const size_t kvbase = (size_t)b * cSE * ldkv + h * cDH;
  char* KsC = (char*)KP;
  bf16* Pw = KP + w * 16 * 136;
  const float S2 = 0.18033688011112042f;  // 0.125 * log2(e)
  const float T2 = 11.541560327111708f;   // 8 * log2(e)

  bf16x8 pk[4], pv[4];  // prefetch registers
  auto LOADR = [&](int kt) {
    const bf16* kp = Kc + kvbase + (size_t)(kt + kr) * ldkv + kof;
#pragma unroll
    for (int i = 0; i < 4; i++) pk[i] = *(const bf16x8*)(kp + i * 8);
    const bf16* vp = Vc + kvbase + (size_t)(kt + 4 * sidx) * ldkv + dseg * 8;
#pragma unroll
    for (int i = 0; i < 4; i++) pv[i] = *(const bf16x8*)(vp + (size_t)i * ldkv);
  };
  auto WRITEL = [&]() {
    const int sw = (kr & 7) << 4;
#pragma unroll
    for (int i = 0; i < 4; i++)
      *(bf16x8*)(KsC + kr * 128 + (((kof + i * 8) * 2) ^ sw)) = pk[i];
#pragma unroll
    for (int e = 0; e < 8; e++) {
      bf16x4 q4;
      q4[0] = pv[0][e]; q4[1] = pv[1][e]; q4[2] = pv[2][e]; q4[3] = pv[3][e];
      *(bf16x4*)(Vs + (dseg * 8 + e) * 136 + 4 * sidx) = q4;
    }
  };
  LOADR(0);
  WRITEL();

  for (int kt = 0; kt < cSE; kt += 128) {
    const bool more = (kt + 128 < cSE);
    if (more) LOADR(kt + 128);    // issue next-tile loads (in flight all phase)
    __syncthreads();              // A: staged tile visible
    // QK^T: 8 key tiles of 16 (reads K region of KP)
    f32x4 s4[8];
#pragma unroll
    for (int t2 = 0; t2 < 8; t2++) {
      const int kr2 = t2 * 16 + c;
      const int sw2 = (kr2 & 7) << 4;
      bf16x8 bk0 = *(const bf16x8*)(KsC + kr2 * 128 + ((g * 16) ^ sw2));
      bf16x8 bk1 = *(const bf16x8*)(KsC + kr2 * 128 + ((64 + g * 16) ^ sw2));
      f32x4 z = zero4;
      z = __builtin_amdgcn_mfma_f32_16x16x32_bf16(aq[0], bk0, z, 0, 0, 0);
      z = __builtin_amdgcn_mfma_f32_16x16x32_bf16(aq[1], bk1, z, 0, 0, 0);
      s4[t2] = z;
    }
    __syncthreads();              // B: all K reads done; P may overwrite
    // softmax in base-2; defer-max; den via ones-row of Vs
#pragma unroll
    for (int r = 0; r < 4; r++) {
      float xv[8];
#pragma unroll
      for (int t2 = 0; t2 < 8; t2++) xv[t2] = s4[t2][r] * S2;
      float tm = xv[0];
#pragma unroll
      for (int t2 = 1; t2 < 8; t2++) tm = fmaxf(tm, xv[t2]);
      tm = fmaxf(tm, __shfl_xor(tm, 1));
      tm = fmaxf(tm, __shfl_xor(tm, 2));
      tm = fmaxf(tm, __shfl_xor(tm, 4));
      tm = fmaxf(tm, __shfl_xor(tm, 8));
      if (tm > mrow[r] + T2) {
        const float corr = exp2f(mrow[r] - tm);
        mrow[r] = tm;
#pragma unroll
        for (int j = 0; j < 5; j++) o5[j][r] *= corr;
      }
      const float m = mrow[r];
      const int qr = g * 4 + r;
#pragma unroll
      for (int t2 = 0; t2 < 8; t2++)
        Pw[qr * 136 + t2 * 16 + c] = (bf16)exp2f(xv[t2] - m);
    }
    // PV: A = P[16x128] (4 k-slots, own wave's slice), B = Vs (5 d-tiles)
    bf16x8 pa[4];
#pragma unroll
    for (int ks = 0; ks < 4; ks++)
      pa[ks] = *(const bf16x8*)(Pw + c * 136 + ks * 32 + g * 8);
#pragma unroll
    for (int j = 0; j < 5; j++) {
#pragma unroll
      for (int ks = 0; ks < 4; ks++) {
        bf16x8 bv = *(const bf16x8*)(Vs + (j * 16 + c) * 136 + ks * 32 + g * 8);
        o5[j] = __builtin_amdgcn_mfma_f32_16x16x32_bf16(pa[ks], bv, o5[j], 0, 0, 0);
      }
    }
    __syncthreads();              // C: P/Vs reads done; next stage may write
    if (more) WRITEL();
  }
#pragma unroll
  for (int r = 0; r < 4; r++) {
    const float den = __shfl(o5[4][r], l & 48);
    const float inv = 1.0f / den;
    const size_t row = (size_t)b * cSD + q0 + g * 4 + r;
#pragma unroll
    for (int j = 0; j < 4; j++)
      O[row * cD + h * cDH + j * 16 + c] = (bf16)(o5[j][r] * inv);
  }
}

// ---------------------------------------------------------------------------
extern "C" void kernel_launch(void* const* d_in, const int* in_sizes, int n_in,
                              void* d_out, int out_size, void* d_ws, size_t ws_size,
                              hipStream_t stream) {
  const float* in_enc = (const float*)d_in[0];
  const float* in_dec = (const float*)d_in[1];
  const int* expr = (const int*)d_in[2];
  const float* var_W = (const float*)d_in[3];
  const float* var_b = (const float*)d_in[4];
  const float* enc_g = (const float*)d_in[5];
  const float* enc_b = (const float*)d_in[6];
  const float* dec_g = (const float*)d_in[7];
  const float* dec_b = (const float*)d_in[8];
  const float* ln1_g = (const float*)d_in[9];
  const float* ln1_b = (const float*)d_in[10];
  const float* Wq = (const float*)d_in[11];
  const float* Wk = (const float*)d_in[12];
  const float* Wv = (const float*)d_in[13];
  const float* Wo = (const float*)d_in[14];
  const float* bo = (const float*)d_in[15];
  const float* ln2_g = (const float*)d_in[16];
  const float* ln2_b = (const float*)d_in[17];
  const float* w1 = (const float*)d_in[18];
  const float* b1 = (const float*)d_in[19];
  const float* w2 = (const float*)d_in[20];
  const float* b2 = (const float*)d_in[21];
  const float* proj = (const float*)d_in[22];
  const float* caWq = (const float*)d_in[23];
  const float* caWk = (const float*)d_in[24];
  const float* caWv = (const float*)d_in[25];
  const float* caWo = (const float*)d_in[26];
  const float* cabo = (const float*)d_in[27];
  const float* crg = (const float*)d_in[28];
  const float* crb = (const float*)d_in[29];
  const float* fw1 = (const float*)d_in[30];
  const float* fb1 = (const float*)d_in[31];
  const float* fw2 = (const float*)d_in[32];
  const float* fb2 = (const float*)d_in[33];
  const float* og = (const float*)d_in[34];
  const float* ob = (const float*)d_in[35];
  const float* hW = (const float*)d_in[36];
  const float* hb = (const float*)d_in[37];

  // ---- workspace layout (f32 units) --------------------------------------
  float* X     = (float*)d_ws;             // [16384,512] f32
  float* DC    = X + 8388608;              // [8192,512] f32
  bf16*  QKV   = (bf16*)(DC + 4194304);    // [16384,1536] bf16 fused
  bf16*  Vt    = QKV + 25165824;           // [64,80,2048] bf16 (decoder: Xb)
  bf16*  Pq    = Vt + 10485760;            // arena (FF mid / decoder overlays)
  bf16*  Pk    = Pq + 37748736;            // [64,288,2048] bf16
  float* part  = (float*)(Pk + 37748736);  // [64,4,288,80] f32
  bf16*  kvT   = (bf16*)(part + 5898240);  // [64,80,288] bf16
  float* bmax  = (float*)(kvT + 1474560);  // [1024+16]
  bf16*  Yb    = (bf16*)(bmax + 1040);     // [16384,512] bf16
  bf16*  DCb   = Yb + 8388608;             // [8192,512] bf16
  bf16*  Wt    = DCb + 4194304;            // [1048576] bf16 arena
  bf16*  projB = Wt + 1048576;             // [288,64] bf16
  bf16*  Wt2   = projB + 18432;            // [1048576] bf16 arena (FF w2T)
  const size_t need_bytes = (size_t)82143264 * 4;
  if (ws_size < need_bytes) return;

  // P-region overlays (phase 0 + decoder); Pq..Pk contiguous 75.5M bf16
  bf16* Pb   = Pq;
  bf16* encB = Pb;                   // [16384,1280] (phase 0)
  bf16* decB = Pk;                   // [8192,1280]  (phase 0)
  bf16* Pmid = Pb;                   // [16384,2048] (FF mid, layer loop)
  bf16* Xb   = Vt;                   // [16384,512]  (decoder; written by last FF2)
  bf16* Qc   = Pb + 8388608;         // [8192,512]
  bf16* KVc  = Pb + 12582912;        // [16384,1024] (K cols 0..511, V 512..1023)
  bf16* Fb   = Pb + 29360128;        // [8192,512]
  bf16* Pm2  = Pb + 33554432;        // [8192,2048]

  const dim3 blk(256);

  // ---- phase 0: embeddings ----------------------------------------------
  castf2b<<<2048, blk, 0, stream>>>(in_enc, encB, 16384 * 1280);
  castf2b<<<2048, blk, 0, stream>>>(in_dec, decB, 8192 * 1280);
  transpose_cast<<<dim3(16, 40), blk, 0, stream>>>(var_W, Wt, 1280, 512);
  gemm_mfma<0, 0, true, false><<<dim3(4, 128), blk, 0, stream>>>(encB, Wt, X, nullptr, var_b, 16384, 512, 1280);
  gemm_mfma<0, 0, true, false><<<dim3(4, 64), blk, 0, stream>>>(decB, Wt, DC, nullptr, var_b, 8192, 512, 1280);
  embed_ln<<<4096, blk, 0, stream>>>(X, expr, enc_g, enc_b);
  ln_rows<false, true, true><<<2048, blk, 0, stream>>>(DC, nullptr, dec_g, dec_b, DC, DCb);

  // ---- encoder layers ----------------------------------------------------
  for (int i = 0; i < cDEPTH; i++) {
    ln_rows<false, false, true><<<4096, blk, 0, stream>>>(X, nullptr, ln1_g + i * cD, ln1_b + i * cD, nullptr, Yb);
    transpose_cast4<<<dim3(16, 16, 4), blk, 0, stream>>>(
        Wq + (size_t)i * cD * cD, Wk + (size_t)i * cD * cD,
        Wv + (size_t)i * cD * cD, Wo + (size_t)i * cD * cD, Wt);
    // fused QKV GEMM: N=1536, B = [WqT;WkT;WvT]
    gemm_mfma<1, 0, false, false><<<dim3(12, 128), blk, 0, stream>>>(Yb, Wt, QKV, nullptr, nullptr, 16384, 1536, 512);
    // FAVOR+ (bf16 MFMA; Q at +0, K at +512, V at +1024, stride 1536)
    proj_cast<<<72, blk, 0, stream>>>(proj + (size_t)i * cM * cDH, projB);
    vtrans<<<dim3(32, 64), blk, 0, stream>>>(QKV + 1024, 1536, Vt);
    favor_phik<1><<<dim3(16, 64), blk, 0, stream>>>(QKV + 512, 1536, projB, bmax, nullptr);
    favor_phik<2><<<dim3(16, 64), blk, 0, stream>>>(QKV + 512, 1536, projB, bmax, Pk);
    favor_kv<<<dim3(4, 64), blk, 0, stream>>>(Pk, Vt, part);
    kv_reduce<<<64, blk, 0, stream>>>(part, kvT);
    favor_qout<<<dim3(16, 64), blk, 0, stream>>>(QKV, 1536, projB, kvT, Yb);
    // Wo + residual
    gemm_mfma<0, 0, true, true><<<dim3(4, 128), blk, 0, stream>>>(Yb, Wt + 786432, X, nullptr, bo + i * cD, 16384, 512, 512);
    // FF (both weight transposes in one launch: w1T->Wt, w2T->Wt2)
    ln_rows<false, false, true><<<4096, blk, 0, stream>>>(X, nullptr, ln2_g + i * cD, ln2_b + i * cD, nullptr, Yb);
    transpose_castFF<<<dim3(1024, 2), blk, 0, stream>>>(
        w1 + (size_t)i * cD * cFF, w2 + (size_t)i * cFF * cD, Wt, Wt2);
    gemm_mfma<1, 1, true, false><<<dim3(16, 128), blk, 0, stream>>>(Yb, Wt, Pmid, nullptr, b1 + i * cFF, 16384, 2048, 512);
    if (i < cDEPTH - 1) {
      gemm_mfma<0, 0, true, true><<<dim3(4, 128), blk, 0, stream>>>(Pmid, Wt2, X, nullptr, b2 + i * cD, 16384, 512, 2048);
    } else {
      // last layer: also emit bf16 mirror of X into Xb (decoder input)
      gemm_mfma<2, 0, true, true><<<dim3(4, 128), blk, 0, stream>>>(Pmid, Wt2, X, Xb, b2 + i * cD, 16384, 512, 2048);
    }
  }

  // ---- decoder / cross-attention ----------------------------------------
  transpose_cast4<<<dim3(16, 16, 4), blk, 0, stream>>>(caWq, caWk, caWv, caWo, Wt);
  gemm_mfma<1, 0, false, false><<<dim3(4, 64), blk, 0, stream>>>(DCb, Wt, Qc, nullptr, nullptr, 8192, 512, 512);
  // fused K+V GEMM: N=1024, B = [WkT;WvT]
  gemm_mfma<1, 0, false, false><<<dim3(8, 128), blk, 0, stream>>>(Xb, Wt + 262144, KVc, nullptr, nullptr, 16384, 1024, 512);
  flash_mfma<<<dim3(1024), blk, 0, stream>>>(Qc, KVc, KVc + 512, Fb, 1024);
  gemm_mfma<0, 0, true, false><<<dim3(4, 64), blk, 0, stream>>>(Fb, Wt + 786432, X, nullptr, cabo, 8192, 512, 512);
  ln_rows<true, false, true><<<2048, blk, 0, stream>>>(X, DC, crg, crb, nullptr, Yb);
  transpose_castFF<<<dim3(1024, 2), blk, 0, stream>>>(fw1, fw2, Wt, Wt2);
  gemm_mfma<1, 1, true, false><<<dim3(16, 64), blk, 0, stream>>>(Yb, Wt, Pm2, nullptr, fb1, 8192, 2048, 512);
  gemm_mfma<0, 0, true, false><<<dim3(4, 64), blk, 0, stream>>>(Pm2, Wt2, X + 4194304, nullptr, fb2, 8192, 512, 2048);
  ln_rows<false, false, true><<<2048, blk, 0, stream>>>(X + 4194304, nullptr, og, ob, nullptr, Yb);
  transpose_cast<<<dim3(4, 16), blk, 0, stream>>>(hW, Wt, 512, 128);
  gemm_mfma<0, 0, true, false><<<dim3(1, 64), blk, 0, stream>>>(Yb, Wt, (float*)d_out, nullptr, hb, 8192, 128, 512);
}

// Round 8
// 2044.120 us; speedup vs baseline: 6.4845x; 1.1136x over previous
//
#include <hip/hip_runtime.h>
#include <hip/hip_bf16.h>
#include <math.h>

// Problem constants
constexpr int cB = 8, cSE = 2048, cSD = 1024, cIN = 1280, cD = 512,
              cDEPTH = 4, cH = 8, cDH = 64, cM = 266, cFF = 2048, cNB = 128;
constexpr int cMP = 288;  // cM padded to multiple of 16 (features pad -> 0)

#define DEV __device__ __forceinline__

typedef __bf16 bf16;
typedef __attribute__((ext_vector_type(8))) __bf16 bf16x8;
typedef __attribute__((ext_vector_type(4))) __bf16 bf16x4;
typedef __attribute__((ext_vector_type(2))) __bf16 bf16x2;
typedef __attribute__((ext_vector_type(4))) float f32x4;

DEV float gelu_f(float x) { return 0.5f * x * (1.0f + erff(x * 0.70710678118654752440f)); }

DEV float wave_sum(float v) {
#pragma unroll
  for (int o = 32; o; o >>= 1) v += __shfl_xor(v, o);
  return v;
}
DEV float wave_max(float v) {
#pragma unroll
  for (int o = 32; o; o >>= 1) v = fmaxf(v, __shfl_xor(v, o));
  return v;
}

#define GL2LDS(gp, lp) __builtin_amdgcn_global_load_lds(                    \
    (const __attribute__((address_space(1))) void*)(gp),                    \
    (__attribute__((address_space(3))) void*)(lp), 16, 0, 0)

// ---------------------------------------------------------------------------
// bf16 MFMA GEMM (m97 structure) with XCD-aware bijective block swizzle.
// C[M,N] = epi(A[M,K] @ Bt[N,K]^T). M%128==0, N%128==0, K%32==0.
// OUT: 0=f32 C, 1=bf16 C, 2=f32 C (+RES) AND bf16 mirror to Cv2.
// ACT: 1 = exact GELU, 2 = scale by 0.125*log2(e) (flash Q prescale).
// ---------------------------------------------------------------------------
template <int OUT, int ACT, bool BIAS, bool RES>
__global__ __launch_bounds__(256) void gemm_mfma(
    const bf16* __restrict__ A, const bf16* __restrict__ Bt,
    void* __restrict__ Cv, bf16* __restrict__ Cv2,
    const float* __restrict__ bias, int M, int N, int K) {
  __shared__ bf16 As[128 * 32];
  __shared__ bf16 Bs[128 * 32];
  const int t = threadIdx.x, l = t & 63, w = t >> 6;
  const int g = l >> 4, c = l & 15;
  // XCD swizzle: blocks on one XCD (id%8) take a contiguous panel chunk
  const int nwg = gridDim.x * gridDim.y;
  int id = blockIdx.y * gridDim.x + blockIdx.x;
  if ((nwg & 7) == 0) id = (id & 7) * (nwg >> 3) + (id >> 3);
  const int m0 = (id / gridDim.x) * 128, n0 = (id % gridDim.x) * 128;
  const int wr = (w >> 1) * 64, wc = (w & 1) * 64;
  const int srow = w * 32 + (l >> 2);
  const int scol = (l & 3) * 8;
  const bf16* gA = A + (size_t)(m0 + srow) * K + scol;
  const bf16* gB = Bt + (size_t)(n0 + srow) * K + scol;
  bf16* lA = As + w * 1024;
  bf16* lB = Bs + w * 1024;

  const f32x4 zero4 = {0.f, 0.f, 0.f, 0.f};
  f32x4 acc[4][4];
#pragma unroll
  for (int i = 0; i < 4; i++)
#pragma unroll
    for (int j = 0; j < 4; j++) acc[i][j] = zero4;

  for (int k0 = 0; k0 < K; k0 += 32) {
    GL2LDS(gA + k0, lA);
    GL2LDS(gA + (size_t)16 * K + k0, lA + 512);
    GL2LDS(gB + k0, lB);
    GL2LDS(gB + (size_t)16 * K + k0, lB + 512);
    __syncthreads();
    bf16x8 af[4], bfr[4];
#pragma unroll
    for (int i = 0; i < 4; i++)
      af[i] = *(const bf16x8*)(As + (wr + i * 16 + c) * 32 + g * 8);
#pragma unroll
    for (int j = 0; j < 4; j++)
      bfr[j] = *(const bf16x8*)(Bs + (wc + j * 16 + c) * 32 + g * 8);
#pragma unroll
    for (int i = 0; i < 4; i++)
#pragma unroll
      for (int j = 0; j < 4; j++)
        acc[i][j] = __builtin_amdgcn_mfma_f32_16x16x32_bf16(af[i], bfr[j], acc[i][j], 0, 0, 0);
    __syncthreads();
  }
  float* Cf = (float*)Cv;
  bf16* Cb = (bf16*)Cv;
#pragma unroll
  for (int i = 0; i < 4; i++) {
    const int mb = m0 + wr + i * 16 + g * 4;
#pragma unroll
    for (int j = 0; j < 4; j++) {
      const int n = n0 + wc + j * 16 + c;
      const float bv = BIAS ? bias[n] : 0.f;
#pragma unroll
      for (int r = 0; r < 4; r++) {
        float v = acc[i][j][r] + bv;
        if (ACT == 1) v = gelu_f(v);
        if (ACT == 2) v *= 0.18033688011112042f;  // 0.125*log2(e)
        const size_t idx = (size_t)(mb + r) * N + n;
        if (OUT == 0 || OUT == 2) {
          float* cp = Cf + idx;
          if (RES) v += *cp;
          *cp = v;
          if (OUT == 2) Cv2[idx] = (bf16)v;
        } else {
          Cb[idx] = (bf16)v;
        }
      }
    }
  }
}

// ---------------------------------------------------------------------------
// transpose + cast: W[K,N] f32 -> Wt[N,K] bf16. 32x32 tiles.
// ---------------------------------------------------------------------------
__global__ __launch_bounds__(256) void transpose_cast(
    const float* __restrict__ W, bf16* __restrict__ Wt, int K, int N) {
  __shared__ float tile[32][33];
  const int tx = threadIdx.x & 31, ty = threadIdx.x >> 5;
  const int k0 = blockIdx.y * 32, n0 = blockIdx.x * 32;
#pragma unroll
  for (int i = ty; i < 32; i += 8) tile[i][tx] = W[(size_t)(k0 + i) * N + n0 + tx];
  __syncthreads();
#pragma unroll
  for (int i = ty; i < 32; i += 8)
    Wt[(size_t)(n0 + i) * K + k0 + tx] = (bf16)tile[tx][i];
}

// 4x 512x512 transposes in one launch; dst slice z*262144
__global__ __launch_bounds__(256) void transpose_cast4(
    const float* __restrict__ W0, const float* __restrict__ W1,
    const float* __restrict__ W2, const float* __restrict__ W3,
    bf16* __restrict__ Wt) {
  __shared__ float tile[32][33];
  const int zz = blockIdx.z;
  const float* W = zz == 0 ? W0 : zz == 1 ? W1 : zz == 2 ? W2 : W3;
  bf16* dst = Wt + (size_t)zz * 262144;
  const int tx = threadIdx.x & 31, ty = threadIdx.x >> 5;
  const int k0 = blockIdx.y * 32, n0 = blockIdx.x * 32;
#pragma unroll
  for (int i = ty; i < 32; i += 8) tile[i][tx] = W[(size_t)(k0 + i) * 512 + n0 + tx];
  __syncthreads();
#pragma unroll
  for (int i = ty; i < 32; i += 8)
    dst[(size_t)(n0 + i) * 512 + k0 + tx] = (bf16)tile[tx][i];
}

// FF pair: z=0 transposes w1 [512,2048]->d1 [2048,512]; z=1: w2 [2048,512]->d2.
__global__ __launch_bounds__(256) void transpose_castFF(
    const float* __restrict__ w1s, const float* __restrict__ w2s,
    bf16* __restrict__ d1, bf16* __restrict__ d2) {
  __shared__ float tile[32][33];
  const int z = blockIdx.y;
  const int K = z ? 2048 : 512, N = z ? 512 : 2048;
  const float* W = z ? w2s : w1s;
  bf16* dst = z ? d2 : d1;
  const int nt = N >> 5;
  const int bid = blockIdx.x;
  const int n0 = (bid % nt) * 32, k0 = (bid / nt) * 32;
  const int tx = threadIdx.x & 31, ty = threadIdx.x >> 5;
#pragma unroll
  for (int i = ty; i < 32; i += 8) tile[i][tx] = W[(size_t)(k0 + i) * N + n0 + tx];
  __syncthreads();
#pragma unroll
  for (int i = ty; i < 32; i += 8)
    dst[(size_t)(n0 + i) * K + k0 + tx] = (bf16)tile[tx][i];
}

// flat f32 -> bf16 cast, n % 4 == 0
__global__ __launch_bounds__(256) void castf2b(
    const float* __restrict__ x, bf16* __restrict__ y, int n) {
  int i = (blockIdx.x * 256 + threadIdx.x) * 4;
  const int stride = gridDim.x * 1024;
  for (; i < n; i += stride) {
    float4 v = *(const float4*)(x + i);
    bf16x4 o;
    o[0] = (bf16)v.x; o[1] = (bf16)v.y; o[2] = (bf16)v.z; o[3] = (bf16)v.w;
    *(bf16x4*)(y + i) = o;
  }
}

// proj [266,64] f32 -> projB [288,64] bf16 with dn prescale, pad rows = 0
__global__ __launch_bounds__(256) void proj_cast(
    const float* __restrict__ proj, bf16* __restrict__ projB) {
  const int idx = blockIdx.x * 256 + threadIdx.x;
  if (idx >= cMP * cDH) return;
  const int m = idx >> 6;
  projB[idx] = (bf16)(m < cM ? proj[idx] * 0.35355339059327373f : 0.f);
}

// V head-transpose: Vh (stride ld) -> Vt [64 z][80 d][2048 s]
// rows 64 = ones (ksum fusion), 65..79 = zeros.
__global__ __launch_bounds__(256) void vtrans(
    const bf16* __restrict__ Vh, int ld, bf16* __restrict__ Vt) {
  __shared__ bf16 tile[64][65];
  const int z = blockIdx.y, b = z >> 3, h = z & 7;
  const int s0 = blockIdx.x * 64;
  const int t = threadIdx.x;
#pragma unroll
  for (int r = t >> 3; r < 64; r += 32) {
    bf16x8 v = *(const bf16x8*)(Vh + ((size_t)b * cSE + s0 + r) * ld + h * cDH + (t & 7) * 8);
#pragma unroll
    for (int e = 0; e < 8; e++) tile[(t & 7) * 8 + e][r] = v[e];
  }
  __syncthreads();
  bf16* vz = Vt + (size_t)z * 80 * cSE;
#pragma unroll
  for (int d = t >> 3; d < 64; d += 32) {
    bf16x8 o;
#pragma unroll
    for (int e = 0; e < 8; e++) o[e] = tile[d][(t & 7) * 8 + e];
    *(bf16x8*)(vz + (size_t)d * cSE + s0 + (t & 7) * 8) = o;
  }
  // ones / zeros rows 64..79
  const int rr = t >> 4, seg = (t & 15) * 4;
  bf16x4 ov;
  const float val = (rr == 0) ? 1.f : 0.f;
  ov[0] = (bf16)val; ov[1] = (bf16)val; ov[2] = (bf16)val; ov[3] = (bf16)val;
  *(bf16x4*)(vz + (size_t)(64 + rr) * cSE + s0 + seg) = ov;
}

// ---------------------------------------------------------------------------
// FAVOR k global max: block max of kd = (K*dn) @ projB^T -> bmax[1024].
// grid (16, 64), 256 thr (4 waves 2x2: 128 s x 288 m).
// ---------------------------------------------------------------------------
__global__ __launch_bounds__(256, 1) void favor_kmax(
    const bf16* __restrict__ Kh, int ld, const bf16* __restrict__ projB,
    float* __restrict__ bmax) {
  __shared__ float sm[4];
  const int z = blockIdx.y, b = z >> 3, h = z & 7;
  const int s0 = blockIdx.x * 128;
  const int t = threadIdx.x, l = t & 63, w = t >> 6, g = l >> 4, c = l & 15;
  const int wr = (w >> 1) * 64, wcol = (w & 1) * 144;
  const f32x4 zero4 = {0.f, 0.f, 0.f, 0.f};
  f32x4 acc[4][9];
#pragma unroll
  for (int i = 0; i < 4; i++)
#pragma unroll
    for (int j = 0; j < 9; j++) acc[i][j] = zero4;
  const size_t abase = ((size_t)b * cSE + s0) * ld + h * cDH;
#pragma unroll
  for (int k0 = 0; k0 < 64; k0 += 32) {
    bf16x8 af[4];
#pragma unroll
    for (int i = 0; i < 4; i++)
      af[i] = *(const bf16x8*)(Kh + abase + (size_t)(wr + i * 16 + c) * ld + k0 + g * 8);
#pragma unroll
    for (int j = 0; j < 9; j++) {
      bf16x8 bfr = *(const bf16x8*)(projB + (wcol + j * 16 + c) * 64 + k0 + g * 8);
#pragma unroll
      for (int i = 0; i < 4; i++)
        acc[i][j] = __builtin_amdgcn_mfma_f32_16x16x32_bf16(af[i], bfr, acc[i][j], 0, 0, 0);
    }
  }
  float m = -3e38f;
#pragma unroll
  for (int i = 0; i < 4; i++)
#pragma unroll
    for (int j = 0; j < 9; j++) {
      const int mc = wcol + j * 16 + c;
      if (mc < cM) {
#pragma unroll
        for (int r = 0; r < 4; r++) m = fmaxf(m, acc[i][j][r]);
      }
    }
  m = wave_max(m);
  if (l == 0) sm[w] = m;
  __syncthreads();
  if (t == 0)
    bmax[blockIdx.y * 16 + blockIdx.x] =
        fmaxf(fmaxf(sm[0], sm[1]), fmaxf(sm[2], sm[3]));
}

// ---------------------------------------------------------------------------
// FUSED phi(k) + kv accumulate. Per block: z, s-chunk of 256 (8 chunks).
// Loop 64-s subtiles: kd via MFMA (regs) -> exp (inline diag, gmax) ->
// kp staged in LDS [288 m][72 s-pad] -> kv += kp^T @ Vt (d=64 col = ksum via
// ones-row). part[z,ch,m,80] f32 out. Pk never touches HBM.
// ---------------------------------------------------------------------------
__global__ __launch_bounds__(256, 1) void favor_kkv(
    const bf16* __restrict__ Kh, int ld, const bf16* __restrict__ projB,
    const bf16* __restrict__ Vt, const float* __restrict__ bmax,
    float* __restrict__ part) {
  __shared__ bf16 kp[288 * 72];
  __shared__ float sm[4];
  const int z = blockIdx.y, b = z >> 3, h = z & 7;
  const int chunk = blockIdx.x;
  const int t = threadIdx.x, l = t & 63, w = t >> 6, g = l >> 4, c = l & 15;
  // inline global-max reduce of bmax[1024]
  float gm;
  {
    float m = -1e30f;
    for (int i = t; i < 1024; i += 256) m = fmaxf(m, bmax[i]);
    m = wave_max(m);
    if (l == 0) sm[w] = m;
    __syncthreads();
    gm = fmaxf(fmaxf(sm[0], sm[1]), fmaxf(sm[2], sm[3]));
  }
  const int pr = (w >> 1) * 32;    // phase-1 s rows (0/32)
  const int wcol = (w & 1) * 144;  // phase-1 m cols
  const int wm = (w & 1) * 144, wd = (w >> 1) * 32;  // phase-2 assignment
  const bool dden = (wd == 32);
  const float ratio = 0.061313927f;  // 266^-0.5
  const f32x4 zero4 = {0.f, 0.f, 0.f, 0.f};
  f32x4 kacc[9][2], kaccx[9];
#pragma unroll
  for (int j = 0; j < 9; j++) {
    kacc[j][0] = zero4; kacc[j][1] = zero4; kaccx[j] = zero4;
  }
  const size_t kbase = (size_t)b * cSE * ld + h * cDH;
  const size_t vtz = (size_t)z * 80 * cSE;

  for (int st = 0; st < 256; st += 64) {
    const int sg = chunk * 256 + st;
    // ---- phase 1: kd tile [64 s x 288 m] in registers ----
    f32x4 pacc[2][9];
#pragma unroll
    for (int i = 0; i < 2; i++)
#pragma unroll
      for (int j = 0; j < 9; j++) pacc[i][j] = zero4;
    float sq[2] = {0.f, 0.f};
#pragma unroll
    for (int k0 = 0; k0 < 64; k0 += 32) {
      bf16x8 af[2];
#pragma unroll
      for (int i = 0; i < 2; i++) {
        af[i] = *(const bf16x8*)(Kh + kbase + (size_t)(sg + pr + i * 16 + c) * ld + k0 + g * 8);
#pragma unroll
        for (int e = 0; e < 8; e++) {
          const float v = (float)af[i][e];
          sq[i] += v * v;
        }
      }
#pragma unroll
      for (int j = 0; j < 9; j++) {
        bf16x8 bfr = *(const bf16x8*)(projB + (wcol + j * 16 + c) * 64 + k0 + g * 8);
        pacc[0][j] = __builtin_amdgcn_mfma_f32_16x16x32_bf16(af[0], bfr, pacc[0][j], 0, 0, 0);
        pacc[1][j] = __builtin_amdgcn_mfma_f32_16x16x32_bf16(af[1], bfr, pacc[1][j], 0, 0, 0);
      }
    }
#pragma unroll
    for (int i = 0; i < 2; i++) {
      sq[i] += __shfl_xor(sq[i], 16);
      sq[i] += __shfl_xor(sq[i], 32);
    }
    float rowsub[2][4];
#pragma unroll
    for (int i = 0; i < 2; i++)
#pragma unroll
      for (int r = 0; r < 4; r++)
        rowsub[i][r] = gm + 0.0625f * __shfl(sq[i], g * 4 + r);
    __syncthreads();  // prev subtile's phase-2 reads of kp done
    // store kp to LDS [m][s_local], bf16x4 along s
#pragma unroll
    for (int i = 0; i < 2; i++)
#pragma unroll
      for (int j = 0; j < 9; j++) {
        const int mc = wcol + j * 16 + c;
        bf16x4 o;
#pragma unroll
        for (int r = 0; r < 4; r++) {
          const float v = (mc < cM)
              ? ratio * (__expf(pacc[i][j][r] - rowsub[i][r]) + 1e-4f) : 0.f;
          o[r] = (bf16)v;
        }
        *(bf16x4*)(kp + (size_t)mc * 72 + pr + i * 16 + g * 4) = o;
      }
    __syncthreads();
    // ---- phase 2: kv += kp^T @ Vt over this subtile ----
#pragma unroll
    for (int k0 = 0; k0 < 64; k0 += 32) {
      bf16x8 bv0 = *(const bf16x8*)(Vt + vtz + (size_t)(wd + c) * cSE + sg + k0 + g * 8);
      bf16x8 bv1 = *(const bf16x8*)(Vt + vtz + (size_t)(wd + 16 + c) * cSE + sg + k0 + g * 8);
      bf16x8 bvx;
      if (dden)
        bvx = *(const bf16x8*)(Vt + vtz + (size_t)(64 + c) * cSE + sg + k0 + g * 8);
#pragma unroll
      for (int j = 0; j < 9; j++) {
        bf16x8 am = *(const bf16x8*)(kp + (size_t)(wm + j * 16 + c) * 72 + k0 + g * 8);
        kacc[j][0] = __builtin_amdgcn_mfma_f32_16x16x32_bf16(am, bv0, kacc[j][0], 0, 0, 0);
        kacc[j][1] = __builtin_amdgcn_mfma_f32_16x16x32_bf16(am, bv1, kacc[j][1], 0, 0, 0);
        if (dden)
          kaccx[j] = __builtin_amdgcn_mfma_f32_16x16x32_bf16(am, bvx, kaccx[j], 0, 0, 0);
      }
    }
  }
  // store partials
  float* po = part + ((size_t)z * 8 + chunk) * (cMP * 80);
#pragma unroll
  for (int j = 0; j < 9; j++)
#pragma unroll
    for (int i = 0; i < 2; i++)
#pragma unroll
      for (int r = 0; r < 4; r++)
        po[(size_t)(wm + j * 16 + g * 4 + r) * 80 + wd + i * 16 + c] = kacc[j][i][r];
  if (dden) {
#pragma unroll
    for (int j = 0; j < 9; j++)
#pragma unroll
      for (int r = 0; r < 4; r++)
        po[(size_t)(wm + j * 16 + g * 4 + r) * 80 + 64 + c] = kaccx[j][r];
  }
}

// reduce 8 chunks + transpose: kvT[z,d(80),m]; row 64 = ksum
__global__ __launch_bounds__(256) void kv_reduce(
    const float* __restrict__ part, bf16* __restrict__ kvT) {
  const int z = blockIdx.x;
  const float* p = part + (size_t)z * 8 * (cMP * 80);
  bf16* o = kvT + (size_t)z * 80 * cMP;
  for (int idx = threadIdx.x; idx < cMP * 80; idx += 256) {
    const int m = idx / 80, d = idx - m * 80;
    float s = 0.f;
#pragma unroll
    for (int cc = 0; cc < 8; cc++) s += p[idx + (size_t)cc * (cMP * 80)];
    o[(size_t)d * cMP + m] = (bf16)s;
  }
}

// ---------------------------------------------------------------------------
// Fused phi(q) + output (Qh stride ld): qd in regs -> row max + inline diag ->
// qp staged in LDS [128][296] -> out = qp @ kvT^T (+den col) -> Y.
// ---------------------------------------------------------------------------
__global__ __launch_bounds__(256, 1) void favor_qout(
    const bf16* __restrict__ Qh, int ld, const bf16* __restrict__ projB,
    const bf16* __restrict__ kvT, bf16* __restrict__ Y) {
  __shared__ bf16 Plds[128 * 296];
  __shared__ float rmaxs[4][64];
  __shared__ float denl[128];
  const int z = blockIdx.y, b = z >> 3, h = z & 7;
  const int s0 = blockIdx.x * 128;
  const int t = threadIdx.x, l = t & 63, w = t >> 6, g = l >> 4, c = l & 15;
  const int wr = (w >> 1) * 64, wcol = (w & 1) * 144;
  const f32x4 zero4 = {0.f, 0.f, 0.f, 0.f};
  f32x4 acc[4][9];
#pragma unroll
  for (int i = 0; i < 4; i++)
#pragma unroll
    for (int j = 0; j < 9; j++) acc[i][j] = zero4;
  float sq[4] = {0.f, 0.f, 0.f, 0.f};
  const size_t abase = ((size_t)b * cSE + s0) * ld + h * cDH;
#pragma unroll
  for (int k0 = 0; k0 < 64; k0 += 32) {
    bf16x8 af[4];
#pragma unroll
    for (int i = 0; i < 4; i++) {
      af[i] = *(const bf16x8*)(Qh + abase + (size_t)(wr + i * 16 + c) * ld + k0 + g * 8);
#pragma unroll
      for (int e = 0; e < 8; e++) {
        const float v = (float)af[i][e];
        sq[i] += v * v;
      }
    }
#pragma unroll
    for (int j = 0; j < 9; j++) {
      bf16x8 bfr = *(const bf16x8*)(projB + (wcol + j * 16 + c) * 64 + k0 + g * 8);
#pragma unroll
      for (int i = 0; i < 4; i++)
        acc[i][j] = __builtin_amdgcn_mfma_f32_16x16x32_bf16(af[i], bfr, acc[i][j], 0, 0, 0);
    }
  }
#pragma unroll
  for (int i = 0; i < 4; i++) {
    sq[i] += __shfl_xor(sq[i], 16);
    sq[i] += __shfl_xor(sq[i], 32);
  }
  const float ratio = 0.061313927f;  // 266^-0.5
  float rowsub[4][4];
#pragma unroll
  for (int i = 0; i < 4; i++)
#pragma unroll
    for (int r = 0; r < 4; r++) {
      float m = -3e38f;
#pragma unroll
      for (int j = 0; j < 9; j++) {
        const int mc = wcol + j * 16 + c;
        m = (mc < cM) ? fmaxf(m, acc[i][j][r]) : m;
      }
      m = fmaxf(m, __shfl_xor(m, 1));
      m = fmaxf(m, __shfl_xor(m, 2));
      m = fmaxf(m, __shfl_xor(m, 4));
      m = fmaxf(m, __shfl_xor(m, 8));
      rowsub[i][r] = m;
    }
  if (c == 0) {
#pragma unroll
    for (int i = 0; i < 4; i++)
#pragma unroll
      for (int r = 0; r < 4; r++) rmaxs[w][i * 16 + g * 4 + r] = rowsub[i][r];
  }
  __syncthreads();
#pragma unroll
  for (int i = 0; i < 4; i++)
#pragma unroll
    for (int r = 0; r < 4; r++) {
      const int row = i * 16 + g * 4 + r;
      rowsub[i][r] = fmaxf(rowsub[i][r], rmaxs[w ^ 1][row]) +
                     0.0625f * __shfl(sq[i], g * 4 + r);
    }
#pragma unroll
  for (int i = 0; i < 4; i++)
#pragma unroll
    for (int j = 0; j < 9; j++) {
      const int mc = wcol + j * 16 + c;
#pragma unroll
      for (int r = 0; r < 4; r++) {
        const float v = (mc < cM)
            ? ratio * (__expf(acc[i][j][r] - rowsub[i][r]) + 1e-4f) : 0.f;
        Plds[(wr + i * 16 + g * 4 + r) * 296 + mc] = (bf16)v;
      }
    }
  __syncthreads();

  // ---- output phase: out = qp @ kvT^T, den from kvT ksum row ----
  const int wd = (w & 1) * 32;
  const bool dden = (wd == 32);
  f32x4 acc2[4][2], accx[4];
#pragma unroll
  for (int i = 0; i < 4; i++) {
    acc2[i][0] = zero4; acc2[i][1] = zero4; accx[i] = zero4;
  }
  const size_t kz = (size_t)z * 80 * cMP;
#pragma unroll 3
  for (int k0 = 0; k0 < cMP; k0 += 32) {
    bf16x8 bv[2], bvx;
#pragma unroll
    for (int j = 0; j < 2; j++)
      bv[j] = *(const bf16x8*)(kvT + kz + (size_t)(wd + j * 16 + c) * cMP + k0 + g * 8);
    if (dden)
      bvx = *(const bf16x8*)(kvT + kz + (size_t)(64 + c) * cMP + k0 + g * 8);
#pragma unroll
    for (int i = 0; i < 4; i++) {
      bf16x8 av = *(const bf16x8*)(Plds + (wr + i * 16 + c) * 296 + k0 + g * 8);
      acc2[i][0] = __builtin_amdgcn_mfma_f32_16x16x32_bf16(av, bv[0], acc2[i][0], 0, 0, 0);
      acc2[i][1] = __builtin_amdgcn_mfma_f32_16x16x32_bf16(av, bv[1], acc2[i][1], 0, 0, 0);
      if (dden)
        accx[i] = __builtin_amdgcn_mfma_f32_16x16x32_bf16(av, bvx, accx[i], 0, 0, 0);
    }
  }
  if (dden && c == 0) {
#pragma unroll
    for (int i = 0; i < 4; i++)
#pragma unroll
      for (int r = 0; r < 4; r++)
        denl[wr + i * 16 + g * 4 + r] = accx[i][r];
  }
  __syncthreads();
#pragma unroll
  for (int i = 0; i < 4; i++)
#pragma unroll
    for (int r = 0; r < 4; r++) {
      const int row = wr + i * 16 + g * 4 + r;
      const float inv = 1.0f / denl[row];
#pragma unroll
      for (int j = 0; j < 2; j++)
        Y[((size_t)b * cSE + s0 + row) * cD + h * cDH + wd + j * 16 + c] =
            (bf16)(acc2[i][j][r] * inv);
    }
}

// ---------------------------------------------------------------------------
// LayerNorm rows of 512; wave per row. WF: f32 out, WB: bf16 out2.
// ---------------------------------------------------------------------------
template <bool ADD, bool WF, bool WB>
__global__ __launch_bounds__(256) void ln_rows(
    const float* __restrict__ in, const float* __restrict__ add,
    const float* __restrict__ g, const float* __restrict__ be,
    float* __restrict__ out, bf16* __restrict__ out2) {
  const int wid = blockIdx.x * 4 + (threadIdx.x >> 6);
  const int lane = threadIdx.x & 63;
  const float* ip = in + (size_t)wid * cD + lane * 8;
  float x[8];
  {
    float4 a = *(const float4*)ip;
    float4 b4 = *(const float4*)(ip + 4);
    x[0] = a.x; x[1] = a.y; x[2] = a.z; x[3] = a.w;
    x[4] = b4.x; x[5] = b4.y; x[6] = b4.z; x[7] = b4.w;
  }
  if (ADD) {
    const float* ap = add + (size_t)wid * cD + lane * 8;
    float4 a = *(const float4*)ap;
    float4 b4 = *(const float4*)(ap + 4);
    x[0] += a.x; x[1] += a.y; x[2] += a.z; x[3] += a.w;
    x[4] += b4.x; x[5] += b4.y; x[6] += b4.z; x[7] += b4.w;
  }
  float s = 0;
#pragma unroll
  for (int i = 0; i < 8; i++) s += x[i];
  s = wave_sum(s);
  const float mu = s * (1.0f / cD);
  float vs = 0;
#pragma unroll
  for (int i = 0; i < 8; i++) { const float d = x[i] - mu; vs += d * d; }
  vs = wave_sum(vs);
  const float rstd = 1.0f / sqrtf(vs * (1.0f / cD) + 1e-5f);
  float r[8];
#pragma unroll
  for (int i = 0; i < 8; i++) {
    const int d = lane * 8 + i;
    r[i] = (x[i] - mu) * rstd * g[d] + be[d];
  }
  if (WF) {
    float* op = out + (size_t)wid * cD + lane * 8;
    float4 a, b4;
    a.x = r[0]; a.y = r[1]; a.z = r[2]; a.w = r[3];
    b4.x = r[4]; b4.y = r[5]; b4.z = r[6]; b4.w = r[7];
    *(float4*)op = a; *(float4*)(op + 4) = b4;
  }
  if (WB) {
    bf16x8 ov;
#pragma unroll
    for (int i = 0; i < 8; i++) ov[i] = (bf16)r[i];
    *(bf16x8*)(out2 + (size_t)wid * cD + lane * 8) = ov;
  }
}

// LN of (enc + sinusoidal(expr)), in-place on f32 X.
__global__ __launch_bounds__(256) void embed_ln(
    float* __restrict__ X, const int* __restrict__ ids,
    const float* __restrict__ g, const float* __restrict__ be) {
  const int wid = blockIdx.x * 4 + (threadIdx.x >> 6);
  const int lane = threadIdx.x & 63;
  const float idv = (float)ids[wid];
  float* xp = X + (size_t)wid * cD + lane * 8;
  float x[8];
  {
    float4 a = *(const float4*)xp;
    float4 b4 = *(const float4*)(xp + 4);
    x[0] = a.x; x[1] = a.y; x[2] = a.z; x[3] = a.w;
    x[4] = b4.x; x[5] = b4.y; x[6] = b4.z; x[7] = b4.w;
  }
  const float kf = -0.03597789207803197f;  // -ln(10000)/256
#pragma unroll
  for (int i = 0; i < 8; i++) {
    const int d = lane * 8 + i;
    float e;
    if (d < 256) e = sinf(idv * expf(kf * (float)d));
    else         e = cosf(idv * expf(kf * (float)(d - 256)));
    x[i] += e;
  }
  float s = 0;
#pragma unroll
  for (int i = 0; i < 8; i++) s += x[i];
  s = wave_sum(s);
  const float mu = s * (1.0f / cD);
  float vs = 0;
#pragma unroll
  for (int i = 0; i < 8; i++) { const float d = x[i] - mu; vs += d * d; }
  vs = wave_sum(vs);
  const float rstd = 1.0f / sqrtf(vs * (1.0f / cD) + 1e-5f);
#pragma unroll
  for (int i = 0; i < 8; i++) {
    const int d = lane * 8 + i;
    xp[i] = (x[i] - mu) * rstd * g[d] + be[d];
  }
}

// ---------------------------------------------------------------------------
// bf16 MFMA flash cross-attention, KVBLK=128, denominator-via-ones-row,
// defer-max (base-2; Q pre-scaled by 0.125*log2e in its projection),
// reg-prefetch staging, XCD-aware 1-D grid, K∪P LDS union (3 barriers/tile).
// ---------------------------------------------------------------------------
__global__ __launch_bounds__(256) void flash_mfma(
    const bf16* __restrict__ Q, const bf16* __restrict__ Kc,
    const bf16* __restrict__ Vc, bf16* __restrict__ O, int ldkv) {
  __shared__ __align__(16) bf16 KP[4 * 16 * 136];  // K (16KB) ∪ P (17.4KB)
  __shared__ __align__(16) bf16 Vs[80 * 136];      // [d][s] padded; row 64 = ones
  const int id = blockIdx.x;
  const int b = (id & 63) >> 3, h = id & 7, qb = id >> 6;
  const int t = threadIdx.x, l = t & 63, w = t >> 6, g = l >> 4, c = l & 15;
  const int q0 = qb * 64 + w * 16;
  bf16x8 aq[2];
  {
    const bf16* qp = Q + ((size_t)b * cSD + q0 + c) * cD + h * cDH + g * 8;
    aq[0] = *(const bf16x8*)qp;
    aq[1] = *(const bf16x8*)(qp + 32);
  }
  // init ones/zero rows of Vs (rows 64..79); persists across tiles
  for (int idx = t; idx < 16 * 136; idx += 256) {
    const int rr = idx / 136, cc = idx - rr * 136;
    Vs[(64 + rr) * 136 + cc] = (bf16)(rr == 0 ? 1.f : 0.f);
  }
  const f32x4 zero4 = {0.f, 0.f, 0.f, 0.f};
  f32x4 o5[5];
#pragma unroll
  for (int j = 0; j < 5; j++) o5[j] = zero4;
  float mrow[4];
#pragma unroll
  for (int r = 0; r < 4; r++) mrow[r] = -1e30f;

  const int kr = t >> 1, kof = (t & 1) * 32;  // K stage: row, elem offset
  const int sidx = t & 31, dseg = t >> 5;     // V stage: s quad, d segment
  const size_t kvbase = (size_t)b * cSE * ldkv + h * cDH;
  char* KsC = (char*)KP;
  bf16* Pw = KP + w * 16 * 136;
  const float T2 = 11.541560327111708f;   // 8 * log2(e)

  bf16x8 pk[4], pv[4];  // prefetch registers
  auto LOADR = [&](int kt) {
    const bf16* kp = Kc + kvbase + (size_t)(kt + kr) * ldkv + kof;
#pragma unroll
    for (int i = 0; i < 4; i++) pk[i] = *(const bf16x8*)(kp + i * 8);
    const bf16* vp = Vc + kvbase + (size_t)(kt + 4 * sidx) * ldkv + dseg * 8;
#pragma unroll
    for (int i = 0; i < 4; i++) pv[i] = *(const bf16x8*)(vp + (size_t)i * ldkv);
  };
  auto WRITEL = [&]() {
    const int sw = (kr & 7) << 4;
#pragma unroll
    for (int i = 0; i < 4; i++)
      *(bf16x8*)(KsC + kr * 128 + (((kof + i * 8) * 2) ^ sw)) = pk[i];
#pragma unroll
    for (int e = 0; e < 8; e++) {
      bf16x4 q4;
      q4[0] = pv[0][e]; q4[1] = pv[1][e]; q4[2] = pv[2][e]; q4[3] = pv[3][e];
      *(bf16x4*)(Vs + (dseg * 8 + e) * 136 + 4 * sidx) = q4;
    }
  };
  LOADR(0);
  WRITEL();

  for (int kt = 0; kt < cSE; kt += 128) {
    const bool more = (kt + 128 < cSE);
    if (more) LOADR(kt + 128);    // issue next-tile loads (in flight all phase)
    __syncthreads();              // A: staged tile visible
    // QK^T: 8 key tiles of 16 (reads K region of KP)
    f32x4 s4[8];
#pragma unroll
    for (int t2 = 0; t2 < 8; t2++) {
      const int kr2 = t2 * 16 + c;
      const int sw2 = (kr2 & 7) << 4;
      bf16x8 bk0 = *(const bf16x8*)(KsC + kr2 * 128 + ((g * 16) ^ sw2));
      bf16x8 bk1 = *(const bf16x8*)(KsC + kr2 * 128 + ((64 + g * 16) ^ sw2));
      f32x4 z = zero4;
      z = __builtin_amdgcn_mfma_f32_16x16x32_bf16(aq[0], bk0, z, 0, 0, 0);
      z = __builtin_amdgcn_mfma_f32_16x16x32_bf16(aq[1], bk1, z, 0, 0, 0);
      s4[t2] = z;
    }
    __syncthreads();              // B: all K reads done; P may overwrite
    // softmax in base-2 (scores already in log2 domain); defer-max
#pragma unroll
    for (int r = 0; r < 4; r++) {
      float xv[8];
#pragma unroll
      for (int t2 = 0; t2 < 8; t2++) xv[t2] = s4[t2][r];
      float tm = xv[0];
#pragma unroll
      for (int t2 = 1; t2 < 8; t2++) tm = fmaxf(tm, xv[t2]);
      tm = fmaxf(tm, __shfl_xor(tm, 1));
      tm = fmaxf(tm, __shfl_xor(tm, 2));
      tm = fmaxf(tm, __shfl_xor(tm, 4));
      tm = fmaxf(tm, __shfl_xor(tm, 8));
      if (tm > mrow[r] + T2) {
        const float corr = exp2f(mrow[r] - tm);
        mrow[r] = tm;
#pragma unroll
        for (int j = 0; j < 5; j++) o5[j][r] *= corr;
      }
      const float m = mrow[r];
      const int qr = g * 4 + r;
#pragma unroll
      for (int t2 = 0; t2 < 8; t2++)
        Pw[qr * 136 + t2 * 16 + c] = (bf16)exp2f(xv[t2] - m);
    }
    // PV: A = P[16x128] (4 k-slots, own wave's slice), B = Vs (5 d-tiles)
    bf16x8 pa[4];
#pragma unroll
    for (int ks = 0; ks < 4; ks++)
      pa[ks] = *(const bf16x8*)(Pw + c * 136 + ks * 32 + g * 8);
#pragma unroll
    for (int j = 0; j < 5; j++) {
#pragma unroll
      for (int ks = 0; ks < 4; ks++) {
        bf16x8 bv = *(const bf16x8*)(Vs + (j * 16 + c) * 136 + ks * 32 + g * 8);
        o5[j] = __builtin_amdgcn_mfma_f32_16x16x32_bf16(pa[ks], bv, o5[j], 0, 0, 0);
      }
    }
    __syncthreads();              // C: P/Vs reads done; next stage may write
    if (more) WRITEL();
  }
#pragma unroll
  for (int r = 0; r < 4; r++) {
    const float den = __shfl(o5[4][r], l & 48);
    const float inv = 1.0f / den;
    const size_t row = (size_t)b * cSD + q0 + g * 4 + r;
#pragma unroll
    for (int j = 0; j < 4; j++)
      O[row * cD + h * cDH + j * 16 + c] = (bf16)(o5[j][r] * inv);
  }
}

// ---------------------------------------------------------------------------
extern "C" void kernel_launch(void* const* d_in, const int* in_sizes, int n_in,
                              void* d_out, int out_size, void* d_ws, size_t ws_size,
                              hipStream_t stream) {
  const float* in_enc = (const float*)d_in[0];
  const float* in_dec = (const float*)d_in[1];
  const int* expr = (const int*)d_in[2];
  const float* var_W = (const float*)d_in[3];
  const float* var_b = (const float*)d_in[4];
  const float* enc_g = (const float*)d_in[5];
  const float* enc_b = (const float*)d_in[6];
  const float* dec_g = (const float*)d_in[7];
  const float* dec_b = (const float*)d_in[8];
  const float* ln1_g = (const float*)d_in[9];
  const float* ln1_b = (const float*)d_in[10];
  const float* Wq = (const float*)d_in[11];
  const float* Wk = (const float*)d_in[12];
  const float* Wv = (const float*)d_in[13];
  const float* Wo = (const float*)d_in[14];
  const float* bo = (const float*)d_in[15];
  const float* ln2_g = (const float*)d_in[16];
  const float* ln2_b = (const float*)d_in[17];
  const float* w1 = (const float*)d_in[18];
  const float* b1 = (const float*)d_in[19];
  const float* w2 = (const float*)d_in[20];
  const float* b2 = (const float*)d_in[21];
  const float* proj = (const float*)d_in[22];
  const float* caWq = (const float*)d_in[23];
  const float* caWk = (const float*)d_in[24];
  const float* caWv = (const float*)d_in[25];
  const float* caWo = (const float*)d_in[26];
  const float* cabo = (const float*)d_in[27];
  const float* crg = (const float*)d_in[28];
  const float* crb = (const float*)d_in[29];
  const float* fw1 = (const float*)d_in[30];
  const float* fb1 = (const float*)d_in[31];
  const float* fw2 = (const float*)d_in[32];
  const float* fb2 = (const float*)d_in[33];
  const float* og = (const float*)d_in[34];
  const float* ob = (const float*)d_in[35];
  const float* hW = (const float*)d_in[36];
  const float* hb = (const float*)d_in[37];

  // ---- workspace layout (f32 units) --------------------------------------
  float* X     = (float*)d_ws;             // [16384,512] f32
  float* DC    = X + 8388608;              // [8192,512] f32
  bf16*  QKV   = (bf16*)(DC + 4194304);    // [16384,1536] bf16 fused
  bf16*  Vt    = QKV + 25165824;           // [64,80,2048] bf16 (decoder: Xb)
  bf16*  Pb    = Vt + 10485760;            // arena 50331648 bf16
  float* part  = (float*)(Pb + 50331648);  // [64,8,288,80] f32 (11796480)
  bf16*  kvT   = (bf16*)(part + 11796480); // [64,80,288] bf16
  float* bmax  = (float*)(kvT + 1474560);  // [1024+16]
  bf16*  Yb    = (bf16*)(bmax + 1040);     // [16384,512] bf16
  bf16*  DCb   = Yb + 8388608;             // [8192,512] bf16
  bf16*  Wt    = DCb + 4194304;            // [1048576] bf16 arena
  bf16*  projB = Wt + 1048576;             // [288,64] bf16
  bf16*  Wt2   = projB + 18432;            // [1048576] bf16 arena (FF w2T)
  const size_t need_bytes = (size_t)75458576 * 4;
  if (ws_size < need_bytes) return;

  // Overlays: phase 0 + decoder
  bf16* encB = Pb;                   // [16384,1280] (phase 0)
  bf16* decB = (bf16*)part;          // [8192,1280]  (phase 0; 21MB < 47MB)
  bf16* Pmid = Pb;                   // [16384,2048] (FF mid, layer loop)
  bf16* Xb   = Vt;                   // [16384,512]  (decoder; written by last FF2)
  bf16* Qc   = Pb + 8388608;         // [8192,512]
  bf16* KVc  = Pb + 12582912;        // [16384,1024] (K cols 0..511, V 512..1023)
  bf16* Fb   = Pb + 29360128;        // [8192,512]
  bf16* Pm2  = Pb + 33554432;        // [8192,2048]

  const dim3 blk(256);

  // ---- phase 0: embeddings ----------------------------------------------
  castf2b<<<2048, blk, 0, stream>>>(in_enc, encB, 16384 * 1280);
  castf2b<<<2048, blk, 0, stream>>>(in_dec, decB, 8192 * 1280);
  transpose_cast<<<dim3(16, 40), blk, 0, stream>>>(var_W, Wt, 1280, 512);
  gemm_mfma<0, 0, true, false><<<dim3(4, 128), blk, 0, stream>>>(encB, Wt, X, nullptr, var_b, 16384, 512, 1280);
  gemm_mfma<0, 0, true, false><<<dim3(4, 64), blk, 0, stream>>>(decB, Wt, DC, nullptr, var_b, 8192, 512, 1280);
  embed_ln<<<4096, blk, 0, stream>>>(X, expr, enc_g, enc_b);
  ln_rows<false, true, true><<<2048, blk, 0, stream>>>(DC, nullptr, dec_g, dec_b, DC, DCb);

  // ---- encoder layers ----------------------------------------------------
  for (int i = 0; i < cDEPTH; i++) {
    ln_rows<false, false, true><<<4096, blk, 0, stream>>>(X, nullptr, ln1_g + i * cD, ln1_b + i * cD, nullptr, Yb);
    transpose_cast4<<<dim3(16, 16, 4), blk, 0, stream>>>(
        Wq + (size_t)i * cD * cD, Wk + (size_t)i * cD * cD,
        Wv + (size_t)i * cD * cD, Wo + (size_t)i * cD * cD, Wt);
    // fused QKV GEMM: N=1536, B = [WqT;WkT;WvT]
    gemm_mfma<1, 0, false, false><<<dim3(12, 128), blk, 0, stream>>>(Yb, Wt, QKV, nullptr, nullptr, 16384, 1536, 512);
    // FAVOR+ (Q at +0, K at +512, V at +1024, stride 1536)
    proj_cast<<<72, blk, 0, stream>>>(proj + (size_t)i * cM * cDH, projB);
    vtrans<<<dim3(32, 64), blk, 0, stream>>>(QKV + 1024, 1536, Vt);
    favor_kmax<<<dim3(16, 64), blk, 0, stream>>>(QKV + 512, 1536, projB, bmax);
    favor_kkv<<<dim3(8, 64), blk, 0, stream>>>(QKV + 512, 1536, projB, Vt, bmax, part);
    kv_reduce<<<64, blk, 0, stream>>>(part, kvT);
    favor_qout<<<dim3(16, 64), blk, 0, stream>>>(QKV, 1536, projB, kvT, Yb);
    // Wo + residual
    gemm_mfma<0, 0, true, true><<<dim3(4, 128), blk, 0, stream>>>(Yb, Wt + 786432, X, nullptr, bo + i * cD, 16384, 512, 512);
    // FF (both weight transposes in one launch: w1T->Wt, w2T->Wt2)
    ln_rows<false, false, true><<<4096, blk, 0, stream>>>(X, nullptr, ln2_g + i * cD, ln2_b + i * cD, nullptr, Yb);
    transpose_castFF<<<dim3(1024, 2), blk, 0, stream>>>(
        w1 + (size_t)i * cD * cFF, w2 + (size_t)i * cFF * cD, Wt, Wt2);
    gemm_mfma<1, 1, true, false><<<dim3(16, 128), blk, 0, stream>>>(Yb, Wt, Pmid, nullptr, b1 + i * cFF, 16384, 2048, 512);
    if (i < cDEPTH - 1) {
      gemm_mfma<0, 0, true, true><<<dim3(4, 128), blk, 0, stream>>>(Pmid, Wt2, X, nullptr, b2 + i * cD, 16384, 512, 2048);
    } else {
      // last layer: also emit bf16 mirror of X into Xb (decoder input)
      gemm_mfma<2, 0, true, true><<<dim3(4, 128), blk, 0, stream>>>(Pmid, Wt2, X, Xb, b2 + i * cD, 16384, 512, 2048);
    }
  }

  // ---- decoder / cross-attention ----------------------------------------
  transpose_cast4<<<dim3(16, 16, 4), blk, 0, stream>>>(caWq, caWk, caWv, caWo, Wt);
  // Q projection with flash prescale folded in (ACT=2)
  gemm_mfma<1, 2, false, false><<<dim3(4, 64), blk, 0, stream>>>(DCb, Wt, Qc, nullptr, nullptr, 8192, 512, 512);
  // fused K+V GEMM: N=1024, B = [WkT;WvT]
  gemm_mfma<1, 0, false, false><<<dim3(8, 128), blk, 0, stream>>>(Xb, Wt + 262144, KVc, nullptr, nullptr, 16384, 1024, 512);
  flash_mfma<<<dim3(1024), blk, 0, stream>>>(Qc, KVc, KVc + 512, Fb, 1024);
  gemm_mfma<0, 0, true, false><<<dim3(4, 64), blk, 0, stream>>>(Fb, Wt + 786432, X, nullptr, cabo, 8192, 512, 512);
  ln_rows<true, false, true><<<2048, blk, 0, stream>>>(X, DC, crg, crb, nullptr, Yb);
  transpose_castFF<<<dim3(1024, 2), blk, 0, stream>>>(fw1, fw2, Wt, Wt2);
  gemm_mfma<1, 1, true, false><<<dim3(16, 64), blk, 0, stream>>>(Yb, Wt, Pm2, nullptr, fb1, 8192, 2048, 512);
  gemm_mfma<0, 0, true, false><<<dim3(4, 64), blk, 0, stream>>>(Pm2, Wt2, X + 4194304, nullptr, fb2, 8192, 512, 2048);
  ln_rows<false, false, true><<<2048, blk, 0, stream>>>(X + 4194304, nullptr, og, ob, nullptr, Yb);
  transpose_cast<<<dim3(4, 16), blk, 0, stream>>>(hW, Wt, 512, 128);
  gemm_mfma<0, 0, true, false><<<dim3(1, 64), blk, 0, stream>>>(Yb, Wt, (float*)d_out, nullptr, hb, 8192, 128, 512);
}

// Round 9
// 1976.874 us; speedup vs baseline: 6.7051x; 1.0340x over previous
//
#include <hip/hip_runtime.h>
#include <hip/hip_bf16.h>
#include <math.h>

// Problem constants
constexpr int cB = 8, cSE = 2048, cSD = 1024, cIN = 1280, cD = 512,
              cDEPTH = 4, cH = 8, cDH = 64, cM = 266, cFF = 2048, cNB = 128;
constexpr int cMP = 288;  // cM padded to multiple of 16 (features pad -> 0)

#define DEV __device__ __forceinline__

typedef __bf16 bf16;
typedef __attribute__((ext_vector_type(8))) __bf16 bf16x8;
typedef __attribute__((ext_vector_type(4))) __bf16 bf16x4;
typedef __attribute__((ext_vector_type(2))) __bf16 bf16x2;
typedef __attribute__((ext_vector_type(4))) float f32x4;

DEV float gelu_f(float x) { return 0.5f * x * (1.0f + erff(x * 0.70710678118654752440f)); }

DEV float wave_sum(float v) {
#pragma unroll
  for (int o = 32; o; o >>= 1) v += __shfl_xor(v, o);
  return v;
}
DEV float wave_max(float v) {
#pragma unroll
  for (int o = 32; o; o >>= 1) v = fmaxf(v, __shfl_xor(v, o));
  return v;
}

#define GL2LDS(gp, lp) __builtin_amdgcn_global_load_lds(                    \
    (const __attribute__((address_space(1))) void*)(gp),                    \
    (__attribute__((address_space(3))) void*)(lp), 16, 0, 0)

// ---------------------------------------------------------------------------
// bf16 MFMA GEMM (m97 structure) with XCD-aware bijective block swizzle.
// C[M,N] = epi(A[M,K] @ Bt[N,K]^T). M%128==0, N%128==0, K%32==0.
// OUT: 0=f32 C, 1=bf16 C, 2=f32 C (+RES) AND bf16 mirror to Cv2.
// ACT: 1 = exact GELU, 2 = scale by 0.125*log2(e) (flash Q prescale).
// ---------------------------------------------------------------------------
template <int OUT, int ACT, bool BIAS, bool RES>
__global__ __launch_bounds__(256) void gemm_mfma(
    const bf16* __restrict__ A, const bf16* __restrict__ Bt,
    void* __restrict__ Cv, bf16* __restrict__ Cv2,
    const float* __restrict__ bias, int M, int N, int K) {
  __shared__ bf16 As[128 * 32];
  __shared__ bf16 Bs[128 * 32];
  const int t = threadIdx.x, l = t & 63, w = t >> 6;
  const int g = l >> 4, c = l & 15;
  // XCD swizzle: blocks on one XCD (id%8) take a contiguous panel chunk
  const int nwg = gridDim.x * gridDim.y;
  int id = blockIdx.y * gridDim.x + blockIdx.x;
  if ((nwg & 7) == 0) id = (id & 7) * (nwg >> 3) + (id >> 3);
  const int m0 = (id / gridDim.x) * 128, n0 = (id % gridDim.x) * 128;
  const int wr = (w >> 1) * 64, wc = (w & 1) * 64;
  const int srow = w * 32 + (l >> 2);
  const int scol = (l & 3) * 8;
  const bf16* gA = A + (size_t)(m0 + srow) * K + scol;
  const bf16* gB = Bt + (size_t)(n0 + srow) * K + scol;
  bf16* lA = As + w * 1024;
  bf16* lB = Bs + w * 1024;

  const f32x4 zero4 = {0.f, 0.f, 0.f, 0.f};
  f32x4 acc[4][4];
#pragma unroll
  for (int i = 0; i < 4; i++)
#pragma unroll
    for (int j = 0; j < 4; j++) acc[i][j] = zero4;

  for (int k0 = 0; k0 < K; k0 += 32) {
    GL2LDS(gA + k0, lA);
    GL2LDS(gA + (size_t)16 * K + k0, lA + 512);
    GL2LDS(gB + k0, lB);
    GL2LDS(gB + (size_t)16 * K + k0, lB + 512);
    __syncthreads();
    bf16x8 af[4], bfr[4];
#pragma unroll
    for (int i = 0; i < 4; i++)
      af[i] = *(const bf16x8*)(As + (wr + i * 16 + c) * 32 + g * 8);
#pragma unroll
    for (int j = 0; j < 4; j++)
      bfr[j] = *(const bf16x8*)(Bs + (wc + j * 16 + c) * 32 + g * 8);
#pragma unroll
    for (int i = 0; i < 4; i++)
#pragma unroll
      for (int j = 0; j < 4; j++)
        acc[i][j] = __builtin_amdgcn_mfma_f32_16x16x32_bf16(af[i], bfr[j], acc[i][j], 0, 0, 0);
    __syncthreads();
  }
  float* Cf = (float*)Cv;
  bf16* Cb = (bf16*)Cv;
#pragma unroll
  for (int i = 0; i < 4; i++) {
    const int mb = m0 + wr + i * 16 + g * 4;
#pragma unroll
    for (int j = 0; j < 4; j++) {
      const int n = n0 + wc + j * 16 + c;
      const float bv = BIAS ? bias[n] : 0.f;
#pragma unroll
      for (int r = 0; r < 4; r++) {
        float v = acc[i][j][r] + bv;
        if (ACT == 1) v = gelu_f(v);
        if (ACT == 2) v *= 0.18033688011112042f;  // 0.125*log2(e)
        const size_t idx = (size_t)(mb + r) * N + n;
        if (OUT == 0 || OUT == 2) {
          float* cp = Cf + idx;
          if (RES) v += *cp;
          *cp = v;
          if (OUT == 2) Cv2[idx] = (bf16)v;
        } else {
          Cb[idx] = (bf16)v;
        }
      }
    }
  }
}

// ---------------------------------------------------------------------------
// mega_prep: ALL per-layer weight transposes + var_W + proj casts, one launch.
// z = layer*6 + mat (mat: 0..3 = Wq/Wk/Wv/Wo 512x512, 4 = w1 512x2048,
// 5 = w2 2048x512); z=24: var_W 1280x512 -> WtVar; z=25: proj cast x4.
// Dest per layer: WL + layer*3145728 + {0,256K,512K,768K | 1M | 2M}.
// ---------------------------------------------------------------------------
__global__ __launch_bounds__(256) void mega_prep(
    const float* __restrict__ Wq, const float* __restrict__ Wk,
    const float* __restrict__ Wv, const float* __restrict__ Wo,
    const float* __restrict__ w1, const float* __restrict__ w2,
    const float* __restrict__ var_W, const float* __restrict__ proj,
    bf16* __restrict__ WL, bf16* __restrict__ WtVar,
    bf16* __restrict__ projB4) {
  const int z = blockIdx.y, bid = blockIdx.x, t = threadIdx.x;
  if (z == 25) {  // proj cast (4 layers), dn prescale, pad rows -> 0
    const int idx = bid * 256 + t;
    if (idx < 4 * cMP * cDH) {
      const int layer = idx / (cMP * cDH), r = idx % (cMP * cDH);
      const int m = r >> 6;
      projB4[idx] = (bf16)(m < cM ? proj[(size_t)layer * cM * cDH + r] * 0.35355339059327373f : 0.f);
    }
    return;
  }
  __shared__ float tile[32][33];
  const float* W;
  bf16* dst;
  int K, N;
  if (z == 24) {
    W = var_W; dst = WtVar; K = 1280; N = 512;
  } else {
    const int layer = z / 6, mat = z % 6;
    bf16* base = WL + (size_t)layer * 3145728;
    if (mat < 4) {
      W = (mat == 0 ? Wq : mat == 1 ? Wk : mat == 2 ? Wv : Wo) + (size_t)layer * 262144;
      dst = base + mat * 262144; K = 512; N = 512;
    } else if (mat == 4) {
      W = w1 + (size_t)layer * 1048576; dst = base + 1048576; K = 512; N = 2048;
    } else {
      W = w2 + (size_t)layer * 1048576; dst = base + 2097152; K = 2048; N = 512;
    }
  }
  const int nt = N >> 5;
  if (bid >= nt * (K >> 5)) return;
  const int n0 = (bid % nt) * 32, k0 = (bid / nt) * 32;
  const int tx = t & 31, ty = t >> 5;
#pragma unroll
  for (int i = ty; i < 32; i += 8) tile[i][tx] = W[(size_t)(k0 + i) * N + n0 + tx];
  __syncthreads();
#pragma unroll
  for (int i = ty; i < 32; i += 8)
    dst[(size_t)(n0 + i) * K + k0 + tx] = (bf16)tile[tx][i];
}

// Decoder weights: z 0..3 caW squares, 4 = fw1 512x2048, 5 = fw2 2048x512,
// 6 = head 512x128. Dest WD + {0,256K,512K,768K | 1M | 2M | 3M}.
__global__ __launch_bounds__(256) void mega_prep_dec(
    const float* __restrict__ caWq, const float* __restrict__ caWk,
    const float* __restrict__ caWv, const float* __restrict__ caWo,
    const float* __restrict__ fw1, const float* __restrict__ fw2,
    const float* __restrict__ hW, bf16* __restrict__ WD) {
  const int z = blockIdx.y, bid = blockIdx.x, t = threadIdx.x;
  __shared__ float tile[32][33];
  const float* W;
  bf16* dst;
  int K, N;
  if (z < 4) {
    W = (z == 0 ? caWq : z == 1 ? caWk : z == 2 ? caWv : caWo);
    dst = WD + z * 262144; K = 512; N = 512;
  } else if (z == 4) {
    W = fw1; dst = WD + 1048576; K = 512; N = 2048;
  } else if (z == 5) {
    W = fw2; dst = WD + 2097152; K = 2048; N = 512;
  } else {
    W = hW; dst = WD + 3145728; K = 512; N = 128;
  }
  const int nt = N >> 5;
  if (bid >= nt * (K >> 5)) return;
  const int n0 = (bid % nt) * 32, k0 = (bid / nt) * 32;
  const int tx = t & 31, ty = t >> 5;
#pragma unroll
  for (int i = ty; i < 32; i += 8) tile[i][tx] = W[(size_t)(k0 + i) * N + n0 + tx];
  __syncthreads();
#pragma unroll
  for (int i = ty; i < 32; i += 8)
    dst[(size_t)(n0 + i) * K + k0 + tx] = (bf16)tile[tx][i];
}

// flat f32 -> bf16 cast, n % 4 == 0
__global__ __launch_bounds__(256) void castf2b(
    const float* __restrict__ x, bf16* __restrict__ y, int n) {
  int i = (blockIdx.x * 256 + threadIdx.x) * 4;
  const int stride = gridDim.x * 1024;
  for (; i < n; i += stride) {
    float4 v = *(const float4*)(x + i);
    bf16x4 o;
    o[0] = (bf16)v.x; o[1] = (bf16)v.y; o[2] = (bf16)v.z; o[3] = (bf16)v.w;
    *(bf16x4*)(y + i) = o;
  }
}

// V head-transpose: Vh (stride ld) -> Vt [64 z][80 d][2048 s]
// rows 64 = ones (ksum fusion), 65..79 = zeros.
__global__ __launch_bounds__(256) void vtrans(
    const bf16* __restrict__ Vh, int ld, bf16* __restrict__ Vt) {
  __shared__ bf16 tile[64][65];
  const int z = blockIdx.y, b = z >> 3, h = z & 7;
  const int s0 = blockIdx.x * 64;
  const int t = threadIdx.x;
#pragma unroll
  for (int r = t >> 3; r < 64; r += 32) {
    bf16x8 v = *(const bf16x8*)(Vh + ((size_t)b * cSE + s0 + r) * ld + h * cDH + (t & 7) * 8);
#pragma unroll
    for (int e = 0; e < 8; e++) tile[(t & 7) * 8 + e][r] = v[e];
  }
  __syncthreads();
  bf16* vz = Vt + (size_t)z * 80 * cSE;
#pragma unroll
  for (int d = t >> 3; d < 64; d += 32) {
    bf16x8 o;
#pragma unroll
    for (int e = 0; e < 8; e++) o[e] = tile[d][(t & 7) * 8 + e];
    *(bf16x8*)(vz + (size_t)d * cSE + s0 + (t & 7) * 8) = o;
  }
  // ones / zeros rows 64..79
  const int rr = t >> 4, seg = (t & 15) * 4;
  bf16x4 ov;
  const float val = (rr == 0) ? 1.f : 0.f;
  ov[0] = (bf16)val; ov[1] = (bf16)val; ov[2] = (bf16)val; ov[3] = (bf16)val;
  *(bf16x4*)(vz + (size_t)(64 + rr) * cSE + s0 + seg) = ov;
}

// ---------------------------------------------------------------------------
// FAVOR k global max: block max of kd = (K*dn) @ projB^T -> bmax[1024].
// ---------------------------------------------------------------------------
__global__ __launch_bounds__(256, 1) void favor_kmax(
    const bf16* __restrict__ Kh, int ld, const bf16* __restrict__ projB,
    float* __restrict__ bmax) {
  __shared__ float sm[4];
  const int z = blockIdx.y, b = z >> 3, h = z & 7;
  const int s0 = blockIdx.x * 128;
  const int t = threadIdx.x, l = t & 63, w = t >> 6, g = l >> 4, c = l & 15;
  const int wr = (w >> 1) * 64, wcol = (w & 1) * 144;
  const f32x4 zero4 = {0.f, 0.f, 0.f, 0.f};
  f32x4 acc[4][9];
#pragma unroll
  for (int i = 0; i < 4; i++)
#pragma unroll
    for (int j = 0; j < 9; j++) acc[i][j] = zero4;
  const size_t abase = ((size_t)b * cSE + s0) * ld + h * cDH;
#pragma unroll
  for (int k0 = 0; k0 < 64; k0 += 32) {
    bf16x8 af[4];
#pragma unroll
    for (int i = 0; i < 4; i++)
      af[i] = *(const bf16x8*)(Kh + abase + (size_t)(wr + i * 16 + c) * ld + k0 + g * 8);
#pragma unroll
    for (int j = 0; j < 9; j++) {
      bf16x8 bfr = *(const bf16x8*)(projB + (wcol + j * 16 + c) * 64 + k0 + g * 8);
#pragma unroll
      for (int i = 0; i < 4; i++)
        acc[i][j] = __builtin_amdgcn_mfma_f32_16x16x32_bf16(af[i], bfr, acc[i][j], 0, 0, 0);
    }
  }
  float m = -3e38f;
#pragma unroll
  for (int i = 0; i < 4; i++)
#pragma unroll
    for (int j = 0; j < 9; j++) {
      const int mc = wcol + j * 16 + c;
      if (mc < cM) {
#pragma unroll
        for (int r = 0; r < 4; r++) m = fmaxf(m, acc[i][j][r]);
      }
    }
  m = wave_max(m);
  if (l == 0) sm[w] = m;
  __syncthreads();
  if (t == 0)
    bmax[blockIdx.y * 16 + blockIdx.x] =
        fmaxf(fmaxf(sm[0], sm[1]), fmaxf(sm[2], sm[3]));
}

// ---------------------------------------------------------------------------
// FUSED phi(k) + kv accumulate. Per block: z, s-chunk of 256 (8 chunks).
// Loop 64-s subtiles: kd via MFMA (regs) -> exp (inline diag, gmax) ->
// kp staged in LDS [288 m][72 s-pad] -> kv += kp^T @ Vt (d=64 col = ksum via
// ones-row). part[z,ch,m,80] f32 out. Pk never touches HBM.
// ---------------------------------------------------------------------------
__global__ __launch_bounds__(256, 1) void favor_kkv(
    const bf16* __restrict__ Kh, int ld, const bf16* __restrict__ projB,
    const bf16* __restrict__ Vt, const float* __restrict__ bmax,
    float* __restrict__ part) {
  __shared__ bf16 kp[288 * 72];
  __shared__ float sm[4];
  const int z = blockIdx.y, b = z >> 3, h = z & 7;
  const int chunk = blockIdx.x;
  const int t = threadIdx.x, l = t & 63, w = t >> 6, g = l >> 4, c = l & 15;
  // inline global-max reduce of bmax[1024]
  float gm;
  {
    float m = -1e30f;
    for (int i = t; i < 1024; i += 256) m = fmaxf(m, bmax[i]);
    m = wave_max(m);
    if (l == 0) sm[w] = m;
    __syncthreads();
    gm = fmaxf(fmaxf(sm[0], sm[1]), fmaxf(sm[2], sm[3]));
  }
  const int pr = (w >> 1) * 32;    // phase-1 s rows (0/32)
  const int wcol = (w & 1) * 144;  // phase-1 m cols
  const int wm = (w & 1) * 144, wd = (w >> 1) * 32;  // phase-2 assignment
  const bool dden = (wd == 32);
  const float ratio = 0.061313927f;  // 266^-0.5
  const f32x4 zero4 = {0.f, 0.f, 0.f, 0.f};
  f32x4 kacc[9][2], kaccx[9];
#pragma unroll
  for (int j = 0; j < 9; j++) {
    kacc[j][0] = zero4; kacc[j][1] = zero4; kaccx[j] = zero4;
  }
  const size_t kbase = (size_t)b * cSE * ld + h * cDH;
  const size_t vtz = (size_t)z * 80 * cSE;

  for (int st = 0; st < 256; st += 64) {
    const int sg = chunk * 256 + st;
    // ---- phase 1: kd tile [64 s x 288 m] in registers ----
    f32x4 pacc[2][9];
#pragma unroll
    for (int i = 0; i < 2; i++)
#pragma unroll
      for (int j = 0; j < 9; j++) pacc[i][j] = zero4;
    float sq[2] = {0.f, 0.f};
#pragma unroll
    for (int k0 = 0; k0 < 64; k0 += 32) {
      bf16x8 af[2];
#pragma unroll
      for (int i = 0; i < 2; i++) {
        af[i] = *(const bf16x8*)(Kh + kbase + (size_t)(sg + pr + i * 16 + c) * ld + k0 + g * 8);
#pragma unroll
        for (int e = 0; e < 8; e++) {
          const float v = (float)af[i][e];
          sq[i] += v * v;
        }
      }
#pragma unroll
      for (int j = 0; j < 9; j++) {
        bf16x8 bfr = *(const bf16x8*)(projB + (wcol + j * 16 + c) * 64 + k0 + g * 8);
        pacc[0][j] = __builtin_amdgcn_mfma_f32_16x16x32_bf16(af[0], bfr, pacc[0][j], 0, 0, 0);
        pacc[1][j] = __builtin_amdgcn_mfma_f32_16x16x32_bf16(af[1], bfr, pacc[1][j], 0, 0, 0);
      }
    }
#pragma unroll
    for (int i = 0; i < 2; i++) {
      sq[i] += __shfl_xor(sq[i], 16);
      sq[i] += __shfl_xor(sq[i], 32);
    }
    float rowsub[2][4];
#pragma unroll
    for (int i = 0; i < 2; i++)
#pragma unroll
      for (int r = 0; r < 4; r++)
        rowsub[i][r] = gm + 0.0625f * __shfl(sq[i], g * 4 + r);
    __syncthreads();  // prev subtile's phase-2 reads of kp done
    // store kp to LDS [m][s_local], bf16x4 along s
#pragma unroll
    for (int i = 0; i < 2; i++)
#pragma unroll
      for (int j = 0; j < 9; j++) {
        const int mc = wcol + j * 16 + c;
        bf16x4 o;
#pragma unroll
        for (int r = 0; r < 4; r++) {
          const float v = (mc < cM)
              ? ratio * (__expf(pacc[i][j][r] - rowsub[i][r]) + 1e-4f) : 0.f;
          o[r] = (bf16)v;
        }
        *(bf16x4*)(kp + (size_t)mc * 72 + pr + i * 16 + g * 4) = o;
      }
    __syncthreads();
    // ---- phase 2: kv += kp^T @ Vt over this subtile ----
#pragma unroll
    for (int k0 = 0; k0 < 64; k0 += 32) {
      bf16x8 bv0 = *(const bf16x8*)(Vt + vtz + (size_t)(wd + c) * cSE + sg + k0 + g * 8);
      bf16x8 bv1 = *(const bf16x8*)(Vt + vtz + (size_t)(wd + 16 + c) * cSE + sg + k0 + g * 8);
      bf16x8 bvx;
      if (dden)
        bvx = *(const bf16x8*)(Vt + vtz + (size_t)(64 + c) * cSE + sg + k0 + g * 8);
#pragma unroll
      for (int j = 0; j < 9; j++) {
        bf16x8 am = *(const bf16x8*)(kp + (size_t)(wm + j * 16 + c) * 72 + k0 + g * 8);
        kacc[j][0] = __builtin_amdgcn_mfma_f32_16x16x32_bf16(am, bv0, kacc[j][0], 0, 0, 0);
        kacc[j][1] = __builtin_amdgcn_mfma_f32_16x16x32_bf16(am, bv1, kacc[j][1], 0, 0, 0);
        if (dden)
          kaccx[j] = __builtin_amdgcn_mfma_f32_16x16x32_bf16(am, bvx, kaccx[j], 0, 0, 0);
      }
    }
  }
  // store partials
  float* po = part + ((size_t)z * 8 + chunk) * (cMP * 80);
#pragma unroll
  for (int j = 0; j < 9; j++)
#pragma unroll
    for (int i = 0; i < 2; i++)
#pragma unroll
      for (int r = 0; r < 4; r++)
        po[(size_t)(wm + j * 16 + g * 4 + r) * 80 + wd + i * 16 + c] = kacc[j][i][r];
  if (dden) {
#pragma unroll
    for (int j = 0; j < 9; j++)
#pragma unroll
      for (int r = 0; r < 4; r++)
        po[(size_t)(wm + j * 16 + g * 4 + r) * 80 + 64 + c] = kaccx[j][r];
  }
}

// reduce 8 chunks + transpose: kvT[z,d(80),m]; row 64 = ksum. grid (4,64).
__global__ __launch_bounds__(256) void kv_reduce(
    const float* __restrict__ part, bf16* __restrict__ kvT) {
  const int z = blockIdx.y, q = blockIdx.x;
  const float* p = part + (size_t)z * 8 * (cMP * 80);
  bf16* o = kvT + (size_t)z * 80 * cMP;
  const int lo = q * 5760, hi = lo + 5760;  // cMP*80/4
  for (int idx = lo + threadIdx.x; idx < hi; idx += 256) {
    const int m = idx / 80, d = idx - m * 80;
    float s = 0.f;
#pragma unroll
    for (int cc = 0; cc < 8; cc++) s += p[idx + (size_t)cc * (cMP * 80)];
    o[(size_t)d * cMP + m] = (bf16)s;
  }
}

// ---------------------------------------------------------------------------
// Fused phi(q) + output (Qh stride ld): qd in regs -> row max + inline diag ->
// qp staged in LDS [128][296] -> out = qp @ kvT^T (+den col) -> Y.
// ---------------------------------------------------------------------------
__global__ __launch_bounds__(256, 1) void favor_qout(
    const bf16* __restrict__ Qh, int ld, const bf16* __restrict__ projB,
    const bf16* __restrict__ kvT, bf16* __restrict__ Y) {
  __shared__ bf16 Plds[128 * 296];
  __shared__ float rmaxs[4][64];
  __shared__ float denl[128];
  const int z = blockIdx.y, b = z >> 3, h = z & 7;
  const int s0 = blockIdx.x * 128;
  const int t = threadIdx.x, l = t & 63, w = t >> 6, g = l >> 4, c = l & 15;
  const int wr = (w >> 1) * 64, wcol = (w & 1) * 144;
  const f32x4 zero4 = {0.f, 0.f, 0.f, 0.f};
  f32x4 acc[4][9];
#pragma unroll
  for (int i = 0; i < 4; i++)
#pragma unroll
    for (int j = 0; j < 9; j++) acc[i][j] = zero4;
  float sq[4] = {0.f, 0.f, 0.f, 0.f};
  const size_t abase = ((size_t)b * cSE + s0) * ld + h * cDH;
#pragma unroll
  for (int k0 = 0; k0 < 64; k0 += 32) {
    bf16x8 af[4];
#pragma unroll
    for (int i = 0; i < 4; i++) {
      af[i] = *(const bf16x8*)(Qh + abase + (size_t)(wr + i * 16 + c) * ld + k0 + g * 8);
#pragma unroll
      for (int e = 0; e < 8; e++) {
        const float v = (float)af[i][e];
        sq[i] += v * v;
      }
    }
#pragma unroll
    for (int j = 0; j < 9; j++) {
      bf16x8 bfr = *(const bf16x8*)(projB + (wcol + j * 16 + c) * 64 + k0 + g * 8);
#pragma unroll
      for (int i = 0; i < 4; i++)
        acc[i][j] = __builtin_amdgcn_mfma_f32_16x16x32_bf16(af[i], bfr, acc[i][j], 0, 0, 0);
    }
  }
#pragma unroll
  for (int i = 0; i < 4; i++) {
    sq[i] += __shfl_xor(sq[i], 16);
    sq[i] += __shfl_xor(sq[i], 32);
  }
  const float ratio = 0.061313927f;  // 266^-0.5
  float rowsub[4][4];
#pragma unroll
  for (int i = 0; i < 4; i++)
#pragma unroll
    for (int r = 0; r < 4; r++) {
      float m = -3e38f;
#pragma unroll
      for (int j = 0; j < 9; j++) {
        const int mc = wcol + j * 16 + c;
        m = (mc < cM) ? fmaxf(m, acc[i][j][r]) : m;
      }
      m = fmaxf(m, __shfl_xor(m, 1));
      m = fmaxf(m, __shfl_xor(m, 2));
      m = fmaxf(m, __shfl_xor(m, 4));
      m = fmaxf(m, __shfl_xor(m, 8));
      rowsub[i][r] = m;
    }
  if (c == 0) {
#pragma unroll
    for (int i = 0; i < 4; i++)
#pragma unroll
      for (int r = 0; r < 4; r++) rmaxs[w][i * 16 + g * 4 + r] = rowsub[i][r];
  }
  __syncthreads();
#pragma unroll
  for (int i = 0; i < 4; i++)
#pragma unroll
    for (int r = 0; r < 4; r++) {
      const int row = i * 16 + g * 4 + r;
      rowsub[i][r] = fmaxf(rowsub[i][r], rmaxs[w ^ 1][row]) +
                     0.0625f * __shfl(sq[i], g * 4 + r);
    }
#pragma unroll
  for (int i = 0; i < 4; i++)
#pragma unroll
    for (int j = 0; j < 9; j++) {
      const int mc = wcol + j * 16 + c;
#pragma unroll
      for (int r = 0; r < 4; r++) {
        const float v = (mc < cM)
            ? ratio * (__expf(acc[i][j][r] - rowsub[i][r]) + 1e-4f) : 0.f;
        Plds[(wr + i * 16 + g * 4 + r) * 296 + mc] = (bf16)v;
      }
    }
  __syncthreads();

  // ---- output phase: out = qp @ kvT^T, den from kvT ksum row ----
  const int wd = (w & 1) * 32;
  const bool dden = (wd == 32);
  f32x4 acc2[4][2], accx[4];
#pragma unroll
  for (int i = 0; i < 4; i++) {
    acc2[i][0] = zero4; acc2[i][1] = zero4; accx[i] = zero4;
  }
  const size_t kz = (size_t)z * 80 * cMP;
#pragma unroll 3
  for (int k0 = 0; k0 < cMP; k0 += 32) {
    bf16x8 bv[2], bvx;
#pragma unroll
    for (int j = 0; j < 2; j++)
      bv[j] = *(const bf16x8*)(kvT + kz + (size_t)(wd + j * 16 + c) * cMP + k0 + g * 8);
    if (dden)
      bvx = *(const bf16x8*)(kvT + kz + (size_t)(64 + c) * cMP + k0 + g * 8);
#pragma unroll
    for (int i = 0; i < 4; i++) {
      bf16x8 av = *(const bf16x8*)(Plds + (wr + i * 16 + c) * 296 + k0 + g * 8);
      acc2[i][0] = __builtin_amdgcn_mfma_f32_16x16x32_bf16(av, bv[0], acc2[i][0], 0, 0, 0);
      acc2[i][1] = __builtin_amdgcn_mfma_f32_16x16x32_bf16(av, bv[1], acc2[i][1], 0, 0, 0);
      if (dden)
        accx[i] = __builtin_amdgcn_mfma_f32_16x16x32_bf16(av, bvx, accx[i], 0, 0, 0);
    }
  }
  if (dden && c == 0) {
#pragma unroll
    for (int i = 0; i < 4; i++)
#pragma unroll
      for (int r = 0; r < 4; r++)
        denl[wr + i * 16 + g * 4 + r] = accx[i][r];
  }
  __syncthreads();
#pragma unroll
  for (int i = 0; i < 4; i++)
#pragma unroll
    for (int r = 0; r < 4; r++) {
      const int row = wr + i * 16 + g * 4 + r;
      const float inv = 1.0f / denl[row];
#pragma unroll
      for (int j = 0; j < 2; j++)
        Y[((size_t)b * cSE + s0 + row) * cD + h * cDH + wd + j * 16 + c] =
            (bf16)(acc2[i][j][r] * inv);
    }
}

// ---------------------------------------------------------------------------
// LayerNorm rows of 512; wave per row. WF: f32 out, WB: bf16 out2.
// ---------------------------------------------------------------------------
template <bool ADD, bool WF, bool WB>
__global__ __launch_bounds__(256) void ln_rows(
    const float* __restrict__ in, const float* __restrict__ add,
    const float* __restrict__ g, const float* __restrict__ be,
    float* __restrict__ out, bf16* __restrict__ out2) {
  const int wid = blockIdx.x * 4 + (threadIdx.x >> 6);
  const int lane = threadIdx.x & 63;
  const float* ip = in + (size_t)wid * cD + lane * 8;
  float x[8];
  {
    float4 a = *(const float4*)ip;
    float4 b4 = *(const float4*)(ip + 4);
    x[0] = a.x; x[1] = a.y; x[2] = a.z; x[3] = a.w;
    x[4] = b4.x; x[5] = b4.y; x[6] = b4.z; x[7] = b4.w;
  }
  if (ADD) {
    const float* ap = add + (size_t)wid * cD + lane * 8;
    float4 a = *(const float4*)ap;
    float4 b4 = *(const float4*)(ap + 4);
    x[0] += a.x; x[1] += a.y; x[2] += a.z; x[3] += a.w;
    x[4] += b4.x; x[5] += b4.y; x[6] += b4.z; x[7] += b4.w;
  }
  float s = 0;
#pragma unroll
  for (int i = 0; i < 8; i++) s += x[i];
  s = wave_sum(s);
  const float mu = s * (1.0f / cD);
  float vs = 0;
#pragma unroll
  for (int i = 0; i < 8; i++) { const float d = x[i] - mu; vs += d * d; }
  vs = wave_sum(vs);
  const float rstd = 1.0f / sqrtf(vs * (1.0f / cD) + 1e-5f);
  float r[8];
#pragma unroll
  for (int i = 0; i < 8; i++) {
    const int d = lane * 8 + i;
    r[i] = (x[i] - mu) * rstd * g[d] + be[d];
  }
  if (WF) {
    float* op = out + (size_t)wid * cD + lane * 8;
    float4 a, b4;
    a.x = r[0]; a.y = r[1]; a.z = r[2]; a.w = r[3];
    b4.x = r[4]; b4.y = r[5]; b4.z = r[6]; b4.w = r[7];
    *(float4*)op = a; *(float4*)(op + 4) = b4;
  }
  if (WB) {
    bf16x8 ov;
#pragma unroll
    for (int i = 0; i < 8; i++) ov[i] = (bf16)r[i];
    *(bf16x8*)(out2 + (size_t)wid * cD + lane * 8) = ov;
  }
}

// LN of (enc + sinusoidal(expr)), in-place on f32 X.
__global__ __launch_bounds__(256) void embed_ln(
    float* __restrict__ X, const int* __restrict__ ids,
    const float* __restrict__ g, const float* __restrict__ be) {
  const int wid = blockIdx.x * 4 + (threadIdx.x >> 6);
  const int lane = threadIdx.x & 63;
  const float idv = (float)ids[wid];
  float* xp = X + (size_t)wid * cD + lane * 8;
  float x[8];
  {
    float4 a = *(const float4*)xp;
    float4 b4 = *(const float4*)(xp + 4);
    x[0] = a.x; x[1] = a.y; x[2] = a.z; x[3] = a.w;
    x[4] = b4.x; x[5] = b4.y; x[6] = b4.z; x[7] = b4.w;
  }
  const float kf = -0.03597789207803197f;  // -ln(10000)/256
#pragma unroll
  for (int i = 0; i < 8; i++) {
    const int d = lane * 8 + i;
    float e;
    if (d < 256) e = sinf(idv * expf(kf * (float)d));
    else         e = cosf(idv * expf(kf * (float)(d - 256)));
    x[i] += e;
  }
  float s = 0;
#pragma unroll
  for (int i = 0; i < 8; i++) s += x[i];
  s = wave_sum(s);
  const float mu = s * (1.0f / cD);
  float vs = 0;
#pragma unroll
  for (int i = 0; i < 8; i++) { const float d = x[i] - mu; vs += d * d; }
  vs = wave_sum(vs);
  const float rstd = 1.0f / sqrtf(vs * (1.0f / cD) + 1e-5f);
#pragma unroll
  for (int i = 0; i < 8; i++) {
    const int d = lane * 8 + i;
    xp[i] = (x[i] - mu) * rstd * g[d] + be[d];
  }
}

// ---------------------------------------------------------------------------
// bf16 MFMA flash cross-attention, KVBLK=128, denominator-via-ones-row,
// defer-max (base-2; Q pre-scaled by 0.125*log2e in its projection),
// reg-prefetch staging, XCD-aware 1-D grid, K∪P LDS union (3 barriers/tile).
// ---------------------------------------------------------------------------
__global__ __launch_bounds__(256) void flash_mfma(
    const bf16* __restrict__ Q, const bf16* __restrict__ Kc,
    const bf16* __restrict__ Vc, bf16* __restrict__ O, int ldkv) {
  __shared__ __align__(16) bf16 KP[4 * 16 * 136];  // K (16KB) ∪ P (17.4KB)
  __shared__ __align__(16) bf16 Vs[80 * 136];      // [d][s] padded; row 64 = ones
  const int id = blockIdx.x;
  const int b = (id & 63) >> 3, h = id & 7, qb = id >> 6;
  const int t = threadIdx.x, l = t & 63, w = t >> 6, g = l >> 4, c = l & 15;
  const int q0 = qb * 64 + w * 16;
  bf16x8 aq[2];
  {
    const bf16* qp = Q + ((size_t)b * cSD + q0 + c) * cD + h * cDH + g * 8;
    aq[0] = *(const bf16x8*)qp;
    aq[1] = *(const bf16x8*)(qp + 32);
  }
  // init ones/zero rows of Vs (rows 64..79); persists across tiles
  for (int idx = t; idx < 16 * 136; idx += 256) {
    const int rr = idx / 136, cc = idx - rr * 136;
    Vs[(64 + rr) * 136 + cc] = (bf16)(rr == 0 ? 1.f : 0.f);
  }
  const f32x4 zero4 = {0.f, 0.f, 0.f, 0.f};
  f32x4 o5[5];
#pragma unroll
  for (int j = 0; j < 5; j++) o5[j] = zero4;
  float mrow[4];
#pragma unroll
  for (int r = 0; r < 4; r++) mrow[r] = -1e30f;

  const int kr = t >> 1, kof = (t & 1) * 32;  // K stage: row, elem offset
  const int sidx = t & 31, dseg = t >> 5;     // V stage: s quad, d segment
  const size_t kvbase = (size_t)b * cSE * ldkv + h * cDH;
  char* KsC = (char*)KP;
  bf16* Pw = KP + w * 16 * 136;
  const float T2 = 11.541560327111708f;   // 8 * log2(e)

  bf16x8 pk[4], pv[4];  // prefetch registers
  auto LOADR = [&](int kt) {
    const bf16* kp = Kc + kvbase + (size_t)(kt + kr) * ldkv + kof;
#pragma unroll
    for (int i = 0; i < 4; i++) pk[i] = *(const bf16x8*)(kp + i * 8);
    const bf16* vp = Vc + kvbase + (size_t)(kt + 4 * sidx) * ldkv + dseg * 8;
#pragma unroll
    for (int i = 0; i < 4; i++) pv[i] = *(const bf16x8*)(vp + (size_t)i * ldkv);
  };
  auto WRITEL = [&]() {
    const int sw = (kr & 7) << 4;
#pragma unroll
    for (int i = 0; i < 4; i++)
      *(bf16x8*)(KsC + kr * 128 + (((kof + i * 8) * 2) ^ sw)) = pk[i];
#pragma unroll
    for (int e = 0; e < 8; e++) {
      bf16x4 q4;
      q4[0] = pv[0][e]; q4[1] = pv[1][e]; q4[2] = pv[2][e]; q4[3] = pv[3][e];
      *(bf16x4*)(Vs + (dseg * 8 + e) * 136 + 4 * sidx) = q4;
    }
  };
  LOADR(0);
  WRITEL();

  for (int kt = 0; kt < cSE; kt += 128) {
    const bool more = (kt + 128 < cSE);
    if (more) LOADR(kt + 128);    // issue next-tile loads (in flight all phase)
    __syncthreads();              // A: staged tile visible
    // QK^T: 8 key tiles of 16 (reads K region of KP)
    f32x4 s4[8];
#pragma unroll
    for (int t2 = 0; t2 < 8; t2++) {
      const int kr2 = t2 * 16 + c;
      const int sw2 = (kr2 & 7) << 4;
      bf16x8 bk0 = *(const bf16x8*)(KsC + kr2 * 128 + ((g * 16) ^ sw2));
      bf16x8 bk1 = *(const bf16x8*)(KsC + kr2 * 128 + ((64 + g * 16) ^ sw2));
      f32x4 z = zero4;
      z = __builtin_amdgcn_mfma_f32_16x16x32_bf16(aq[0], bk0, z, 0, 0, 0);
      z = __builtin_amdgcn_mfma_f32_16x16x32_bf16(aq[1], bk1, z, 0, 0, 0);
      s4[t2] = z;
    }
    __syncthreads();              // B: all K reads done; P may overwrite
    // softmax in base-2 (scores already in log2 domain); defer-max
#pragma unroll
    for (int r = 0; r < 4; r++) {
      float xv[8];
#pragma unroll
      for (int t2 = 0; t2 < 8; t2++) xv[t2] = s4[t2][r];
      float tm = xv[0];
#pragma unroll
      for (int t2 = 1; t2 < 8; t2++) tm = fmaxf(tm, xv[t2]);
      tm = fmaxf(tm, __shfl_xor(tm, 1));
      tm = fmaxf(tm, __shfl_xor(tm, 2));
      tm = fmaxf(tm, __shfl_xor(tm, 4));
      tm = fmaxf(tm, __shfl_xor(tm, 8));
      if (tm > mrow[r] + T2) {
        const float corr = exp2f(mrow[r] - tm);
        mrow[r] = tm;
#pragma unroll
        for (int j = 0; j < 5; j++) o5[j][r] *= corr;
      }
      const float m = mrow[r];
      const int qr = g * 4 + r;
#pragma unroll
      for (int t2 = 0; t2 < 8; t2++)
        Pw[qr * 136 + t2 * 16 + c] = (bf16)exp2f(xv[t2] - m);
    }
    // PV: A = P[16x128] (4 k-slots, own wave's slice), B = Vs (5 d-tiles)
    bf16x8 pa[4];
#pragma unroll
    for (int ks = 0; ks < 4; ks++)
      pa[ks] = *(const bf16x8*)(Pw + c * 136 + ks * 32 + g * 8);
#pragma unroll
    for (int j = 0; j < 5; j++) {
#pragma unroll
      for (int ks = 0; ks < 4; ks++) {
        bf16x8 bv = *(const bf16x8*)(Vs + (j * 16 + c) * 136 + ks * 32 + g * 8);
        o5[j] = __builtin_amdgcn_mfma_f32_16x16x32_bf16(pa[ks], bv, o5[j], 0, 0, 0);
      }
    }
    __syncthreads();              // C: P/Vs reads done; next stage may write
    if (more) WRITEL();
  }
#pragma unroll
  for (int r = 0; r < 4; r++) {
    const float den = __shfl(o5[4][r], l & 48);
    const float inv = 1.0f / den;
    const size_t row = (size_t)b * cSD + q0 + g * 4 + r;
#pragma unroll
    for (int j = 0; j < 4; j++)
      O[row * cD + h * cDH + j * 16 + c] = (bf16)(o5[j][r] * inv);
  }
}

// ---------------------------------------------------------------------------
extern "C" void kernel_launch(void* const* d_in, const int* in_sizes, int n_in,
                              void* d_out, int out_size, void* d_ws, size_t ws_size,
                              hipStream_t stream) {
  const float* in_enc = (const float*)d_in[0];
  const float* in_dec = (const float*)d_in[1];
  const int* expr = (const int*)d_in[2];
  const float* var_W = (const float*)d_in[3];
  const float* var_b = (const float*)d_in[4];
  const float* enc_g = (const float*)d_in[5];
  const float* enc_b = (const float*)d_in[6];
  const float* dec_g = (const float*)d_in[7];
  const float* dec_b = (const float*)d_in[8];
  const float* ln1_g = (const float*)d_in[9];
  const float* ln1_b = (const float*)d_in[10];
  const float* Wq = (const float*)d_in[11];
  const float* Wk = (const float*)d_in[12];
  const float* Wv = (const float*)d_in[13];
  const float* Wo = (const float*)d_in[14];
  const float* bo = (const float*)d_in[15];
  const float* ln2_g = (const float*)d_in[16];
  const float* ln2_b = (const float*)d_in[17];
  const float* w1 = (const float*)d_in[18];
  const float* b1 = (const float*)d_in[19];
  const float* w2 = (const float*)d_in[20];
  const float* b2 = (const float*)d_in[21];
  const float* proj = (const float*)d_in[22];
  const float* caWq = (const float*)d_in[23];
  const float* caWk = (const float*)d_in[24];
  const float* caWv = (const float*)d_in[25];
  const float* caWo = (const float*)d_in[26];
  const float* cabo = (const float*)d_in[27];
  const float* crg = (const float*)d_in[28];
  const float* crb = (const float*)d_in[29];
  const float* fw1 = (const float*)d_in[30];
  const float* fb1 = (const float*)d_in[31];
  const float* fw2 = (const float*)d_in[32];
  const float* fb2 = (const float*)d_in[33];
  const float* og = (const float*)d_in[34];
  const float* ob = (const float*)d_in[35];
  const float* hW = (const float*)d_in[36];
  const float* hb = (const float*)d_in[37];

  // ---- workspace layout (f32 units) --------------------------------------
  float* X     = (float*)d_ws;             // [16384,512] f32
  float* DC    = X + 8388608;              // [8192,512] f32
  bf16*  QKV   = (bf16*)(DC + 4194304);    // [16384,1536] bf16 fused
  bf16*  Vt    = QKV + 25165824;           // [64,80,2048] bf16 (decoder: Xb)
  bf16*  Pb    = Vt + 10485760;            // arena 50331648 bf16
  float* part  = (float*)(Pb + 50331648);  // [64,8,288,80] f32 (11796480)
  bf16*  kvT   = (bf16*)(part + 11796480); // [64,80,288] bf16
  float* bmax  = (float*)(kvT + 1474560);  // [1024+16]
  bf16*  Yb    = (bf16*)(bmax + 1040);     // [16384,512] bf16
  bf16*  DCb   = Yb + 8388608;             // [8192,512] bf16
  bf16*  Wt    = DCb + 4194304;            // [1048576] bf16 arena (var_W^T)
  bf16*  projB4 = Wt + 1048576;            // [4,288,64] bf16
  const size_t need_bytes = (size_t)75458576 * 4;
  if (ws_size < need_bytes) return;

  // Overlays
  bf16* encB = Pb;                   // [16384,1280] (phase 0)
  bf16* decB = (bf16*)part;          // [8192,1280]  (phase 0; 21MB < 47MB)
  bf16* Pmid = Pb;                   // [16384,2048] (FF mid, layer loop)
  bf16* WL   = Pb + 33554432;        // [4,3145728] bf16 layer weights
                                     //   (dead space for Pmid; decoder Pm2
                                     //    overlaps it only after layers done)
  bf16* Xb   = Vt;                   // [16384,512]  (decoder; written by last FF2)
  bf16* Qc   = Pb + 8388608;         // [8192,512]
  bf16* KVc  = Pb + 12582912;        // [16384,1024] (K cols 0..511, V 512..1023)
  bf16* Fb   = Pb + 29360128;        // [8192,512]
  bf16* Pm2  = Pb + 33554432;        // [8192,2048] (decoder FF mid; after WL dead)
  bf16* WD   = (bf16*)part;          // decoder weights arena (part dead by then)

  const dim3 blk(256);

  // ---- phase 0: embeddings + ALL layer weight prep -----------------------
  castf2b<<<2048, blk, 0, stream>>>(in_enc, encB, 16384 * 1280);
  castf2b<<<2048, blk, 0, stream>>>(in_dec, decB, 8192 * 1280);
  mega_prep<<<dim3(1024, 26), blk, 0, stream>>>(Wq, Wk, Wv, Wo, w1, w2, var_W, proj,
                                                WL, Wt, projB4);
  gemm_mfma<0, 0, true, false><<<dim3(4, 128), blk, 0, stream>>>(encB, Wt, X, nullptr, var_b, 16384, 512, 1280);
  gemm_mfma<0, 0, true, false><<<dim3(4, 64), blk, 0, stream>>>(decB, Wt, DC, nullptr, var_b, 8192, 512, 1280);
  embed_ln<<<4096, blk, 0, stream>>>(X, expr, enc_g, enc_b);
  ln_rows<false, true, true><<<2048, blk, 0, stream>>>(DC, nullptr, dec_g, dec_b, DC, DCb);

  // ---- encoder layers ----------------------------------------------------
  for (int i = 0; i < cDEPTH; i++) {
    bf16* Wl = WL + (size_t)i * 3145728;
    bf16* projB = projB4 + (size_t)i * (cMP * cDH);
    ln_rows<false, false, true><<<4096, blk, 0, stream>>>(X, nullptr, ln1_g + i * cD, ln1_b + i * cD, nullptr, Yb);
    // fused QKV GEMM: N=1536, B = [WqT;WkT;WvT]
    gemm_mfma<1, 0, false, false><<<dim3(12, 128), blk, 0, stream>>>(Yb, Wl, QKV, nullptr, nullptr, 16384, 1536, 512);
    // FAVOR+ (Q at +0, K at +512, V at +1024, stride 1536)
    vtrans<<<dim3(32, 64), blk, 0, stream>>>(QKV + 1024, 1536, Vt);
    favor_kmax<<<dim3(16, 64), blk, 0, stream>>>(QKV + 512, 1536, projB, bmax);
    favor_kkv<<<dim3(8, 64), blk, 0, stream>>>(QKV + 512, 1536, projB, Vt, bmax, part);
    kv_reduce<<<dim3(4, 64), blk, 0, stream>>>(part, kvT);
    favor_qout<<<dim3(16, 64), blk, 0, stream>>>(QKV, 1536, projB, kvT, Yb);
    // Wo + residual
    gemm_mfma<0, 0, true, true><<<dim3(4, 128), blk, 0, stream>>>(Yb, Wl + 786432, X, nullptr, bo + i * cD, 16384, 512, 512);
    // FF
    ln_rows<false, false, true><<<4096, blk, 0, stream>>>(X, nullptr, ln2_g + i * cD, ln2_b + i * cD, nullptr, Yb);
    gemm_mfma<1, 1, true, false><<<dim3(16, 128), blk, 0, stream>>>(Yb, Wl + 1048576, Pmid, nullptr, b1 + i * cFF, 16384, 2048, 512);
    if (i < cDEPTH - 1) {
      gemm_mfma<0, 0, true, true><<<dim3(4, 128), blk, 0, stream>>>(Pmid, Wl + 2097152, X, nullptr, b2 + i * cD, 16384, 512, 2048);
    } else {
      // last layer: also emit bf16 mirror of X into Xb (decoder input)
      gemm_mfma<2, 0, true, true><<<dim3(4, 128), blk, 0, stream>>>(Pmid, Wl + 2097152, X, Xb, b2 + i * cD, 16384, 512, 2048);
    }
  }

  // ---- decoder / cross-attention ----------------------------------------
  mega_prep_dec<<<dim3(1024, 7), blk, 0, stream>>>(caWq, caWk, caWv, caWo, fw1, fw2, hW, WD);
  // Q projection with flash prescale folded in (ACT=2)
  gemm_mfma<1, 2, false, false><<<dim3(4, 64), blk, 0, stream>>>(DCb, WD, Qc, nullptr, nullptr, 8192, 512, 512);
  // fused K+V GEMM: N=1024, B = [WkT;WvT]
  gemm_mfma<1, 0, false, false><<<dim3(8, 128), blk, 0, stream>>>(Xb, WD + 262144, KVc, nullptr, nullptr, 16384, 1024, 512);
  flash_mfma<<<dim3(1024), blk, 0, stream>>>(Qc, KVc, KVc + 512, Fb, 1024);
  gemm_mfma<0, 0, true, false><<<dim3(4, 64), blk, 0, stream>>>(Fb, WD + 786432, X, nullptr, cabo, 8192, 512, 512);
  ln_rows<true, false, true><<<2048, blk, 0, stream>>>(X, DC, crg, crb, nullptr, Yb);
  gemm_mfma<1, 1, true, false><<<dim3(16, 64), blk, 0, stream>>>(Yb, WD + 1048576, Pm2, nullptr, fb1, 8192, 2048, 512);
  gemm_mfma<0, 0, true, false><<<dim3(4, 64), blk, 0, stream>>>(Pm2, WD + 2097152, X + 4194304, nullptr, fb2, 8192, 512, 2048);
  ln_rows<false, false, true><<<2048, blk, 0, stream>>>(X + 4194304, nullptr, og, ob, nullptr, Yb);
  gemm_mfma<0, 0, true, false><<<dim3(1, 64), blk, 0, stream>>>(Yb, WD + 3145728, (float*)d_out, nullptr, hb, 8192, 128, 512);
}

// Round 10
// 1931.622 us; speedup vs baseline: 6.8622x; 1.0234x over previous
//
#include <hip/hip_runtime.h>
#include <hip/hip_bf16.h>
#include <math.h>

// Problem constants
constexpr int cB = 8, cSE = 2048, cSD = 1024, cIN = 1280, cD = 512,
              cDEPTH = 4, cH = 8, cDH = 64, cM = 266, cFF = 2048, cNB = 128;
constexpr int cMP = 288;  // cM padded to multiple of 16 (features pad -> 0)

#define DEV __device__ __forceinline__

typedef __bf16 bf16;
typedef __attribute__((ext_vector_type(8))) __bf16 bf16x8;
typedef __attribute__((ext_vector_type(4))) __bf16 bf16x4;
typedef __attribute__((ext_vector_type(2))) __bf16 bf16x2;
typedef __attribute__((ext_vector_type(4))) float f32x4;

DEV float gelu_f(float x) { return 0.5f * x * (1.0f + erff(x * 0.70710678118654752440f)); }

DEV float wave_sum(float v) {
#pragma unroll
  for (int o = 32; o; o >>= 1) v += __shfl_xor(v, o);
  return v;
}
DEV float wave_max(float v) {
#pragma unroll
  for (int o = 32; o; o >>= 1) v = fmaxf(v, __shfl_xor(v, o));
  return v;
}

#define GL2LDS(gp, lp) __builtin_amdgcn_global_load_lds(                    \
    (const __attribute__((address_space(1))) void*)(gp),                    \
    (__attribute__((address_space(3))) void*)(lp), 16, 0, 0)

// ---------------------------------------------------------------------------
// bf16 MFMA GEMM, BK=64 dual-panel staging (one barrier pair per 64-K),
// XCD-aware bijective block swizzle.
// C[M,N] = epi(A[M,K] @ Bt[N,K]^T). M%128==0, N%128==0, K%64==0.
// OUT: 0=f32 C, 1=bf16 C, 2=f32 C (+RES) AND bf16 mirror to Cv2.
// ACT: 1 = exact GELU, 2 = scale by 0.125*log2(e) (flash Q prescale).
// ---------------------------------------------------------------------------
template <int OUT, int ACT, bool BIAS, bool RES>
__global__ __launch_bounds__(256) void gemm_mfma(
    const bf16* __restrict__ A, const bf16* __restrict__ Bt,
    void* __restrict__ Cv, bf16* __restrict__ Cv2,
    const float* __restrict__ bias, int M, int N, int K) {
  __shared__ bf16 As[2 * 128 * 32];  // two K-half panels, each [128][32]
  __shared__ bf16 Bs[2 * 128 * 32];
  const int t = threadIdx.x, l = t & 63, w = t >> 6;
  const int g = l >> 4, c = l & 15;
  // XCD swizzle: blocks on one XCD (id%8) take a contiguous panel chunk
  const int nwg = gridDim.x * gridDim.y;
  int id = blockIdx.y * gridDim.x + blockIdx.x;
  if ((nwg & 7) == 0) id = (id & 7) * (nwg >> 3) + (id >> 3);
  const int m0 = (id / gridDim.x) * 128, n0 = (id % gridDim.x) * 128;
  const int wr = (w >> 1) * 64, wc = (w & 1) * 64;
  const int srow = w * 32 + (l >> 2);
  const int scol = (l & 3) * 8;
  const bf16* gA = A + (size_t)(m0 + srow) * K + scol;
  const bf16* gB = Bt + (size_t)(n0 + srow) * K + scol;
  bf16* lA = As + w * 1024;
  bf16* lB = Bs + w * 1024;

  const f32x4 zero4 = {0.f, 0.f, 0.f, 0.f};
  f32x4 acc[4][4];
#pragma unroll
  for (int i = 0; i < 4; i++)
#pragma unroll
    for (int j = 0; j < 4; j++) acc[i][j] = zero4;

  for (int k0 = 0; k0 < K; k0 += 64) {
    // stage both 32-wide K-halves (8 async loads), one barrier pair total
    GL2LDS(gA + k0, lA);
    GL2LDS(gA + (size_t)16 * K + k0, lA + 512);
    GL2LDS(gB + k0, lB);
    GL2LDS(gB + (size_t)16 * K + k0, lB + 512);
    GL2LDS(gA + k0 + 32, lA + 4096);
    GL2LDS(gA + (size_t)16 * K + k0 + 32, lA + 4096 + 512);
    GL2LDS(gB + k0 + 32, lB + 4096);
    GL2LDS(gB + (size_t)16 * K + k0 + 32, lB + 4096 + 512);
    __syncthreads();
#pragma unroll
    for (int hh = 0; hh < 2; hh++) {
      bf16x8 af[4], bfr[4];
#pragma unroll
      for (int i = 0; i < 4; i++)
        af[i] = *(const bf16x8*)(As + hh * 4096 + (wr + i * 16 + c) * 32 + g * 8);
#pragma unroll
      for (int j = 0; j < 4; j++)
        bfr[j] = *(const bf16x8*)(Bs + hh * 4096 + (wc + j * 16 + c) * 32 + g * 8);
#pragma unroll
      for (int i = 0; i < 4; i++)
#pragma unroll
        for (int j = 0; j < 4; j++)
          acc[i][j] = __builtin_amdgcn_mfma_f32_16x16x32_bf16(af[i], bfr[j], acc[i][j], 0, 0, 0);
    }
    __syncthreads();
  }
  float* Cf = (float*)Cv;
  bf16* Cb = (bf16*)Cv;
#pragma unroll
  for (int i = 0; i < 4; i++) {
    const int mb = m0 + wr + i * 16 + g * 4;
#pragma unroll
    for (int j = 0; j < 4; j++) {
      const int n = n0 + wc + j * 16 + c;
      const float bv = BIAS ? bias[n] : 0.f;
#pragma unroll
      for (int r = 0; r < 4; r++) {
        float v = acc[i][j][r] + bv;
        if (ACT == 1) v = gelu_f(v);
        if (ACT == 2) v *= 0.18033688011112042f;  // 0.125*log2(e)
        const size_t idx = (size_t)(mb + r) * N + n;
        if (OUT == 0 || OUT == 2) {
          float* cp = Cf + idx;
          if (RES) v += *cp;
          *cp = v;
          if (OUT == 2) Cv2[idx] = (bf16)v;
        } else {
          Cb[idx] = (bf16)v;
        }
      }
    }
  }
}

// ---------------------------------------------------------------------------
// mega_prep: ALL per-layer weight transposes + var_W + proj casts + the two
// f32->bf16 input casts, one launch.
// z = layer*6 + mat (mat: 0..3 = Wq/Wk/Wv/Wo 512x512, 4 = w1 512x2048,
// 5 = w2 2048x512); z=24: var_W; z=25: proj cast x4; z=26: enc cast;
// z=27: dec cast.
// ---------------------------------------------------------------------------
__global__ __launch_bounds__(256) void mega_prep(
    const float* __restrict__ Wq, const float* __restrict__ Wk,
    const float* __restrict__ Wv, const float* __restrict__ Wo,
    const float* __restrict__ w1, const float* __restrict__ w2,
    const float* __restrict__ var_W, const float* __restrict__ proj,
    const float* __restrict__ in_enc, const float* __restrict__ in_dec,
    bf16* __restrict__ WL, bf16* __restrict__ WtVar,
    bf16* __restrict__ projB4, bf16* __restrict__ encB,
    bf16* __restrict__ decB) {
  const int z = blockIdx.y, bid = blockIdx.x, t = threadIdx.x;
  if (z >= 26) {  // input casts (grid-stride, 4-vec)
    const float* src = (z == 26) ? in_enc : in_dec;
    bf16* dst = (z == 26) ? encB : decB;
    const int n = (z == 26) ? 16384 * 1280 : 8192 * 1280;
    int i = (bid * 256 + t) * 4;
    const int stride = 1024 * 256 * 4;
    for (; i < n; i += stride) {
      float4 v = *(const float4*)(src + i);
      bf16x4 o;
      o[0] = (bf16)v.x; o[1] = (bf16)v.y; o[2] = (bf16)v.z; o[3] = (bf16)v.w;
      *(bf16x4*)(dst + i) = o;
    }
    return;
  }
  if (z == 25) {  // proj cast (4 layers), dn prescale, pad rows -> 0
    const int idx = bid * 256 + t;
    if (idx < 4 * cMP * cDH) {
      const int layer = idx / (cMP * cDH), r = idx % (cMP * cDH);
      const int m = r >> 6;
      projB4[idx] = (bf16)(m < cM ? proj[(size_t)layer * cM * cDH + r] * 0.35355339059327373f : 0.f);
    }
    return;
  }
  __shared__ float tile[32][33];
  const float* W;
  bf16* dst;
  int K, N;
  if (z == 24) {
    W = var_W; dst = WtVar; K = 1280; N = 512;
  } else {
    const int layer = z / 6, mat = z % 6;
    bf16* base = WL + (size_t)layer * 3145728;
    if (mat < 4) {
      W = (mat == 0 ? Wq : mat == 1 ? Wk : mat == 2 ? Wv : Wo) + (size_t)layer * 262144;
      dst = base + mat * 262144; K = 512; N = 512;
    } else if (mat == 4) {
      W = w1 + (size_t)layer * 1048576; dst = base + 1048576; K = 512; N = 2048;
    } else {
      W = w2 + (size_t)layer * 1048576; dst = base + 2097152; K = 2048; N = 512;
    }
  }
  const int nt = N >> 5;
  if (bid >= nt * (K >> 5)) return;
  const int n0 = (bid % nt) * 32, k0 = (bid / nt) * 32;
  const int tx = t & 31, ty = t >> 5;
#pragma unroll
  for (int i = ty; i < 32; i += 8) tile[i][tx] = W[(size_t)(k0 + i) * N + n0 + tx];
  __syncthreads();
#pragma unroll
  for (int i = ty; i < 32; i += 8)
    dst[(size_t)(n0 + i) * K + k0 + tx] = (bf16)tile[tx][i];
}

// Decoder weights: z 0..3 caW squares, 4 = fw1 512x2048, 5 = fw2 2048x512,
// 6 = head 512x128. Dest WD + {0,256K,512K,768K | 1M | 2M | 3M}.
__global__ __launch_bounds__(256) void mega_prep_dec(
    const float* __restrict__ caWq, const float* __restrict__ caWk,
    const float* __restrict__ caWv, const float* __restrict__ caWo,
    const float* __restrict__ fw1, const float* __restrict__ fw2,
    const float* __restrict__ hW, bf16* __restrict__ WD) {
  const int z = blockIdx.y, bid = blockIdx.x, t = threadIdx.x;
  __shared__ float tile[32][33];
  const float* W;
  bf16* dst;
  int K, N;
  if (z < 4) {
    W = (z == 0 ? caWq : z == 1 ? caWk : z == 2 ? caWv : caWo);
    dst = WD + z * 262144; K = 512; N = 512;
  } else if (z == 4) {
    W = fw1; dst = WD + 1048576; K = 512; N = 2048;
  } else if (z == 5) {
    W = fw2; dst = WD + 2097152; K = 2048; N = 512;
  } else {
    W = hW; dst = WD + 3145728; K = 512; N = 128;
  }
  const int nt = N >> 5;
  if (bid >= nt * (K >> 5)) return;
  const int n0 = (bid % nt) * 32, k0 = (bid / nt) * 32;
  const int tx = t & 31, ty = t >> 5;
#pragma unroll
  for (int i = ty; i < 32; i += 8) tile[i][tx] = W[(size_t)(k0 + i) * N + n0 + tx];
  __syncthreads();
#pragma unroll
  for (int i = ty; i < 32; i += 8)
    dst[(size_t)(n0 + i) * K + k0 + tx] = (bf16)tile[tx][i];
}

// ---------------------------------------------------------------------------
// favor_prep: fused V head-transpose (blocks x<32) + k global max (x>=32).
// vtrans role: Vh (stride 1536) -> Vt [64 z][80 d][2048 s]; rows 64..79
// = ones/zeros. kmax role: block max of kd -> bmax[z*16 + (x-32)].
// grid (48, 64).
// ---------------------------------------------------------------------------
__global__ __launch_bounds__(256) void favor_prep(
    const bf16* __restrict__ QKV, const bf16* __restrict__ projB,
    bf16* __restrict__ Vt, float* __restrict__ bmax) {
  const int z = blockIdx.y, b = z >> 3, h = z & 7;
  const int t = threadIdx.x;
  const int ld = 1536;
  if (blockIdx.x < 32) {
    // ---- vtrans role ----
    __shared__ bf16 tile[64][65];
    const bf16* Vh = QKV + 1024;
    const int s0 = blockIdx.x * 64;
#pragma unroll
    for (int r = t >> 3; r < 64; r += 32) {
      bf16x8 v = *(const bf16x8*)(Vh + ((size_t)b * cSE + s0 + r) * ld + h * cDH + (t & 7) * 8);
#pragma unroll
      for (int e = 0; e < 8; e++) tile[(t & 7) * 8 + e][r] = v[e];
    }
    __syncthreads();
    bf16* vz = Vt + (size_t)z * 80 * cSE;
#pragma unroll
    for (int d = t >> 3; d < 64; d += 32) {
      bf16x8 o;
#pragma unroll
      for (int e = 0; e < 8; e++) o[e] = tile[d][(t & 7) * 8 + e];
      *(bf16x8*)(vz + (size_t)d * cSE + s0 + (t & 7) * 8) = o;
    }
    const int rr = t >> 4, seg = (t & 15) * 4;
    bf16x4 ov;
    const float val = (rr == 0) ? 1.f : 0.f;
    ov[0] = (bf16)val; ov[1] = (bf16)val; ov[2] = (bf16)val; ov[3] = (bf16)val;
    *(bf16x4*)(vz + (size_t)(64 + rr) * cSE + s0 + seg) = ov;
    return;
  }
  // ---- kmax role ----
  __shared__ float sm[4];
  const bf16* Kh = QKV + 512;
  const int xb = blockIdx.x - 32;
  const int s0 = xb * 128;
  const int l = t & 63, w = t >> 6, g = l >> 4, c = l & 15;
  const int wr = (w >> 1) * 64, wcol = (w & 1) * 144;
  const f32x4 zero4 = {0.f, 0.f, 0.f, 0.f};
  f32x4 acc[4][9];
#pragma unroll
  for (int i = 0; i < 4; i++)
#pragma unroll
    for (int j = 0; j < 9; j++) acc[i][j] = zero4;
  const size_t abase = ((size_t)b * cSE + s0) * ld + h * cDH;
#pragma unroll
  for (int k0 = 0; k0 < 64; k0 += 32) {
    bf16x8 af[4];
#pragma unroll
    for (int i = 0; i < 4; i++)
      af[i] = *(const bf16x8*)(Kh + abase + (size_t)(wr + i * 16 + c) * ld + k0 + g * 8);
#pragma unroll
    for (int j = 0; j < 9; j++) {
      bf16x8 bfr = *(const bf16x8*)(projB + (wcol + j * 16 + c) * 64 + k0 + g * 8);
#pragma unroll
      for (int i = 0; i < 4; i++)
        acc[i][j] = __builtin_amdgcn_mfma_f32_16x16x32_bf16(af[i], bfr, acc[i][j], 0, 0, 0);
    }
  }
  float m = -3e38f;
#pragma unroll
  for (int i = 0; i < 4; i++)
#pragma unroll
    for (int j = 0; j < 9; j++) {
      const int mc = wcol + j * 16 + c;
      if (mc < cM) {
#pragma unroll
        for (int r = 0; r < 4; r++) m = fmaxf(m, acc[i][j][r]);
      }
    }
  m = wave_max(m);
  if (l == 0) sm[w] = m;
  __syncthreads();
  if (t == 0)
    bmax[z * 16 + xb] = fmaxf(fmaxf(sm[0], sm[1]), fmaxf(sm[2], sm[3]));
}

// ---------------------------------------------------------------------------
// FUSED phi(k) + kv accumulate. Per block: z, s-chunk of 256 (8 chunks).
// ---------------------------------------------------------------------------
__global__ __launch_bounds__(256, 1) void favor_kkv(
    const bf16* __restrict__ Kh, int ld, const bf16* __restrict__ projB,
    const bf16* __restrict__ Vt, const float* __restrict__ bmax,
    float* __restrict__ part) {
  __shared__ bf16 kp[288 * 72];
  __shared__ float sm[4];
  const int z = blockIdx.y, b = z >> 3, h = z & 7;
  const int chunk = blockIdx.x;
  const int t = threadIdx.x, l = t & 63, w = t >> 6, g = l >> 4, c = l & 15;
  float gm;
  {
    float m = -1e30f;
    for (int i = t; i < 1024; i += 256) m = fmaxf(m, bmax[i]);
    m = wave_max(m);
    if (l == 0) sm[w] = m;
    __syncthreads();
    gm = fmaxf(fmaxf(sm[0], sm[1]), fmaxf(sm[2], sm[3]));
  }
  const int pr = (w >> 1) * 32;
  const int wcol = (w & 1) * 144;
  const int wm = (w & 1) * 144, wd = (w >> 1) * 32;
  const bool dden = (wd == 32);
  const float ratio = 0.061313927f;  // 266^-0.5
  const f32x4 zero4 = {0.f, 0.f, 0.f, 0.f};
  f32x4 kacc[9][2], kaccx[9];
#pragma unroll
  for (int j = 0; j < 9; j++) {
    kacc[j][0] = zero4; kacc[j][1] = zero4; kaccx[j] = zero4;
  }
  const size_t kbase = (size_t)b * cSE * ld + h * cDH;
  const size_t vtz = (size_t)z * 80 * cSE;

  for (int st = 0; st < 256; st += 64) {
    const int sg = chunk * 256 + st;
    f32x4 pacc[2][9];
#pragma unroll
    for (int i = 0; i < 2; i++)
#pragma unroll
      for (int j = 0; j < 9; j++) pacc[i][j] = zero4;
    float sq[2] = {0.f, 0.f};
#pragma unroll
    for (int k0 = 0; k0 < 64; k0 += 32) {
      bf16x8 af[2];
#pragma unroll
      for (int i = 0; i < 2; i++) {
        af[i] = *(const bf16x8*)(Kh + kbase + (size_t)(sg + pr + i * 16 + c) * ld + k0 + g * 8);
#pragma unroll
        for (int e = 0; e < 8; e++) {
          const float v = (float)af[i][e];
          sq[i] += v * v;
        }
      }
#pragma unroll
      for (int j = 0; j < 9; j++) {
        bf16x8 bfr = *(const bf16x8*)(projB + (wcol + j * 16 + c) * 64 + k0 + g * 8);
        pacc[0][j] = __builtin_amdgcn_mfma_f32_16x16x32_bf16(af[0], bfr, pacc[0][j], 0, 0, 0);
        pacc[1][j] = __builtin_amdgcn_mfma_f32_16x16x32_bf16(af[1], bfr, pacc[1][j], 0, 0, 0);
      }
    }
#pragma unroll
    for (int i = 0; i < 2; i++) {
      sq[i] += __shfl_xor(sq[i], 16);
      sq[i] += __shfl_xor(sq[i], 32);
    }
    float rowsub[2][4];
#pragma unroll
    for (int i = 0; i < 2; i++)
#pragma unroll
      for (int r = 0; r < 4; r++)
        rowsub[i][r] = gm + 0.0625f * __shfl(sq[i], g * 4 + r);
    __syncthreads();
#pragma unroll
    for (int i = 0; i < 2; i++)
#pragma unroll
      for (int j = 0; j < 9; j++) {
        const int mc = wcol + j * 16 + c;
        bf16x4 o;
#pragma unroll
        for (int r = 0; r < 4; r++) {
          const float v = (mc < cM)
              ? ratio * (__expf(pacc[i][j][r] - rowsub[i][r]) + 1e-4f) : 0.f;
          o[r] = (bf16)v;
        }
        *(bf16x4*)(kp + (size_t)mc * 72 + pr + i * 16 + g * 4) = o;
      }
    __syncthreads();
#pragma unroll
    for (int k0 = 0; k0 < 64; k0 += 32) {
      bf16x8 bv0 = *(const bf16x8*)(Vt + vtz + (size_t)(wd + c) * cSE + sg + k0 + g * 8);
      bf16x8 bv1 = *(const bf16x8*)(Vt + vtz + (size_t)(wd + 16 + c) * cSE + sg + k0 + g * 8);
      bf16x8 bvx;
      if (dden)
        bvx = *(const bf16x8*)(Vt + vtz + (size_t)(64 + c) * cSE + sg + k0 + g * 8);
#pragma unroll
      for (int j = 0; j < 9; j++) {
        bf16x8 am = *(const bf16x8*)(kp + (size_t)(wm + j * 16 + c) * 72 + k0 + g * 8);
        kacc[j][0] = __builtin_amdgcn_mfma_f32_16x16x32_bf16(am, bv0, kacc[j][0], 0, 0, 0);
        kacc[j][1] = __builtin_amdgcn_mfma_f32_16x16x32_bf16(am, bv1, kacc[j][1], 0, 0, 0);
        if (dden)
          kaccx[j] = __builtin_amdgcn_mfma_f32_16x16x32_bf16(am, bvx, kaccx[j], 0, 0, 0);
      }
    }
  }
  float* po = part + ((size_t)z * 8 + chunk) * (cMP * 80);
#pragma unroll
  for (int j = 0; j < 9; j++)
#pragma unroll
    for (int i = 0; i < 2; i++)
#pragma unroll
      for (int r = 0; r < 4; r++)
        po[(size_t)(wm + j * 16 + g * 4 + r) * 80 + wd + i * 16 + c] = kacc[j][i][r];
  if (dden) {
#pragma unroll
    for (int j = 0; j < 9; j++)
#pragma unroll
      for (int r = 0; r < 4; r++)
        po[(size_t)(wm + j * 16 + g * 4 + r) * 80 + 64 + c] = kaccx[j][r];
  }
}

// reduce 8 chunks + transpose: kvT[z,d(80),m]; row 64 = ksum. grid (4,64).
__global__ __launch_bounds__(256) void kv_reduce(
    const float* __restrict__ part, bf16* __restrict__ kvT) {
  const int z = blockIdx.y, q = blockIdx.x;
  const float* p = part + (size_t)z * 8 * (cMP * 80);
  bf16* o = kvT + (size_t)z * 80 * cMP;
  const int lo = q * 5760, hi = lo + 5760;  // cMP*80/4
  for (int idx = lo + threadIdx.x; idx < hi; idx += 256) {
    const int m = idx / 80, d = idx - m * 80;
    float s = 0.f;
#pragma unroll
    for (int cc = 0; cc < 8; cc++) s += p[idx + (size_t)cc * (cMP * 80)];
    o[(size_t)d * cMP + m] = (bf16)s;
  }
}

// ---------------------------------------------------------------------------
// Fused phi(q) + output (Qh stride ld): qd in regs -> row max + inline diag ->
// qp staged in LDS [128][296] -> out = qp @ kvT^T (+den col) -> Y.
// ---------------------------------------------------------------------------
__global__ __launch_bounds__(256, 1) void favor_qout(
    const bf16* __restrict__ Qh, int ld, const bf16* __restrict__ projB,
    const bf16* __restrict__ kvT, bf16* __restrict__ Y) {
  __shared__ bf16 Plds[128 * 296];
  __shared__ float rmaxs[4][64];
  __shared__ float denl[128];
  const int z = blockIdx.y, b = z >> 3, h = z & 7;
  const int s0 = blockIdx.x * 128;
  const int t = threadIdx.x, l = t & 63, w = t >> 6, g = l >> 4, c = l & 15;
  const int wr = (w >> 1) * 64, wcol = (w & 1) * 144;
  const f32x4 zero4 = {0.f, 0.f, 0.f, 0.f};
  f32x4 acc[4][9];
#pragma unroll
  for (int i = 0; i < 4; i++)
#pragma unroll
    for (int j = 0; j < 9; j++) acc[i][j] = zero4;
  float sq[4] = {0.f, 0.f, 0.f, 0.f};
  const size_t abase = ((size_t)b * cSE + s0) * ld + h * cDH;
#pragma unroll
  for (int k0 = 0; k0 < 64; k0 += 32) {
    bf16x8 af[4];
#pragma unroll
    for (int i = 0; i < 4; i++) {
      af[i] = *(const bf16x8*)(Qh + abase + (size_t)(wr + i * 16 + c) * ld + k0 + g * 8);
#pragma unroll
      for (int e = 0; e < 8; e++) {
        const float v = (float)af[i][e];
        sq[i] += v * v;
      }
    }
#pragma unroll
    for (int j = 0; j < 9; j++) {
      bf16x8 bfr = *(const bf16x8*)(projB + (wcol + j * 16 + c) * 64 + k0 + g * 8);
#pragma unroll
      for (int i = 0; i < 4; i++)
        acc[i][j] = __builtin_amdgcn_mfma_f32_16x16x32_bf16(af[i], bfr, acc[i][j], 0, 0, 0);
    }
  }
#pragma unroll
  for (int i = 0; i < 4; i++) {
    sq[i] += __shfl_xor(sq[i], 16);
    sq[i] += __shfl_xor(sq[i], 32);
  }
  const float ratio = 0.061313927f;  // 266^-0.5
  float rowsub[4][4];
#pragma unroll
  for (int i = 0; i < 4; i++)
#pragma unroll
    for (int r = 0; r < 4; r++) {
      float m = -3e38f;
#pragma unroll
      for (int j = 0; j < 9; j++) {
        const int mc = wcol + j * 16 + c;
        m = (mc < cM) ? fmaxf(m, acc[i][j][r]) : m;
      }
      m = fmaxf(m, __shfl_xor(m, 1));
      m = fmaxf(m, __shfl_xor(m, 2));
      m = fmaxf(m, __shfl_xor(m, 4));
      m = fmaxf(m, __shfl_xor(m, 8));
      rowsub[i][r] = m;
    }
  if (c == 0) {
#pragma unroll
    for (int i = 0; i < 4; i++)
#pragma unroll
      for (int r = 0; r < 4; r++) rmaxs[w][i * 16 + g * 4 + r] = rowsub[i][r];
  }
  __syncthreads();
#pragma unroll
  for (int i = 0; i < 4; i++)
#pragma unroll
    for (int r = 0; r < 4; r++) {
      const int row = i * 16 + g * 4 + r;
      rowsub[i][r] = fmaxf(rowsub[i][r], rmaxs[w ^ 1][row]) +
                     0.0625f * __shfl(sq[i], g * 4 + r);
    }
#pragma unroll
  for (int i = 0; i < 4; i++)
#pragma unroll
    for (int j = 0; j < 9; j++) {
      const int mc = wcol + j * 16 + c;
#pragma unroll
      for (int r = 0; r < 4; r++) {
        const float v = (mc < cM)
            ? ratio * (__expf(acc[i][j][r] - rowsub[i][r]) + 1e-4f) : 0.f;
        Plds[(wr + i * 16 + g * 4 + r) * 296 + mc] = (bf16)v;
      }
    }
  __syncthreads();

  // ---- output phase: out = qp @ kvT^T, den from kvT ksum row ----
  const int wd = (w & 1) * 32;
  const bool dden = (wd == 32);
  f32x4 acc2[4][2], accx[4];
#pragma unroll
  for (int i = 0; i < 4; i++) {
    acc2[i][0] = zero4; acc2[i][1] = zero4; accx[i] = zero4;
  }
  const size_t kz = (size_t)z * 80 * cMP;
#pragma unroll 3
  for (int k0 = 0; k0 < cMP; k0 += 32) {
    bf16x8 bv[2], bvx;
#pragma unroll
    for (int j = 0; j < 2; j++)
      bv[j] = *(const bf16x8*)(kvT + kz + (size_t)(wd + j * 16 + c) * cMP + k0 + g * 8);
    if (dden)
      bvx = *(const bf16x8*)(kvT + kz + (size_t)(64 + c) * cMP + k0 + g * 8);
#pragma unroll
    for (int i = 0; i < 4; i++) {
      bf16x8 av = *(const bf16x8*)(Plds + (wr + i * 16 + c) * 296 + k0 + g * 8);
      acc2[i][0] = __builtin_amdgcn_mfma_f32_16x16x32_bf16(av, bv[0], acc2[i][0], 0, 0, 0);
      acc2[i][1] = __builtin_amdgcn_mfma_f32_16x16x32_bf16(av, bv[1], acc2[i][1], 0, 0, 0);
      if (dden)
        accx[i] = __builtin_amdgcn_mfma_f32_16x16x32_bf16(av, bvx, accx[i], 0, 0, 0);
    }
  }
  if (dden && c == 0) {
#pragma unroll
    for (int i = 0; i < 4; i++)
#pragma unroll
      for (int r = 0; r < 4; r++)
        denl[wr + i * 16 + g * 4 + r] = accx[i][r];
  }
  __syncthreads();
#pragma unroll
  for (int i = 0; i < 4; i++)
#pragma unroll
    for (int r = 0; r < 4; r++) {
      const int row = wr + i * 16 + g * 4 + r;
      const float inv = 1.0f / denl[row];
#pragma unroll
      for (int j = 0; j < 2; j++)
        Y[((size_t)b * cSE + s0 + row) * cD + h * cDH + wd + j * 16 + c] =
            (bf16)(acc2[i][j][r] * inv);
    }
}

// ---------------------------------------------------------------------------
// LayerNorm rows of 512; wave per row. WF: f32 out, WB: bf16 out2.
// ---------------------------------------------------------------------------
template <bool ADD, bool WF, bool WB>
__global__ __launch_bounds__(256) void ln_rows(
    const float* __restrict__ in, const float* __restrict__ add,
    const float* __restrict__ g, const float* __restrict__ be,
    float* __restrict__ out, bf16* __restrict__ out2) {
  const int wid = blockIdx.x * 4 + (threadIdx.x >> 6);
  const int lane = threadIdx.x & 63;
  const float* ip = in + (size_t)wid * cD + lane * 8;
  float x[8];
  {
    float4 a = *(const float4*)ip;
    float4 b4 = *(const float4*)(ip + 4);
    x[0] = a.x; x[1] = a.y; x[2] = a.z; x[3] = a.w;
    x[4] = b4.x; x[5] = b4.y; x[6] = b4.z; x[7] = b4.w;
  }
  if (ADD) {
    const float* ap = add + (size_t)wid * cD + lane * 8;
    float4 a = *(const float4*)ap;
    float4 b4 = *(const float4*)(ap + 4);
    x[0] += a.x; x[1] += a.y; x[2] += a.z; x[3] += a.w;
    x[4] += b4.x; x[5] += b4.y; x[6] += b4.z; x[7] += b4.w;
  }
  float s = 0;
#pragma unroll
  for (int i = 0; i < 8; i++) s += x[i];
  s = wave_sum(s);
  const float mu = s * (1.0f / cD);
  float vs = 0;
#pragma unroll
  for (int i = 0; i < 8; i++) { const float d = x[i] - mu; vs += d * d; }
  vs = wave_sum(vs);
  const float rstd = 1.0f / sqrtf(vs * (1.0f / cD) + 1e-5f);
  float r[8];
#pragma unroll
  for (int i = 0; i < 8; i++) {
    const int d = lane * 8 + i;
    r[i] = (x[i] - mu) * rstd * g[d] + be[d];
  }
  if (WF) {
    float* op = out + (size_t)wid * cD + lane * 8;
    float4 a, b4;
    a.x = r[0]; a.y = r[1]; a.z = r[2]; a.w = r[3];
    b4.x = r[4]; b4.y = r[5]; b4.z = r[6]; b4.w = r[7];
    *(float4*)op = a; *(float4*)(op + 4) = b4;
  }
  if (WB) {
    bf16x8 ov;
#pragma unroll
    for (int i = 0; i < 8; i++) ov[i] = (bf16)r[i];
    *(bf16x8*)(out2 + (size_t)wid * cD + lane * 8) = ov;
  }
}

// LN of (enc + sinusoidal(expr)), in-place on f32 X.
__global__ __launch_bounds__(256) void embed_ln(
    float* __restrict__ X, const int* __restrict__ ids,
    const float* __restrict__ g, const float* __restrict__ be) {
  const int wid = blockIdx.x * 4 + (threadIdx.x >> 6);
  const int lane = threadIdx.x & 63;
  const float idv = (float)ids[wid];
  float* xp = X + (size_t)wid * cD + lane * 8;
  float x[8];
  {
    float4 a = *(const float4*)xp;
    float4 b4 = *(const float4*)(xp + 4);
    x[0] = a.x; x[1] = a.y; x[2] = a.z; x[3] = a.w;
    x[4] = b4.x; x[5] = b4.y; x[6] = b4.z; x[7] = b4.w;
  }
  const float kf = -0.03597789207803197f;  // -ln(10000)/256
#pragma unroll
  for (int i = 0; i < 8; i++) {
    const int d = lane * 8 + i;
    float e;
    if (d < 256) e = sinf(idv * expf(kf * (float)d));
    else         e = cosf(idv * expf(kf * (float)(d - 256)));
    x[i] += e;
  }
  float s = 0;
#pragma unroll
  for (int i = 0; i < 8; i++) s += x[i];
  s = wave_sum(s);
  const float mu = s * (1.0f / cD);
  float vs = 0;
#pragma unroll
  for (int i = 0; i < 8; i++) { const float d = x[i] - mu; vs += d * d; }
  vs = wave_sum(vs);
  const float rstd = 1.0f / sqrtf(vs * (1.0f / cD) + 1e-5f);
#pragma unroll
  for (int i = 0; i < 8; i++) {
    const int d = lane * 8 + i;
    xp[i] = (x[i] - mu) * rstd * g[d] + be[d];
  }
}

// ---------------------------------------------------------------------------
// bf16 MFMA flash cross-attention, KVBLK=128, denominator-via-ones-row,
// defer-max (base-2; Q pre-scaled by 0.125*log2e in its projection),
// reg-prefetch staging, XCD-aware 1-D grid, K∪P LDS union (3 barriers/tile).
// ---------------------------------------------------------------------------
__global__ __launch_bounds__(256) void flash_mfma(
    const bf16* __restrict__ Q, const bf16* __restrict__ Kc,
    const bf16* __restrict__ Vc, bf16* __restrict__ O, int ldkv) {
  __shared__ __align__(16) bf16 KP[4 * 16 * 136];  // K (16KB) ∪ P (17.4KB)
  __shared__ __align__(16) bf16 Vs[80 * 136];      // [d][s] padded; row 64 = ones
  const int id = blockIdx.x;
  const int b = (id & 63) >> 3, h = id & 7, qb = id >> 6;
  const int t = threadIdx.x, l = t & 63, w = t >> 6, g = l >> 4, c = l & 15;
  const int q0 = qb * 64 + w * 16;
  bf16x8 aq[2];
  {
    const bf16* qp = Q + ((size_t)b * cSD + q0 + c) * cD + h * cDH + g * 8;
    aq[0] = *(const bf16x8*)qp;
    aq[1] = *(const bf16x8*)(qp + 32);
  }
  for (int idx = t; idx < 16 * 136; idx += 256) {
    const int rr = idx / 136, cc = idx - rr * 136;
    Vs[(64 + rr) * 136 + cc] = (bf16)(rr == 0 ? 1.f : 0.f);
  }
  const f32x4 zero4 = {0.f, 0.f, 0.f, 0.f};
  f32x4 o5[5];
#pragma unroll
  for (int j = 0; j < 5; j++) o5[j] = zero4;
  float mrow[4];
#pragma unroll
  for (int r = 0; r < 4; r++) mrow[r] = -1e30f;

  const int kr = t >> 1, kof = (t & 1) * 32;
  const int sidx = t & 31, dseg = t >> 5;
  const size_t kvbase = (size_t)b * cSE * ldkv + h * cDH;
  char* KsC = (char*)KP;
  bf16* Pw = KP + w * 16 * 136;
  const float T2 = 11.541560327111708f;   // 8 * log2(e)

  bf16x8 pk[4], pv[4];
  auto LOADR = [&](int kt) {
    const bf16* kp = Kc + kvbase + (size_t)(kt + kr) * ldkv + kof;
#pragma unroll
    for (int i = 0; i < 4; i++) pk[i] = *(const bf16x8*)(kp + i * 8);
    const bf16* vp = Vc + kvbase + (size_t)(kt + 4 * sidx) * ldkv + dseg * 8;
#pragma unroll
    for (int i = 0; i < 4; i++) pv[i] = *(const bf16x8*)(vp + (size_t)i * ldkv);
  };
  auto WRITEL = [&]() {
    const int sw = (kr & 7) << 4;
#pragma unroll
    for (int i = 0; i < 4; i++)
      *(bf16x8*)(KsC + kr * 128 + (((kof + i * 8) * 2) ^ sw)) = pk[i];
#pragma unroll
    for (int e = 0; e < 8; e++) {
      bf16x4 q4;
      q4[0] = pv[0][e]; q4[1] = pv[1][e]; q4[2] = pv[2][e]; q4[3] = pv[3][e];
      *(bf16x4*)(Vs + (dseg * 8 + e) * 136 + 4 * sidx) = q4;
    }
  };
  LOADR(0);
  WRITEL();

  for (int kt = 0; kt < cSE; kt += 128) {
    const bool more = (kt + 128 < cSE);
    if (more) LOADR(kt + 128);
    __syncthreads();              // A: staged tile visible
    f32x4 s4[8];
#pragma unroll
    for (int t2 = 0; t2 < 8; t2++) {
      const int kr2 = t2 * 16 + c;
      const int sw2 = (kr2 & 7) << 4;
      bf16x8 bk0 = *(const bf16x8*)(KsC + kr2 * 128 + ((g * 16) ^ sw2));
      bf16x8 bk1 = *(const bf16x8*)(KsC + kr2 * 128 + ((64 + g * 16) ^ sw2));
      f32x4 z = zero4;
      z = __builtin_amdgcn_mfma_f32_16x16x32_bf16(aq[0], bk0, z, 0, 0, 0);
      z = __builtin_amdgcn_mfma_f32_16x16x32_bf16(aq[1], bk1, z, 0, 0, 0);
      s4[t2] = z;
    }
    __syncthreads();              // B: all K reads done; P may overwrite
#pragma unroll
    for (int r = 0; r < 4; r++) {
      float xv[8];
#pragma unroll
      for (int t2 = 0; t2 < 8; t2++) xv[t2] = s4[t2][r];
      float tm = xv[0];
#pragma unroll
      for (int t2 = 1; t2 < 8; t2++) tm = fmaxf(tm, xv[t2]);
      tm = fmaxf(tm, __shfl_xor(tm, 1));
      tm = fmaxf(tm, __shfl_xor(tm, 2));
      tm = fmaxf(tm, __shfl_xor(tm, 4));
      tm = fmaxf(tm, __shfl_xor(tm, 8));
      if (tm > mrow[r] + T2) {
        const float corr = exp2f(mrow[r] - tm);
        mrow[r] = tm;
#pragma unroll
        for (int j = 0; j < 5; j++) o5[j][r] *= corr;
      }
      const float m = mrow[r];
      const int qr = g * 4 + r;
#pragma unroll
      for (int t2 = 0; t2 < 8; t2++)
        Pw[qr * 136 + t2 * 16 + c] = (bf16)exp2f(xv[t2] - m);
    }
    bf16x8 pa[4];
#pragma unroll
    for (int ks = 0; ks < 4; ks++)
      pa[ks] = *(const bf16x8*)(Pw + c * 136 + ks * 32 + g * 8);
#pragma unroll
    for (int j = 0; j < 5; j++) {
#pragma unroll
      for (int ks = 0; ks < 4; ks++) {
        bf16x8 bv = *(const bf16x8*)(Vs + (j * 16 + c) * 136 + ks * 32 + g * 8);
        o5[j] = __builtin_amdgcn_mfma_f32_16x16x32_bf16(pa[ks], bv, o5[j], 0, 0, 0);
      }
    }
    __syncthreads();              // C: P/Vs reads done; next stage may write
    if (more) WRITEL();
  }
#pragma unroll
  for (int r = 0; r < 4; r++) {
    const float den = __shfl(o5[4][r], l & 48);
    const float inv = 1.0f / den;
    const size_t row = (size_t)b * cSD + q0 + g * 4 + r;
#pragma unroll
    for (int j = 0; j < 4; j++)
      O[row * cD + h * cDH + j * 16 + c] = (bf16)(o5[j][r] * inv);
  }
}

// ---------------------------------------------------------------------------
extern "C" void kernel_launch(void* const* d_in, const int* in_sizes, int n_in,
                              void* d_out, int out_size, void* d_ws, size_t ws_size,
                              hipStream_t stream) {
  const float* in_enc = (const float*)d_in[0];
  const float* in_dec = (const float*)d_in[1];
  const int* expr = (const int*)d_in[2];
  const float* var_W = (const float*)d_in[3];
  const float* var_b = (const float*)d_in[4];
  const float* enc_g = (const float*)d_in[5];
  const float* enc_b = (const float*)d_in[6];
  const float* dec_g = (const float*)d_in[7];
  const float* dec_b = (const float*)d_in[8];
  const float* ln1_g = (const float*)d_in[9];
  const float* ln1_b = (const float*)d_in[10];
  const float* Wq = (const float*)d_in[11];
  const float* Wk = (const float*)d_in[12];
  const float* Wv = (const float*)d_in[13];
  const float* Wo = (const float*)d_in[14];
  const float* bo = (const float*)d_in[15];
  const float* ln2_g = (const float*)d_in[16];
  const float* ln2_b = (const float*)d_in[17];
  const float* w1 = (const float*)d_in[18];
  const float* b1 = (const float*)d_in[19];
  const float* w2 = (const float*)d_in[20];
  const float* b2 = (const float*)d_in[21];
  const float* proj = (const float*)d_in[22];
  const float* caWq = (const float*)d_in[23];
  const float* caWk = (const float*)d_in[24];
  const float* caWv = (const float*)d_in[25];
  const float* caWo = (const float*)d_in[26];
  const float* cabo = (const float*)d_in[27];
  const float* crg = (const float*)d_in[28];
  const float* crb = (const float*)d_in[29];
  const float* fw1 = (const float*)d_in[30];
  const float* fb1 = (const float*)d_in[31];
  const float* fw2 = (const float*)d_in[32];
  const float* fb2 = (const float*)d_in[33];
  const float* og = (const float*)d_in[34];
  const float* ob = (const float*)d_in[35];
  const float* hW = (const float*)d_in[36];
  const float* hb = (const float*)d_in[37];

  // ---- workspace layout (f32 units) --------------------------------------
  float* X     = (float*)d_ws;             // [16384,512] f32
  float* DC    = X + 8388608;              // [8192,512] f32
  bf16*  QKV   = (bf16*)(DC + 4194304);    // [16384,1536] bf16 fused
  bf16*  Vt    = QKV + 25165824;           // [64,80,2048] bf16 (decoder: Xb)
  bf16*  Pb    = Vt + 10485760;            // arena 50331648 bf16
  float* part  = (float*)(Pb + 50331648);  // [64,8,288,80] f32 (11796480)
  bf16*  kvT   = (bf16*)(part + 11796480); // [64,80,288] bf16
  float* bmax  = (float*)(kvT + 1474560);  // [1024+16]
  bf16*  Yb    = (bf16*)(bmax + 1040);     // [16384,512] bf16
  bf16*  DCb   = Yb + 8388608;             // [8192,512] bf16
  bf16*  Wt    = DCb + 4194304;            // [1048576] bf16 arena (var_W^T)
  bf16*  projB4 = Wt + 1048576;            // [4,288,64] bf16
  const size_t need_bytes = (size_t)75458576 * 4;
  if (ws_size < need_bytes) return;

  // Overlays
  bf16* encB = Pb;                   // [16384,1280] (phase 0)
  bf16* decB = (bf16*)part;          // [8192,1280]  (phase 0; 21MB < 47MB)
  bf16* Pmid = Pb;                   // [16384,2048] (FF mid, layer loop)
  bf16* WL   = Pb + 33554432;        // [4,3145728] bf16 layer weights
  bf16* Xb   = Vt;                   // [16384,512]  (decoder; written by last FF2)
  bf16* Qc   = Pb + 8388608;         // [8192,512]
  bf16* KVc  = Pb + 12582912;        // [16384,1024] (K cols 0..511, V 512..1023)
  bf16* Fb   = Pb + 29360128;        // [8192,512]
  bf16* Pm2  = Pb + 33554432;        // [8192,2048] (decoder FF mid; after WL dead)
  bf16* WD   = (bf16*)part;          // decoder weights arena (part dead by then)

  const dim3 blk(256);

  // ---- phase 0: input casts + ALL layer weight prep (one launch) ---------
  mega_prep<<<dim3(1024, 28), blk, 0, stream>>>(Wq, Wk, Wv, Wo, w1, w2, var_W, proj,
                                                in_enc, in_dec, WL, Wt, projB4,
                                                encB, decB);
  gemm_mfma<0, 0, true, false><<<dim3(4, 128), blk, 0, stream>>>(encB, Wt, X, nullptr, var_b, 16384, 512, 1280);
  gemm_mfma<0, 0, true, false><<<dim3(4, 64), blk, 0, stream>>>(decB, Wt, DC, nullptr, var_b, 8192, 512, 1280);
  embed_ln<<<4096, blk, 0, stream>>>(X, expr, enc_g, enc_b);
  ln_rows<false, true, true><<<2048, blk, 0, stream>>>(DC, nullptr, dec_g, dec_b, DC, DCb);

  // ---- encoder layers ----------------------------------------------------
  for (int i = 0; i < cDEPTH; i++) {
    bf16* Wl = WL + (size_t)i * 3145728;
    bf16* projB = projB4 + (size_t)i * (cMP * cDH);
    ln_rows<false, false, true><<<4096, blk, 0, stream>>>(X, nullptr, ln1_g + i * cD, ln1_b + i * cD, nullptr, Yb);
    // fused QKV GEMM: N=1536, B = [WqT;WkT;WvT]
    gemm_mfma<1, 0, false, false><<<dim3(12, 128), blk, 0, stream>>>(Yb, Wl, QKV, nullptr, nullptr, 16384, 1536, 512);
    // FAVOR+ (Q at +0, K at +512, V at +1024, stride 1536)
    favor_prep<<<dim3(48, 64), blk, 0, stream>>>(QKV, projB, Vt, bmax);
    favor_kkv<<<dim3(8, 64), blk, 0, stream>>>(QKV + 512, 1536, projB, Vt, bmax, part);
    kv_reduce<<<dim3(4, 64), blk, 0, stream>>>(part, kvT);
    favor_qout<<<dim3(16, 64), blk, 0, stream>>>(QKV, 1536, projB, kvT, Yb);
    // Wo + residual
    gemm_mfma<0, 0, true, true><<<dim3(4, 128), blk, 0, stream>>>(Yb, Wl + 786432, X, nullptr, bo + i * cD, 16384, 512, 512);
    // FF
    ln_rows<false, false, true><<<4096, blk, 0, stream>>>(X, nullptr, ln2_g + i * cD, ln2_b + i * cD, nullptr, Yb);
    gemm_mfma<1, 1, true, false><<<dim3(16, 128), blk, 0, stream>>>(Yb, Wl + 1048576, Pmid, nullptr, b1 + i * cFF, 16384, 2048, 512);
    if (i < cDEPTH - 1) {
      gemm_mfma<0, 0, true, true><<<dim3(4, 128), blk, 0, stream>>>(Pmid, Wl + 2097152, X, nullptr, b2 + i * cD, 16384, 512, 2048);
    } else {
      gemm_mfma<2, 0, true, true><<<dim3(4, 128), blk, 0, stream>>>(Pmid, Wl + 2097152, X, Xb, b2 + i * cD, 16384, 512, 2048);
    }
  }

  // ---- decoder / cross-attention ----------------------------------------
  mega_prep_dec<<<dim3(1024, 7), blk, 0, stream>>>(caWq, caWk, caWv, caWo, fw1, fw2, hW, WD);
  // Q projection with flash prescale folded in (ACT=2)
  gemm_mfma<1, 2, false, false><<<dim3(4, 64), blk, 0, stream>>>(DCb, WD, Qc, nullptr, nullptr, 8192, 512, 512);
  // fused K+V GEMM: N=1024, B = [WkT;WvT]
  gemm_mfma<1, 0, false, false><<<dim3(8, 128), blk, 0, stream>>>(Xb, WD + 262144, KVc, nullptr, nullptr, 16384, 1024, 512);
  flash_mfma<<<dim3(1024), blk, 0, stream>>>(Qc, KVc, KVc + 512, Fb, 1024);
  gemm_mfma<0, 0, true, false><<<dim3(4, 64), blk, 0, stream>>>(Fb, WD + 786432, X, nullptr, cabo, 8192, 512, 512);
  ln_rows<true, false, true><<<2048, blk, 0, stream>>>(X, DC, crg, crb, nullptr, Yb);
  gemm_mfma<1, 1, true, false><<<dim3(16, 64), blk, 0, stream>>>(Yb, WD + 1048576, Pm2, nullptr, fb1, 8192, 2048, 512);
  gemm_mfma<0, 0, true, false><<<dim3(4, 64), blk, 0, stream>>>(Pm2, WD + 2097152, X + 4194304, nullptr, fb2, 8192, 512, 2048);
  ln_rows<false, false, true><<<2048, blk, 0, stream>>>(X + 4194304, nullptr, og, ob, nullptr, Yb);
  gemm_mfma<0, 0, true, false><<<dim3(1, 64), blk, 0, stream>>>(Yb, WD + 3145728, (float*)d_out, nullptr, hb, 8192, 128, 512);
}

// Round 11
// 1849.779 us; speedup vs baseline: 7.1658x; 1.0442x over previous
//
#include <hip/hip_runtime.h>
#include <hip/hip_bf16.h>
#include <math.h>

// Problem constants
constexpr int cB = 8, cSE = 2048, cSD = 1024, cIN = 1280, cD = 512,
              cDEPTH = 4, cH = 8, cDH = 64, cM = 266, cFF = 2048, cNB = 128;
constexpr int cMP = 288;  // cM padded to multiple of 16 (features pad -> 0)

#define DEV __device__ __forceinline__

typedef __bf16 bf16;
typedef __attribute__((ext_vector_type(8))) __bf16 bf16x8;
typedef __attribute__((ext_vector_type(4))) __bf16 bf16x4;
typedef __attribute__((ext_vector_type(2))) __bf16 bf16x2;
typedef __attribute__((ext_vector_type(4))) float f32x4;

DEV float gelu_f(float x) { return 0.5f * x * (1.0f + erff(x * 0.70710678118654752440f)); }

DEV float wave_sum(float v) {
#pragma unroll
  for (int o = 32; o; o >>= 1) v += __shfl_xor(v, o);
  return v;
}
DEV float wave_max(float v) {
#pragma unroll
  for (int o = 32; o; o >>= 1) v = fmaxf(v, __shfl_xor(v, o));
  return v;
}

#define GL2LDS(gp, lp) __builtin_amdgcn_global_load_lds(                    \
    (const __attribute__((address_space(1))) void*)(gp),                    \
    (__attribute__((address_space(3))) void*)(lp), 16, 0, 0)

// ---------------------------------------------------------------------------
// bf16 MFMA GEMM, BK=64 dual-panel staging, XCD-aware bijective swizzle.
// C[M,N] = epi(A[M,K] @ Bt[N,K]^T). M%128==0, N%128==0, K%64==0.
// OUT: 0=f32 C (+RES f32), 1=bf16 C, 3=bf16 C with bf16 residual RMW.
// ACT: 1 = exact GELU, 2 = scale by 0.125*log2(e) (flash Q prescale).
// ---------------------------------------------------------------------------
template <int OUT, int ACT, bool BIAS, bool RES>
__global__ __launch_bounds__(256) void gemm_mfma(
    const bf16* __restrict__ A, const bf16* __restrict__ Bt,
    void* __restrict__ Cv, bf16* __restrict__ Cv2,
    const float* __restrict__ bias, int M, int N, int K) {
  __shared__ bf16 As[2 * 128 * 32];  // two K-half panels, each [128][32]
  __shared__ bf16 Bs[2 * 128 * 32];
  const int t = threadIdx.x, l = t & 63, w = t >> 6;
  const int g = l >> 4, c = l & 15;
  const int nwg = gridDim.x * gridDim.y;
  int id = blockIdx.y * gridDim.x + blockIdx.x;
  if ((nwg & 7) == 0) id = (id & 7) * (nwg >> 3) + (id >> 3);
  const int m0 = (id / gridDim.x) * 128, n0 = (id % gridDim.x) * 128;
  const int wr = (w >> 1) * 64, wc = (w & 1) * 64;
  const int srow = w * 32 + (l >> 2);
  const int scol = (l & 3) * 8;
  const bf16* gA = A + (size_t)(m0 + srow) * K + scol;
  const bf16* gB = Bt + (size_t)(n0 + srow) * K + scol;
  bf16* lA = As + w * 1024;
  bf16* lB = Bs + w * 1024;

  const f32x4 zero4 = {0.f, 0.f, 0.f, 0.f};
  f32x4 acc[4][4];
#pragma unroll
  for (int i = 0; i < 4; i++)
#pragma unroll
    for (int j = 0; j < 4; j++) acc[i][j] = zero4;

  for (int k0 = 0; k0 < K; k0 += 64) {
    GL2LDS(gA + k0, lA);
    GL2LDS(gA + (size_t)16 * K + k0, lA + 512);
    GL2LDS(gB + k0, lB);
    GL2LDS(gB + (size_t)16 * K + k0, lB + 512);
    GL2LDS(gA + k0 + 32, lA + 4096);
    GL2LDS(gA + (size_t)16 * K + k0 + 32, lA + 4096 + 512);
    GL2LDS(gB + k0 + 32, lB + 4096);
    GL2LDS(gB + (size_t)16 * K + k0 + 32, lB + 4096 + 512);
    __syncthreads();
#pragma unroll
    for (int hh = 0; hh < 2; hh++) {
      bf16x8 af[4], bfr[4];
#pragma unroll
      for (int i = 0; i < 4; i++)
        af[i] = *(const bf16x8*)(As + hh * 4096 + (wr + i * 16 + c) * 32 + g * 8);
#pragma unroll
      for (int j = 0; j < 4; j++)
        bfr[j] = *(const bf16x8*)(Bs + hh * 4096 + (wc + j * 16 + c) * 32 + g * 8);
#pragma unroll
      for (int i = 0; i < 4; i++)
#pragma unroll
        for (int j = 0; j < 4; j++)
          acc[i][j] = __builtin_amdgcn_mfma_f32_16x16x32_bf16(af[i], bfr[j], acc[i][j], 0, 0, 0);
    }
    __syncthreads();
  }
  float* Cf = (float*)Cv;
  bf16* Cb = (bf16*)Cv;
#pragma unroll
  for (int i = 0; i < 4; i++) {
    const int mb = m0 + wr + i * 16 + g * 4;
#pragma unroll
    for (int j = 0; j < 4; j++) {
      const int n = n0 + wc + j * 16 + c;
      const float bv = BIAS ? bias[n] : 0.f;
#pragma unroll
      for (int r = 0; r < 4; r++) {
        float v = acc[i][j][r] + bv;
        if (ACT == 1) v = gelu_f(v);
        if (ACT == 2) v *= 0.18033688011112042f;  // 0.125*log2(e)
        const size_t idx = (size_t)(mb + r) * N + n;
        if (OUT == 0) {
          float* cp = Cf + idx;
          if (RES) v += *cp;
          *cp = v;
        } else if (OUT == 3) {
          bf16* cp = Cb + idx;
          v += (float)*cp;     // bf16 residual, f32 accumulate
          *cp = (bf16)v;
        } else {
          Cb[idx] = (bf16)v;
        }
      }
    }
  }
}

// ---------------------------------------------------------------------------
// mega_prep: ALL per-layer weight transposes + var_W + proj casts + the two
// f32->bf16 input casts, one launch. (z roles as round 10)
// ---------------------------------------------------------------------------
__global__ __launch_bounds__(256) void mega_prep(
    const float* __restrict__ Wq, const float* __restrict__ Wk,
    const float* __restrict__ Wv, const float* __restrict__ Wo,
    const float* __restrict__ w1, const float* __restrict__ w2,
    const float* __restrict__ var_W, const float* __restrict__ proj,
    const float* __restrict__ in_enc, const float* __restrict__ in_dec,
    bf16* __restrict__ WL, bf16* __restrict__ WtVar,
    bf16* __restrict__ projB4, bf16* __restrict__ encB,
    bf16* __restrict__ decB) {
  const int z = blockIdx.y, bid = blockIdx.x, t = threadIdx.x;
  if (z >= 26) {
    const float* src = (z == 26) ? in_enc : in_dec;
    bf16* dst = (z == 26) ? encB : decB;
    const int n = (z == 26) ? 16384 * 1280 : 8192 * 1280;
    int i = (bid * 256 + t) * 4;
    const int stride = 1024 * 256 * 4;
    for (; i < n; i += stride) {
      float4 v = *(const float4*)(src + i);
      bf16x4 o;
      o[0] = (bf16)v.x; o[1] = (bf16)v.y; o[2] = (bf16)v.z; o[3] = (bf16)v.w;
      *(bf16x4*)(dst + i) = o;
    }
    return;
  }
  if (z == 25) {
    const int idx = bid * 256 + t;
    if (idx < 4 * cMP * cDH) {
      const int layer = idx / (cMP * cDH), r = idx % (cMP * cDH);
      const int m = r >> 6;
      projB4[idx] = (bf16)(m < cM ? proj[(size_t)layer * cM * cDH + r] * 0.35355339059327373f : 0.f);
    }
    return;
  }
  __shared__ float tile[32][33];
  const float* W;
  bf16* dst;
  int K, N;
  if (z == 24) {
    W = var_W; dst = WtVar; K = 1280; N = 512;
  } else {
    const int layer = z / 6, mat = z % 6;
    bf16* base = WL + (size_t)layer * 3145728;
    if (mat < 4) {
      W = (mat == 0 ? Wq : mat == 1 ? Wk : mat == 2 ? Wv : Wo) + (size_t)layer * 262144;
      dst = base + mat * 262144; K = 512; N = 512;
    } else if (mat == 4) {
      W = w1 + (size_t)layer * 1048576; dst = base + 1048576; K = 512; N = 2048;
    } else {
      W = w2 + (size_t)layer * 1048576; dst = base + 2097152; K = 2048; N = 512;
    }
  }
  const int nt = N >> 5;
  if (bid >= nt * (K >> 5)) return;
  const int n0 = (bid % nt) * 32, k0 = (bid / nt) * 32;
  const int tx = t & 31, ty = t >> 5;
#pragma unroll
  for (int i = ty; i < 32; i += 8) tile[i][tx] = W[(size_t)(k0 + i) * N + n0 + tx];
  __syncthreads();
#pragma unroll
  for (int i = ty; i < 32; i += 8)
    dst[(size_t)(n0 + i) * K + k0 + tx] = (bf16)tile[tx][i];
}

// Decoder weights (z roles as round 10).
__global__ __launch_bounds__(256) void mega_prep_dec(
    const float* __restrict__ caWq, const float* __restrict__ caWk,
    const float* __restrict__ caWv, const float* __restrict__ caWo,
    const float* __restrict__ fw1, const float* __restrict__ fw2,
    const float* __restrict__ hW, bf16* __restrict__ WD) {
  const int z = blockIdx.y, bid = blockIdx.x, t = threadIdx.x;
  __shared__ float tile[32][33];
  const float* W;
  bf16* dst;
  int K, N;
  if (z < 4) {
    W = (z == 0 ? caWq : z == 1 ? caWk : z == 2 ? caWv : caWo);
    dst = WD + z * 262144; K = 512; N = 512;
  } else if (z == 4) {
    W = fw1; dst = WD + 1048576; K = 512; N = 2048;
  } else if (z == 5) {
    W = fw2; dst = WD + 2097152; K = 2048; N = 512;
  } else {
    W = hW; dst = WD + 3145728; K = 512; N = 128;
  }
  const int nt = N >> 5;
  if (bid >= nt * (K >> 5)) return;
  const int n0 = (bid % nt) * 32, k0 = (bid / nt) * 32;
  const int tx = t & 31, ty = t >> 5;
#pragma unroll
  for (int i = ty; i < 32; i += 8) tile[i][tx] = W[(size_t)(k0 + i) * N + n0 + tx];
  __syncthreads();
#pragma unroll
  for (int i = ty; i < 32; i += 8)
    dst[(size_t)(n0 + i) * K + k0 + tx] = (bf16)tile[tx][i];
}

// ---------------------------------------------------------------------------
// favor_prep: fused V head-transpose (blocks x<32) + k global max (x>=32).
// ---------------------------------------------------------------------------
__global__ __launch_bounds__(256) void favor_prep(
    const bf16* __restrict__ QKV, const bf16* __restrict__ projB,
    bf16* __restrict__ Vt, float* __restrict__ bmax) {
  const int z = blockIdx.y, b = z >> 3, h = z & 7;
  const int t = threadIdx.x;
  const int ld = 1536;
  if (blockIdx.x < 32) {
    __shared__ bf16 tile[64][65];
    const bf16* Vh = QKV + 1024;
    const int s0 = blockIdx.x * 64;
#pragma unroll
    for (int r = t >> 3; r < 64; r += 32) {
      bf16x8 v = *(const bf16x8*)(Vh + ((size_t)b * cSE + s0 + r) * ld + h * cDH + (t & 7) * 8);
#pragma unroll
      for (int e = 0; e < 8; e++) tile[(t & 7) * 8 + e][r] = v[e];
    }
    __syncthreads();
    bf16* vz = Vt + (size_t)z * 80 * cSE;
#pragma unroll
    for (int d = t >> 3; d < 64; d += 32) {
      bf16x8 o;
#pragma unroll
      for (int e = 0; e < 8; e++) o[e] = tile[d][(t & 7) * 8 + e];
      *(bf16x8*)(vz + (size_t)d * cSE + s0 + (t & 7) * 8) = o;
    }
    const int rr = t >> 4, seg = (t & 15) * 4;
    bf16x4 ov;
    const float val = (rr == 0) ? 1.f : 0.f;
    ov[0] = (bf16)val; ov[1] = (bf16)val; ov[2] = (bf16)val; ov[3] = (bf16)val;
    *(bf16x4*)(vz + (size_t)(64 + rr) * cSE + s0 + seg) = ov;
    return;
  }
  __shared__ float sm[4];
  const bf16* Kh = QKV + 512;
  const int xb = blockIdx.x - 32;
  const int s0 = xb * 128;
  const int l = t & 63, w = t >> 6, g = l >> 4, c = l & 15;
  const int wr = (w >> 1) * 64, wcol = (w & 1) * 144;
  const f32x4 zero4 = {0.f, 0.f, 0.f, 0.f};
  f32x4 acc[4][9];
#pragma unroll
  for (int i = 0; i < 4; i++)
#pragma unroll
    for (int j = 0; j < 9; j++) acc[i][j] = zero4;
  const size_t abase = ((size_t)b * cSE + s0) * ld + h * cDH;
#pragma unroll
  for (int k0 = 0; k0 < 64; k0 += 32) {
    bf16x8 af[4];
#pragma unroll
    for (int i = 0; i < 4; i++)
      af[i] = *(const bf16x8*)(Kh + abase + (size_t)(wr + i * 16 + c) * ld + k0 + g * 8);
#pragma unroll
    for (int j = 0; j < 9; j++) {
      bf16x8 bfr = *(const bf16x8*)(projB + (wcol + j * 16 + c) * 64 + k0 + g * 8);
#pragma unroll
      for (int i = 0; i < 4; i++)
        acc[i][j] = __builtin_amdgcn_mfma_f32_16x16x32_bf16(af[i], bfr, acc[i][j], 0, 0, 0);
    }
  }
  float m = -3e38f;
#pragma unroll
  for (int i = 0; i < 4; i++)
#pragma unroll
    for (int j = 0; j < 9; j++) {
      const int mc = wcol + j * 16 + c;
      if (mc < cM) {
#pragma unroll
        for (int r = 0; r < 4; r++) m = fmaxf(m, acc[i][j][r]);
      }
    }
  m = wave_max(m);
  if (l == 0) sm[w] = m;
  __syncthreads();
  if (t == 0)
    bmax[z * 16 + xb] = fmaxf(fmaxf(sm[0], sm[1]), fmaxf(sm[2], sm[3]));
}

// ---------------------------------------------------------------------------
// FUSED phi(k) + kv accumulate (as round 10).
// ---------------------------------------------------------------------------
__global__ __launch_bounds__(256, 1) void favor_kkv(
    const bf16* __restrict__ Kh, int ld, const bf16* __restrict__ projB,
    const bf16* __restrict__ Vt, const float* __restrict__ bmax,
    float* __restrict__ part) {
  __shared__ bf16 kp[288 * 72];
  __shared__ float sm[4];
  const int z = blockIdx.y, b = z >> 3, h = z & 7;
  const int chunk = blockIdx.x;
  const int t = threadIdx.x, l = t & 63, w = t >> 6, g = l >> 4, c = l & 15;
  float gm;
  {
    float m = -1e30f;
    for (int i = t; i < 1024; i += 256) m = fmaxf(m, bmax[i]);
    m = wave_max(m);
    if (l == 0) sm[w] = m;
    __syncthreads();
    gm = fmaxf(fmaxf(sm[0], sm[1]), fmaxf(sm[2], sm[3]));
  }
  const int pr = (w >> 1) * 32;
  const int wcol = (w & 1) * 144;
  const int wm = (w & 1) * 144, wd = (w >> 1) * 32;
  const bool dden = (wd == 32);
  const float ratio = 0.061313927f;  // 266^-0.5
  const f32x4 zero4 = {0.f, 0.f, 0.f, 0.f};
  f32x4 kacc[9][2], kaccx[9];
#pragma unroll
  for (int j = 0; j < 9; j++) {
    kacc[j][0] = zero4; kacc[j][1] = zero4; kaccx[j] = zero4;
  }
  const size_t kbase = (size_t)b * cSE * ld + h * cDH;
  const size_t vtz = (size_t)z * 80 * cSE;

  for (int st = 0; st < 256; st += 64) {
    const int sg = chunk * 256 + st;
    f32x4 pacc[2][9];
#pragma unroll
    for (int i = 0; i < 2; i++)
#pragma unroll
      for (int j = 0; j < 9; j++) pacc[i][j] = zero4;
    float sq[2] = {0.f, 0.f};
#pragma unroll
    for (int k0 = 0; k0 < 64; k0 += 32) {
      bf16x8 af[2];
#pragma unroll
      for (int i = 0; i < 2; i++) {
        af[i] = *(const bf16x8*)(Kh + kbase + (size_t)(sg + pr + i * 16 + c) * ld + k0 + g * 8);
#pragma unroll
        for (int e = 0; e < 8; e++) {
          const float v = (float)af[i][e];
          sq[i] += v * v;
        }
      }
#pragma unroll
      for (int j = 0; j < 9; j++) {
        bf16x8 bfr = *(const bf16x8*)(projB + (wcol + j * 16 + c) * 64 + k0 + g * 8);
        pacc[0][j] = __builtin_amdgcn_mfma_f32_16x16x32_bf16(af[0], bfr, pacc[0][j], 0, 0, 0);
        pacc[1][j] = __builtin_amdgcn_mfma_f32_16x16x32_bf16(af[1], bfr, pacc[1][j], 0, 0, 0);
      }
    }
#pragma unroll
    for (int i = 0; i < 2; i++) {
      sq[i] += __shfl_xor(sq[i], 16);
      sq[i] += __shfl_xor(sq[i], 32);
    }
    float rowsub[2][4];
#pragma unroll
    for (int i = 0; i < 2; i++)
#pragma unroll
      for (int r = 0; r < 4; r++)
        rowsub[i][r] = gm + 0.0625f * __shfl(sq[i], g * 4 + r);
    __syncthreads();
#pragma unroll
    for (int i = 0; i < 2; i++)
#pragma unroll
      for (int j = 0; j < 9; j++) {
        const int mc = wcol + j * 16 + c;
        bf16x4 o;
#pragma unroll
        for (int r = 0; r < 4; r++) {
          const float v = (mc < cM)
              ? ratio * (__expf(pacc[i][j][r] - rowsub[i][r]) + 1e-4f) : 0.f;
          o[r] = (bf16)v;
        }
        *(bf16x4*)(kp + (size_t)mc * 72 + pr + i * 16 + g * 4) = o;
      }
    __syncthreads();
#pragma unroll
    for (int k0 = 0; k0 < 64; k0 += 32) {
      bf16x8 bv0 = *(const bf16x8*)(Vt + vtz + (size_t)(wd + c) * cSE + sg + k0 + g * 8);
      bf16x8 bv1 = *(const bf16x8*)(Vt + vtz + (size_t)(wd + 16 + c) * cSE + sg + k0 + g * 8);
      bf16x8 bvx;
      if (dden)
        bvx = *(const bf16x8*)(Vt + vtz + (size_t)(64 + c) * cSE + sg + k0 + g * 8);
#pragma unroll
      for (int j = 0; j < 9; j++) {
        bf16x8 am = *(const bf16x8*)(kp + (size_t)(wm + j * 16 + c) * 72 + k0 + g * 8);
        kacc[j][0] = __builtin_amdgcn_mfma_f32_16x16x32_bf16(am, bv0, kacc[j][0], 0, 0, 0);
        kacc[j][1] = __builtin_amdgcn_mfma_f32_16x16x32_bf16(am, bv1, kacc[j][1], 0, 0, 0);
        if (dden)
          kaccx[j] = __builtin_amdgcn_mfma_f32_16x16x32_bf16(am, bvx, kaccx[j], 0, 0, 0);
      }
    }
  }
  float* po = part + ((size_t)z * 8 + chunk) * (cMP * 80);
#pragma unroll
  for (int j = 0; j < 9; j++)
#pragma unroll
    for (int i = 0; i < 2; i++)
#pragma unroll
      for (int r = 0; r < 4; r++)
        po[(size_t)(wm + j * 16 + g * 4 + r) * 80 + wd + i * 16 + c] = kacc[j][i][r];
  if (dden) {
#pragma unroll
    for (int j = 0; j < 9; j++)
#pragma unroll
      for (int r = 0; r < 4; r++)
        po[(size_t)(wm + j * 16 + g * 4 + r) * 80 + 64 + c] = kaccx[j][r];
  }
}

// reduce 8 chunks + transpose: kvT[z,d(80),m]; row 64 = ksum. grid (4,64).
__global__ __launch_bounds__(256) void kv_reduce(
    const float* __restrict__ part, bf16* __restrict__ kvT) {
  const int z = blockIdx.y, q = blockIdx.x;
  const float* p = part + (size_t)z * 8 * (cMP * 80);
  bf16* o = kvT + (size_t)z * 80 * cMP;
  const int lo = q * 5760, hi = lo + 5760;  // cMP*80/4
  for (int idx = lo + threadIdx.x; idx < hi; idx += 256) {
    const int m = idx / 80, d = idx - m * 80;
    float s = 0.f;
#pragma unroll
    for (int cc = 0; cc < 8; cc++) s += p[idx + (size_t)cc * (cMP * 80)];
    o[(size_t)d * cMP + m] = (bf16)s;
  }
}

// ---------------------------------------------------------------------------
// Fused phi(q) + output (as round 10).
// ---------------------------------------------------------------------------
__global__ __launch_bounds__(256, 1) void favor_qout(
    const bf16* __restrict__ Qh, int ld, const bf16* __restrict__ projB,
    const bf16* __restrict__ kvT, bf16* __restrict__ Y) {
  __shared__ bf16 Plds[128 * 296];
  __shared__ float rmaxs[4][64];
  __shared__ float denl[128];
  const int z = blockIdx.y, b = z >> 3, h = z & 7;
  const int s0 = blockIdx.x * 128;
  const int t = threadIdx.x, l = t & 63, w = t >> 6, g = l >> 4, c = l & 15;
  const int wr = (w >> 1) * 64, wcol = (w & 1) * 144;
  const f32x4 zero4 = {0.f, 0.f, 0.f, 0.f};
  f32x4 acc[4][9];
#pragma unroll
  for (int i = 0; i < 4; i++)
#pragma unroll
    for (int j = 0; j < 9; j++) acc[i][j] = zero4;
  float sq[4] = {0.f, 0.f, 0.f, 0.f};
  const size_t abase = ((size_t)b * cSE + s0) * ld + h * cDH;
#pragma unroll
  for (int k0 = 0; k0 < 64; k0 += 32) {
    bf16x8 af[4];
#pragma unroll
    for (int i = 0; i < 4; i++) {
      af[i] = *(const bf16x8*)(Qh + abase + (size_t)(wr + i * 16 + c) * ld + k0 + g * 8);
#pragma unroll
      for (int e = 0; e < 8; e++) {
        const float v = (float)af[i][e];
        sq[i] += v * v;
      }
    }
#pragma unroll
    for (int j = 0; j < 9; j++) {
      bf16x8 bfr = *(const bf16x8*)(projB + (wcol + j * 16 + c) * 64 + k0 + g * 8);
#pragma unroll
      for (int i = 0; i < 4; i++)
        acc[i][j] = __builtin_amdgcn_mfma_f32_16x16x32_bf16(af[i], bfr, acc[i][j], 0, 0, 0);
    }
  }
#pragma unroll
  for (int i = 0; i < 4; i++) {
    sq[i] += __shfl_xor(sq[i], 16);
    sq[i] += __shfl_xor(sq[i], 32);
  }
  const float ratio = 0.061313927f;  // 266^-0.5
  float rowsub[4][4];
#pragma unroll
  for (int i = 0; i < 4; i++)
#pragma unroll
    for (int r = 0; r < 4; r++) {
      float m = -3e38f;
#pragma unroll
      for (int j = 0; j < 9; j++) {
        const int mc = wcol + j * 16 + c;
        m = (mc < cM) ? fmaxf(m, acc[i][j][r]) : m;
      }
      m = fmaxf(m, __shfl_xor(m, 1));
      m = fmaxf(m, __shfl_xor(m, 2));
      m = fmaxf(m, __shfl_xor(m, 4));
      m = fmaxf(m, __shfl_xor(m, 8));
      rowsub[i][r] = m;
    }
  if (c == 0) {
#pragma unroll
    for (int i = 0; i < 4; i++)
#pragma unroll
      for (int r = 0; r < 4; r++) rmaxs[w][i * 16 + g * 4 + r] = rowsub[i][r];
  }
  __syncthreads();
#pragma unroll
  for (int i = 0; i < 4; i++)
#pragma unroll
    for (int r = 0; r < 4; r++) {
      const int row = i * 16 + g * 4 + r;
      rowsub[i][r] = fmaxf(rowsub[i][r], rmaxs[w ^ 1][row]) +
                     0.0625f * __shfl(sq[i], g * 4 + r);
    }
#pragma unroll
  for (int i = 0; i < 4; i++)
#pragma unroll
    for (int j = 0; j < 9; j++) {
      const int mc = wcol + j * 16 + c;
#pragma unroll
      for (int r = 0; r < 4; r++) {
        const float v = (mc < cM)
            ? ratio * (__expf(acc[i][j][r] - rowsub[i][r]) + 1e-4f) : 0.f;
        Plds[(wr + i * 16 + g * 4 + r) * 296 + mc] = (bf16)v;
      }
    }
  __syncthreads();

  const int wd = (w & 1) * 32;
  const bool dden = (wd == 32);
  f32x4 acc2[4][2], accx[4];
#pragma unroll
  for (int i = 0; i < 4; i++) {
    acc2[i][0] = zero4; acc2[i][1] = zero4; accx[i] = zero4;
  }
  const size_t kz = (size_t)z * 80 * cMP;
#pragma unroll 3
  for (int k0 = 0; k0 < cMP; k0 += 32) {
    bf16x8 bv[2], bvx;
#pragma unroll
    for (int j = 0; j < 2; j++)
      bv[j] = *(const bf16x8*)(kvT + kz + (size_t)(wd + j * 16 + c) * cMP + k0 + g * 8);
    if (dden)
      bvx = *(const bf16x8*)(kvT + kz + (size_t)(64 + c) * cMP + k0 + g * 8);
#pragma unroll
    for (int i = 0; i < 4; i++) {
      bf16x8 av = *(const bf16x8*)(Plds + (wr + i * 16 + c) * 296 + k0 + g * 8);
      acc2[i][0] = __builtin_amdgcn_mfma_f32_16x16x32_bf16(av, bv[0], acc2[i][0], 0, 0, 0);
      acc2[i][1] = __builtin_amdgcn_mfma_f32_16x16x32_bf16(av, bv[1], acc2[i][1], 0, 0, 0);
      if (dden)
        accx[i] = __builtin_amdgcn_mfma_f32_16x16x32_bf16(av, bvx, accx[i], 0, 0, 0);
    }
  }
  if (dden && c == 0) {
#pragma unroll
    for (int i = 0; i < 4; i++)
#pragma unroll
      for (int r = 0; r < 4; r++)
        denl[wr + i * 16 + g * 4 + r] = accx[i][r];
  }
  __syncthreads();
#pragma unroll
  for (int i = 0; i < 4; i++)
#pragma unroll
    for (int r = 0; r < 4; r++) {
      const int row = wr + i * 16 + g * 4 + r;
      const float inv = 1.0f / denl[row];
#pragma unroll
      for (int j = 0; j < 2; j++)
        Y[((size_t)b * cSE + s0 + row) * cD + h * cDH + wd + j * 16 + c] =
            (bf16)(acc2[i][j][r] * inv);
    }
}

// ---------------------------------------------------------------------------
// LayerNorm rows of 512, bf16 in / bf16 out (f32 stats). ADD: bf16 residual.
// ---------------------------------------------------------------------------
template <bool ADD>
__global__ __launch_bounds__(256) void ln_rows_b(
    const bf16* __restrict__ in, const bf16* __restrict__ add,
    const float* __restrict__ g, const float* __restrict__ be,
    bf16* __restrict__ out) {
  const int wid = blockIdx.x * 4 + (threadIdx.x >> 6);
  const int lane = threadIdx.x & 63;
  bf16x8 iv = *(const bf16x8*)(in + (size_t)wid * cD + lane * 8);
  float x[8];
#pragma unroll
  for (int i = 0; i < 8; i++) x[i] = (float)iv[i];
  if (ADD) {
    bf16x8 av = *(const bf16x8*)(add + (size_t)wid * cD + lane * 8);
#pragma unroll
    for (int i = 0; i < 8; i++) x[i] += (float)av[i];
  }
  float s = 0;
#pragma unroll
  for (int i = 0; i < 8; i++) s += x[i];
  s = wave_sum(s);
  const float mu = s * (1.0f / cD);
  float vs = 0;
#pragma unroll
  for (int i = 0; i < 8; i++) { const float d = x[i] - mu; vs += d * d; }
  vs = wave_sum(vs);
  const float rstd = 1.0f / sqrtf(vs * (1.0f / cD) + 1e-5f);
  bf16x8 ov;
#pragma unroll
  for (int i = 0; i < 8; i++) {
    const int d = lane * 8 + i;
    ov[i] = (bf16)((x[i] - mu) * rstd * g[d] + be[d]);
  }
  *(bf16x8*)(out + (size_t)wid * cD + lane * 8) = ov;
}

// LN of (enc + sinusoidal(expr)), in-place on bf16 X.
__global__ __launch_bounds__(256) void embed_ln_b(
    bf16* __restrict__ X, const int* __restrict__ ids,
    const float* __restrict__ g, const float* __restrict__ be) {
  const int wid = blockIdx.x * 4 + (threadIdx.x >> 6);
  const int lane = threadIdx.x & 63;
  const float idv = (float)ids[wid];
  bf16* xp = X + (size_t)wid * cD + lane * 8;
  bf16x8 iv = *(const bf16x8*)xp;
  float x[8];
#pragma unroll
  for (int i = 0; i < 8; i++) x[i] = (float)iv[i];
  const float kf = -0.03597789207803197f;  // -ln(10000)/256
#pragma unroll
  for (int i = 0; i < 8; i++) {
    const int d = lane * 8 + i;
    float e;
    if (d < 256) e = sinf(idv * expf(kf * (float)d));
    else         e = cosf(idv * expf(kf * (float)(d - 256)));
    x[i] += e;
  }
  float s = 0;
#pragma unroll
  for (int i = 0; i < 8; i++) s += x[i];
  s = wave_sum(s);
  const float mu = s * (1.0f / cD);
  float vs = 0;
#pragma unroll
  for (int i = 0; i < 8; i++) { const float d = x[i] - mu; vs += d * d; }
  vs = wave_sum(vs);
  const float rstd = 1.0f / sqrtf(vs * (1.0f / cD) + 1e-5f);
  bf16x8 ov;
#pragma unroll
  for (int i = 0; i < 8; i++) {
    const int d = lane * 8 + i;
    ov[i] = (bf16)((x[i] - mu) * rstd * g[d] + be[d]);
  }
  *(bf16x8*)xp = ov;
}

// ---------------------------------------------------------------------------
// bf16 MFMA flash cross-attention (round 10 + setprio around MFMA clusters).
// ---------------------------------------------------------------------------
__global__ __launch_bounds__(256) void flash_mfma(
    const bf16* __restrict__ Q, const bf16* __restrict__ Kc,
    const bf16* __restrict__ Vc, bf16* __restrict__ O, int ldkv) {
  __shared__ __align__(16) bf16 KP[4 * 16 * 136];  // K (16KB) ∪ P (17.4KB)
  __shared__ __align__(16) bf16 Vs[80 * 136];      // [d][s] padded; row 64 = ones
  const int id = blockIdx.x;
  const int b = (id & 63) >> 3, h = id & 7, qb = id >> 6;
  const int t = threadIdx.x, l = t & 63, w = t >> 6, g = l >> 4, c = l & 15;
  const int q0 = qb * 64 + w * 16;
  bf16x8 aq[2];
  {
    const bf16* qp = Q + ((size_t)b * cSD + q0 + c) * cD + h * cDH + g * 8;
    aq[0] = *(const bf16x8*)qp;
    aq[1] = *(const bf16x8*)(qp + 32);
  }
  for (int idx = t; idx < 16 * 136; idx += 256) {
    const int rr = idx / 136, cc = idx - rr * 136;
    Vs[(64 + rr) * 136 + cc] = (bf16)(rr == 0 ? 1.f : 0.f);
  }
  const f32x4 zero4 = {0.f, 0.f, 0.f, 0.f};
  f32x4 o5[5];
#pragma unroll
  for (int j = 0; j < 5; j++) o5[j] = zero4;
  float mrow[4];
#pragma unroll
  for (int r = 0; r < 4; r++) mrow[r] = -1e30f;

  const int kr = t >> 1, kof = (t & 1) * 32;
  const int sidx = t & 31, dseg = t >> 5;
  const size_t kvbase = (size_t)b * cSE * ldkv + h * cDH;
  char* KsC = (char*)KP;
  bf16* Pw = KP + w * 16 * 136;
  const float T2 = 11.541560327111708f;   // 8 * log2(e)

  bf16x8 pk[4], pv[4];
  auto LOADR = [&](int kt) {
    const bf16* kp = Kc + kvbase + (size_t)(kt + kr) * ldkv + kof;
#pragma unroll
    for (int i = 0; i < 4; i++) pk[i] = *(const bf16x8*)(kp + i * 8);
    const bf16* vp = Vc + kvbase + (size_t)(kt + 4 * sidx) * ldkv + dseg * 8;
#pragma unroll
    for (int i = 0; i < 4; i++) pv[i] = *(const bf16x8*)(vp + (size_t)i * ldkv);
  };
  auto WRITEL = [&]() {
    const int sw = (kr & 7) << 4;
#pragma unroll
    for (int i = 0; i < 4; i++)
      *(bf16x8*)(KsC + kr * 128 + (((kof + i * 8) * 2) ^ sw)) = pk[i];
#pragma unroll
    for (int e = 0; e < 8; e++) {
      bf16x4 q4;
      q4[0] = pv[0][e]; q4[1] = pv[1][e]; q4[2] = pv[2][e]; q4[3] = pv[3][e];
      *(bf16x4*)(Vs + (dseg * 8 + e) * 136 + 4 * sidx) = q4;
    }
  };
  LOADR(0);
  WRITEL();

  for (int kt = 0; kt < cSE; kt += 128) {
    const bool more = (kt + 128 < cSE);
    if (more) LOADR(kt + 128);
    __syncthreads();              // A: staged tile visible
    f32x4 s4[8];
    __builtin_amdgcn_s_setprio(1);
#pragma unroll
    for (int t2 = 0; t2 < 8; t2++) {
      const int kr2 = t2 * 16 + c;
      const int sw2 = (kr2 & 7) << 4;
      bf16x8 bk0 = *(const bf16x8*)(KsC + kr2 * 128 + ((g * 16) ^ sw2));
      bf16x8 bk1 = *(const bf16x8*)(KsC + kr2 * 128 + ((64 + g * 16) ^ sw2));
      f32x4 z = zero4;
      z = __builtin_amdgcn_mfma_f32_16x16x32_bf16(aq[0], bk0, z, 0, 0, 0);
      z = __builtin_amdgcn_mfma_f32_16x16x32_bf16(aq[1], bk1, z, 0, 0, 0);
      s4[t2] = z;
    }
    __builtin_amdgcn_s_setprio(0);
    __syncthreads();              // B: all K reads done; P may overwrite
#pragma unroll
    for (int r = 0; r < 4; r++) {
      float xv[8];
#pragma unroll
      for (int t2 = 0; t2 < 8; t2++) xv[t2] = s4[t2][r];
      float tm = xv[0];
#pragma unroll
      for (int t2 = 1; t2 < 8; t2++) tm = fmaxf(tm, xv[t2]);
      tm = fmaxf(tm, __shfl_xor(tm, 1));
      tm = fmaxf(tm, __shfl_xor(tm, 2));
      tm = fmaxf(tm, __shfl_xor(tm, 4));
      tm = fmaxf(tm, __shfl_xor(tm, 8));
      if (tm > mrow[r] + T2) {
        const float corr = exp2f(mrow[r] - tm);
        mrow[r] = tm;
#pragma unroll
        for (int j = 0; j < 5; j++) o5[j][r] *= corr;
      }
      const float m = mrow[r];
      const int qr = g * 4 + r;
#pragma unroll
      for (int t2 = 0; t2 < 8; t2++)
        Pw[qr * 136 + t2 * 16 + c] = (bf16)exp2f(xv[t2] - m);
    }
    bf16x8 pa[4];
#pragma unroll
    for (int ks = 0; ks < 4; ks++)
      pa[ks] = *(const bf16x8*)(Pw + c * 136 + ks * 32 + g * 8);
    __builtin_amdgcn_s_setprio(1);
#pragma unroll
    for (int j = 0; j < 5; j++) {
#pragma unroll
      for (int ks = 0; ks < 4; ks++) {
        bf16x8 bv = *(const bf16x8*)(Vs + (j * 16 + c) * 136 + ks * 32 + g * 8);
        o5[j] = __builtin_amdgcn_mfma_f32_16x16x32_bf16(pa[ks], bv, o5[j], 0, 0, 0);
      }
    }
    __builtin_amdgcn_s_setprio(0);
    __syncthreads();              // C: P/Vs reads done; next stage may write
    if (more) WRITEL();
  }
#pragma unroll
  for (int r = 0; r < 4; r++) {
    const float den = __shfl(o5[4][r], l & 48);
    const float inv = 1.0f / den;
    const size_t row = (size_t)b * cSD + q0 + g * 4 + r;
#pragma unroll
    for (int j = 0; j < 4; j++)
      O[row * cD + h * cDH + j * 16 + c] = (bf16)(o5[j][r] * inv);
  }
}

// ---------------------------------------------------------------------------
extern "C" void kernel_launch(void* const* d_in, const int* in_sizes, int n_in,
                              void* d_out, int out_size, void* d_ws, size_t ws_size,
                              hipStream_t stream) {
  const float* in_enc = (const float*)d_in[0];
  const float* in_dec = (const float*)d_in[1];
  const int* expr = (const int*)d_in[2];
  const float* var_W = (const float*)d_in[3];
  const float* var_b = (const float*)d_in[4];
  const float* enc_g = (const float*)d_in[5];
  const float* enc_b = (const float*)d_in[6];
  const float* dec_g = (const float*)d_in[7];
  const float* dec_b = (const float*)d_in[8];
  const float* ln1_g = (const float*)d_in[9];
  const float* ln1_b = (const float*)d_in[10];
  const float* Wq = (const float*)d_in[11];
  const float* Wk = (const float*)d_in[12];
  const float* Wv = (const float*)d_in[13];
  const float* Wo = (const float*)d_in[14];
  const float* bo = (const float*)d_in[15];
  const float* ln2_g = (const float*)d_in[16];
  const float* ln2_b = (const float*)d_in[17];
  const float* w1 = (const float*)d_in[18];
  const float* b1 = (const float*)d_in[19];
  const float* w2 = (const float*)d_in[20];
  const float* b2 = (const float*)d_in[21];
  const float* proj = (const float*)d_in[22];
  const float* caWq = (const float*)d_in[23];
  const float* caWk = (const float*)d_in[24];
  const float* caWv = (const float*)d_in[25];
  const float* caWo = (const float*)d_in[26];
  const float* cabo = (const float*)d_in[27];
  const float* crg = (const float*)d_in[28];
  const float* crb = (const float*)d_in[29];
  const float* fw1 = (const float*)d_in[30];
  const float* fb1 = (const float*)d_in[31];
  const float* fw2 = (const float*)d_in[32];
  const float* fb2 = (const float*)d_in[33];
  const float* og = (const float*)d_in[34];
  const float* ob = (const float*)d_in[35];
  const float* hW = (const float*)d_in[36];
  const float* hb = (const float*)d_in[37];

  // ---- workspace layout (f32 units; offsets preserved from round 10) -----
  float* base  = (float*)d_ws;
  bf16*  Xr    = (bf16*)base;              // [16384,512] bf16 residual stream
  bf16*  Dt1   = Xr + 8388608;             // [8192,512] bf16 decoder temp
  bf16*  Dt2   = Dt1 + 4194304;            // [8192,512] bf16 decoder temp
  bf16*  QKV   = (bf16*)(base + 12582912); // [16384,1536] bf16 fused
  bf16*  Vt    = QKV + 25165824;           // [64,80,2048] bf16
  bf16*  Pb    = Vt + 10485760;            // arena 50331648 bf16
  float* part  = (float*)(Pb + 50331648);  // [64,8,288,80] f32
  bf16*  kvT   = (bf16*)(part + 11796480); // [64,80,288] bf16
  float* bmax  = (float*)(kvT + 1474560);  // [1024+16]
  bf16*  Yb    = (bf16*)(bmax + 1040);     // [16384,512] bf16
  bf16*  DCb   = Yb + 8388608;             // [8192,512] bf16 (LN'd dec)
  bf16*  Wt    = DCb + 4194304;            // [1048576] bf16 arena (var_W^T)
  bf16*  projB4 = Wt + 1048576;            // [4,288,64] bf16
  const size_t need_bytes = (size_t)75458576 * 4;
  if (ws_size < need_bytes) return;

  // Overlays
  bf16* encB = Pb;                   // [16384,1280] (phase 0)
  bf16* decB = (bf16*)part;          // [8192,1280]  (phase 0)
  bf16* Pmid = Pb;                   // [16384,2048] (FF mid, layer loop)
  bf16* WL   = Pb + 33554432;        // [4,3145728] bf16 layer weights
  bf16* Qc   = Pb + 8388608;         // [8192,512]
  bf16* KVc  = Pb + 12582912;        // [16384,1024]
  bf16* Fb   = Pb + 29360128;        // [8192,512]
  bf16* Pm2  = Pb + 33554432;        // [8192,2048] (decoder FF mid; WL dead)
  bf16* WD   = (bf16*)part;          // decoder weights arena (part dead)

  const dim3 blk(256);

  // ---- phase 0: input casts + ALL layer weight prep (one launch) ---------
  mega_prep<<<dim3(1024, 28), blk, 0, stream>>>(Wq, Wk, Wv, Wo, w1, w2, var_W, proj,
                                                in_enc, in_dec, WL, Wt, projB4,
                                                encB, decB);
  gemm_mfma<1, 0, true, false><<<dim3(4, 128), blk, 0, stream>>>(encB, Wt, Xr, nullptr, var_b, 16384, 512, 1280);
  gemm_mfma<1, 0, true, false><<<dim3(4, 64), blk, 0, stream>>>(decB, Wt, Dt1, nullptr, var_b, 8192, 512, 1280);
  embed_ln_b<<<4096, blk, 0, stream>>>(Xr, expr, enc_g, enc_b);
  ln_rows_b<false><<<2048, blk, 0, stream>>>(Dt1, nullptr, dec_g, dec_b, DCb);

  // ---- encoder layers ----------------------------------------------------
  for (int i = 0; i < cDEPTH; i++) {
    bf16* Wl = WL + (size_t)i * 3145728;
    bf16* projB = projB4 + (size_t)i * (cMP * cDH);
    ln_rows_b<false><<<4096, blk, 0, stream>>>(Xr, nullptr, ln1_g + i * cD, ln1_b + i * cD, Yb);
    // fused QKV GEMM: N=1536, B = [WqT;WkT;WvT]
    gemm_mfma<1, 0, false, false><<<dim3(12, 128), blk, 0, stream>>>(Yb, Wl, QKV, nullptr, nullptr, 16384, 1536, 512);
    // FAVOR+ (Q at +0, K at +512, V at +1024, stride 1536)
    favor_prep<<<dim3(48, 64), blk, 0, stream>>>(QKV, projB, Vt, bmax);
    favor_kkv<<<dim3(8, 64), blk, 0, stream>>>(QKV + 512, 1536, projB, Vt, bmax, part);
    kv_reduce<<<dim3(4, 64), blk, 0, stream>>>(part, kvT);
    favor_qout<<<dim3(16, 64), blk, 0, stream>>>(QKV, 1536, projB, kvT, Yb);
    // Wo + bf16 residual RMW into Xr
    gemm_mfma<3, 0, true, false><<<dim3(4, 128), blk, 0, stream>>>(Yb, Wl + 786432, Xr, nullptr, bo + i * cD, 16384, 512, 512);
    // FF
    ln_rows_b<false><<<4096, blk, 0, stream>>>(Xr, nullptr, ln2_g + i * cD, ln2_b + i * cD, Yb);
    gemm_mfma<1, 1, true, false><<<dim3(16, 128), blk, 0, stream>>>(Yb, Wl + 1048576, Pmid, nullptr, b1 + i * cFF, 16384, 2048, 512);
    gemm_mfma<3, 0, true, false><<<dim3(4, 128), blk, 0, stream>>>(Pmid, Wl + 2097152, Xr, nullptr, b2 + i * cD, 16384, 512, 2048);
  }

  // ---- decoder / cross-attention ----------------------------------------
  mega_prep_dec<<<dim3(1024, 7), blk, 0, stream>>>(caWq, caWk, caWv, caWo, fw1, fw2, hW, WD);
  // Q projection with flash prescale folded in (ACT=2)
  gemm_mfma<1, 2, false, false><<<dim3(4, 64), blk, 0, stream>>>(DCb, WD, Qc, nullptr, nullptr, 8192, 512, 512);
  // fused K+V GEMM reads Xr directly: N=1024, B = [WkT;WvT]
  gemm_mfma<1, 0, false, false><<<dim3(8, 128), blk, 0, stream>>>(Xr, WD + 262144, KVc, nullptr, nullptr, 16384, 1024, 512);
  flash_mfma<<<dim3(1024), blk, 0, stream>>>(Qc, KVc, KVc + 512, Fb, 1024);
  gemm_mfma<1, 0, true, false><<<dim3(4, 64), blk, 0, stream>>>(Fb, WD + 786432, Dt1, nullptr, cabo, 8192, 512, 512);
  ln_rows_b<true><<<2048, blk, 0, stream>>>(Dt1, DCb, crg, crb, Yb);
  gemm_mfma<1, 1, true, false><<<dim3(16, 64), blk, 0, stream>>>(Yb, WD + 1048576, Pm2, nullptr, fb1, 8192, 2048, 512);
  gemm_mfma<1, 0, true, false><<<dim3(4, 64), blk, 0, stream>>>(Pm2, WD + 2097152, Dt2, nullptr, fb2, 8192, 512, 2048);
  ln_rows_b<false><<<2048, blk, 0, stream>>>(Dt2, nullptr, og, ob, Yb);
  gemm_mfma<0, 0, true, false><<<dim3(1, 64), blk, 0, stream>>>(Yb, WD + 3145728, (float*)d_out, nullptr, hb, 8192, 128, 512);
}